// Round 1
// baseline (668.925 us; speedup 1.0000x reference)
//
#include <hip/hip_runtime.h>
#include <hip/hip_bf16.h>

#define CD 96
#define LROW 3136          // 56*56
#define QSCALE 0.17677669529663687f  // 1/sqrt(32)

__device__ __forceinline__ float bflo(unsigned u) { return __uint_as_float(u << 16); }
__device__ __forceinline__ float bfhi(unsigned u) { return __uint_as_float(u & 0xffff0000u); }

// ---------------- LayerNorm (one wave per 96-col row) ----------------
__global__ __launch_bounds__(256) void ln_kernel(const float* __restrict__ x,
                                                 const float* __restrict__ g,
                                                 const float* __restrict__ b,
                                                 float* __restrict__ out, int rows) {
  int wid = threadIdx.x >> 6, lane = threadIdx.x & 63;
  int row = (blockIdx.x << 2) + wid;
  if (row >= rows) return;
  const float* xr = x + (size_t)row * CD;
  float v0 = xr[lane];
  float v1 = (lane < 32) ? xr[64 + lane] : 0.f;
  float s = v0 + v1;
#pragma unroll
  for (int off = 32; off >= 1; off >>= 1) s += __shfl_xor(s, off);
  float mu = s * (1.f / 96.f);
  float d0 = v0 - mu;
  float d1 = (lane < 32) ? v1 - mu : 0.f;
  float q = d0 * d0 + d1 * d1;
#pragma unroll
  for (int off = 32; off >= 1; off >>= 1) q += __shfl_xor(q, off);
  float rstd = rsqrtf(q * (1.f / 96.f) + 1e-6f);
  float* orow = out + (size_t)row * CD;
  orow[lane] = d0 * rstd * g[lane] + b[lane];
  if (lane < 32) orow[64 + lane] = d1 * rstd * g[64 + lane] + b[64 + lane];
}

// ---------------- fused shifted-window attention: one block per window ----------------
__global__ __launch_bounds__(256) void win_attn_kernel(
    const float* __restrict__ hsrc, const float* __restrict__ xin,
    const float* __restrict__ qkv_w, const float* __restrict__ qkv_b,
    const float* __restrict__ proj_w, const float* __restrict__ proj_b,
    float* __restrict__ x1) {
  __shared__ __align__(16) __hip_bfloat16 xw[49][96];
  __shared__ __align__(16) float qh[49][36];
  __shared__ __align__(16) float kh[49][36];
  __shared__ __align__(16) float vh[49][36];
  __shared__ __align__(16) float S[49][49];
  __shared__ __align__(16) float outw[49][100];
  __shared__ int cnt[49];
  __shared__ int gidx[49];

  int tid = threadIdx.x;
  int b = blockIdx.x >> 6, w64 = blockIdx.x & 63;
  int wr = w64 >> 3, wc = w64 & 7;

  if (tid < 49) {
    int i = tid / 7, j = tid % 7;
    int sh = wr * 7 + i, sw = wc * 7 + j;             // coords in shifted/mask image
    int hr = (sh < 49) ? 0 : ((sh < 53) ? 1 : 2);     // region thresholds: 56-7, 56-3
    int wreg = (sw < 49) ? 0 : ((sw < 53) ? 1 : 2);
    cnt[tid] = hr * 3 + wreg;
    gidx[tid] = ((sh + 3) % 56) * 56 + ((sw + 3) % 56);  // roll(-3) load == roll(+3) store
  }
  __syncthreads();

  for (int idx = tid; idx < 49 * 96; idx += 256) {
    int p = idx / 96, c = idx % 96;
    xw[p][c] = __float2bfloat16(hsrc[((size_t)b * LROW + gidx[p]) * CD + c]);
  }
  __syncthreads();

  int dd = tid & 31, pg = tid >> 5;  // 32 dims x 8 row-groups

  for (int hh = 0; hh < 3; ++hh) {
    // ---- qkv for this head: thread owns col dd, rows pg+8i (weights reused across rows) ----
    {
      float aq[7], ak[7], av[7];
#pragma unroll
      for (int i = 0; i < 7; ++i) { aq[i] = 0.f; ak[i] = 0.f; av[i] = 0.f; }
      for (int k0 = 0; k0 < 96; k0 += 8) {
        float xf[7][8];
#pragma unroll
        for (int i = 0; i < 7; ++i) {
          int p = pg + 8 * i;
          if (p < 49) {
            uint4 u = *reinterpret_cast<const uint4*>(&xw[p][k0]);
            xf[i][0] = bflo(u.x); xf[i][1] = bfhi(u.x);
            xf[i][2] = bflo(u.y); xf[i][3] = bfhi(u.y);
            xf[i][4] = bflo(u.z); xf[i][5] = bfhi(u.z);
            xf[i][6] = bflo(u.w); xf[i][7] = bfhi(u.w);
          } else {
#pragma unroll
            for (int kq = 0; kq < 8; ++kq) xf[i][kq] = 0.f;
          }
        }
#pragma unroll
        for (int kq = 0; kq < 8; ++kq) {
          const float* wrow = qkv_w + (size_t)(k0 + kq) * 288 + hh * 32 + dd;
          float wq = wrow[0], wk = wrow[96], wv = wrow[192];
#pragma unroll
          for (int i = 0; i < 7; ++i) {
            aq[i] += xf[i][kq] * wq;
            ak[i] += xf[i][kq] * wk;
            av[i] += xf[i][kq] * wv;
          }
        }
      }
      float bq = qkv_b[hh * 32 + dd];
      float bk = qkv_b[96 + hh * 32 + dd];
      float bv = qkv_b[192 + hh * 32 + dd];
#pragma unroll
      for (int i = 0; i < 7; ++i) {
        int p = pg + 8 * i;
        if (p < 49) {
          qh[p][dd] = (aq[i] + bq) * QSCALE;
          kh[p][dd] = ak[i] + bk;
          vh[p][dd] = av[i] + bv;
        }
      }
    }
    __syncthreads();
    // ---- S = qk^T + mask (196 threads: row i, j strided by 4) ----
    if (tid < 196) {
      int i = tid >> 2, jq = tid & 3;
      float qr[32];
      const float4* q4 = reinterpret_cast<const float4*>(&qh[i][0]);
#pragma unroll
      for (int dq = 0; dq < 8; ++dq) {
        float4 t = q4[dq];
        qr[dq * 4 + 0] = t.x; qr[dq * 4 + 1] = t.y;
        qr[dq * 4 + 2] = t.z; qr[dq * 4 + 3] = t.w;
      }
      int ci = cnt[i];
      for (int j = jq; j < 49; j += 4) {
        const float4* k4 = reinterpret_cast<const float4*>(&kh[j][0]);
        float s = 0.f;
#pragma unroll
        for (int dq = 0; dq < 8; ++dq) {
          float4 kv = k4[dq];
          s += qr[dq*4+0]*kv.x + qr[dq*4+1]*kv.y + qr[dq*4+2]*kv.z + qr[dq*4+3]*kv.w;
        }
        S[i][j] = s + ((ci == cnt[j]) ? 0.f : -100.f);
      }
    }
    __syncthreads();
    // ---- row softmax (49 rows, 1 thread each; tiny) ----
    if (tid < 49) {
      float mx = -1e30f;
      for (int j = 0; j < 49; ++j) mx = fmaxf(mx, S[tid][j]);
      float sum = 0.f;
      for (int j = 0; j < 49; ++j) { float p = __expf(S[tid][j] - mx); S[tid][j] = p; sum += p; }
      float inv = 1.f / sum;
      for (int j = 0; j < 49; ++j) S[tid][j] *= inv;
    }
    __syncthreads();
    // ---- PV: thread owns (p, 4 dims) ----
    for (int slot = tid; slot < 392; slot += 256) {
      int p = slot >> 3, d4 = (slot & 7) * 4;
      float a0 = 0.f, a1 = 0.f, a2 = 0.f, a3 = 0.f;
      for (int j = 0; j < 49; ++j) {
        float pp = S[p][j];
        float4 vv = *reinterpret_cast<const float4*>(&vh[j][d4]);
        a0 += pp * vv.x; a1 += pp * vv.y; a2 += pp * vv.z; a3 += pp * vv.w;
      }
      float* op = &outw[p][hh * 32 + d4];
      op[0] = a0; op[1] = a1; op[2] = a2; op[3] = a3;
    }
    __syncthreads();
  }
  // ---- proj + shortcut + unshift scatter ----
  for (int slot = tid; slot < 1176; slot += 256) {
    int p = slot / 24, c4 = (slot % 24) * 4;
    float a0 = 0.f, a1 = 0.f, a2 = 0.f, a3 = 0.f;
    for (int k0 = 0; k0 < 96; k0 += 4) {
      float4 ow = *reinterpret_cast<const float4*>(&outw[p][k0]);
      const float* w0 = proj_w + (size_t)k0 * 96 + c4;
      float4 wa = *reinterpret_cast<const float4*>(w0);
      float4 wb = *reinterpret_cast<const float4*>(w0 + 96);
      float4 wc2 = *reinterpret_cast<const float4*>(w0 + 192);
      float4 wd = *reinterpret_cast<const float4*>(w0 + 288);
      a0 += ow.x*wa.x + ow.y*wb.x + ow.z*wc2.x + ow.w*wd.x;
      a1 += ow.x*wa.y + ow.y*wb.y + ow.z*wc2.y + ow.w*wd.y;
      a2 += ow.x*wa.z + ow.y*wb.z + ow.z*wc2.z + ow.w*wd.z;
      a3 += ow.x*wa.w + ow.y*wb.w + ow.z*wc2.w + ow.w*wd.w;
    }
    size_t rowo = ((size_t)b * LROW + gidx[p]) * CD + c4;
    float4 sc = *reinterpret_cast<const float4*>(&xin[rowo]);
    float4 pb = *reinterpret_cast<const float4*>(&proj_b[c4]);
    float4 res;
    res.x = a0 + pb.x + sc.x; res.y = a1 + pb.y + sc.y;
    res.z = a2 + pb.z + sc.z; res.w = a3 + pb.w + sc.w;
    *reinterpret_cast<float4*>(&x1[rowo]) = res;
  }
}

// ---------------- generic skinny GEMM: out = f(A@B + bias [+res]) ----------------
// MODE 0: plain, 1: +res, 2: gelu(tanh approx)
template <int MODE>
__global__ __launch_bounds__(256) void gemm_kernel(
    const float* __restrict__ A, const float* __restrict__ B,
    const float* __restrict__ bias, const float* __restrict__ res,
    float* __restrict__ out, int M, int K, int N) {
  __shared__ __align__(16) float As_t[32][68];  // transposed A tile (k-major)
  __shared__ __align__(16) float Bs[32][98];
  int tid = threadIdx.x;
  int m0 = blockIdx.x * 64, n0 = blockIdx.y * 96;
  int tr = tid >> 4, tc = tid & 15;
  float acc[4][6];
#pragma unroll
  for (int i = 0; i < 4; ++i)
#pragma unroll
    for (int j = 0; j < 6; ++j) acc[i][j] = 0.f;
  for (int k0 = 0; k0 < K; k0 += 32) {
    for (int idx = tid; idx < 2048; idx += 256) {
      int r = idx >> 5, c = idx & 31;
      As_t[c][r] = A[(size_t)(m0 + r) * K + k0 + c];
    }
    for (int idx = tid; idx < 3072; idx += 256) {
      int r = idx / 96, c = idx % 96;
      Bs[r][c] = B[(size_t)(k0 + r) * N + n0 + c];
    }
    __syncthreads();
#pragma unroll 8
    for (int kk = 0; kk < 32; ++kk) {
      float4 av = *reinterpret_cast<const float4*>(&As_t[kk][tr * 4]);
      float2 b0 = *reinterpret_cast<const float2*>(&Bs[kk][tc * 6]);
      float2 b1 = *reinterpret_cast<const float2*>(&Bs[kk][tc * 6 + 2]);
      float2 b2 = *reinterpret_cast<const float2*>(&Bs[kk][tc * 6 + 4]);
      float aa[4] = {av.x, av.y, av.z, av.w};
      float bb[6] = {b0.x, b0.y, b1.x, b1.y, b2.x, b2.y};
#pragma unroll
      for (int i = 0; i < 4; ++i)
#pragma unroll
        for (int j = 0; j < 6; ++j) acc[i][j] += aa[i] * bb[j];
    }
    __syncthreads();
  }
#pragma unroll
  for (int i = 0; i < 4; ++i) {
    int m = m0 + tr * 4 + i;
#pragma unroll
    for (int j = 0; j < 6; ++j) {
      int n = n0 + tc * 6 + j;
      float v = acc[i][j] + bias[n];
      if (MODE == 1) v += res[(size_t)m * N + n];
      if (MODE == 2) {
        float u = v;
        float t = tanhf(0.7978845608028654f * (u + 0.044715f * u * u * u));
        v = 0.5f * u * (1.f + t);
      }
      out[(size_t)m * N + n] = v;
    }
  }
}

// ---------------- flash attention over N=3136, hd=32; one block = 64 q-rows of one (b,h) ----------------
__global__ __launch_bounds__(256) void flash_kernel(const float* __restrict__ qkv,
                                                    float* __restrict__ ao) {
  __shared__ __align__(16) float Ks[64][36];
  __shared__ __align__(16) float Vs[64][36];
  __shared__ __align__(16) float Ps[64][68];
  int tid = threadIdx.x;
  int q0 = blockIdx.x * 64;
  int b = blockIdx.y / 3, h = blockIdx.y % 3;
  const float* base = qkv + (size_t)b * LROW * 288;

  int r = tid >> 2, qq = tid & 3;  // 4 threads per q-row
  int c0 = qq * 8;

  float qreg[32];
  {
    const float* qrow = base + (size_t)(q0 + r) * 288 + h * 32;
#pragma unroll
    for (int d = 0; d < 32; ++d) qreg[d] = qrow[d] * QSCALE;
  }

  float m = -1e30f, l = 0.f;
  float o[8];
#pragma unroll
  for (int i = 0; i < 8; ++i) o[i] = 0.f;

  for (int kt = 0; kt < 49; ++kt) {
    __syncthreads();  // previous PV finished reading Vs
    for (int idx = tid; idx < 2048; idx += 256) {
      int rr = idx >> 5, cc = idx & 31;
      const float* rowp = base + (size_t)(kt * 64 + rr) * 288 + h * 32 + cc;
      Ks[rr][cc] = rowp[96];
      Vs[rr][cc] = rowp[192];
    }
    __syncthreads();
    float sv[16];
    float smax = -1e30f;
#pragma unroll
    for (int jj = 0; jj < 16; ++jj) {
      int j = qq + jj * 4;  // interleaved: 4 distinct bank groups per instr
      const float4* k4 = reinterpret_cast<const float4*>(&Ks[j][0]);
      float s = 0.f;
#pragma unroll
      for (int dq = 0; dq < 8; ++dq) {
        float4 kv = k4[dq];
        s += qreg[dq*4+0]*kv.x + qreg[dq*4+1]*kv.y + qreg[dq*4+2]*kv.z + qreg[dq*4+3]*kv.w;
      }
      sv[jj] = s;
      smax = fmaxf(smax, s);
    }
    smax = fmaxf(smax, __shfl_xor(smax, 1));
    smax = fmaxf(smax, __shfl_xor(smax, 2));
    float mn = fmaxf(m, smax);
    float alpha = __expf(m - mn);
    float rsum = 0.f;
#pragma unroll
    for (int jj = 0; jj < 16; ++jj) {
      float p = __expf(sv[jj] - mn);
      Ps[r][qq + jj * 4] = p;
      rsum += p;
    }
    rsum += __shfl_xor(rsum, 1);
    rsum += __shfl_xor(rsum, 2);
    l = l * alpha + rsum;
    m = mn;
#pragma unroll
    for (int i = 0; i < 8; ++i) o[i] *= alpha;
#pragma unroll 4
    for (int j = 0; j < 64; ++j) {  // Ps row written by this quad (same wave -> no barrier needed)
      float pp = Ps[r][j];
      const float4* v4 = reinterpret_cast<const float4*>(&Vs[j][c0]);
      float4 va = v4[0], vb = v4[1];
      o[0] += pp*va.x; o[1] += pp*va.y; o[2] += pp*va.z; o[3] += pp*va.w;
      o[4] += pp*vb.x; o[5] += pp*vb.y; o[6] += pp*vb.z; o[7] += pp*vb.w;
    }
  }
  float inv = 1.f / l;
  float* orow = ao + ((size_t)b * LROW + q0 + r) * CD + h * 32 + c0;
  float4 w0, w1;
  w0.x = o[0]*inv; w0.y = o[1]*inv; w0.z = o[2]*inv; w0.w = o[3]*inv;
  w1.x = o[4]*inv; w1.y = o[5]*inv; w1.z = o[6]*inv; w1.w = o[7]*inv;
  *reinterpret_cast<float4*>(orow) = w0;
  *reinterpret_cast<float4*>(orow + 4) = w1;
}

__global__ void tail_kernel(const int* __restrict__ Hp, const int* __restrict__ Wp,
                            float* __restrict__ o) {
  o[0] = (float)Hp[0];
  o[1] = (float)Wp[0];
}

extern "C" void kernel_launch(void* const* d_in, const int* in_sizes, int n_in,
                              void* d_out, int out_size, void* d_ws, size_t ws_size,
                              hipStream_t stream) {
  const float* x      = (const float*)d_in[0];
  const int*   Hp     = (const int*)d_in[1];
  const int*   Wp     = (const int*)d_in[2];
  const float* n1s    = (const float*)d_in[3];
  const float* n1b    = (const float*)d_in[4];
  const float* qkv_w  = (const float*)d_in[5];
  const float* qkv_b  = (const float*)d_in[6];
  const float* proj_w = (const float*)d_in[7];
  const float* proj_b = (const float*)d_in[8];
  const float* ln1s   = (const float*)d_in[9];
  const float* ln1b   = (const float*)d_in[10];
  const float* qkv2_w = (const float*)d_in[11];
  const float* qkv2_b = (const float*)d_in[12];
  const float* out_w  = (const float*)d_in[13];
  const float* out_b  = (const float*)d_in[14];
  const float* ln2s   = (const float*)d_in[15];
  const float* ln2b   = (const float*)d_in[16];
  const float* fc1_w  = (const float*)d_in[17];
  const float* fc1_b  = (const float*)d_in[18];
  const float* fc2_w  = (const float*)d_in[19];
  const float* fc2_b  = (const float*)d_in[20];

  float* wsf = (float*)d_ws;
  const size_t U = (size_t)4 * LROW * CD;  // 1,204,224
  // lifetime-overlaid workspace (8U floats = 38.5 MB total)
  float* buf_h   = wsf;           // LN1 out -> (reuse) LN-tb1 out -> flash ao
  float* buf_x1  = wsf + U;       // x after window attn (residual for out-proj)
  float* buf_qkv = wsf + 2 * U;   // 3U; later first U reused as x2
  float* buf_ao  = wsf;           // reuse of buf_h
  float* buf_x2  = wsf + 2 * U;   // reuse of qkv[0:U] (qkv dead after flash)
  float* buf_z   = wsf + 3 * U;   // LN2 out (reuse of qkv[U:2U])
  float* buf_t   = wsf + 4 * U;   // 4U: fc1 out (12544 x 384)
  float* outx    = (float*)d_out;

  const int M = 4 * LROW;  // 12544 rows

  ln_kernel<<<M / 4, 256, 0, stream>>>(x, n1s, n1b, buf_h, M);
  win_attn_kernel<<<256, 256, 0, stream>>>(buf_h, x, qkv_w, qkv_b, proj_w, proj_b, buf_x1);
  ln_kernel<<<M / 4, 256, 0, stream>>>(buf_x1, ln1s, ln1b, buf_h, M);
  gemm_kernel<0><<<dim3(M / 64, 3), 256, 0, stream>>>(buf_h, qkv2_w, qkv2_b, nullptr, buf_qkv, M, 96, 288);
  flash_kernel<<<dim3(49, 12), 256, 0, stream>>>(buf_qkv, buf_ao);
  gemm_kernel<1><<<dim3(M / 64, 1), 256, 0, stream>>>(buf_ao, out_w, out_b, buf_x1, buf_x2, M, 96, 96);
  ln_kernel<<<M / 4, 256, 0, stream>>>(buf_x2, ln2s, ln2b, buf_z, M);
  gemm_kernel<2><<<dim3(M / 64, 4), 256, 0, stream>>>(buf_z, fc1_w, fc1_b, nullptr, buf_t, M, 96, 384);
  gemm_kernel<1><<<dim3(M / 64, 1), 256, 0, stream>>>(buf_t, fc2_w, fc2_b, buf_x2, outx, M, 384, 96);
  tail_kernel<<<1, 1, 0, stream>>>(Hp, Wp, outx + U);
}

// Round 2
// 459.177 us; speedup vs baseline: 1.4568x; 1.4568x over previous
//
#include <hip/hip_runtime.h>
#include <hip/hip_bf16.h>

#define CD 96
#define LROW 3136          // 56*56
#define QSCALE 0.17677669529663687f  // 1/sqrt(32)

using f32x4 = __attribute__((ext_vector_type(4))) float;
using bf8   = __attribute__((ext_vector_type(8))) short;

__device__ __forceinline__ float bflo(unsigned u) { return __uint_as_float(u << 16); }
__device__ __forceinline__ float bfhi(unsigned u) { return __uint_as_float(u & 0xffff0000u); }
__device__ __forceinline__ short f2bf(float f) {
  union { float f; unsigned u; } v; v.f = f;
  unsigned r = v.u + 0x7fffu + ((v.u >> 16) & 1u);
  return (short)(r >> 16);
}

// ---------------- LayerNorm (one wave per 96-col row) ----------------
__global__ __launch_bounds__(256) void ln_kernel(const float* __restrict__ x,
                                                 const float* __restrict__ g,
                                                 const float* __restrict__ b,
                                                 float* __restrict__ out, int rows) {
  int wid = threadIdx.x >> 6, lane = threadIdx.x & 63;
  int row = (blockIdx.x << 2) + wid;
  if (row >= rows) return;
  const float* xr = x + (size_t)row * CD;
  float v0 = xr[lane];
  float v1 = (lane < 32) ? xr[64 + lane] : 0.f;
  float s = v0 + v1;
#pragma unroll
  for (int off = 32; off >= 1; off >>= 1) s += __shfl_xor(s, off);
  float mu = s * (1.f / 96.f);
  float d0 = v0 - mu;
  float d1 = (lane < 32) ? v1 - mu : 0.f;
  float q = d0 * d0 + d1 * d1;
#pragma unroll
  for (int off = 32; off >= 1; off >>= 1) q += __shfl_xor(q, off);
  float rstd = rsqrtf(q * (1.f / 96.f) + 1e-6f);
  float* orow = out + (size_t)row * CD;
  orow[lane] = d0 * rstd * g[lane] + b[lane];
  if (lane < 32) orow[64 + lane] = d1 * rstd * g[64 + lane] + b[64 + lane];
}

// ---------------- fused shifted-window attention: one block per window ----------------
__global__ __launch_bounds__(256) void win_attn_kernel(
    const float* __restrict__ hsrc, const float* __restrict__ xin,
    const float* __restrict__ qkv_w, const float* __restrict__ qkv_b,
    const float* __restrict__ proj_w, const float* __restrict__ proj_b,
    float* __restrict__ x1) {
  __shared__ __align__(16) __hip_bfloat16 xw[49][96];
  __shared__ __align__(16) float qh[49][36];
  __shared__ __align__(16) float kh[49][36];
  __shared__ __align__(16) float vh[49][36];
  __shared__ __align__(16) float S[49][49];
  __shared__ __align__(16) float outw[49][100];
  __shared__ int cnt[49];
  __shared__ int gidx[49];

  int tid = threadIdx.x;
  int b = blockIdx.x >> 6, w64 = blockIdx.x & 63;
  int wr = w64 >> 3, wc = w64 & 7;

  if (tid < 49) {
    int i = tid / 7, j = tid % 7;
    int sh = wr * 7 + i, sw = wc * 7 + j;             // coords in shifted/mask image
    int hr = (sh < 49) ? 0 : ((sh < 53) ? 1 : 2);     // region thresholds: 56-7, 56-3
    int wreg = (sw < 49) ? 0 : ((sw < 53) ? 1 : 2);
    cnt[tid] = hr * 3 + wreg;
    gidx[tid] = ((sh + 3) % 56) * 56 + ((sw + 3) % 56);  // roll(-3) load == roll(+3) store
  }
  __syncthreads();

  for (int idx = tid; idx < 49 * 96; idx += 256) {
    int p = idx / 96, c = idx % 96;
    xw[p][c] = __float2bfloat16(hsrc[((size_t)b * LROW + gidx[p]) * CD + c]);
  }
  __syncthreads();

  int dd = tid & 31, pg = tid >> 5;  // 32 dims x 8 row-groups

  for (int hh = 0; hh < 3; ++hh) {
    // ---- qkv for this head: thread owns col dd, rows pg+8i (weights reused across rows) ----
    {
      float aq[7], ak[7], av[7];
#pragma unroll
      for (int i = 0; i < 7; ++i) { aq[i] = 0.f; ak[i] = 0.f; av[i] = 0.f; }
      for (int k0 = 0; k0 < 96; k0 += 8) {
        float xf[7][8];
#pragma unroll
        for (int i = 0; i < 7; ++i) {
          int p = pg + 8 * i;
          if (p < 49) {
            uint4 u = *reinterpret_cast<const uint4*>(&xw[p][k0]);
            xf[i][0] = bflo(u.x); xf[i][1] = bfhi(u.x);
            xf[i][2] = bflo(u.y); xf[i][3] = bfhi(u.y);
            xf[i][4] = bflo(u.z); xf[i][5] = bfhi(u.z);
            xf[i][6] = bflo(u.w); xf[i][7] = bfhi(u.w);
          } else {
#pragma unroll
            for (int kq = 0; kq < 8; ++kq) xf[i][kq] = 0.f;
          }
        }
#pragma unroll
        for (int kq = 0; kq < 8; ++kq) {
          const float* wrow = qkv_w + (size_t)(k0 + kq) * 288 + hh * 32 + dd;
          float wq = wrow[0], wk = wrow[96], wv = wrow[192];
#pragma unroll
          for (int i = 0; i < 7; ++i) {
            aq[i] += xf[i][kq] * wq;
            ak[i] += xf[i][kq] * wk;
            av[i] += xf[i][kq] * wv;
          }
        }
      }
      float bq = qkv_b[hh * 32 + dd];
      float bk = qkv_b[96 + hh * 32 + dd];
      float bv = qkv_b[192 + hh * 32 + dd];
#pragma unroll
      for (int i = 0; i < 7; ++i) {
        int p = pg + 8 * i;
        if (p < 49) {
          qh[p][dd] = (aq[i] + bq) * QSCALE;
          kh[p][dd] = ak[i] + bk;
          vh[p][dd] = av[i] + bv;
        }
      }
    }
    __syncthreads();
    // ---- S = qk^T + mask (196 threads: row i, j strided by 4) ----
    if (tid < 196) {
      int i = tid >> 2, jq = tid & 3;
      float qr[32];
      const float4* q4 = reinterpret_cast<const float4*>(&qh[i][0]);
#pragma unroll
      for (int dq = 0; dq < 8; ++dq) {
        float4 t = q4[dq];
        qr[dq * 4 + 0] = t.x; qr[dq * 4 + 1] = t.y;
        qr[dq * 4 + 2] = t.z; qr[dq * 4 + 3] = t.w;
      }
      int ci = cnt[i];
      for (int j = jq; j < 49; j += 4) {
        const float4* k4 = reinterpret_cast<const float4*>(&kh[j][0]);
        float s = 0.f;
#pragma unroll
        for (int dq = 0; dq < 8; ++dq) {
          float4 kv = k4[dq];
          s += qr[dq*4+0]*kv.x + qr[dq*4+1]*kv.y + qr[dq*4+2]*kv.z + qr[dq*4+3]*kv.w;
        }
        S[i][j] = s + ((ci == cnt[j]) ? 0.f : -100.f);
      }
    }
    __syncthreads();
    // ---- row softmax (49 rows, 1 thread each; tiny) ----
    if (tid < 49) {
      float mx = -1e30f;
      for (int j = 0; j < 49; ++j) mx = fmaxf(mx, S[tid][j]);
      float sum = 0.f;
      for (int j = 0; j < 49; ++j) { float p = __expf(S[tid][j] - mx); S[tid][j] = p; sum += p; }
      float inv = 1.f / sum;
      for (int j = 0; j < 49; ++j) S[tid][j] *= inv;
    }
    __syncthreads();
    // ---- PV: thread owns (p, 4 dims) ----
    for (int slot = tid; slot < 392; slot += 256) {
      int p = slot >> 3, d4 = (slot & 7) * 4;
      float a0 = 0.f, a1 = 0.f, a2 = 0.f, a3 = 0.f;
      for (int j = 0; j < 49; ++j) {
        float pp = S[p][j];
        float4 vv = *reinterpret_cast<const float4*>(&vh[j][d4]);
        a0 += pp * vv.x; a1 += pp * vv.y; a2 += pp * vv.z; a3 += pp * vv.w;
      }
      float* op = &outw[p][hh * 32 + d4];
      op[0] = a0; op[1] = a1; op[2] = a2; op[3] = a3;
    }
    __syncthreads();
  }
  // ---- proj + shortcut + unshift scatter ----
  for (int slot = tid; slot < 1176; slot += 256) {
    int p = slot / 24, c4 = (slot % 24) * 4;
    float a0 = 0.f, a1 = 0.f, a2 = 0.f, a3 = 0.f;
    for (int k0 = 0; k0 < 96; k0 += 4) {
      float4 ow = *reinterpret_cast<const float4*>(&outw[p][k0]);
      const float* w0 = proj_w + (size_t)k0 * 96 + c4;
      float4 wa = *reinterpret_cast<const float4*>(w0);
      float4 wb = *reinterpret_cast<const float4*>(w0 + 96);
      float4 wc2 = *reinterpret_cast<const float4*>(w0 + 192);
      float4 wd = *reinterpret_cast<const float4*>(w0 + 288);
      a0 += ow.x*wa.x + ow.y*wb.x + ow.z*wc2.x + ow.w*wd.x;
      a1 += ow.x*wa.y + ow.y*wb.y + ow.z*wc2.y + ow.w*wd.y;
      a2 += ow.x*wa.z + ow.y*wb.z + ow.z*wc2.z + ow.w*wd.z;
      a3 += ow.x*wa.w + ow.y*wb.w + ow.z*wc2.w + ow.w*wd.w;
    }
    size_t rowo = ((size_t)b * LROW + gidx[p]) * CD + c4;
    float4 sc = *reinterpret_cast<const float4*>(&xin[rowo]);
    float4 pb = *reinterpret_cast<const float4*>(&proj_b[c4]);
    float4 res;
    res.x = a0 + pb.x + sc.x; res.y = a1 + pb.y + sc.y;
    res.z = a2 + pb.z + sc.z; res.w = a3 + pb.w + sc.w;
    *reinterpret_cast<float4*>(&x1[rowo]) = res;
  }
}

// ---------------- generic skinny GEMM: out = f(A@B + bias [+res]) ----------------
// MODE 0: plain, 1: +res, 2: gelu(tanh approx)
template <int MODE>
__global__ __launch_bounds__(256) void gemm_kernel(
    const float* __restrict__ A, const float* __restrict__ B,
    const float* __restrict__ bias, const float* __restrict__ res,
    float* __restrict__ out, int M, int K, int N) {
  __shared__ __align__(16) float As_t[32][68];  // transposed A tile (k-major)
  __shared__ __align__(16) float Bs[32][98];
  int tid = threadIdx.x;
  int m0 = blockIdx.x * 64, n0 = blockIdx.y * 96;
  int tr = tid >> 4, tc = tid & 15;
  float acc[4][6];
#pragma unroll
  for (int i = 0; i < 4; ++i)
#pragma unroll
    for (int j = 0; j < 6; ++j) acc[i][j] = 0.f;
  for (int k0 = 0; k0 < K; k0 += 32) {
    for (int idx = tid; idx < 2048; idx += 256) {
      int r = idx >> 5, c = idx & 31;
      As_t[c][r] = A[(size_t)(m0 + r) * K + k0 + c];
    }
    for (int idx = tid; idx < 3072; idx += 256) {
      int r = idx / 96, c = idx % 96;
      Bs[r][c] = B[(size_t)(k0 + r) * N + n0 + c];
    }
    __syncthreads();
#pragma unroll 8
    for (int kk = 0; kk < 32; ++kk) {
      float4 av = *reinterpret_cast<const float4*>(&As_t[kk][tr * 4]);
      float2 b0 = *reinterpret_cast<const float2*>(&Bs[kk][tc * 6]);
      float2 b1 = *reinterpret_cast<const float2*>(&Bs[kk][tc * 6 + 2]);
      float2 b2 = *reinterpret_cast<const float2*>(&Bs[kk][tc * 6 + 4]);
      float aa[4] = {av.x, av.y, av.z, av.w};
      float bb[6] = {b0.x, b0.y, b1.x, b1.y, b2.x, b2.y};
#pragma unroll
      for (int i = 0; i < 4; ++i)
#pragma unroll
        for (int j = 0; j < 6; ++j) acc[i][j] += aa[i] * bb[j];
    }
    __syncthreads();
  }
#pragma unroll
  for (int i = 0; i < 4; ++i) {
    int m = m0 + tr * 4 + i;
#pragma unroll
    for (int j = 0; j < 6; ++j) {
      int n = n0 + tc * 6 + j;
      float v = acc[i][j] + bias[n];
      if (MODE == 1) v += res[(size_t)m * N + n];
      if (MODE == 2) {
        float u = v;
        float t = tanhf(0.7978845608028654f * (u + 0.044715f * u * u * u));
        v = 0.5f * u * (1.f + t);
      }
      out[(size_t)m * N + n] = v;
    }
  }
}

// ---------------- MFMA flash attention over N=3136, hd=32 ----------------
// one block = 64 q-rows of one (b,h); 4 waves, each owns a 16-row q-subtile.
// KV tiles of 64. S-frag layout: col=lane&15 (kv), row=(lane>>4)*4+reg (q).
__global__ __launch_bounds__(256) void flash_mfma_kernel(const float* __restrict__ qkv,
                                                         float* __restrict__ ao) {
  __shared__ __align__(16) short Ks[64][40];      // K tile, 80B row stride (16B-aligned, 2-way banks)
  __shared__ __align__(16) short Vt[32][72];      // V tile transposed: [d][kv], 144B stride
  __shared__ __align__(16) short Pw[4][16][72];   // per-wave P tile [q][kv]
  int tid = threadIdx.x;
  int lane = tid & 63, wid = tid >> 6;
  int q0 = blockIdx.x * 64;
  int b = blockIdx.y / 3, h = blockIdx.y % 3;
  const float* base = qkv + (size_t)b * LROW * 288 + h * 32;

  int lr = lane & 15, lg = lane >> 4;

  // Q A-fragment: row = lr (q_local), k = 8*lg + i (contiguous d)
  bf8 qf;
  {
    const float* qp = base + (size_t)(q0 + wid * 16 + lr) * 288 + 8 * lg;
#pragma unroll
    for (int i = 0; i < 8; ++i) qf[i] = f2bf(qp[i]);
  }

  f32x4 Oa0 = {0.f, 0.f, 0.f, 0.f}, Oa1 = {0.f, 0.f, 0.f, 0.f};
  float m4[4], l4[4];
#pragma unroll
  for (int r = 0; r < 4; ++r) { m4[r] = -1e30f; l4[r] = 0.f; }

  for (int kt = 0; kt < 49; ++kt) {
    __syncthreads();  // previous iter's PV done reading Ks/Vt
    for (int idx = tid; idx < 2048; idx += 256) {
      int rr = idx >> 5, cc = idx & 31;  // kv row, d col
      const float* rowp = base + (size_t)(kt * 64 + rr) * 288 + cc;
      Ks[rr][cc] = f2bf(rowp[96]);
      Vt[cc][rr] = f2bf(rowp[192]);
    }
    __syncthreads();

    // QK^T: 4 kv-subtiles, K-dim = 32 = hd (one MFMA each)
    f32x4 S[4];
#pragma unroll
    for (int t = 0; t < 4; ++t) {
      bf8 kf = *reinterpret_cast<const bf8*>(&Ks[t * 16 + lr][8 * lg]);
      f32x4 z = {0.f, 0.f, 0.f, 0.f};
      S[t] = __builtin_amdgcn_mfma_f32_16x16x32_bf16(qf, kf, z, 0, 0, 0);
    }
#pragma unroll
    for (int t = 0; t < 4; ++t)
#pragma unroll
      for (int r = 0; r < 4; ++r) S[t][r] *= QSCALE;

    // online softmax per owned q-row (reg r); kv-reduce = in-lane over t + shfl over lane&15
    float al[4];
#pragma unroll
    for (int r = 0; r < 4; ++r) {
      float sm = fmaxf(fmaxf(S[0][r], S[1][r]), fmaxf(S[2][r], S[3][r]));
      sm = fmaxf(sm, __shfl_xor(sm, 1));
      sm = fmaxf(sm, __shfl_xor(sm, 2));
      sm = fmaxf(sm, __shfl_xor(sm, 4));
      sm = fmaxf(sm, __shfl_xor(sm, 8));
      float mn = fmaxf(m4[r], sm);
      al[r] = __expf(m4[r] - mn);
      m4[r] = mn;
      float rs = 0.f;
#pragma unroll
      for (int t = 0; t < 4; ++t) {
        float p = __expf(S[t][r] - mn);
        S[t][r] = p;
        rs += p;
      }
      rs += __shfl_xor(rs, 1);
      rs += __shfl_xor(rs, 2);
      rs += __shfl_xor(rs, 4);
      rs += __shfl_xor(rs, 8);
      l4[r] = l4[r] * al[r] + rs;
    }

    // P -> bf16 -> per-wave LDS strip (same-wave producer/consumer: no barrier)
#pragma unroll
    for (int t = 0; t < 4; ++t)
#pragma unroll
      for (int r = 0; r < 4; ++r)
        Pw[wid][lg * 4 + r][t * 16 + lr] = f2bf(S[t][r]);

#pragma unroll
    for (int r = 0; r < 4; ++r) { Oa0[r] *= al[r]; Oa1[r] *= al[r]; }

    // PV: O[16q][32d] += P[16q][64kv] * V[64kv][32d], split k into 2 chunks, d into 2 tiles
#pragma unroll
    for (int c = 0; c < 2; ++c) {
      bf8 pa = *reinterpret_cast<const bf8*>(&Pw[wid][lr][c * 32 + 8 * lg]);
      bf8 v0 = *reinterpret_cast<const bf8*>(&Vt[lr][c * 32 + 8 * lg]);
      bf8 v1 = *reinterpret_cast<const bf8*>(&Vt[16 + lr][c * 32 + 8 * lg]);
      Oa0 = __builtin_amdgcn_mfma_f32_16x16x32_bf16(pa, v0, Oa0, 0, 0, 0);
      Oa1 = __builtin_amdgcn_mfma_f32_16x16x32_bf16(pa, v1, Oa1, 0, 0, 0);
    }
  }

  // epilogue: O/l, scatter per D-layout (row = lg*4+r, col = lr)
#pragma unroll
  for (int r = 0; r < 4; ++r) {
    float inv = 1.f / l4[r];
    int qrow = q0 + wid * 16 + lg * 4 + r;
    float* op = ao + ((size_t)b * LROW + qrow) * CD + h * 32;
    op[lr] = Oa0[r] * inv;
    op[16 + lr] = Oa1[r] * inv;
  }
}

__global__ void tail_kernel(const int* __restrict__ Hp, const int* __restrict__ Wp,
                            float* __restrict__ o) {
  o[0] = (float)Hp[0];
  o[1] = (float)Wp[0];
}

extern "C" void kernel_launch(void* const* d_in, const int* in_sizes, int n_in,
                              void* d_out, int out_size, void* d_ws, size_t ws_size,
                              hipStream_t stream) {
  const float* x      = (const float*)d_in[0];
  const int*   Hp     = (const int*)d_in[1];
  const int*   Wp     = (const int*)d_in[2];
  const float* n1s    = (const float*)d_in[3];
  const float* n1b    = (const float*)d_in[4];
  const float* qkv_w  = (const float*)d_in[5];
  const float* qkv_b  = (const float*)d_in[6];
  const float* proj_w = (const float*)d_in[7];
  const float* proj_b = (const float*)d_in[8];
  const float* ln1s   = (const float*)d_in[9];
  const float* ln1b   = (const float*)d_in[10];
  const float* qkv2_w = (const float*)d_in[11];
  const float* qkv2_b = (const float*)d_in[12];
  const float* out_w  = (const float*)d_in[13];
  const float* out_b  = (const float*)d_in[14];
  const float* ln2s   = (const float*)d_in[15];
  const float* ln2b   = (const float*)d_in[16];
  const float* fc1_w  = (const float*)d_in[17];
  const float* fc1_b  = (const float*)d_in[18];
  const float* fc2_w  = (const float*)d_in[19];
  const float* fc2_b  = (const float*)d_in[20];

  float* wsf = (float*)d_ws;
  const size_t U = (size_t)4 * LROW * CD;  // 1,204,224
  float* buf_h   = wsf;           // LN1 out -> (reuse) LN-tb1 out -> flash ao
  float* buf_x1  = wsf + U;       // x after window attn (residual for out-proj)
  float* buf_qkv = wsf + 2 * U;   // 3U
  float* buf_ao  = wsf;           // reuse of buf_h
  float* buf_x2  = wsf + 2 * U;   // reuse of qkv[0:U] (qkv dead after flash)
  float* buf_z   = wsf + 3 * U;   // LN2 out
  float* buf_t   = wsf + 4 * U;   // 4U: fc1 out (12544 x 384)
  float* outx    = (float*)d_out;

  const int M = 4 * LROW;  // 12544 rows

  ln_kernel<<<M / 4, 256, 0, stream>>>(x, n1s, n1b, buf_h, M);
  win_attn_kernel<<<256, 256, 0, stream>>>(buf_h, x, qkv_w, qkv_b, proj_w, proj_b, buf_x1);
  ln_kernel<<<M / 4, 256, 0, stream>>>(buf_x1, ln1s, ln1b, buf_h, M);
  gemm_kernel<0><<<dim3(M / 64, 3), 256, 0, stream>>>(buf_h, qkv2_w, qkv2_b, nullptr, buf_qkv, M, 96, 288);
  flash_mfma_kernel<<<dim3(49, 12), 256, 0, stream>>>(buf_qkv, buf_ao);
  gemm_kernel<1><<<dim3(M / 64, 1), 256, 0, stream>>>(buf_ao, out_w, out_b, buf_x1, buf_x2, M, 96, 96);
  ln_kernel<<<M / 4, 256, 0, stream>>>(buf_x2, ln2s, ln2b, buf_z, M);
  gemm_kernel<2><<<dim3(M / 64, 4), 256, 0, stream>>>(buf_z, fc1_w, fc1_b, nullptr, buf_t, M, 96, 384);
  gemm_kernel<1><<<dim3(M / 64, 1), 256, 0, stream>>>(buf_t, fc2_w, fc2_b, buf_x2, outx, M, 384, 96);
  tail_kernel<<<1, 1, 0, stream>>>(Hp, Wp, outx + U);
}

// Round 3
// 394.746 us; speedup vs baseline: 1.6946x; 1.1632x over previous
//
#include <hip/hip_runtime.h>
#include <hip/hip_bf16.h>

#define CD 96
#define LROW 3136          // 56*56
#define QSCALE 0.17677669529663687f  // 1/sqrt(32)
#define LOG2E 1.4426950408889634f

using f32x4 = __attribute__((ext_vector_type(4))) float;
using bf8   = __attribute__((ext_vector_type(8))) short;

__device__ __forceinline__ float bflo(unsigned u) { return __uint_as_float(u << 16); }
__device__ __forceinline__ float bfhi(unsigned u) { return __uint_as_float(u & 0xffff0000u); }
__device__ __forceinline__ short f2bf(float f) {
  union { float f; unsigned u; } v; v.f = f;
  unsigned r = v.u + 0x7fffu + ((v.u >> 16) & 1u);
  return (short)(r >> 16);
}

// ---------------- LayerNorm (one wave per 96-col row) ----------------
__global__ __launch_bounds__(256) void ln_kernel(const float* __restrict__ x,
                                                 const float* __restrict__ g,
                                                 const float* __restrict__ b,
                                                 float* __restrict__ out, int rows) {
  int wid = threadIdx.x >> 6, lane = threadIdx.x & 63;
  int row = (blockIdx.x << 2) + wid;
  if (row >= rows) return;
  const float* xr = x + (size_t)row * CD;
  float v0 = xr[lane];
  float v1 = (lane < 32) ? xr[64 + lane] : 0.f;
  float s = v0 + v1;
#pragma unroll
  for (int off = 32; off >= 1; off >>= 1) s += __shfl_xor(s, off);
  float mu = s * (1.f / 96.f);
  float d0 = v0 - mu;
  float d1 = (lane < 32) ? v1 - mu : 0.f;
  float q = d0 * d0 + d1 * d1;
#pragma unroll
  for (int off = 32; off >= 1; off >>= 1) q += __shfl_xor(q, off);
  float rstd = rsqrtf(q * (1.f / 96.f) + 1e-6f);
  float* orow = out + (size_t)row * CD;
  orow[lane] = d0 * rstd * g[lane] + b[lane];
  if (lane < 32) orow[64 + lane] = d1 * rstd * g[64 + lane] + b[64 + lane];
}

// ---------------- fused shifted-window attention: one block per window ----------------
__global__ __launch_bounds__(256) void win_attn_kernel(
    const float* __restrict__ hsrc, const float* __restrict__ xin,
    const float* __restrict__ qkv_w, const float* __restrict__ qkv_b,
    const float* __restrict__ proj_w, const float* __restrict__ proj_b,
    float* __restrict__ x1) {
  __shared__ __align__(16) __hip_bfloat16 xw[49][96];
  __shared__ __align__(16) float qh[49][36];
  __shared__ __align__(16) float kh[49][36];
  __shared__ __align__(16) float vh[49][36];
  __shared__ __align__(16) float S[49][49];
  __shared__ __align__(16) float outw[49][100];
  __shared__ int cnt[49];
  __shared__ int gidx[49];

  int tid = threadIdx.x;
  int b = blockIdx.x >> 6, w64 = blockIdx.x & 63;
  int wr = w64 >> 3, wc = w64 & 7;

  if (tid < 49) {
    int i = tid / 7, j = tid % 7;
    int sh = wr * 7 + i, sw = wc * 7 + j;             // coords in shifted/mask image
    int hr = (sh < 49) ? 0 : ((sh < 53) ? 1 : 2);     // region thresholds: 56-7, 56-3
    int wreg = (sw < 49) ? 0 : ((sw < 53) ? 1 : 2);
    cnt[tid] = hr * 3 + wreg;
    gidx[tid] = ((sh + 3) % 56) * 56 + ((sw + 3) % 56);  // roll(-3) load == roll(+3) store
  }
  __syncthreads();

  for (int idx = tid; idx < 49 * 96; idx += 256) {
    int p = idx / 96, c = idx % 96;
    xw[p][c] = __float2bfloat16(hsrc[((size_t)b * LROW + gidx[p]) * CD + c]);
  }
  __syncthreads();

  int dd = tid & 31, pg = tid >> 5;  // 32 dims x 8 row-groups

  for (int hh = 0; hh < 3; ++hh) {
    // ---- qkv for this head: thread owns col dd, rows pg+8i (weights reused across rows) ----
    {
      float aq[7], ak[7], av[7];
#pragma unroll
      for (int i = 0; i < 7; ++i) { aq[i] = 0.f; ak[i] = 0.f; av[i] = 0.f; }
      for (int k0 = 0; k0 < 96; k0 += 8) {
        float xf[7][8];
#pragma unroll
        for (int i = 0; i < 7; ++i) {
          int p = pg + 8 * i;
          if (p < 49) {
            uint4 u = *reinterpret_cast<const uint4*>(&xw[p][k0]);
            xf[i][0] = bflo(u.x); xf[i][1] = bfhi(u.x);
            xf[i][2] = bflo(u.y); xf[i][3] = bfhi(u.y);
            xf[i][4] = bflo(u.z); xf[i][5] = bfhi(u.z);
            xf[i][6] = bflo(u.w); xf[i][7] = bfhi(u.w);
          } else {
#pragma unroll
            for (int kq = 0; kq < 8; ++kq) xf[i][kq] = 0.f;
          }
        }
#pragma unroll
        for (int kq = 0; kq < 8; ++kq) {
          const float* wrow = qkv_w + (size_t)(k0 + kq) * 288 + hh * 32 + dd;
          float wq = wrow[0], wk = wrow[96], wv = wrow[192];
#pragma unroll
          for (int i = 0; i < 7; ++i) {
            aq[i] += xf[i][kq] * wq;
            ak[i] += xf[i][kq] * wk;
            av[i] += xf[i][kq] * wv;
          }
        }
      }
      float bq = qkv_b[hh * 32 + dd];
      float bk = qkv_b[96 + hh * 32 + dd];
      float bv = qkv_b[192 + hh * 32 + dd];
#pragma unroll
      for (int i = 0; i < 7; ++i) {
        int p = pg + 8 * i;
        if (p < 49) {
          qh[p][dd] = (aq[i] + bq) * QSCALE;
          kh[p][dd] = ak[i] + bk;
          vh[p][dd] = av[i] + bv;
        }
      }
    }
    __syncthreads();
    // ---- S = qk^T + mask (196 threads: row i, j strided by 4) ----
    if (tid < 196) {
      int i = tid >> 2, jq = tid & 3;
      float qr[32];
      const float4* q4 = reinterpret_cast<const float4*>(&qh[i][0]);
#pragma unroll
      for (int dq = 0; dq < 8; ++dq) {
        float4 t = q4[dq];
        qr[dq * 4 + 0] = t.x; qr[dq * 4 + 1] = t.y;
        qr[dq * 4 + 2] = t.z; qr[dq * 4 + 3] = t.w;
      }
      int ci = cnt[i];
      for (int j = jq; j < 49; j += 4) {
        const float4* k4 = reinterpret_cast<const float4*>(&kh[j][0]);
        float s = 0.f;
#pragma unroll
        for (int dq = 0; dq < 8; ++dq) {
          float4 kv = k4[dq];
          s += qr[dq*4+0]*kv.x + qr[dq*4+1]*kv.y + qr[dq*4+2]*kv.z + qr[dq*4+3]*kv.w;
        }
        S[i][j] = s + ((ci == cnt[j]) ? 0.f : -100.f);
      }
    }
    __syncthreads();
    // ---- row softmax (49 rows, 1 thread each; tiny) ----
    if (tid < 49) {
      float mx = -1e30f;
      for (int j = 0; j < 49; ++j) mx = fmaxf(mx, S[tid][j]);
      float sum = 0.f;
      for (int j = 0; j < 49; ++j) { float p = __expf(S[tid][j] - mx); S[tid][j] = p; sum += p; }
      float inv = 1.f / sum;
      for (int j = 0; j < 49; ++j) S[tid][j] *= inv;
    }
    __syncthreads();
    // ---- PV: thread owns (p, 4 dims) ----
    for (int slot = tid; slot < 392; slot += 256) {
      int p = slot >> 3, d4 = (slot & 7) * 4;
      float a0 = 0.f, a1 = 0.f, a2 = 0.f, a3 = 0.f;
      for (int j = 0; j < 49; ++j) {
        float pp = S[p][j];
        float4 vv = *reinterpret_cast<const float4*>(&vh[j][d4]);
        a0 += pp * vv.x; a1 += pp * vv.y; a2 += pp * vv.z; a3 += pp * vv.w;
      }
      float* op = &outw[p][hh * 32 + d4];
      op[0] = a0; op[1] = a1; op[2] = a2; op[3] = a3;
    }
    __syncthreads();
  }
  // ---- proj + shortcut + unshift scatter ----
  for (int slot = tid; slot < 1176; slot += 256) {
    int p = slot / 24, c4 = (slot % 24) * 4;
    float a0 = 0.f, a1 = 0.f, a2 = 0.f, a3 = 0.f;
    for (int k0 = 0; k0 < 96; k0 += 4) {
      float4 ow = *reinterpret_cast<const float4*>(&outw[p][k0]);
      const float* w0 = proj_w + (size_t)k0 * 96 + c4;
      float4 wa = *reinterpret_cast<const float4*>(w0);
      float4 wb = *reinterpret_cast<const float4*>(w0 + 96);
      float4 wc2 = *reinterpret_cast<const float4*>(w0 + 192);
      float4 wd = *reinterpret_cast<const float4*>(w0 + 288);
      a0 += ow.x*wa.x + ow.y*wb.x + ow.z*wc2.x + ow.w*wd.x;
      a1 += ow.x*wa.y + ow.y*wb.y + ow.z*wc2.y + ow.w*wd.y;
      a2 += ow.x*wa.z + ow.y*wb.z + ow.z*wc2.z + ow.w*wd.z;
      a3 += ow.x*wa.w + ow.y*wb.w + ow.z*wc2.w + ow.w*wd.w;
    }
    size_t rowo = ((size_t)b * LROW + gidx[p]) * CD + c4;
    float4 sc = *reinterpret_cast<const float4*>(&xin[rowo]);
    float4 pb = *reinterpret_cast<const float4*>(&proj_b[c4]);
    float4 res;
    res.x = a0 + pb.x + sc.x; res.y = a1 + pb.y + sc.y;
    res.z = a2 + pb.z + sc.z; res.w = a3 + pb.w + sc.w;
    *reinterpret_cast<float4*>(&x1[rowo]) = res;
  }
}

// ---------------- generic skinny GEMM: out = f(A@B + bias [+res]) ----------------
// MODE 0: plain, 1: +res, 2: gelu(tanh approx)
template <int MODE>
__global__ __launch_bounds__(256) void gemm_kernel(
    const float* __restrict__ A, const float* __restrict__ B,
    const float* __restrict__ bias, const float* __restrict__ res,
    float* __restrict__ out, int M, int K, int N) {
  __shared__ __align__(16) float As_t[32][68];  // transposed A tile (k-major)
  __shared__ __align__(16) float Bs[32][98];
  int tid = threadIdx.x;
  int m0 = blockIdx.x * 64, n0 = blockIdx.y * 96;
  int tr = tid >> 4, tc = tid & 15;
  float acc[4][6];
#pragma unroll
  for (int i = 0; i < 4; ++i)
#pragma unroll
    for (int j = 0; j < 6; ++j) acc[i][j] = 0.f;
  for (int k0 = 0; k0 < K; k0 += 32) {
    for (int idx = tid; idx < 2048; idx += 256) {
      int r = idx >> 5, c = idx & 31;
      As_t[c][r] = A[(size_t)(m0 + r) * K + k0 + c];
    }
    for (int idx = tid; idx < 3072; idx += 256) {
      int r = idx / 96, c = idx % 96;
      Bs[r][c] = B[(size_t)(k0 + r) * N + n0 + c];
    }
    __syncthreads();
#pragma unroll 8
    for (int kk = 0; kk < 32; ++kk) {
      float4 av = *reinterpret_cast<const float4*>(&As_t[kk][tr * 4]);
      float2 b0 = *reinterpret_cast<const float2*>(&Bs[kk][tc * 6]);
      float2 b1 = *reinterpret_cast<const float2*>(&Bs[kk][tc * 6 + 2]);
      float2 b2 = *reinterpret_cast<const float2*>(&Bs[kk][tc * 6 + 4]);
      float aa[4] = {av.x, av.y, av.z, av.w};
      float bb[6] = {b0.x, b0.y, b1.x, b1.y, b2.x, b2.y};
#pragma unroll
      for (int i = 0; i < 4; ++i)
#pragma unroll
        for (int j = 0; j < 6; ++j) acc[i][j] += aa[i] * bb[j];
    }
    __syncthreads();
  }
#pragma unroll
  for (int i = 0; i < 4; ++i) {
    int m = m0 + tr * 4 + i;
#pragma unroll
    for (int j = 0; j < 6; ++j) {
      int n = n0 + tc * 6 + j;
      float v = acc[i][j] + bias[n];
      if (MODE == 1) v += res[(size_t)m * N + n];
      if (MODE == 2) {
        float u = v;
        float t = tanhf(0.7978845608028654f * (u + 0.044715f * u * u * u));
        v = 0.5f * u * (1.f + t);
      }
      out[(size_t)m * N + n] = v;
    }
  }
}

// ---------------- qkv GEMM: fp32 x fp32 -> bf16 q/k/v with flash-friendly layouts ----------------
// q: [bh][n][32] bf16, pre-scaled by QSCALE*LOG2E; k: [bh][n][32]; v: [bh][32][n] (transposed)
__global__ __launch_bounds__(256) void gemm_qkv_kernel(
    const float* __restrict__ A, const float* __restrict__ B,
    const float* __restrict__ bias,
    short* __restrict__ qb, short* __restrict__ kb, short* __restrict__ vtb) {
  __shared__ __align__(16) float As_t[32][68];
  __shared__ __align__(16) float Bs[32][98];
  int tid = threadIdx.x;
  int m0 = blockIdx.x * 64, n0 = blockIdx.y * 96;
  int tr = tid >> 4, tc = tid & 15;
  float acc[4][6];
#pragma unroll
  for (int i = 0; i < 4; ++i)
#pragma unroll
    for (int j = 0; j < 6; ++j) acc[i][j] = 0.f;
  for (int k0 = 0; k0 < 96; k0 += 32) {
    for (int idx = tid; idx < 2048; idx += 256) {
      int r = idx >> 5, c = idx & 31;
      As_t[c][r] = A[(size_t)(m0 + r) * 96 + k0 + c];
    }
    for (int idx = tid; idx < 3072; idx += 256) {
      int r = idx / 96, c = idx % 96;
      Bs[r][c] = B[(size_t)(k0 + r) * 288 + n0 + c];
    }
    __syncthreads();
#pragma unroll 8
    for (int kk = 0; kk < 32; ++kk) {
      float4 av = *reinterpret_cast<const float4*>(&As_t[kk][tr * 4]);
      float2 b0 = *reinterpret_cast<const float2*>(&Bs[kk][tc * 6]);
      float2 b1 = *reinterpret_cast<const float2*>(&Bs[kk][tc * 6 + 2]);
      float2 b2 = *reinterpret_cast<const float2*>(&Bs[kk][tc * 6 + 4]);
      float aa[4] = {av.x, av.y, av.z, av.w};
      float bb[6] = {b0.x, b0.y, b1.x, b1.y, b2.x, b2.y};
#pragma unroll
      for (int i = 0; i < 4; ++i)
#pragma unroll
        for (int j = 0; j < 6; ++j) acc[i][j] += aa[i] * bb[j];
    }
    __syncthreads();
  }
  int sec = n0 / 96;  // 0=q, 1=k, 2=v (uniform per block)
#pragma unroll
  for (int i = 0; i < 4; ++i) {
    int m = m0 + tr * 4 + i;
    int bb2 = m / LROW, nn = m % LROW;
#pragma unroll
    for (int j = 0; j < 6; ++j) {
      int hd_ = tc * 6 + j;            // 0..95
      int hh = hd_ >> 5, dd2 = hd_ & 31;
      float v = acc[i][j] + bias[n0 + hd_];
      size_t bh = (size_t)bb2 * 3 + hh;
      if (sec == 0)      qb[(bh * LROW + nn) * 32 + dd2] = f2bf(v * (QSCALE * LOG2E));
      else if (sec == 1) kb[(bh * LROW + nn) * 32 + dd2] = f2bf(v);
      else               vtb[(bh * 32 + dd2) * LROW + nn] = f2bf(v);
    }
  }
}

// ---------------- MFMA flash attention over N=3136, hd=32 ----------------
// one block = 32 q-rows of one (b,h); 2 waves x 16 q-rows. KV tiles of 64.
// S-frag layout: col=lane&15 (kv), row=(lane>>4)*4+reg (q). Softmax in log2 domain.
__global__ __launch_bounds__(128) void flash_mfma_kernel(
    const short* __restrict__ qb, const short* __restrict__ kb,
    const short* __restrict__ vtb, float* __restrict__ ao) {
  __shared__ __align__(16) short Ks[64][40];      // 80B rows: 16B-aligned, conflict-free b128 reads
  __shared__ __align__(16) short Vt[32][72];      // transposed V tile [d][kv], 144B rows
  __shared__ __align__(16) short Pw[2][16][72];   // per-wave P tile [q][kv]
  int tid = threadIdx.x;
  int lane = tid & 63, wid = tid >> 6;
  int q0 = blockIdx.x * 32;
  int bh = blockIdx.y;
  int b = bh / 3, h = bh % 3;
  const short* qbb = qb + (size_t)bh * LROW * 32;
  const short* kbb = kb + (size_t)bh * LROW * 32;
  const short* vbb = vtb + (size_t)bh * 32 * LROW;

  int lr = lane & 15, lg = lane >> 4;

  // Q A-fragment: row=lr, k=8*lg+i (pre-scaled bf16, direct 16B load)
  bf8 qf = *reinterpret_cast<const bf8*>(qbb + (size_t)(q0 + wid * 16 + lr) * 32 + lg * 8);

  f32x4 Oa0 = {0.f, 0.f, 0.f, 0.f}, Oa1 = {0.f, 0.f, 0.f, 0.f};
  float m4[4], l4[4];
#pragma unroll
  for (int r = 0; r < 4; ++r) { m4[r] = -1e30f; l4[r] = 0.f; }

  for (int kt = 0; kt < 49; ++kt) {
    __syncthreads();  // previous iter's MFMA reads done
    // stage K tile (64x32 bf16 = 4KB) and V^T tile (32x64 bf16 = 4KB), vectorized
#pragma unroll
    for (int p = 0; p < 2; ++p) {
      int idx = tid + p * 128;
      int rr = idx >> 2, c = idx & 3;
      uint4 ku = *reinterpret_cast<const uint4*>(kbb + (size_t)(kt * 64 + rr) * 32 + c * 8);
      *reinterpret_cast<uint4*>(&Ks[rr][c * 8]) = ku;
      int d = idx >> 3, c2 = idx & 7;
      uint4 vu = *reinterpret_cast<const uint4*>(vbb + (size_t)d * LROW + kt * 64 + c2 * 8);
      *reinterpret_cast<uint4*>(&Vt[d][c2 * 8]) = vu;
    }
    __syncthreads();

    // QK^T: 4 kv-subtiles, one MFMA each (K-dim = hd = 32)
    f32x4 S[4];
#pragma unroll
    for (int t = 0; t < 4; ++t) {
      bf8 kf = *reinterpret_cast<const bf8*>(&Ks[t * 16 + lr][8 * lg]);
      f32x4 z = {0.f, 0.f, 0.f, 0.f};
      S[t] = __builtin_amdgcn_mfma_f32_16x16x32_bf16(qf, kf, z, 0, 0, 0);
    }

    // online softmax (log2 domain; Q pre-scaled by QSCALE*log2e)
    float al[4];
#pragma unroll
    for (int r = 0; r < 4; ++r) {
      float sm = fmaxf(fmaxf(S[0][r], S[1][r]), fmaxf(S[2][r], S[3][r]));
      sm = fmaxf(sm, __shfl_xor(sm, 1));
      sm = fmaxf(sm, __shfl_xor(sm, 2));
      sm = fmaxf(sm, __shfl_xor(sm, 4));
      sm = fmaxf(sm, __shfl_xor(sm, 8));
      float mn = fmaxf(m4[r], sm);
      al[r] = exp2f(m4[r] - mn);
      m4[r] = mn;
      float rs = 0.f;
#pragma unroll
      for (int t = 0; t < 4; ++t) {
        float p = exp2f(S[t][r] - mn);
        S[t][r] = p;
        rs += p;
      }
      rs += __shfl_xor(rs, 1);
      rs += __shfl_xor(rs, 2);
      rs += __shfl_xor(rs, 4);
      rs += __shfl_xor(rs, 8);
      l4[r] = l4[r] * al[r] + rs;
    }

    // P -> bf16 -> per-wave LDS strip (same-wave producer/consumer)
#pragma unroll
    for (int t = 0; t < 4; ++t)
#pragma unroll
      for (int r = 0; r < 4; ++r)
        Pw[wid][lg * 4 + r][t * 16 + lr] = f2bf(S[t][r]);

#pragma unroll
    for (int r = 0; r < 4; ++r) { Oa0[r] *= al[r]; Oa1[r] *= al[r]; }

    // PV: O[16q][32d] += P[16q][64kv] * V[64kv][32d]
#pragma unroll
    for (int c = 0; c < 2; ++c) {
      bf8 pa = *reinterpret_cast<const bf8*>(&Pw[wid][lr][c * 32 + 8 * lg]);
      bf8 v0 = *reinterpret_cast<const bf8*>(&Vt[lr][c * 32 + 8 * lg]);
      bf8 v1 = *reinterpret_cast<const bf8*>(&Vt[16 + lr][c * 32 + 8 * lg]);
      Oa0 = __builtin_amdgcn_mfma_f32_16x16x32_bf16(pa, v0, Oa0, 0, 0, 0);
      Oa1 = __builtin_amdgcn_mfma_f32_16x16x32_bf16(pa, v1, Oa1, 0, 0, 0);
    }
  }

  // epilogue: O/l, scatter per D-layout (row = lg*4+r, col = lr)
#pragma unroll
  for (int r = 0; r < 4; ++r) {
    float inv = 1.f / l4[r];
    int qrow = q0 + wid * 16 + lg * 4 + r;
    float* op = ao + ((size_t)b * LROW + qrow) * CD + h * 32;
    op[lr] = Oa0[r] * inv;
    op[16 + lr] = Oa1[r] * inv;
  }
}

__global__ void tail_kernel(const int* __restrict__ Hp, const int* __restrict__ Wp,
                            float* __restrict__ o) {
  o[0] = (float)Hp[0];
  o[1] = (float)Wp[0];
}

extern "C" void kernel_launch(void* const* d_in, const int* in_sizes, int n_in,
                              void* d_out, int out_size, void* d_ws, size_t ws_size,
                              hipStream_t stream) {
  const float* x      = (const float*)d_in[0];
  const int*   Hp     = (const int*)d_in[1];
  const int*   Wp     = (const int*)d_in[2];
  const float* n1s    = (const float*)d_in[3];
  const float* n1b    = (const float*)d_in[4];
  const float* qkv_w  = (const float*)d_in[5];
  const float* qkv_b  = (const float*)d_in[6];
  const float* proj_w = (const float*)d_in[7];
  const float* proj_b = (const float*)d_in[8];
  const float* ln1s   = (const float*)d_in[9];
  const float* ln1b   = (const float*)d_in[10];
  const float* qkv2_w = (const float*)d_in[11];
  const float* qkv2_b = (const float*)d_in[12];
  const float* out_w  = (const float*)d_in[13];
  const float* out_b  = (const float*)d_in[14];
  const float* ln2s   = (const float*)d_in[15];
  const float* ln2b   = (const float*)d_in[16];
  const float* fc1_w  = (const float*)d_in[17];
  const float* fc1_b  = (const float*)d_in[18];
  const float* fc2_w  = (const float*)d_in[19];
  const float* fc2_b  = (const float*)d_in[20];

  float* wsf = (float*)d_ws;
  const size_t U = (size_t)4 * LROW * CD;  // 1,204,224
  float* buf_h   = wsf;                    // LN outs; later flash ao
  float* buf_x1  = wsf + U;                // x after window attn (residual)
  short* qb      = (short*)(wsf + 2 * U);  // bf16 q [bh][n][32], pre-scaled
  short* kb      = qb + U;                 // bf16 k [bh][n][32]
  short* vtb     = kb + U;                 // bf16 v^T [bh][32][n]
  float* buf_ao  = wsf;                    // reuse buf_h
  float* buf_x2  = wsf + 2 * U;            // reuse qkv region (dead after flash)
  float* buf_z   = wsf + 3 * U;
  float* buf_t   = wsf + 4 * U;            // 4U: fc1 out (12544 x 384)
  float* outx    = (float*)d_out;

  const int M = 4 * LROW;  // 12544 rows

  ln_kernel<<<M / 4, 256, 0, stream>>>(x, n1s, n1b, buf_h, M);
  win_attn_kernel<<<256, 256, 0, stream>>>(buf_h, x, qkv_w, qkv_b, proj_w, proj_b, buf_x1);
  ln_kernel<<<M / 4, 256, 0, stream>>>(buf_x1, ln1s, ln1b, buf_h, M);
  gemm_qkv_kernel<<<dim3(M / 64, 3), 256, 0, stream>>>(buf_h, qkv2_w, qkv2_b, qb, kb, vtb);
  flash_mfma_kernel<<<dim3(LROW / 32, 12), 128, 0, stream>>>(qb, kb, vtb, buf_ao);
  gemm_kernel<1><<<dim3(M / 64, 1), 256, 0, stream>>>(buf_ao, out_w, out_b, buf_x1, buf_x2, M, 96, 96);
  ln_kernel<<<M / 4, 256, 0, stream>>>(buf_x2, ln2s, ln2b, buf_z, M);
  gemm_kernel<2><<<dim3(M / 64, 4), 256, 0, stream>>>(buf_z, fc1_w, fc1_b, nullptr, buf_t, M, 96, 384);
  gemm_kernel<1><<<dim3(M / 64, 1), 256, 0, stream>>>(buf_t, fc2_w, fc2_b, buf_x2, outx, M, 384, 96);
  tail_kernel<<<1, 1, 0, stream>>>(Hp, Wp, outx + U);
}

// Round 4
// 378.570 us; speedup vs baseline: 1.7670x; 1.0427x over previous
//
#include <hip/hip_runtime.h>
#include <hip/hip_bf16.h>

#define CD 96
#define LROW 3136          // 56*56
#define QSCALE 0.17677669529663687f  // 1/sqrt(32)
#define LOG2E 1.4426950408889634f

using f32x4 = __attribute__((ext_vector_type(4))) float;
using bf8   = __attribute__((ext_vector_type(8))) short;

__device__ __forceinline__ float bflo(unsigned u) { return __uint_as_float(u << 16); }
__device__ __forceinline__ float bfhi(unsigned u) { return __uint_as_float(u & 0xffff0000u); }
__device__ __forceinline__ short f2bf(float f) {
  union { float f; unsigned u; } v; v.f = f;
  unsigned r = v.u + 0x7fffu + ((v.u >> 16) & 1u);
  return (short)(r >> 16);
}
// pack two f32 into 2 bf16 (truncation; P in [0,1], feeds l-normalized PV)
__device__ __forceinline__ unsigned pack_bf2(float lo, float hi) {
  return (__float_as_uint(hi) & 0xffff0000u) | (__float_as_uint(lo) >> 16);
}

// ---------------- LayerNorm (one wave per 96-col row) ----------------
__global__ __launch_bounds__(256) void ln_kernel(const float* __restrict__ x,
                                                 const float* __restrict__ g,
                                                 const float* __restrict__ b,
                                                 float* __restrict__ out, int rows) {
  int wid = threadIdx.x >> 6, lane = threadIdx.x & 63;
  int row = (blockIdx.x << 2) + wid;
  if (row >= rows) return;
  const float* xr = x + (size_t)row * CD;
  float v0 = xr[lane];
  float v1 = (lane < 32) ? xr[64 + lane] : 0.f;
  float s = v0 + v1;
#pragma unroll
  for (int off = 32; off >= 1; off >>= 1) s += __shfl_xor(s, off);
  float mu = s * (1.f / 96.f);
  float d0 = v0 - mu;
  float d1 = (lane < 32) ? v1 - mu : 0.f;
  float q = d0 * d0 + d1 * d1;
#pragma unroll
  for (int off = 32; off >= 1; off >>= 1) q += __shfl_xor(q, off);
  float rstd = rsqrtf(q * (1.f / 96.f) + 1e-6f);
  float* orow = out + (size_t)row * CD;
  orow[lane] = d0 * rstd * g[lane] + b[lane];
  if (lane < 32) orow[64 + lane] = d1 * rstd * g[64 + lane] + b[64 + lane];
}

// ---------------- fused shifted-window attention: one block per window ----------------
__global__ __launch_bounds__(256) void win_attn_kernel(
    const float* __restrict__ hsrc, const float* __restrict__ xin,
    const float* __restrict__ qkv_w, const float* __restrict__ qkv_b,
    const float* __restrict__ proj_w, const float* __restrict__ proj_b,
    float* __restrict__ x1) {
  __shared__ __align__(16) __hip_bfloat16 xw[49][96];
  __shared__ __align__(16) float qh[49][36];
  __shared__ __align__(16) float kh[49][36];
  __shared__ __align__(16) float vh[49][36];
  __shared__ __align__(16) float S[49][49];
  __shared__ __align__(16) float outw[49][100];
  __shared__ int cnt[49];
  __shared__ int gidx[49];

  int tid = threadIdx.x;
  int b = blockIdx.x >> 6, w64 = blockIdx.x & 63;
  int wr = w64 >> 3, wc = w64 & 7;

  if (tid < 49) {
    int i = tid / 7, j = tid % 7;
    int sh = wr * 7 + i, sw = wc * 7 + j;             // coords in shifted/mask image
    int hr = (sh < 49) ? 0 : ((sh < 53) ? 1 : 2);     // region thresholds: 56-7, 56-3
    int wreg = (sw < 49) ? 0 : ((sw < 53) ? 1 : 2);
    cnt[tid] = hr * 3 + wreg;
    gidx[tid] = ((sh + 3) % 56) * 56 + ((sw + 3) % 56);  // roll(-3) load == roll(+3) store
  }
  __syncthreads();

  for (int idx = tid; idx < 49 * 96; idx += 256) {
    int p = idx / 96, c = idx % 96;
    xw[p][c] = __float2bfloat16(hsrc[((size_t)b * LROW + gidx[p]) * CD + c]);
  }
  __syncthreads();

  int dd = tid & 31, pg = tid >> 5;  // 32 dims x 8 row-groups

  for (int hh = 0; hh < 3; ++hh) {
    // ---- qkv for this head: thread owns col dd, rows pg+8i (weights reused across rows) ----
    {
      float aq[7], ak[7], av[7];
#pragma unroll
      for (int i = 0; i < 7; ++i) { aq[i] = 0.f; ak[i] = 0.f; av[i] = 0.f; }
      for (int k0 = 0; k0 < 96; k0 += 8) {
        float xf[7][8];
#pragma unroll
        for (int i = 0; i < 7; ++i) {
          int p = pg + 8 * i;
          if (p < 49) {
            uint4 u = *reinterpret_cast<const uint4*>(&xw[p][k0]);
            xf[i][0] = bflo(u.x); xf[i][1] = bfhi(u.x);
            xf[i][2] = bflo(u.y); xf[i][3] = bfhi(u.y);
            xf[i][4] = bflo(u.z); xf[i][5] = bfhi(u.z);
            xf[i][6] = bflo(u.w); xf[i][7] = bfhi(u.w);
          } else {
#pragma unroll
            for (int kq = 0; kq < 8; ++kq) xf[i][kq] = 0.f;
          }
        }
#pragma unroll
        for (int kq = 0; kq < 8; ++kq) {
          const float* wrow = qkv_w + (size_t)(k0 + kq) * 288 + hh * 32 + dd;
          float wq = wrow[0], wk = wrow[96], wv = wrow[192];
#pragma unroll
          for (int i = 0; i < 7; ++i) {
            aq[i] += xf[i][kq] * wq;
            ak[i] += xf[i][kq] * wk;
            av[i] += xf[i][kq] * wv;
          }
        }
      }
      float bq = qkv_b[hh * 32 + dd];
      float bk = qkv_b[96 + hh * 32 + dd];
      float bv = qkv_b[192 + hh * 32 + dd];
#pragma unroll
      for (int i = 0; i < 7; ++i) {
        int p = pg + 8 * i;
        if (p < 49) {
          qh[p][dd] = (aq[i] + bq) * QSCALE;
          kh[p][dd] = ak[i] + bk;
          vh[p][dd] = av[i] + bv;
        }
      }
    }
    __syncthreads();
    // ---- S = qk^T + mask (196 threads: row i, j strided by 4) ----
    if (tid < 196) {
      int i = tid >> 2, jq = tid & 3;
      float qr[32];
      const float4* q4 = reinterpret_cast<const float4*>(&qh[i][0]);
#pragma unroll
      for (int dq = 0; dq < 8; ++dq) {
        float4 t = q4[dq];
        qr[dq * 4 + 0] = t.x; qr[dq * 4 + 1] = t.y;
        qr[dq * 4 + 2] = t.z; qr[dq * 4 + 3] = t.w;
      }
      int ci = cnt[i];
      for (int j = jq; j < 49; j += 4) {
        const float4* k4 = reinterpret_cast<const float4*>(&kh[j][0]);
        float s = 0.f;
#pragma unroll
        for (int dq = 0; dq < 8; ++dq) {
          float4 kv = k4[dq];
          s += qr[dq*4+0]*kv.x + qr[dq*4+1]*kv.y + qr[dq*4+2]*kv.z + qr[dq*4+3]*kv.w;
        }
        S[i][j] = s + ((ci == cnt[j]) ? 0.f : -100.f);
      }
    }
    __syncthreads();
    // ---- row softmax (49 rows, 1 thread each; tiny) ----
    if (tid < 49) {
      float mx = -1e30f;
      for (int j = 0; j < 49; ++j) mx = fmaxf(mx, S[tid][j]);
      float sum = 0.f;
      for (int j = 0; j < 49; ++j) { float p = __expf(S[tid][j] - mx); S[tid][j] = p; sum += p; }
      float inv = 1.f / sum;
      for (int j = 0; j < 49; ++j) S[tid][j] *= inv;
    }
    __syncthreads();
    // ---- PV: thread owns (p, 4 dims) ----
    for (int slot = tid; slot < 392; slot += 256) {
      int p = slot >> 3, d4 = (slot & 7) * 4;
      float a0 = 0.f, a1 = 0.f, a2 = 0.f, a3 = 0.f;
      for (int j = 0; j < 49; ++j) {
        float pp = S[p][j];
        float4 vv = *reinterpret_cast<const float4*>(&vh[j][d4]);
        a0 += pp * vv.x; a1 += pp * vv.y; a2 += pp * vv.z; a3 += pp * vv.w;
      }
      float* op = &outw[p][hh * 32 + d4];
      op[0] = a0; op[1] = a1; op[2] = a2; op[3] = a3;
    }
    __syncthreads();
  }
  // ---- proj + shortcut + unshift scatter ----
  for (int slot = tid; slot < 1176; slot += 256) {
    int p = slot / 24, c4 = (slot % 24) * 4;
    float a0 = 0.f, a1 = 0.f, a2 = 0.f, a3 = 0.f;
    for (int k0 = 0; k0 < 96; k0 += 4) {
      float4 ow = *reinterpret_cast<const float4*>(&outw[p][k0]);
      const float* w0 = proj_w + (size_t)k0 * 96 + c4;
      float4 wa = *reinterpret_cast<const float4*>(w0);
      float4 wb = *reinterpret_cast<const float4*>(w0 + 96);
      float4 wc2 = *reinterpret_cast<const float4*>(w0 + 192);
      float4 wd = *reinterpret_cast<const float4*>(w0 + 288);
      a0 += ow.x*wa.x + ow.y*wb.x + ow.z*wc2.x + ow.w*wd.x;
      a1 += ow.x*wa.y + ow.y*wb.y + ow.z*wc2.y + ow.w*wd.y;
      a2 += ow.x*wa.z + ow.y*wb.z + ow.z*wc2.z + ow.w*wd.z;
      a3 += ow.x*wa.w + ow.y*wb.w + ow.z*wc2.w + ow.w*wd.w;
    }
    size_t rowo = ((size_t)b * LROW + gidx[p]) * CD + c4;
    float4 sc = *reinterpret_cast<const float4*>(&xin[rowo]);
    float4 pb = *reinterpret_cast<const float4*>(&proj_b[c4]);
    float4 res;
    res.x = a0 + pb.x + sc.x; res.y = a1 + pb.y + sc.y;
    res.z = a2 + pb.z + sc.z; res.w = a3 + pb.w + sc.w;
    *reinterpret_cast<float4*>(&x1[rowo]) = res;
  }
}

// ---------------- generic skinny GEMM: out = f(A@B + bias [+res]) ----------------
// MODE 0: plain, 1: +res, 2: gelu(tanh approx)
template <int MODE>
__global__ __launch_bounds__(256) void gemm_kernel(
    const float* __restrict__ A, const float* __restrict__ B,
    const float* __restrict__ bias, const float* __restrict__ res,
    float* __restrict__ out, int M, int K, int N) {
  __shared__ __align__(16) float As_t[32][68];  // transposed A tile (k-major)
  __shared__ __align__(16) float Bs[32][98];
  int tid = threadIdx.x;
  int m0 = blockIdx.x * 64, n0 = blockIdx.y * 96;
  int tr = tid >> 4, tc = tid & 15;
  float acc[4][6];
#pragma unroll
  for (int i = 0; i < 4; ++i)
#pragma unroll
    for (int j = 0; j < 6; ++j) acc[i][j] = 0.f;
  for (int k0 = 0; k0 < K; k0 += 32) {
    for (int idx = tid; idx < 2048; idx += 256) {
      int r = idx >> 5, c = idx & 31;
      As_t[c][r] = A[(size_t)(m0 + r) * K + k0 + c];
    }
    for (int idx = tid; idx < 3072; idx += 256) {
      int r = idx / 96, c = idx % 96;
      Bs[r][c] = B[(size_t)(k0 + r) * N + n0 + c];
    }
    __syncthreads();
#pragma unroll 8
    for (int kk = 0; kk < 32; ++kk) {
      float4 av = *reinterpret_cast<const float4*>(&As_t[kk][tr * 4]);
      float2 b0 = *reinterpret_cast<const float2*>(&Bs[kk][tc * 6]);
      float2 b1 = *reinterpret_cast<const float2*>(&Bs[kk][tc * 6 + 2]);
      float2 b2 = *reinterpret_cast<const float2*>(&Bs[kk][tc * 6 + 4]);
      float aa[4] = {av.x, av.y, av.z, av.w};
      float bb[6] = {b0.x, b0.y, b1.x, b1.y, b2.x, b2.y};
#pragma unroll
      for (int i = 0; i < 4; ++i)
#pragma unroll
        for (int j = 0; j < 6; ++j) acc[i][j] += aa[i] * bb[j];
    }
    __syncthreads();
  }
#pragma unroll
  for (int i = 0; i < 4; ++i) {
    int m = m0 + tr * 4 + i;
#pragma unroll
    for (int j = 0; j < 6; ++j) {
      int n = n0 + tc * 6 + j;
      float v = acc[i][j] + bias[n];
      if (MODE == 1) v += res[(size_t)m * N + n];
      if (MODE == 2) {
        float u = v;
        float t = tanhf(0.7978845608028654f * (u + 0.044715f * u * u * u));
        v = 0.5f * u * (1.f + t);
      }
      out[(size_t)m * N + n] = v;
    }
  }
}

// ---------------- qkv GEMM: fp32 x fp32 -> bf16 q/k/v with flash-friendly layouts ----------------
// q: [bh][n][32] bf16, pre-scaled by QSCALE*LOG2E; k: [bh][n][32]; v: [bh][32][n] (transposed)
__global__ __launch_bounds__(256) void gemm_qkv_kernel(
    const float* __restrict__ A, const float* __restrict__ B,
    const float* __restrict__ bias,
    short* __restrict__ qb, short* __restrict__ kb, short* __restrict__ vtb) {
  __shared__ __align__(16) float As_t[32][68];
  __shared__ __align__(16) float Bs[32][98];
  int tid = threadIdx.x;
  int m0 = blockIdx.x * 64, n0 = blockIdx.y * 96;
  int tr = tid >> 4, tc = tid & 15;
  float acc[4][6];
#pragma unroll
  for (int i = 0; i < 4; ++i)
#pragma unroll
    for (int j = 0; j < 6; ++j) acc[i][j] = 0.f;
  for (int k0 = 0; k0 < 96; k0 += 32) {
    for (int idx = tid; idx < 2048; idx += 256) {
      int r = idx >> 5, c = idx & 31;
      As_t[c][r] = A[(size_t)(m0 + r) * 96 + k0 + c];
    }
    for (int idx = tid; idx < 3072; idx += 256) {
      int r = idx / 96, c = idx % 96;
      Bs[r][c] = B[(size_t)(k0 + r) * 288 + n0 + c];
    }
    __syncthreads();
#pragma unroll 8
    for (int kk = 0; kk < 32; ++kk) {
      float4 av = *reinterpret_cast<const float4*>(&As_t[kk][tr * 4]);
      float2 b0 = *reinterpret_cast<const float2*>(&Bs[kk][tc * 6]);
      float2 b1 = *reinterpret_cast<const float2*>(&Bs[kk][tc * 6 + 2]);
      float2 b2 = *reinterpret_cast<const float2*>(&Bs[kk][tc * 6 + 4]);
      float aa[4] = {av.x, av.y, av.z, av.w};
      float bb[6] = {b0.x, b0.y, b1.x, b1.y, b2.x, b2.y};
#pragma unroll
      for (int i = 0; i < 4; ++i)
#pragma unroll
        for (int j = 0; j < 6; ++j) acc[i][j] += aa[i] * bb[j];
    }
    __syncthreads();
  }
  int sec = n0 / 96;  // 0=q, 1=k, 2=v (uniform per block)
#pragma unroll
  for (int i = 0; i < 4; ++i) {
    int m = m0 + tr * 4 + i;
    int bb2 = m / LROW, nn = m % LROW;
#pragma unroll
    for (int j = 0; j < 6; ++j) {
      int hd_ = tc * 6 + j;            // 0..95
      int hh = hd_ >> 5, dd2 = hd_ & 31;
      float v = acc[i][j] + bias[n0 + hd_];
      size_t bh = (size_t)bb2 * 3 + hh;
      if (sec == 0)      qb[(bh * LROW + nn) * 32 + dd2] = f2bf(v * (QSCALE * LOG2E));
      else if (sec == 1) kb[(bh * LROW + nn) * 32 + dd2] = f2bf(v);
      else               vtb[(bh * 32 + dd2) * LROW + nn] = f2bf(v);
    }
  }
}

// ---------------- MFMA flash attention, swapped-operand form ----------------
// one block = 32 q-rows of one (b,h); 2 waves x 16 q-rows. KV tiles of 64.
// S^T = mfma(K, Q): lane holds 16 kv-values for q = lane&15 -> in-lane softmax.
// O^T = mfma(V^T, P^T): alpha/l are per-lane scalars.
__global__ __launch_bounds__(128) void flash_mfma_kernel(
    const short* __restrict__ qb, const short* __restrict__ kb,
    const short* __restrict__ vtb, float* __restrict__ ao) {
  __shared__ __align__(16) short Ks[64][40];      // K tile [kv][d], 80B rows
  __shared__ __align__(16) short Vt[32][80];      // V^T tile [d][kv], 160B rows
  __shared__ __align__(16) short Pt[2][16][80];   // per-wave P tile [q][kv], 160B rows
  int tid = threadIdx.x;
  int lane = tid & 63, wid = tid >> 6;
  int q0 = blockIdx.x * 32;
  int bh = blockIdx.y;
  int b = bh / 3, h = bh % 3;
  const short* qbb = qb + (size_t)bh * LROW * 32;
  const short* kbb = kb + (size_t)bh * LROW * 32;
  const short* vbb = vtb + (size_t)bh * 32 * LROW;

  int lr = lane & 15, lg = lane >> 4;

  // Q B-fragment: col = lr (q), k = 8*lg + i (pre-scaled bf16, direct 16B load)
  bf8 qf = *reinterpret_cast<const bf8*>(qbb + (size_t)(q0 + wid * 16 + lr) * 32 + lg * 8);

  f32x4 Oa0 = {0.f, 0.f, 0.f, 0.f}, Oa1 = {0.f, 0.f, 0.f, 0.f};  // O^T: d=lg*4+r (+0/+16), q=lr
  float m = -1e30f, l = 0.f;  // per-lane softmax state for q = lr

  for (int kt = 0; kt < 49; ++kt) {
    __syncthreads();  // previous iter's MFMA reads done
#pragma unroll
    for (int p = 0; p < 2; ++p) {
      int idx = tid + p * 128;
      int rr = idx >> 2, c = idx & 3;
      uint4 ku = *reinterpret_cast<const uint4*>(kbb + (size_t)(kt * 64 + rr) * 32 + c * 8);
      *reinterpret_cast<uint4*>(&Ks[rr][c * 8]) = ku;
      int d = idx >> 3, c2 = idx & 7;
      uint4 vu = *reinterpret_cast<const uint4*>(vbb + (size_t)d * LROW + kt * 64 + c2 * 8);
      *reinterpret_cast<uint4*>(&Vt[d][c2 * 8]) = vu;
    }
    __syncthreads();

    // S^T: 4 kv-subtiles; rows = kv (t*16 + lg*4 + r), cols = q (lr)
    f32x4 St[4];
#pragma unroll
    for (int t = 0; t < 4; ++t) {
      bf8 kf = *reinterpret_cast<const bf8*>(&Ks[t * 16 + lr][8 * lg]);
      f32x4 z = {0.f, 0.f, 0.f, 0.f};
      St[t] = __builtin_amdgcn_mfma_f32_16x16x32_bf16(kf, qf, z, 0, 0, 0);
    }

    // in-lane max over 16 kv values, then 2 shfl across lg groups
    float px = St[0][0];
#pragma unroll
    for (int t = 0; t < 4; ++t)
#pragma unroll
      for (int r = 0; r < 4; ++r) px = fmaxf(px, St[t][r]);
    px = fmaxf(px, __shfl_xor(px, 16));
    px = fmaxf(px, __shfl_xor(px, 32));
    float mn = fmaxf(m, px);
    float al = exp2f(m - mn);
    m = mn;
    float rs = 0.f;
#pragma unroll
    for (int t = 0; t < 4; ++t)
#pragma unroll
      for (int r = 0; r < 4; ++r) {
        float p = exp2f(St[t][r] - mn);
        St[t][r] = p;
        rs += p;
      }
    rs += __shfl_xor(rs, 16);
    rs += __shfl_xor(rs, 32);
    l = l * al + rs;

    // P^T -> bf16 (truncate) -> 4 x ds_write_b64: lane owns kv = t*16+lg*4+{0..3} at q=lr
#pragma unroll
    for (int t = 0; t < 4; ++t) {
      uint2 w;
      w.x = pack_bf2(St[t][0], St[t][1]);
      w.y = pack_bf2(St[t][2], St[t][3]);
      *reinterpret_cast<uint2*>(&Pt[wid][lr][t * 16 + lg * 4]) = w;
    }

#pragma unroll
    for (int r = 0; r < 4; ++r) { Oa0[r] *= al; Oa1[r] *= al; }

    // O^T += V^T x P^T  (A = V^T rows d, B = P^T cols q; same-wave P produce/consume)
#pragma unroll
    for (int c = 0; c < 2; ++c) {
      bf8 pbf = *reinterpret_cast<const bf8*>(&Pt[wid][lr][c * 32 + 8 * lg]);
      bf8 v0 = *reinterpret_cast<const bf8*>(&Vt[lr][c * 32 + 8 * lg]);
      bf8 v1 = *reinterpret_cast<const bf8*>(&Vt[16 + lr][c * 32 + 8 * lg]);
      Oa0 = __builtin_amdgcn_mfma_f32_16x16x32_bf16(v0, pbf, Oa0, 0, 0, 0);
      Oa1 = __builtin_amdgcn_mfma_f32_16x16x32_bf16(v1, pbf, Oa1, 0, 0, 0);
    }
  }

  // epilogue: O = O^T / l; lane writes d = lg*4+r (+0/+16) of row q = lr
  float inv = 1.f / l;
  int qrow = q0 + wid * 16 + lr;
  float* op = ao + ((size_t)b * LROW + qrow) * CD + h * 32;
#pragma unroll
  for (int r = 0; r < 4; ++r) {
    op[lg * 4 + r] = Oa0[r] * inv;
    op[16 + lg * 4 + r] = Oa1[r] * inv;
  }
}

__global__ void tail_kernel(const int* __restrict__ Hp, const int* __restrict__ Wp,
                            float* __restrict__ o) {
  o[0] = (float)Hp[0];
  o[1] = (float)Wp[0];
}

extern "C" void kernel_launch(void* const* d_in, const int* in_sizes, int n_in,
                              void* d_out, int out_size, void* d_ws, size_t ws_size,
                              hipStream_t stream) {
  const float* x      = (const float*)d_in[0];
  const int*   Hp     = (const int*)d_in[1];
  const int*   Wp     = (const int*)d_in[2];
  const float* n1s    = (const float*)d_in[3];
  const float* n1b    = (const float*)d_in[4];
  const float* qkv_w  = (const float*)d_in[5];
  const float* qkv_b  = (const float*)d_in[6];
  const float* proj_w = (const float*)d_in[7];
  const float* proj_b = (const float*)d_in[8];
  const float* ln1s   = (const float*)d_in[9];
  const float* ln1b   = (const float*)d_in[10];
  const float* qkv2_w = (const float*)d_in[11];
  const float* qkv2_b = (const float*)d_in[12];
  const float* out_w  = (const float*)d_in[13];
  const float* out_b  = (const float*)d_in[14];
  const float* ln2s   = (const float*)d_in[15];
  const float* ln2b   = (const float*)d_in[16];
  const float* fc1_w  = (const float*)d_in[17];
  const float* fc1_b  = (const float*)d_in[18];
  const float* fc2_w  = (const float*)d_in[19];
  const float* fc2_b  = (const float*)d_in[20];

  float* wsf = (float*)d_ws;
  const size_t U = (size_t)4 * LROW * CD;  // 1,204,224
  float* buf_h   = wsf;                    // LN outs; later flash ao
  float* buf_x1  = wsf + U;                // x after window attn (residual)
  short* qb      = (short*)(wsf + 2 * U);  // bf16 q [bh][n][32], pre-scaled
  short* kb      = qb + U;                 // bf16 k [bh][n][32]
  short* vtb     = kb + U;                 // bf16 v^T [bh][32][n]
  float* buf_ao  = wsf;                    // reuse buf_h
  float* buf_x2  = wsf + 2 * U;            // reuse qkv region (dead after flash)
  float* buf_z   = wsf + 3 * U;
  float* buf_t   = wsf + 4 * U;            // 4U: fc1 out (12544 x 384)
  float* outx    = (float*)d_out;

  const int M = 4 * LROW;  // 12544 rows

  ln_kernel<<<M / 4, 256, 0, stream>>>(x, n1s, n1b, buf_h, M);
  win_attn_kernel<<<256, 256, 0, stream>>>(buf_h, x, qkv_w, qkv_b, proj_w, proj_b, buf_x1);
  ln_kernel<<<M / 4, 256, 0, stream>>>(buf_x1, ln1s, ln1b, buf_h, M);
  gemm_qkv_kernel<<<dim3(M / 64, 3), 256, 0, stream>>>(buf_h, qkv2_w, qkv2_b, qb, kb, vtb);
  flash_mfma_kernel<<<dim3(LROW / 32, 12), 128, 0, stream>>>(qb, kb, vtb, buf_ao);
  gemm_kernel<1><<<dim3(M / 64, 1), 256, 0, stream>>>(buf_ao, out_w, out_b, buf_x1, buf_x2, M, 96, 96);
  ln_kernel<<<M / 4, 256, 0, stream>>>(buf_x2, ln2s, ln2b, buf_z, M);
  gemm_kernel<2><<<dim3(M / 64, 4), 256, 0, stream>>>(buf_z, fc1_w, fc1_b, nullptr, buf_t, M, 96, 384);
  gemm_kernel<1><<<dim3(M / 64, 1), 256, 0, stream>>>(buf_t, fc2_w, fc2_b, buf_x2, outx, M, 384, 96);
  tail_kernel<<<1, 1, 0, stream>>>(Hp, Wp, outx + U);
}

// Round 5
// 226.488 us; speedup vs baseline: 2.9535x; 1.6715x over previous
//
#include <hip/hip_runtime.h>
#include <hip/hip_bf16.h>

#define CD 96
#define LROW 3136          // 56*56
#define QSCALE 0.17677669529663687f  // 1/sqrt(32)
#define LOG2E 1.4426950408889634f

using f32x4 = __attribute__((ext_vector_type(4))) float;
using bf8   = __attribute__((ext_vector_type(8))) short;

__device__ __forceinline__ float bflo(unsigned u) { return __uint_as_float(u << 16); }
__device__ __forceinline__ float bfhi(unsigned u) { return __uint_as_float(u & 0xffff0000u); }
__device__ __forceinline__ short f2bf(float f) {
  union { float f; unsigned u; } v; v.f = f;
  unsigned r = v.u + 0x7fffu + ((v.u >> 16) & 1u);
  return (short)(r >> 16);
}
// truncating pack (internal P values in [0,1])
__device__ __forceinline__ unsigned pack_bf2(float lo, float hi) {
  return (__float_as_uint(hi) & 0xffff0000u) | (__float_as_uint(lo) >> 16);
}
// rounding pack (for stored outputs)
__device__ __forceinline__ unsigned pack_bf2r(float lo, float hi) {
  return ((unsigned)(unsigned short)f2bf(hi) << 16) | (unsigned short)f2bf(lo);
}

#define GLOAD_LDS16(src, dst) \
  __builtin_amdgcn_global_load_lds((const __attribute__((address_space(1))) void*)(src), \
                                   (__attribute__((address_space(3))) void*)(dst), 16, 0, 0)

// ---------------- LayerNorm (one wave per 96-col row) -> bf16 out ----------------
__global__ __launch_bounds__(256) void ln_kernel(const float* __restrict__ x,
                                                 const float* __restrict__ g,
                                                 const float* __restrict__ b,
                                                 short* __restrict__ out, int rows) {
  int wid = threadIdx.x >> 6, lane = threadIdx.x & 63;
  int row = (blockIdx.x << 2) + wid;
  if (row >= rows) return;
  const float* xr = x + (size_t)row * CD;
  float v0 = xr[lane];
  float v1 = (lane < 32) ? xr[64 + lane] : 0.f;
  float s = v0 + v1;
#pragma unroll
  for (int off = 32; off >= 1; off >>= 1) s += __shfl_xor(s, off);
  float mu = s * (1.f / 96.f);
  float d0 = v0 - mu;
  float d1 = (lane < 32) ? v1 - mu : 0.f;
  float q = d0 * d0 + d1 * d1;
#pragma unroll
  for (int off = 32; off >= 1; off >>= 1) q += __shfl_xor(q, off);
  float rstd = rsqrtf(q * (1.f / 96.f) + 1e-6f);
  short* orow = out + (size_t)row * CD;
  orow[lane] = f2bf(d0 * rstd * g[lane] + b[lane]);
  if (lane < 32) orow[64 + lane] = f2bf(d1 * rstd * g[64 + lane] + b[64 + lane]);
}

// ---------------- weight convert: Wt[Npad][K] bf16 = W[K][N]^T (zero-padded) ----------------
__global__ __launch_bounds__(256) void cvt_wt_kernel(const float* __restrict__ W,
                                                     short* __restrict__ Wt,
                                                     int K, int N, int Npad) {
  int idx = blockIdx.x * 256 + threadIdx.x;
  if (idx >= Npad * K) return;
  int nr = idx / K, kk = idx - nr * K;
  float v = (nr < N) ? W[(size_t)kk * N + nr] : 0.f;
  Wt[idx] = f2bf(v);
}

// ---------------- fused shifted-window attention: one block per window ----------------
__global__ __launch_bounds__(256) void win_attn_kernel(
    const __hip_bfloat16* __restrict__ hsrc, const float* __restrict__ xin,
    const float* __restrict__ qkv_w, const float* __restrict__ qkv_b,
    const float* __restrict__ proj_w, const float* __restrict__ proj_b,
    float* __restrict__ x1) {
  __shared__ __align__(16) __hip_bfloat16 xw[49][96];
  __shared__ __align__(16) float qh[49][36];
  __shared__ __align__(16) float kh[49][36];
  __shared__ __align__(16) float vh[49][36];
  __shared__ __align__(16) float S[49][49];
  __shared__ __align__(16) float outw[49][100];
  __shared__ int cnt[49];
  __shared__ int gidx[49];

  int tid = threadIdx.x;
  int b = blockIdx.x >> 6, w64 = blockIdx.x & 63;
  int wr = w64 >> 3, wc = w64 & 7;

  if (tid < 49) {
    int i = tid / 7, j = tid % 7;
    int sh = wr * 7 + i, sw = wc * 7 + j;
    int hr = (sh < 49) ? 0 : ((sh < 53) ? 1 : 2);
    int wreg = (sw < 49) ? 0 : ((sw < 53) ? 1 : 2);
    cnt[tid] = hr * 3 + wreg;
    gidx[tid] = ((sh + 3) % 56) * 56 + ((sw + 3) % 56);
  }
  __syncthreads();

  for (int idx = tid; idx < 49 * 96; idx += 256) {
    int p = idx / 96, c = idx % 96;
    xw[p][c] = hsrc[((size_t)b * LROW + gidx[p]) * CD + c];
  }
  __syncthreads();

  int dd = tid & 31, pg = tid >> 5;

  for (int hh = 0; hh < 3; ++hh) {
    {
      float aq[7], ak[7], av[7];
#pragma unroll
      for (int i = 0; i < 7; ++i) { aq[i] = 0.f; ak[i] = 0.f; av[i] = 0.f; }
      for (int k0 = 0; k0 < 96; k0 += 8) {
        float xf[7][8];
#pragma unroll
        for (int i = 0; i < 7; ++i) {
          int p = pg + 8 * i;
          if (p < 49) {
            uint4 u = *reinterpret_cast<const uint4*>(&xw[p][k0]);
            xf[i][0] = bflo(u.x); xf[i][1] = bfhi(u.x);
            xf[i][2] = bflo(u.y); xf[i][3] = bfhi(u.y);
            xf[i][4] = bflo(u.z); xf[i][5] = bfhi(u.z);
            xf[i][6] = bflo(u.w); xf[i][7] = bfhi(u.w);
          } else {
#pragma unroll
            for (int kq = 0; kq < 8; ++kq) xf[i][kq] = 0.f;
          }
        }
#pragma unroll
        for (int kq = 0; kq < 8; ++kq) {
          const float* wrow = qkv_w + (size_t)(k0 + kq) * 288 + hh * 32 + dd;
          float wq = wrow[0], wk = wrow[96], wv = wrow[192];
#pragma unroll
          for (int i = 0; i < 7; ++i) {
            aq[i] += xf[i][kq] * wq;
            ak[i] += xf[i][kq] * wk;
            av[i] += xf[i][kq] * wv;
          }
        }
      }
      float bq = qkv_b[hh * 32 + dd];
      float bk = qkv_b[96 + hh * 32 + dd];
      float bv = qkv_b[192 + hh * 32 + dd];
#pragma unroll
      for (int i = 0; i < 7; ++i) {
        int p = pg + 8 * i;
        if (p < 49) {
          qh[p][dd] = (aq[i] + bq) * QSCALE;
          kh[p][dd] = ak[i] + bk;
          vh[p][dd] = av[i] + bv;
        }
      }
    }
    __syncthreads();
    if (tid < 196) {
      int i = tid >> 2, jq = tid & 3;
      float qr[32];
      const float4* q4 = reinterpret_cast<const float4*>(&qh[i][0]);
#pragma unroll
      for (int dq = 0; dq < 8; ++dq) {
        float4 t = q4[dq];
        qr[dq * 4 + 0] = t.x; qr[dq * 4 + 1] = t.y;
        qr[dq * 4 + 2] = t.z; qr[dq * 4 + 3] = t.w;
      }
      int ci = cnt[i];
      for (int j = jq; j < 49; j += 4) {
        const float4* k4 = reinterpret_cast<const float4*>(&kh[j][0]);
        float s = 0.f;
#pragma unroll
        for (int dq = 0; dq < 8; ++dq) {
          float4 kv = k4[dq];
          s += qr[dq*4+0]*kv.x + qr[dq*4+1]*kv.y + qr[dq*4+2]*kv.z + qr[dq*4+3]*kv.w;
        }
        S[i][j] = s + ((ci == cnt[j]) ? 0.f : -100.f);
      }
    }
    __syncthreads();
    if (tid < 49) {
      float mx = -1e30f;
      for (int j = 0; j < 49; ++j) mx = fmaxf(mx, S[tid][j]);
      float sum = 0.f;
      for (int j = 0; j < 49; ++j) { float p = __expf(S[tid][j] - mx); S[tid][j] = p; sum += p; }
      float inv = 1.f / sum;
      for (int j = 0; j < 49; ++j) S[tid][j] *= inv;
    }
    __syncthreads();
    for (int slot = tid; slot < 392; slot += 256) {
      int p = slot >> 3, d4 = (slot & 7) * 4;
      float a0 = 0.f, a1 = 0.f, a2 = 0.f, a3 = 0.f;
      for (int j = 0; j < 49; ++j) {
        float pp = S[p][j];
        float4 vv = *reinterpret_cast<const float4*>(&vh[j][d4]);
        a0 += pp * vv.x; a1 += pp * vv.y; a2 += pp * vv.z; a3 += pp * vv.w;
      }
      float* op = &outw[p][hh * 32 + d4];
      op[0] = a0; op[1] = a1; op[2] = a2; op[3] = a3;
    }
    __syncthreads();
  }
  for (int slot = tid; slot < 1176; slot += 256) {
    int p = slot / 24, c4 = (slot % 24) * 4;
    float a0 = 0.f, a1 = 0.f, a2 = 0.f, a3 = 0.f;
    for (int k0 = 0; k0 < 96; k0 += 4) {
      float4 ow = *reinterpret_cast<const float4*>(&outw[p][k0]);
      const float* w0 = proj_w + (size_t)k0 * 96 + c4;
      float4 wa = *reinterpret_cast<const float4*>(w0);
      float4 wb = *reinterpret_cast<const float4*>(w0 + 96);
      float4 wc2 = *reinterpret_cast<const float4*>(w0 + 192);
      float4 wd = *reinterpret_cast<const float4*>(w0 + 288);
      a0 += ow.x*wa.x + ow.y*wb.x + ow.z*wc2.x + ow.w*wd.x;
      a1 += ow.x*wa.y + ow.y*wb.y + ow.z*wc2.y + ow.w*wd.y;
      a2 += ow.x*wa.z + ow.y*wb.z + ow.z*wc2.z + ow.w*wd.z;
      a3 += ow.x*wa.w + ow.y*wb.w + ow.z*wc2.w + ow.w*wd.w;
    }
    size_t rowo = ((size_t)b * LROW + gidx[p]) * CD + c4;
    float4 sc = *reinterpret_cast<const float4*>(&xin[rowo]);
    float4 pb = *reinterpret_cast<const float4*>(&proj_b[c4]);
    float4 res;
    res.x = a0 + pb.x + sc.x; res.y = a1 + pb.y + sc.y;
    res.z = a2 + pb.z + sc.z; res.w = a3 + pb.w + sc.w;
    *reinterpret_cast<float4*>(&x1[rowo]) = res;
  }
}

// ---------------- bf16 MFMA GEMM: out = f(A[M][K] @ Wt[Npad][K]^T + bias [+res]) ----------------
// BM=128, BN=64, BK=32; 4 waves, wave owns 32 rows x 64 cols.
// MODE 0: gelu -> bf16 out; MODE 1: +res -> fp32 out.
template <int MODE>
__global__ __launch_bounds__(256) void gemm_mfma_kernel(
    const short* __restrict__ A, const short* __restrict__ Bt,
    const float* __restrict__ bias, const float* __restrict__ res,
    void* __restrict__ outp, int M, int K, int N) {
  __shared__ __align__(16) short As[2][128 * 32];
  __shared__ __align__(16) short Bs[2][64 * 32];
  int tid = threadIdx.x, lane = tid & 63, wid = tid >> 6;
  int lr = lane & 15, lg = lane >> 4;
  int m0 = blockIdx.x * 128, n0 = blockIdx.y * 64;
  int nk = K >> 5;

  f32x4 acc[2][4];
#pragma unroll
  for (int i = 0; i < 2; ++i)
#pragma unroll
    for (int j = 0; j < 4; ++j) acc[i][j] = (f32x4){0.f, 0.f, 0.f, 0.f};

  auto stage = [&](int bf, int ks) {
    int k0 = ks * 32;
#pragma unroll
    for (int p = 0; p < 2; ++p) {
      int idx = tid + p * 256;
      GLOAD_LDS16(A + (size_t)(m0 + (idx >> 2)) * K + k0 + (idx & 3) * 8,
                  &As[bf][idx * 8]);
    }
    GLOAD_LDS16(Bt + (size_t)(n0 + (tid >> 2)) * K + k0 + (tid & 3) * 8,
                &Bs[bf][tid * 8]);
  };

  stage(0, 0);
  __syncthreads();  // drains vmcnt
  int buf = 0;
  for (int ks = 0; ks < nk; ++ks) {
    if (ks + 1 < nk) stage(buf ^ 1, ks + 1);
    bf8 bfr[4], afr[2];
#pragma unroll
    for (int ni = 0; ni < 4; ++ni)
      bfr[ni] = *reinterpret_cast<const bf8*>(&Bs[buf][(ni * 16 + lr) * 32 + lg * 8]);
#pragma unroll
    for (int mi = 0; mi < 2; ++mi)
      afr[mi] = *reinterpret_cast<const bf8*>(&As[buf][(wid * 32 + mi * 16 + lr) * 32 + lg * 8]);
    __builtin_amdgcn_s_setprio(1);
#pragma unroll
    for (int mi = 0; mi < 2; ++mi)
#pragma unroll
      for (int ni = 0; ni < 4; ++ni)
        acc[mi][ni] = __builtin_amdgcn_mfma_f32_16x16x32_bf16(afr[mi], bfr[ni], acc[mi][ni], 0, 0, 0);
    __builtin_amdgcn_s_setprio(0);
    __syncthreads();
    buf ^= 1;
  }

#pragma unroll
  for (int mi = 0; mi < 2; ++mi)
#pragma unroll
    for (int ni = 0; ni < 4; ++ni)
#pragma unroll
      for (int r = 0; r < 4; ++r) {
        int mrow = m0 + wid * 32 + mi * 16 + lg * 4 + r;
        int n = n0 + ni * 16 + lr;
        if (n < N) {
          float v = acc[mi][ni][r] + bias[n];
          if (MODE == 0) {
            float t = tanhf(0.7978845608028654f * (v + 0.044715f * v * v * v));
            ((short*)outp)[(size_t)mrow * N + n] = f2bf(0.5f * v * (1.f + t));
          } else {
            v += res[(size_t)mrow * N + n];
            ((float*)outp)[(size_t)mrow * N + n] = v;
          }
        }
      }
}

// ---------------- qkv GEMM (bf16 MFMA) with flash-layout scatter epilogue ----------------
// A[M][96] bf16, Wt[320][96] bf16 (N=288 real). q pre-scaled by QSCALE*LOG2E.
__global__ __launch_bounds__(256) void qkv_mfma_kernel(
    const short* __restrict__ A, const short* __restrict__ Bt,
    const float* __restrict__ bias,
    short* __restrict__ qb, short* __restrict__ kb, short* __restrict__ vtb) {
  __shared__ __align__(16) short As[2][128 * 32];
  __shared__ __align__(16) short Bs[2][64 * 32];
  int tid = threadIdx.x, lane = tid & 63, wid = tid >> 6;
  int lr = lane & 15, lg = lane >> 4;
  int m0 = blockIdx.x * 128, n0 = blockIdx.y * 64;
  const int K = 96;

  f32x4 acc[2][4];
#pragma unroll
  for (int i = 0; i < 2; ++i)
#pragma unroll
    for (int j = 0; j < 4; ++j) acc[i][j] = (f32x4){0.f, 0.f, 0.f, 0.f};

  auto stage = [&](int bf, int ks) {
    int k0 = ks * 32;
#pragma unroll
    for (int p = 0; p < 2; ++p) {
      int idx = tid + p * 256;
      GLOAD_LDS16(A + (size_t)(m0 + (idx >> 2)) * K + k0 + (idx & 3) * 8,
                  &As[bf][idx * 8]);
    }
    GLOAD_LDS16(Bt + (size_t)(n0 + (tid >> 2)) * K + k0 + (tid & 3) * 8,
                &Bs[bf][tid * 8]);
  };

  stage(0, 0);
  __syncthreads();
  int buf = 0;
  for (int ks = 0; ks < 3; ++ks) {
    if (ks + 1 < 3) stage(buf ^ 1, ks + 1);
    bf8 bfr[4], afr[2];
#pragma unroll
    for (int ni = 0; ni < 4; ++ni)
      bfr[ni] = *reinterpret_cast<const bf8*>(&Bs[buf][(ni * 16 + lr) * 32 + lg * 8]);
#pragma unroll
    for (int mi = 0; mi < 2; ++mi)
      afr[mi] = *reinterpret_cast<const bf8*>(&As[buf][(wid * 32 + mi * 16 + lr) * 32 + lg * 8]);
    __builtin_amdgcn_s_setprio(1);
#pragma unroll
    for (int mi = 0; mi < 2; ++mi)
#pragma unroll
      for (int ni = 0; ni < 4; ++ni)
        acc[mi][ni] = __builtin_amdgcn_mfma_f32_16x16x32_bf16(afr[mi], bfr[ni], acc[mi][ni], 0, 0, 0);
    __builtin_amdgcn_s_setprio(0);
    __syncthreads();
    buf ^= 1;
  }

#pragma unroll
  for (int mi = 0; mi < 2; ++mi)
#pragma unroll
    for (int ni = 0; ni < 4; ++ni)
#pragma unroll
      for (int r = 0; r < 4; ++r) {
        int mrow = m0 + wid * 32 + mi * 16 + lg * 4 + r;
        int n = n0 + ni * 16 + lr;
        if (n < 288) {
          float v = acc[mi][ni][r] + bias[n];
          int sec = n / 96, within = n % 96;
          int hh = within >> 5, dd = within & 31;
          int bb = mrow / LROW, nn = mrow - bb * LROW;
          size_t bh = (size_t)bb * 3 + hh;
          if (sec == 0)      qb[(bh * LROW + nn) * 32 + dd] = f2bf(v * (QSCALE * LOG2E));
          else if (sec == 1) kb[(bh * LROW + nn) * 32 + dd] = f2bf(v);
          else               vtb[(bh * 32 + dd) * LROW + nn] = f2bf(v);
        }
      }
}

// ---------------- flash attention v3: barrier-free, K/V direct global->reg, prefetched ----------------
// block = 32 q-rows of one (b,h), 2 waves x 16 q. KV tiles of 64.
// S^T = mfma(K,Q) -> in-lane softmax; O^T = mfma(V^T, P^T). Only P goes through LDS (same-wave).
__global__ __launch_bounds__(128) void flash_mfma_kernel(
    const short* __restrict__ qb, const short* __restrict__ kb,
    const short* __restrict__ vtb, short* __restrict__ aob) {
  __shared__ __align__(16) short Pt[2][16][40];
  int tid = threadIdx.x, lane = tid & 63, wid = tid >> 6;
  int q0 = blockIdx.x * 32, bh = blockIdx.y;
  int b = bh / 3, h = bh % 3;
  const short* qbb = qb + (size_t)bh * LROW * 32;
  const short* kbb = kb + (size_t)bh * LROW * 32;
  const short* vbb = vtb + (size_t)bh * 32 * LROW;
  int lr = lane & 15, lg = lane >> 4;

  bf8 qf = *reinterpret_cast<const bf8*>(qbb + (size_t)(q0 + wid * 16 + lr) * 32 + lg * 8);
  const short* kp0 = kbb + (size_t)lr * 32 + lg * 8;            // + kt*2048 + t*512
  const short* vp0 = vbb + (size_t)lr * LROW + lg * 8;          // + kt*64 + c*32
  const short* vp1 = vbb + (size_t)(16 + lr) * LROW + lg * 8;

  f32x4 Oa0 = {0.f, 0.f, 0.f, 0.f}, Oa1 = {0.f, 0.f, 0.f, 0.f};
  float m = -1e30f, l = 0.f;

  bf8 kA[4], v0A[2], v1A[2], kB[4], v0B[2], v1B[2];

  auto loadt = [&](bf8 (&Kf)[4], bf8 (&V0)[2], bf8 (&V1)[2], int kt) {
    const short* kp = kp0 + (size_t)kt * 2048;
#pragma unroll
    for (int t = 0; t < 4; ++t) Kf[t] = *reinterpret_cast<const bf8*>(kp + t * 512);
#pragma unroll
    for (int c = 0; c < 2; ++c) {
      V0[c] = *reinterpret_cast<const bf8*>(vp0 + kt * 64 + c * 32);
      V1[c] = *reinterpret_cast<const bf8*>(vp1 + kt * 64 + c * 32);
    }
  };

  auto body = [&](bf8 (&Kf)[4], bf8 (&V0)[2], bf8 (&V1)[2]) {
    f32x4 z = {0.f, 0.f, 0.f, 0.f};
    f32x4 St[4];
    __builtin_amdgcn_s_setprio(1);
#pragma unroll
    for (int t = 0; t < 4; ++t)
      St[t] = __builtin_amdgcn_mfma_f32_16x16x32_bf16(Kf[t], qf, z, 0, 0, 0);
    __builtin_amdgcn_s_setprio(0);

    float px = St[0][0];
#pragma unroll
    for (int t = 0; t < 4; ++t)
#pragma unroll
      for (int r = 0; r < 4; ++r) px = fmaxf(px, St[t][r]);
    px = fmaxf(px, __shfl_xor(px, 16));
    px = fmaxf(px, __shfl_xor(px, 32));
    float mn = fmaxf(m, px);
    float al = exp2f(m - mn);
    m = mn;
    float rs = 0.f;
#pragma unroll
    for (int t = 0; t < 4; ++t)
#pragma unroll
      for (int r = 0; r < 4; ++r) {
        float p = exp2f(St[t][r] - mn);
        St[t][r] = p;
        rs += p;
      }
    rs += __shfl_xor(rs, 16);
    rs += __shfl_xor(rs, 32);
    l = l * al + rs;

#pragma unroll
    for (int t = 0; t < 4; ++t) {
      uint2 w;
      w.x = pack_bf2(St[t][0], St[t][1]);
      w.y = pack_bf2(St[t][2], St[t][3]);
      *reinterpret_cast<uint2*>(&Pt[wid][lr][t * 16 + lg * 4]) = w;
    }
#pragma unroll
    for (int r = 0; r < 4; ++r) { Oa0[r] *= al; Oa1[r] *= al; }

    __builtin_amdgcn_s_setprio(1);
#pragma unroll
    for (int c = 0; c < 2; ++c) {
      bf8 pbf = *reinterpret_cast<const bf8*>(&Pt[wid][lr][c * 32 + 8 * lg]);
      Oa0 = __builtin_amdgcn_mfma_f32_16x16x32_bf16(V0[c], pbf, Oa0, 0, 0, 0);
      Oa1 = __builtin_amdgcn_mfma_f32_16x16x32_bf16(V1[c], pbf, Oa1, 0, 0, 0);
    }
    __builtin_amdgcn_s_setprio(0);
  };

  loadt(kA, v0A, v1A, 0);
  for (int kt = 0; kt < 48; kt += 2) {
    loadt(kB, v0B, v1B, kt + 1);
    body(kA, v0A, v1A);
    loadt(kA, v0A, v1A, kt + 2);
    body(kB, v0B, v1B);
  }
  body(kA, v0A, v1A);  // tile 48

  float inv = 1.f / l;
  int qrow = q0 + wid * 16 + lr;
  short* op = aob + ((size_t)b * LROW + qrow) * CD + h * 32 + lg * 4;
  uint2 w0, w1;
  w0.x = pack_bf2r(Oa0[0] * inv, Oa0[1] * inv);
  w0.y = pack_bf2r(Oa0[2] * inv, Oa0[3] * inv);
  w1.x = pack_bf2r(Oa1[0] * inv, Oa1[1] * inv);
  w1.y = pack_bf2r(Oa1[2] * inv, Oa1[3] * inv);
  *reinterpret_cast<uint2*>(op) = w0;
  *reinterpret_cast<uint2*>(op + 16) = w1;
}

__global__ void tail_kernel(const int* __restrict__ Hp, const int* __restrict__ Wp,
                            float* __restrict__ o) {
  o[0] = (float)Hp[0];
  o[1] = (float)Wp[0];
}

extern "C" void kernel_launch(void* const* d_in, const int* in_sizes, int n_in,
                              void* d_out, int out_size, void* d_ws, size_t ws_size,
                              hipStream_t stream) {
  const float* x      = (const float*)d_in[0];
  const int*   Hp     = (const int*)d_in[1];
  const int*   Wp     = (const int*)d_in[2];
  const float* n1s    = (const float*)d_in[3];
  const float* n1b    = (const float*)d_in[4];
  const float* qkv_w  = (const float*)d_in[5];
  const float* qkv_b  = (const float*)d_in[6];
  const float* proj_w = (const float*)d_in[7];
  const float* proj_b = (const float*)d_in[8];
  const float* ln1s   = (const float*)d_in[9];
  const float* ln1b   = (const float*)d_in[10];
  const float* qkv2_w = (const float*)d_in[11];
  const float* qkv2_b = (const float*)d_in[12];
  const float* out_w  = (const float*)d_in[13];
  const float* out_b  = (const float*)d_in[14];
  const float* ln2s   = (const float*)d_in[15];
  const float* ln2b   = (const float*)d_in[16];
  const float* fc1_w  = (const float*)d_in[17];
  const float* fc1_b  = (const float*)d_in[18];
  const float* fc2_w  = (const float*)d_in[19];
  const float* fc2_b  = (const float*)d_in[20];

  float* wsf = (float*)d_ws;
  const size_t U = (size_t)4 * LROW * CD;  // 1,204,224
  float* x1   = wsf;                         // [0, U) fp32
  float* x2   = wsf + U;                     // [U, 2U) fp32
  short* hb   = (short*)(wsf + 2 * U);       // U shorts: LN outs / flash ao (bf16)
  short* tb   = (short*)(wsf + 2 * U + U / 2); // 4U shorts: fc1 out bf16 [M][384]
  short* qb   = (short*)(wsf + 4 * U + U / 2); // U shorts
  short* kb   = qb + U;                      // U shorts
  short* vtb  = kb + U;                      // U shorts
  short* wqkv = (short*)(wsf + 6 * U);       // 320*96
  short* wout = wqkv + 320 * 96;             // 128*96
  short* wfc1 = wout + 128 * 96;             // 384*96
  short* wfc2 = wfc1 + 384 * 96;             // 128*384
  short* aob  = hb;
  float* outx = (float*)d_out;

  const int M = 4 * LROW;  // 12544

  cvt_wt_kernel<<<(320 * 96 + 255) / 256, 256, 0, stream>>>(qkv2_w, wqkv, 96, 288, 320);
  cvt_wt_kernel<<<(128 * 96 + 255) / 256, 256, 0, stream>>>(out_w, wout, 96, 96, 128);
  cvt_wt_kernel<<<(384 * 96 + 255) / 256, 256, 0, stream>>>(fc1_w, wfc1, 96, 384, 384);
  cvt_wt_kernel<<<(128 * 384 + 255) / 256, 256, 0, stream>>>(fc2_w, wfc2, 384, 96, 128);

  ln_kernel<<<M / 4, 256, 0, stream>>>(x, n1s, n1b, hb, M);
  win_attn_kernel<<<256, 256, 0, stream>>>((const __hip_bfloat16*)hb, x, qkv_w, qkv_b, proj_w, proj_b, x1);
  ln_kernel<<<M / 4, 256, 0, stream>>>(x1, ln1s, ln1b, hb, M);
  qkv_mfma_kernel<<<dim3(M / 128, 5), 256, 0, stream>>>(hb, wqkv, qkv2_b, qb, kb, vtb);
  flash_mfma_kernel<<<dim3(LROW / 32, 12), 128, 0, stream>>>(qb, kb, vtb, aob);
  gemm_mfma_kernel<1><<<dim3(M / 128, 2), 256, 0, stream>>>(aob, wout, out_b, x1, x2, M, 96, 96);
  ln_kernel<<<M / 4, 256, 0, stream>>>(x2, ln2s, ln2b, hb, M);
  gemm_mfma_kernel<0><<<dim3(M / 128, 6), 256, 0, stream>>>(hb, wfc1, fc1_b, nullptr, tb, M, 96, 384);
  gemm_mfma_kernel<1><<<dim3(M / 128, 2), 256, 0, stream>>>(tb, wfc2, fc2_b, x2, outx, M, 384, 96);
  tail_kernel<<<1, 1, 0, stream>>>(Hp, Wp, outx + U);
}

// Round 6
// 210.048 us; speedup vs baseline: 3.1846x; 1.0783x over previous
//
#include <hip/hip_runtime.h>
#include <hip/hip_bf16.h>

#define CD 96
#define LROW 3136          // 56*56
#define QSCALE 0.17677669529663687f  // 1/sqrt(32)
#define LOG2E 1.4426950408889634f

using f32x4 = __attribute__((ext_vector_type(4))) float;
using bf8   = __attribute__((ext_vector_type(8))) short;

__device__ __forceinline__ float bflo(unsigned u) { return __uint_as_float(u << 16); }
__device__ __forceinline__ float bfhi(unsigned u) { return __uint_as_float(u & 0xffff0000u); }
__device__ __forceinline__ short f2bf(float f) {
  union { float f; unsigned u; } v; v.f = f;
  unsigned r = v.u + 0x7fffu + ((v.u >> 16) & 1u);
  return (short)(r >> 16);
}
// truncating pack (internal P values; relative err <= 2^-8, fine pre-normalization)
__device__ __forceinline__ unsigned pack_bf2(float lo, float hi) {
  return (__float_as_uint(hi) & 0xffff0000u) | (__float_as_uint(lo) >> 16);
}
// rounding pack (for stored outputs)
__device__ __forceinline__ unsigned pack_bf2r(float lo, float hi) {
  return ((unsigned)(unsigned short)f2bf(hi) << 16) | (unsigned short)f2bf(lo);
}

#define GLOAD_LDS16(src, dst) \
  __builtin_amdgcn_global_load_lds((const __attribute__((address_space(1))) void*)(src), \
                                   (__attribute__((address_space(3))) void*)(dst), 16, 0, 0)

// ---------------- LayerNorm (one wave per 96-col row) -> bf16 out ----------------
__global__ __launch_bounds__(256) void ln_kernel(const float* __restrict__ x,
                                                 const float* __restrict__ g,
                                                 const float* __restrict__ b,
                                                 short* __restrict__ out, int rows) {
  int wid = threadIdx.x >> 6, lane = threadIdx.x & 63;
  int row = (blockIdx.x << 2) + wid;
  if (row >= rows) return;
  const float* xr = x + (size_t)row * CD;
  float v0 = xr[lane];
  float v1 = (lane < 32) ? xr[64 + lane] : 0.f;
  float s = v0 + v1;
#pragma unroll
  for (int off = 32; off >= 1; off >>= 1) s += __shfl_xor(s, off);
  float mu = s * (1.f / 96.f);
  float d0 = v0 - mu;
  float d1 = (lane < 32) ? v1 - mu : 0.f;
  float q = d0 * d0 + d1 * d1;
#pragma unroll
  for (int off = 32; off >= 1; off >>= 1) q += __shfl_xor(q, off);
  float rstd = rsqrtf(q * (1.f / 96.f) + 1e-6f);
  short* orow = out + (size_t)row * CD;
  orow[lane] = f2bf(d0 * rstd * g[lane] + b[lane]);
  if (lane < 32) orow[64 + lane] = f2bf(d1 * rstd * g[64 + lane] + b[64 + lane]);
}

// ---------------- weight convert: Wt[Npad][K] bf16 = W[K][N]^T (zero-padded) ----------------
__global__ __launch_bounds__(256) void cvt_wt_kernel(const float* __restrict__ W,
                                                     short* __restrict__ Wt,
                                                     int K, int N, int Npad) {
  int idx = blockIdx.x * 256 + threadIdx.x;
  if (idx >= Npad * K) return;
  int nr = idx / K, kk = idx - nr * K;
  float v = (nr < N) ? W[(size_t)kk * N + nr] : 0.f;
  Wt[idx] = f2bf(v);
}

// ---------------- fused shifted-window attention: one block per window ----------------
__global__ __launch_bounds__(256) void win_attn_kernel(
    const __hip_bfloat16* __restrict__ hsrc, const float* __restrict__ xin,
    const float* __restrict__ qkv_w, const float* __restrict__ qkv_b,
    const float* __restrict__ proj_w, const float* __restrict__ proj_b,
    float* __restrict__ x1) {
  __shared__ __align__(16) __hip_bfloat16 xw[49][96];
  __shared__ __align__(16) float qh[49][36];
  __shared__ __align__(16) float kh[49][36];
  __shared__ __align__(16) float vh[49][36];
  __shared__ __align__(16) float S[49][49];
  __shared__ __align__(16) float outw[49][100];
  __shared__ int cnt[49];
  __shared__ int gidx[49];

  int tid = threadIdx.x;
  int b = blockIdx.x >> 6, w64 = blockIdx.x & 63;
  int wr = w64 >> 3, wc = w64 & 7;

  if (tid < 49) {
    int i = tid / 7, j = tid % 7;
    int sh = wr * 7 + i, sw = wc * 7 + j;
    int hr = (sh < 49) ? 0 : ((sh < 53) ? 1 : 2);
    int wreg = (sw < 49) ? 0 : ((sw < 53) ? 1 : 2);
    cnt[tid] = hr * 3 + wreg;
    gidx[tid] = ((sh + 3) % 56) * 56 + ((sw + 3) % 56);
  }
  __syncthreads();

  for (int idx = tid; idx < 49 * 96; idx += 256) {
    int p = idx / 96, c = idx % 96;
    xw[p][c] = hsrc[((size_t)b * LROW + gidx[p]) * CD + c];
  }
  __syncthreads();

  int dd = tid & 31, pg = tid >> 5;

  for (int hh = 0; hh < 3; ++hh) {
    {
      float aq[7], ak[7], av[7];
#pragma unroll
      for (int i = 0; i < 7; ++i) { aq[i] = 0.f; ak[i] = 0.f; av[i] = 0.f; }
      for (int k0 = 0; k0 < 96; k0 += 8) {
        float xf[7][8];
#pragma unroll
        for (int i = 0; i < 7; ++i) {
          int p = pg + 8 * i;
          if (p < 49) {
            uint4 u = *reinterpret_cast<const uint4*>(&xw[p][k0]);
            xf[i][0] = bflo(u.x); xf[i][1] = bfhi(u.x);
            xf[i][2] = bflo(u.y); xf[i][3] = bfhi(u.y);
            xf[i][4] = bflo(u.z); xf[i][5] = bfhi(u.z);
            xf[i][6] = bflo(u.w); xf[i][7] = bfhi(u.w);
          } else {
#pragma unroll
            for (int kq = 0; kq < 8; ++kq) xf[i][kq] = 0.f;
          }
        }
#pragma unroll
        for (int kq = 0; kq < 8; ++kq) {
          const float* wrow = qkv_w + (size_t)(k0 + kq) * 288 + hh * 32 + dd;
          float wq = wrow[0], wk = wrow[96], wv = wrow[192];
#pragma unroll
          for (int i = 0; i < 7; ++i) {
            aq[i] += xf[i][kq] * wq;
            ak[i] += xf[i][kq] * wk;
            av[i] += xf[i][kq] * wv;
          }
        }
      }
      float bq = qkv_b[hh * 32 + dd];
      float bk = qkv_b[96 + hh * 32 + dd];
      float bv = qkv_b[192 + hh * 32 + dd];
#pragma unroll
      for (int i = 0; i < 7; ++i) {
        int p = pg + 8 * i;
        if (p < 49) {
          qh[p][dd] = (aq[i] + bq) * QSCALE;
          kh[p][dd] = ak[i] + bk;
          vh[p][dd] = av[i] + bv;
        }
      }
    }
    __syncthreads();
    if (tid < 196) {
      int i = tid >> 2, jq = tid & 3;
      float qr[32];
      const float4* q4 = reinterpret_cast<const float4*>(&qh[i][0]);
#pragma unroll
      for (int dq = 0; dq < 8; ++dq) {
        float4 t = q4[dq];
        qr[dq * 4 + 0] = t.x; qr[dq * 4 + 1] = t.y;
        qr[dq * 4 + 2] = t.z; qr[dq * 4 + 3] = t.w;
      }
      int ci = cnt[i];
      for (int j = jq; j < 49; j += 4) {
        const float4* k4 = reinterpret_cast<const float4*>(&kh[j][0]);
        float s = 0.f;
#pragma unroll
        for (int dq = 0; dq < 8; ++dq) {
          float4 kv = k4[dq];
          s += qr[dq*4+0]*kv.x + qr[dq*4+1]*kv.y + qr[dq*4+2]*kv.z + qr[dq*4+3]*kv.w;
        }
        S[i][j] = s + ((ci == cnt[j]) ? 0.f : -100.f);
      }
    }
    __syncthreads();
    if (tid < 49) {
      float mx = -1e30f;
      for (int j = 0; j < 49; ++j) mx = fmaxf(mx, S[tid][j]);
      float sum = 0.f;
      for (int j = 0; j < 49; ++j) { float p = __expf(S[tid][j] - mx); S[tid][j] = p; sum += p; }
      float inv = 1.f / sum;
      for (int j = 0; j < 49; ++j) S[tid][j] *= inv;
    }
    __syncthreads();
    for (int slot = tid; slot < 392; slot += 256) {
      int p = slot >> 3, d4 = (slot & 7) * 4;
      float a0 = 0.f, a1 = 0.f, a2 = 0.f, a3 = 0.f;
      for (int j = 0; j < 49; ++j) {
        float pp = S[p][j];
        float4 vv = *reinterpret_cast<const float4*>(&vh[j][d4]);
        a0 += pp * vv.x; a1 += pp * vv.y; a2 += pp * vv.z; a3 += pp * vv.w;
      }
      float* op = &outw[p][hh * 32 + d4];
      op[0] = a0; op[1] = a1; op[2] = a2; op[3] = a3;
    }
    __syncthreads();
  }
  for (int slot = tid; slot < 1176; slot += 256) {
    int p = slot / 24, c4 = (slot % 24) * 4;
    float a0 = 0.f, a1 = 0.f, a2 = 0.f, a3 = 0.f;
    for (int k0 = 0; k0 < 96; k0 += 4) {
      float4 ow = *reinterpret_cast<const float4*>(&outw[p][k0]);
      const float* w0 = proj_w + (size_t)k0 * 96 + c4;
      float4 wa = *reinterpret_cast<const float4*>(w0);
      float4 wb = *reinterpret_cast<const float4*>(w0 + 96);
      float4 wc2 = *reinterpret_cast<const float4*>(w0 + 192);
      float4 wd = *reinterpret_cast<const float4*>(w0 + 288);
      a0 += ow.x*wa.x + ow.y*wb.x + ow.z*wc2.x + ow.w*wd.x;
      a1 += ow.x*wa.y + ow.y*wb.y + ow.z*wc2.y + ow.w*wd.y;
      a2 += ow.x*wa.z + ow.y*wb.z + ow.z*wc2.z + ow.w*wd.z;
      a3 += ow.x*wa.w + ow.y*wb.w + ow.z*wc2.w + ow.w*wd.w;
    }
    size_t rowo = ((size_t)b * LROW + gidx[p]) * CD + c4;
    float4 sc = *reinterpret_cast<const float4*>(&xin[rowo]);
    float4 pb = *reinterpret_cast<const float4*>(&proj_b[c4]);
    float4 res;
    res.x = a0 + pb.x + sc.x; res.y = a1 + pb.y + sc.y;
    res.z = a2 + pb.z + sc.z; res.w = a3 + pb.w + sc.w;
    *reinterpret_cast<float4*>(&x1[rowo]) = res;
  }
}

// ---------------- bf16 MFMA GEMM: out = f(A[M][K] @ Wt[Npad][K]^T + bias [+res]) ----------------
template <int MODE>
__global__ __launch_bounds__(256) void gemm_mfma_kernel(
    const short* __restrict__ A, const short* __restrict__ Bt,
    const float* __restrict__ bias, const float* __restrict__ res,
    void* __restrict__ outp, int M, int K, int N) {
  __shared__ __align__(16) short As[2][128 * 32];
  __shared__ __align__(16) short Bs[2][64 * 32];
  int tid = threadIdx.x, lane = tid & 63, wid = tid >> 6;
  int lr = lane & 15, lg = lane >> 4;
  int m0 = blockIdx.x * 128, n0 = blockIdx.y * 64;
  int nk = K >> 5;

  f32x4 acc[2][4];
#pragma unroll
  for (int i = 0; i < 2; ++i)
#pragma unroll
    for (int j = 0; j < 4; ++j) acc[i][j] = (f32x4){0.f, 0.f, 0.f, 0.f};

  auto stage = [&](int bf, int ks) {
    int k0 = ks * 32;
#pragma unroll
    for (int p = 0; p < 2; ++p) {
      int idx = tid + p * 256;
      GLOAD_LDS16(A + (size_t)(m0 + (idx >> 2)) * K + k0 + (idx & 3) * 8,
                  &As[bf][idx * 8]);
    }
    GLOAD_LDS16(Bt + (size_t)(n0 + (tid >> 2)) * K + k0 + (tid & 3) * 8,
                &Bs[bf][tid * 8]);
  };

  stage(0, 0);
  __syncthreads();
  int buf = 0;
  for (int ks = 0; ks < nk; ++ks) {
    if (ks + 1 < nk) stage(buf ^ 1, ks + 1);
    bf8 bfr[4], afr[2];
#pragma unroll
    for (int ni = 0; ni < 4; ++ni)
      bfr[ni] = *reinterpret_cast<const bf8*>(&Bs[buf][(ni * 16 + lr) * 32 + lg * 8]);
#pragma unroll
    for (int mi = 0; mi < 2; ++mi)
      afr[mi] = *reinterpret_cast<const bf8*>(&As[buf][(wid * 32 + mi * 16 + lr) * 32 + lg * 8]);
    __builtin_amdgcn_s_setprio(1);
#pragma unroll
    for (int mi = 0; mi < 2; ++mi)
#pragma unroll
      for (int ni = 0; ni < 4; ++ni)
        acc[mi][ni] = __builtin_amdgcn_mfma_f32_16x16x32_bf16(afr[mi], bfr[ni], acc[mi][ni], 0, 0, 0);
    __builtin_amdgcn_s_setprio(0);
    __syncthreads();
    buf ^= 1;
  }

#pragma unroll
  for (int mi = 0; mi < 2; ++mi)
#pragma unroll
    for (int ni = 0; ni < 4; ++ni)
#pragma unroll
      for (int r = 0; r < 4; ++r) {
        int mrow = m0 + wid * 32 + mi * 16 + lg * 4 + r;
        int n = n0 + ni * 16 + lr;
        if (n < N) {
          float v = acc[mi][ni][r] + bias[n];
          if (MODE == 0) {
            float t = tanhf(0.7978845608028654f * (v + 0.044715f * v * v * v));
            ((short*)outp)[(size_t)mrow * N + n] = f2bf(0.5f * v * (1.f + t));
          } else {
            v += res[(size_t)mrow * N + n];
            ((float*)outp)[(size_t)mrow * N + n] = v;
          }
        }
      }
}

// ---------------- qkv GEMM (bf16 MFMA) with flash-layout scatter epilogue ----------------
__global__ __launch_bounds__(256) void qkv_mfma_kernel(
    const short* __restrict__ A, const short* __restrict__ Bt,
    const float* __restrict__ bias,
    short* __restrict__ qb, short* __restrict__ kb, short* __restrict__ vtb) {
  __shared__ __align__(16) short As[2][128 * 32];
  __shared__ __align__(16) short Bs[2][64 * 32];
  int tid = threadIdx.x, lane = tid & 63, wid = tid >> 6;
  int lr = lane & 15, lg = lane >> 4;
  int m0 = blockIdx.x * 128, n0 = blockIdx.y * 64;
  const int K = 96;

  f32x4 acc[2][4];
#pragma unroll
  for (int i = 0; i < 2; ++i)
#pragma unroll
    for (int j = 0; j < 4; ++j) acc[i][j] = (f32x4){0.f, 0.f, 0.f, 0.f};

  auto stage = [&](int bf, int ks) {
    int k0 = ks * 32;
#pragma unroll
    for (int p = 0; p < 2; ++p) {
      int idx = tid + p * 256;
      GLOAD_LDS16(A + (size_t)(m0 + (idx >> 2)) * K + k0 + (idx & 3) * 8,
                  &As[bf][idx * 8]);
    }
    GLOAD_LDS16(Bt + (size_t)(n0 + (tid >> 2)) * K + k0 + (tid & 3) * 8,
                &Bs[bf][tid * 8]);
  };

  stage(0, 0);
  __syncthreads();
  int buf = 0;
  for (int ks = 0; ks < 3; ++ks) {
    if (ks + 1 < 3) stage(buf ^ 1, ks + 1);
    bf8 bfr[4], afr[2];
#pragma unroll
    for (int ni = 0; ni < 4; ++ni)
      bfr[ni] = *reinterpret_cast<const bf8*>(&Bs[buf][(ni * 16 + lr) * 32 + lg * 8]);
#pragma unroll
    for (int mi = 0; mi < 2; ++mi)
      afr[mi] = *reinterpret_cast<const bf8*>(&As[buf][(wid * 32 + mi * 16 + lr) * 32 + lg * 8]);
    __builtin_amdgcn_s_setprio(1);
#pragma unroll
    for (int mi = 0; mi < 2; ++mi)
#pragma unroll
      for (int ni = 0; ni < 4; ++ni)
        acc[mi][ni] = __builtin_amdgcn_mfma_f32_16x16x32_bf16(afr[mi], bfr[ni], acc[mi][ni], 0, 0, 0);
    __builtin_amdgcn_s_setprio(0);
    __syncthreads();
    buf ^= 1;
  }

#pragma unroll
  for (int mi = 0; mi < 2; ++mi)
#pragma unroll
    for (int ni = 0; ni < 4; ++ni)
#pragma unroll
      for (int r = 0; r < 4; ++r) {
        int mrow = m0 + wid * 32 + mi * 16 + lg * 4 + r;
        int n = n0 + ni * 16 + lr;
        if (n < 288) {
          float v = acc[mi][ni][r] + bias[n];
          int sec = n / 96, within = n % 96;
          int hh = within >> 5, dd = within & 31;
          int bb = mrow / LROW, nn = mrow - bb * LROW;
          size_t bh = (size_t)bb * 3 + hh;
          if (sec == 0)      qb[(bh * LROW + nn) * 32 + dd] = f2bf(v * (QSCALE * LOG2E));
          else if (sec == 1) kb[(bh * LROW + nn) * 32 + dd] = f2bf(v);
          else               vtb[(bh * 32 + dd) * LROW + nn] = f2bf(v);
        }
      }
}

// ---------------- flash attention v4: 32q/wave, split-KV x2, defer-max, barrier-free ----------------
// grid (49, 12, 2): 64 q-rows per block (2 waves x 32q), split s owns KV tiles [s?25:0, s?49:25).
// S^T = mfma(K,Q) per q-group; in-lane softmax (log2); O^T = mfma(V^T,P^T).
// Unnormalized partials (O, m, l) -> merge kernel.
__global__ __launch_bounds__(128) void flash_mfma_kernel(
    const short* __restrict__ qb, const short* __restrict__ kb,
    const short* __restrict__ vtb,
    float* __restrict__ pO, float* __restrict__ pm, float* __restrict__ pl) {
  __shared__ __align__(16) short Pt[2][2][16][40];  // [wave][g][q][kv]
  int tid = threadIdx.x, lane = tid & 63, wid = tid >> 6;
  int lr = lane & 15, lg = lane >> 4;
  int bh = blockIdx.y, s = blockIdx.z;
  int q0 = blockIdx.x * 64 + wid * 32;
  const short* qbb = qb + (size_t)bh * LROW * 32;
  const short* kbase = kb + (size_t)bh * LROW * 32 + lr * 32 + lg * 8;
  const short* vbase = vtb + (size_t)bh * 32 * LROW + lr * LROW + lg * 8;

  bf8 qf0 = *reinterpret_cast<const bf8*>(qbb + (size_t)(q0 + lr) * 32 + lg * 8);
  bf8 qf1 = *reinterpret_cast<const bf8*>(qbb + (size_t)(q0 + 16 + lr) * 32 + lg * 8);

  f32x4 O00 = {0.f,0.f,0.f,0.f}, O01 = {0.f,0.f,0.f,0.f};  // g0: d-half 0/1
  f32x4 O10 = {0.f,0.f,0.f,0.f}, O11 = {0.f,0.f,0.f,0.f};  // g1
  float m0v = -1e30f, l0v = 0.f, m1v = -1e30f, l1v = 0.f;

  int t0 = s ? 25 : 0, t1 = s ? 49 : 25;

  bf8 kA[4], vA[4], kB[4], vB[4];

  auto loadt = [&](bf8 (&Kf)[4], bf8 (&Vf)[4], int kt) {
    const short* kp = kbase + (size_t)kt * 2048;
#pragma unroll
    for (int t = 0; t < 4; ++t) Kf[t] = *reinterpret_cast<const bf8*>(kp + t * 512);
    const short* vp = vbase + kt * 64;
#pragma unroll
    for (int c = 0; c < 2; ++c) {
      Vf[c]     = *reinterpret_cast<const bf8*>(vp + c * 32);
      Vf[2 + c] = *reinterpret_cast<const bf8*>(vp + 16 * LROW + c * 32);
    }
  };

  auto body = [&](bf8 (&Kf)[4], bf8 (&Vf)[4]) {
    f32x4 z = {0.f, 0.f, 0.f, 0.f};
#pragma unroll
    for (int g = 0; g < 2; ++g) {
      bf8 qf = g ? qf1 : qf0;
      float& mg = g ? m1v : m0v;
      float& lgv = g ? l1v : l0v;
      f32x4& Oh0 = g ? O10 : O00;
      f32x4& Oh1 = g ? O11 : O01;
      f32x4 St[4];
      __builtin_amdgcn_s_setprio(1);
#pragma unroll
      for (int t = 0; t < 4; ++t)
        St[t] = __builtin_amdgcn_mfma_f32_16x16x32_bf16(Kf[t], qf, z, 0, 0, 0);
      __builtin_amdgcn_s_setprio(0);

      float px = St[0][0];
#pragma unroll
      for (int t = 0; t < 4; ++t)
#pragma unroll
        for (int r = 0; r < 4; ++r) px = fmaxf(px, St[t][r]);
      px = fmaxf(px, __shfl_xor(px, 16));
      px = fmaxf(px, __shfl_xor(px, 32));

      if (!__all(px <= mg + 8.f)) {   // defer-max: skip rescale while max growth < 2^8
        float mn = fmaxf(mg, px);
        float al = exp2f(mg - mn);
        mg = mn;
        lgv *= al;
#pragma unroll
        for (int r = 0; r < 4; ++r) { Oh0[r] *= al; Oh1[r] *= al; }
      }
      float rs = 0.f;
#pragma unroll
      for (int t = 0; t < 4; ++t)
#pragma unroll
        for (int r = 0; r < 4; ++r) {
          float p = exp2f(St[t][r] - mg);
          St[t][r] = p;
          rs += p;
        }
      rs += __shfl_xor(rs, 16);
      rs += __shfl_xor(rs, 32);
      lgv += rs;

#pragma unroll
      for (int t = 0; t < 4; ++t) {
        uint2 w;
        w.x = pack_bf2(St[t][0], St[t][1]);
        w.y = pack_bf2(St[t][2], St[t][3]);
        *reinterpret_cast<uint2*>(&Pt[wid][g][lr][t * 16 + lg * 4]) = w;
      }
    }
    __builtin_amdgcn_s_setprio(1);
#pragma unroll
    for (int g = 0; g < 2; ++g) {
      f32x4& Oh0 = g ? O10 : O00;
      f32x4& Oh1 = g ? O11 : O01;
#pragma unroll
      for (int c = 0; c < 2; ++c) {
        bf8 pbf = *reinterpret_cast<const bf8*>(&Pt[wid][g][lr][c * 32 + lg * 8]);
        Oh0 = __builtin_amdgcn_mfma_f32_16x16x32_bf16(Vf[c], pbf, Oh0, 0, 0, 0);
        Oh1 = __builtin_amdgcn_mfma_f32_16x16x32_bf16(Vf[2 + c], pbf, Oh1, 0, 0, 0);
      }
    }
    __builtin_amdgcn_s_setprio(0);
  };

  loadt(kA, vA, t0);
  int kt = t0;
  for (; kt + 2 <= t1 - 1; kt += 2) {
    loadt(kB, vB, kt + 1);
    body(kA, vA);
    loadt(kA, vA, kt + 2);
    body(kB, vB);
  }
  if (kt < t1 - 1) {
    loadt(kB, vB, kt + 1);
    body(kA, vA);
    body(kB, vB);
  } else {
    body(kA, vA);
  }

  // write unnormalized partials; lane (lr, lg) holds d = lg*4+r (+16 half1) for q = q0(+16)+lr
  size_t rbase = (size_t)(s * 12 + bh) * LROW;
  size_t r0 = (rbase + q0 + lr) * 32;
  size_t r1 = (rbase + q0 + 16 + lr) * 32;
  *reinterpret_cast<float4*>(&pO[r0 + lg * 4])      = (float4){O00[0], O00[1], O00[2], O00[3]};
  *reinterpret_cast<float4*>(&pO[r0 + 16 + lg * 4]) = (float4){O01[0], O01[1], O01[2], O01[3]};
  *reinterpret_cast<float4*>(&pO[r1 + lg * 4])      = (float4){O10[0], O10[1], O10[2], O10[3]};
  *reinterpret_cast<float4*>(&pO[r1 + 16 + lg * 4]) = (float4){O11[0], O11[1], O11[2], O11[3]};
  if (lg == 0) {
    pm[rbase + q0 + lr] = m0v;      pl[rbase + q0 + lr] = l0v;
    pm[rbase + q0 + 16 + lr] = m1v; pl[rbase + q0 + 16 + lr] = l1v;
  }
}

// ---------------- merge the two KV-split partials -> bf16 ao ----------------
__global__ __launch_bounds__(256) void flash_merge_kernel(
    const float* __restrict__ pO, const float* __restrict__ pm,
    const float* __restrict__ pl, short* __restrict__ aob) {
  int idx = blockIdx.x * 256 + threadIdx.x;   // (bh*LROW + q)*32 + d ; total 12*LROW*32
  int d = idx & 31, row = idx >> 5;
  const int NR = 12 * LROW;
  float m0 = pm[row], m1 = pm[row + NR];
  float l0 = pl[row], l1 = pl[row + NR];
  float o0 = pO[idx], o1 = pO[idx + NR * 32];
  float ms = fmaxf(m0, m1);
  float a0 = exp2f(m0 - ms), a1 = exp2f(m1 - ms);
  float o = (a0 * o0 + a1 * o1) / (a0 * l0 + a1 * l1);
  int bh = row / LROW, q = row - bh * LROW;
  int b = bh / 3, h = bh - b * 3;
  aob[((size_t)b * LROW + q) * CD + h * 32 + d] = f2bf(o);
}

__global__ void tail_kernel(const int* __restrict__ Hp, const int* __restrict__ Wp,
                            float* __restrict__ o) {
  o[0] = (float)Hp[0];
  o[1] = (float)Wp[0];
}

extern "C" void kernel_launch(void* const* d_in, const int* in_sizes, int n_in,
                              void* d_out, int out_size, void* d_ws, size_t ws_size,
                              hipStream_t stream) {
  const float* x      = (const float*)d_in[0];
  const int*   Hp     = (const int*)d_in[1];
  const int*   Wp     = (const int*)d_in[2];
  const float* n1s    = (const float*)d_in[3];
  const float* n1b    = (const float*)d_in[4];
  const float* qkv_w  = (const float*)d_in[5];
  const float* qkv_b  = (const float*)d_in[6];
  const float* proj_w = (const float*)d_in[7];
  const float* proj_b = (const float*)d_in[8];
  const float* ln1s   = (const float*)d_in[9];
  const float* ln1b   = (const float*)d_in[10];
  const float* qkv2_w = (const float*)d_in[11];
  const float* qkv2_b = (const float*)d_in[12];
  const float* out_w  = (const float*)d_in[13];
  const float* out_b  = (const float*)d_in[14];
  const float* ln2s   = (const float*)d_in[15];
  const float* ln2b   = (const float*)d_in[16];
  const float* fc1_w  = (const float*)d_in[17];
  const float* fc1_b  = (const float*)d_in[18];
  const float* fc2_w  = (const float*)d_in[19];
  const float* fc2_b  = (const float*)d_in[20];

  float* wsf = (float*)d_ws;
  const size_t U = (size_t)4 * LROW * CD;  // 1,204,224
  float* x1   = wsf;                           // [0, U) fp32
  float* x2   = wsf + U;                       // [U, 2U) fp32 (holds pm/pl during flash)
  short* hb   = (short*)(wsf + 2 * U);         // [2U, 2.5U): bf16 LN outs / flash ao
  short* tb   = (short*)(wsf + 2 * U + U / 2); // [2.5U, 4.5U): fc1 out bf16 (holds pO during flash)
  short* qb   = (short*)(wsf + 4 * U + U / 2); // U shorts
  short* kb   = qb + U;
  short* vtb  = kb + U;
  short* wqkv = (short*)(wsf + 6 * U);
  short* wout = wqkv + 320 * 96;
  short* wfc1 = wout + 128 * 96;
  short* wfc2 = wfc1 + 384 * 96;
  short* aob  = hb;
  float* pO   = (float*)tb;                    // 2U floats (exactly 2 splits x 12*LROW*32)
  float* pm   = x2;                            // 2*12*LROW floats
  float* pl   = x2 + 2 * 12 * LROW;
  float* outx = (float*)d_out;

  const int M = 4 * LROW;  // 12544

  cvt_wt_kernel<<<(320 * 96 + 255) / 256, 256, 0, stream>>>(qkv2_w, wqkv, 96, 288, 320);
  cvt_wt_kernel<<<(128 * 96 + 255) / 256, 256, 0, stream>>>(out_w, wout, 96, 96, 128);
  cvt_wt_kernel<<<(384 * 96 + 255) / 256, 256, 0, stream>>>(fc1_w, wfc1, 96, 384, 384);
  cvt_wt_kernel<<<(128 * 384 + 255) / 256, 256, 0, stream>>>(fc2_w, wfc2, 384, 96, 128);

  ln_kernel<<<M / 4, 256, 0, stream>>>(x, n1s, n1b, hb, M);
  win_attn_kernel<<<256, 256, 0, stream>>>((const __hip_bfloat16*)hb, x, qkv_w, qkv_b, proj_w, proj_b, x1);
  ln_kernel<<<M / 4, 256, 0, stream>>>(x1, ln1s, ln1b, hb, M);
  qkv_mfma_kernel<<<dim3(M / 128, 5), 256, 0, stream>>>(hb, wqkv, qkv2_b, qb, kb, vtb);
  flash_mfma_kernel<<<dim3(49, 12, 2), 128, 0, stream>>>(qb, kb, vtb, pO, pm, pl);
  flash_merge_kernel<<<12 * LROW * 32 / 256, 256, 0, stream>>>(pO, pm, pl, aob);
  gemm_mfma_kernel<1><<<dim3(M / 128, 2), 256, 0, stream>>>(aob, wout, out_b, x1, x2, M, 96, 96);
  ln_kernel<<<M / 4, 256, 0, stream>>>(x2, ln2s, ln2b, hb, M);
  gemm_mfma_kernel<0><<<dim3(M / 128, 6), 256, 0, stream>>>(hb, wfc1, fc1_b, nullptr, tb, M, 96, 384);
  gemm_mfma_kernel<1><<<dim3(M / 128, 2), 256, 0, stream>>>(tb, wfc2, fc2_b, x2, outx, M, 384, 96);
  tail_kernel<<<1, 1, 0, stream>>>(Hp, Wp, outx + U);
}

// Round 7
// 161.255 us; speedup vs baseline: 4.1482x; 1.3026x over previous
//
#include <hip/hip_runtime.h>
#include <hip/hip_bf16.h>

#define CD 96
#define LROW 3136          // 56*56
#define QSCALE 0.17677669529663687f  // 1/sqrt(32)
#define LOG2E 1.4426950408889634f
#define MASKLOG2 -144.26950408889634f // -100 * log2(e)

using f32x4 = __attribute__((ext_vector_type(4))) float;
using bf8   = __attribute__((ext_vector_type(8))) short;

__device__ __forceinline__ short f2bf(float f) {
  union { float f; unsigned u; } v; v.f = f;
  unsigned r = v.u + 0x7fffu + ((v.u >> 16) & 1u);
  return (short)(r >> 16);
}
// truncating pack (internal P values in [0,1])
__device__ __forceinline__ unsigned pack_bf2(float lo, float hi) {
  return (__float_as_uint(hi) & 0xffff0000u) | (__float_as_uint(lo) >> 16);
}

#define GLOAD_LDS16(src, dst) \
  __builtin_amdgcn_global_load_lds((const __attribute__((address_space(1))) void*)(src), \
                                   (__attribute__((address_space(3))) void*)(dst), 16, 0, 0)

// ---------------- LayerNorm (one wave per 96-col row) -> bf16 out ----------------
__global__ __launch_bounds__(256) void ln_kernel(const float* __restrict__ x,
                                                 const float* __restrict__ g,
                                                 const float* __restrict__ b,
                                                 short* __restrict__ out, int rows) {
  int wid = threadIdx.x >> 6, lane = threadIdx.x & 63;
  int row = (blockIdx.x << 2) + wid;
  if (row >= rows) return;
  const float* xr = x + (size_t)row * CD;
  float v0 = xr[lane];
  float v1 = (lane < 32) ? xr[64 + lane] : 0.f;
  float s = v0 + v1;
#pragma unroll
  for (int off = 32; off >= 1; off >>= 1) s += __shfl_xor(s, off);
  float mu = s * (1.f / 96.f);
  float d0 = v0 - mu;
  float d1 = (lane < 32) ? v1 - mu : 0.f;
  float q = d0 * d0 + d1 * d1;
#pragma unroll
  for (int off = 32; off >= 1; off >>= 1) q += __shfl_xor(q, off);
  float rstd = rsqrtf(q * (1.f / 96.f) + 1e-6f);
  short* orow = out + (size_t)row * CD;
  orow[lane] = f2bf(d0 * rstd * g[lane] + b[lane]);
  if (lane < 32) orow[64 + lane] = f2bf(d1 * rstd * g[64 + lane] + b[64 + lane]);
}

// ---------------- weight convert: Wt[Npad][K] bf16 = W[K][N]^T (zero-padded) ----------------
__global__ __launch_bounds__(256) void cvt_wt_kernel(const float* __restrict__ W,
                                                     short* __restrict__ Wt,
                                                     int K, int N, int Npad) {
  int idx = blockIdx.x * 256 + threadIdx.x;
  if (idx >= Npad * K) return;
  int nr = idx / K, kk = idx - nr * K;
  float v = (nr < N) ? W[(size_t)kk * N + nr] : 0.f;
  Wt[idx] = f2bf(v);
}

// ---------------- MFMA shifted-window attention: one block per window, 4 waves ----------------
// qkv GEMM (64x288x96) -> swapped-operand attention per head -> proj GEMM + residual scatter.
__global__ __launch_bounds__(256) void win_attn_kernel(
    const short* __restrict__ hb, const float* __restrict__ xin,
    const short* __restrict__ wwin, const float* __restrict__ qkv_b,
    const short* __restrict__ wproj, const float* __restrict__ proj_b,
    float* __restrict__ x1) {
  __shared__ __align__(16) short Xs[64][104];     // gathered window input (bf16), rows>=49 zero
  __shared__ __align__(16) short Qs[3][64][40];   // per-head Q (pre-scaled), [q][d]
  __shared__ __align__(16) short Ks[3][64][40];   // per-head K, [kv][d]
  __shared__ __align__(16) short Vt[3][32][72];   // per-head V^T, [d][kv]
  __shared__ __align__(16) short Os[64][104];     // attention out [q][c], bf16
  __shared__ __align__(16) short Ptw[4][16][72];  // per-wave P^T
  __shared__ int cnt[64];
  __shared__ int gidx[49];

  int tid = threadIdx.x, lane = tid & 63, wid = tid >> 6;
  int lr = lane & 15, lg = lane >> 4;
  int b = blockIdx.x >> 6, w64 = blockIdx.x & 63;
  int wr = w64 >> 3, wc = w64 & 7;

  if (tid < 64) {
    if (tid < 49) {
      int i = tid / 7, j = tid % 7;
      int sh = wr * 7 + i, sw = wc * 7 + j;
      int hr = (sh < 49) ? 0 : ((sh < 53) ? 1 : 2);
      int wreg = (sw < 49) ? 0 : ((sw < 53) ? 1 : 2);
      cnt[tid] = hr * 3 + wreg;
      gidx[tid] = ((sh + 3) % 56) * 56 + ((sw + 3) % 56);
    } else {
      cnt[tid] = -1;  // pad sentinel
    }
  }
  __syncthreads();

  // gather X (49 real rows, 15 zero rows)
  for (int c = tid; c < 768; c += 256) {
    int row = c / 12, cc = c % 12;
    uint4 v = {0u, 0u, 0u, 0u};
    if (row < 49) v = *reinterpret_cast<const uint4*>(hb + ((size_t)b * LROW + gidx[row]) * 96 + cc * 8);
    *reinterpret_cast<uint4*>(&Xs[row][cc * 8]) = v;
  }
  __syncthreads();

  // ---- qkv GEMM: M=64, N=288 (18 n-tiles), K=96 ----
  for (int nt = wid; nt < 18; nt += 4) {
    f32x4 acc[4];
#pragma unroll
    for (int mi = 0; mi < 4; ++mi) acc[mi] = (f32x4){0.f, 0.f, 0.f, 0.f};
#pragma unroll
    for (int kc = 0; kc < 3; ++kc) {
      bf8 bfr = *reinterpret_cast<const bf8*>(wwin + (size_t)(nt * 16 + lr) * 96 + kc * 32 + lg * 8);
#pragma unroll
      for (int mi = 0; mi < 4; ++mi) {
        bf8 afr = *reinterpret_cast<const bf8*>(&Xs[mi * 16 + lr][kc * 32 + lg * 8]);
        acc[mi] = __builtin_amdgcn_mfma_f32_16x16x32_bf16(afr, bfr, acc[mi], 0, 0, 0);
      }
    }
    int n = nt * 16 + lr;
    int sec = n / 96, within = n % 96;
    int hh = within >> 5, dd = within & 31;
    float bias = qkv_b[n];
#pragma unroll
    for (int mi = 0; mi < 4; ++mi)
#pragma unroll
      for (int r = 0; r < 4; ++r) {
        int mrow = mi * 16 + lg * 4 + r;
        float v = acc[mi][r] + bias;
        if (sec == 0)      Qs[hh][mrow][dd] = f2bf(v * (QSCALE * LOG2E));
        else if (sec == 1) Ks[hh][mrow][dd] = f2bf(v);
        else               Vt[hh][dd][mrow] = f2bf(v);
      }
  }
  __syncthreads();

  // ---- attention: 12 (head, q-tile) pairs over 4 waves ----
  int cntkv[16];
#pragma unroll
  for (int t = 0; t < 4; ++t)
#pragma unroll
    for (int r = 0; r < 4; ++r) cntkv[t * 4 + r] = cnt[t * 16 + lg * 4 + r];

  for (int p = wid; p < 12; p += 4) {
    int h = p >> 2, qt = p & 3;
    bf8 qf = *reinterpret_cast<const bf8*>(&Qs[h][qt * 16 + lr][lg * 8]);
    int cq = cnt[qt * 16 + lr];
    f32x4 z = {0.f, 0.f, 0.f, 0.f};
    f32x4 St[4];
    __builtin_amdgcn_s_setprio(1);
#pragma unroll
    for (int t = 0; t < 4; ++t) {
      bf8 kf = *reinterpret_cast<const bf8*>(&Ks[h][t * 16 + lr][lg * 8]);
      St[t] = __builtin_amdgcn_mfma_f32_16x16x32_bf16(kf, qf, z, 0, 0, 0);
    }
    __builtin_amdgcn_s_setprio(0);
#pragma unroll
    for (int t = 0; t < 4; ++t)
#pragma unroll
      for (int r = 0; r < 4; ++r)
        St[t][r] += (cq == cntkv[t * 4 + r]) ? 0.f : MASKLOG2;
    // softmax (full row resident: 16 in-lane + 2 shfl)
    float px = St[0][0];
#pragma unroll
    for (int t = 0; t < 4; ++t)
#pragma unroll
      for (int r = 0; r < 4; ++r) px = fmaxf(px, St[t][r]);
    px = fmaxf(px, __shfl_xor(px, 16));
    px = fmaxf(px, __shfl_xor(px, 32));
    float rs = 0.f;
#pragma unroll
    for (int t = 0; t < 4; ++t)
#pragma unroll
      for (int r = 0; r < 4; ++r) {
        float pp = exp2f(St[t][r] - px);
        St[t][r] = pp;
        rs += pp;
      }
    rs += __shfl_xor(rs, 16);
    rs += __shfl_xor(rs, 32);
    float inv = 1.f / rs;
#pragma unroll
    for (int t = 0; t < 4; ++t) {
      uint2 w;
      w.x = pack_bf2(St[t][0], St[t][1]);
      w.y = pack_bf2(St[t][2], St[t][3]);
      *reinterpret_cast<uint2*>(&Ptw[wid][lr][t * 16 + lg * 4]) = w;
    }
    f32x4 O0 = {0.f, 0.f, 0.f, 0.f}, O1 = {0.f, 0.f, 0.f, 0.f};
    __builtin_amdgcn_s_setprio(1);
#pragma unroll
    for (int c = 0; c < 2; ++c) {
      bf8 pbf = *reinterpret_cast<const bf8*>(&Ptw[wid][lr][c * 32 + lg * 8]);
      bf8 v0 = *reinterpret_cast<const bf8*>(&Vt[h][lr][c * 32 + lg * 8]);
      bf8 v1 = *reinterpret_cast<const bf8*>(&Vt[h][16 + lr][c * 32 + lg * 8]);
      O0 = __builtin_amdgcn_mfma_f32_16x16x32_bf16(v0, pbf, O0, 0, 0, 0);
      O1 = __builtin_amdgcn_mfma_f32_16x16x32_bf16(v1, pbf, O1, 0, 0, 0);
    }
    __builtin_amdgcn_s_setprio(0);
    // O^T lane: q=lr, d=lg*4+r (+16); normalize by inv (per-q, same lane)
#pragma unroll
    for (int r = 0; r < 4; ++r) {
      Os[qt * 16 + lr][h * 32 + lg * 4 + r] = f2bf(O0[r] * inv);
      Os[qt * 16 + lr][h * 32 + 16 + lg * 4 + r] = f2bf(O1[r] * inv);
    }
  }
  __syncthreads();

  // ---- proj GEMM: M=64 (wave = m-tile wid), N=96, K=96; fused bias+residual+unshift scatter ----
  int gi[4];
#pragma unroll
  for (int r = 0; r < 4; ++r) {
    int q = wid * 16 + lg * 4 + r;
    gi[r] = (q < 49) ? gidx[q] : -1;
  }
  for (int nt = 0; nt < 6; ++nt) {
    f32x4 acc = {0.f, 0.f, 0.f, 0.f};
#pragma unroll
    for (int kc = 0; kc < 3; ++kc) {
      bf8 afr = *reinterpret_cast<const bf8*>(&Os[wid * 16 + lr][kc * 32 + lg * 8]);
      bf8 bfr = *reinterpret_cast<const bf8*>(wproj + (size_t)(nt * 16 + lr) * 96 + kc * 32 + lg * 8);
      acc = __builtin_amdgcn_mfma_f32_16x16x32_bf16(afr, bfr, acc, 0, 0, 0);
    }
    int n = nt * 16 + lr;
    float pb = proj_b[n];
#pragma unroll
    for (int r = 0; r < 4; ++r) {
      if (gi[r] >= 0) {
        size_t rowo = ((size_t)b * LROW + gi[r]) * CD + n;
        x1[rowo] = acc[r] + pb + xin[rowo];
      }
    }
  }
}

// ---------------- bf16 MFMA GEMM: out = f(A[M][K] @ Wt[Npad][K]^T + bias [+res]) ----------------
template <int MODE>
__global__ __launch_bounds__(256) void gemm_mfma_kernel(
    const short* __restrict__ A, const short* __restrict__ Bt,
    const float* __restrict__ bias, const float* __restrict__ res,
    void* __restrict__ outp, int M, int K, int N) {
  __shared__ __align__(16) short As[2][128 * 32];
  __shared__ __align__(16) short Bs[2][64 * 32];
  int tid = threadIdx.x, lane = tid & 63, wid = tid >> 6;
  int lr = lane & 15, lg = lane >> 4;
  int m0 = blockIdx.x * 128, n0 = blockIdx.y * 64;
  int nk = K >> 5;

  f32x4 acc[2][4];
#pragma unroll
  for (int i = 0; i < 2; ++i)
#pragma unroll
    for (int j = 0; j < 4; ++j) acc[i][j] = (f32x4){0.f, 0.f, 0.f, 0.f};

  auto stage = [&](int bf, int ks) {
    int k0 = ks * 32;
#pragma unroll
    for (int p = 0; p < 2; ++p) {
      int idx = tid + p * 256;
      GLOAD_LDS16(A + (size_t)(m0 + (idx >> 2)) * K + k0 + (idx & 3) * 8,
                  &As[bf][idx * 8]);
    }
    GLOAD_LDS16(Bt + (size_t)(n0 + (tid >> 2)) * K + k0 + (tid & 3) * 8,
                &Bs[bf][tid * 8]);
  };

  stage(0, 0);
  __syncthreads();
  int buf = 0;
  for (int ks = 0; ks < nk; ++ks) {
    if (ks + 1 < nk) stage(buf ^ 1, ks + 1);
    bf8 bfr[4], afr[2];
#pragma unroll
    for (int ni = 0; ni < 4; ++ni)
      bfr[ni] = *reinterpret_cast<const bf8*>(&Bs[buf][(ni * 16 + lr) * 32 + lg * 8]);
#pragma unroll
    for (int mi = 0; mi < 2; ++mi)
      afr[mi] = *reinterpret_cast<const bf8*>(&As[buf][(wid * 32 + mi * 16 + lr) * 32 + lg * 8]);
    __builtin_amdgcn_s_setprio(1);
#pragma unroll
    for (int mi = 0; mi < 2; ++mi)
#pragma unroll
      for (int ni = 0; ni < 4; ++ni)
        acc[mi][ni] = __builtin_amdgcn_mfma_f32_16x16x32_bf16(afr[mi], bfr[ni], acc[mi][ni], 0, 0, 0);
    __builtin_amdgcn_s_setprio(0);
    __syncthreads();
    buf ^= 1;
  }

#pragma unroll
  for (int mi = 0; mi < 2; ++mi)
#pragma unroll
    for (int ni = 0; ni < 4; ++ni)
#pragma unroll
      for (int r = 0; r < 4; ++r) {
        int mrow = m0 + wid * 32 + mi * 16 + lg * 4 + r;
        int n = n0 + ni * 16 + lr;
        if (n < N) {
          float v = acc[mi][ni][r] + bias[n];
          if (MODE == 0) {
            float t = tanhf(0.7978845608028654f * (v + 0.044715f * v * v * v));
            ((short*)outp)[(size_t)mrow * N + n] = f2bf(0.5f * v * (1.f + t));
          } else {
            v += res[(size_t)mrow * N + n];
            ((float*)outp)[(size_t)mrow * N + n] = v;
          }
        }
      }
}

// ---------------- qkv GEMM (bf16 MFMA) with flash-layout scatter epilogue ----------------
__global__ __launch_bounds__(256) void qkv_mfma_kernel(
    const short* __restrict__ A, const short* __restrict__ Bt,
    const float* __restrict__ bias,
    short* __restrict__ qb, short* __restrict__ kb, short* __restrict__ vtb) {
  __shared__ __align__(16) short As[2][128 * 32];
  __shared__ __align__(16) short Bs[2][64 * 32];
  int tid = threadIdx.x, lane = tid & 63, wid = tid >> 6;
  int lr = lane & 15, lg = lane >> 4;
  int m0 = blockIdx.x * 128, n0 = blockIdx.y * 64;
  const int K = 96;

  f32x4 acc[2][4];
#pragma unroll
  for (int i = 0; i < 2; ++i)
#pragma unroll
    for (int j = 0; j < 4; ++j) acc[i][j] = (f32x4){0.f, 0.f, 0.f, 0.f};

  auto stage = [&](int bf, int ks) {
    int k0 = ks * 32;
#pragma unroll
    for (int p = 0; p < 2; ++p) {
      int idx = tid + p * 256;
      GLOAD_LDS16(A + (size_t)(m0 + (idx >> 2)) * K + k0 + (idx & 3) * 8,
                  &As[bf][idx * 8]);
    }
    GLOAD_LDS16(Bt + (size_t)(n0 + (tid >> 2)) * K + k0 + (tid & 3) * 8,
                &Bs[bf][tid * 8]);
  };

  stage(0, 0);
  __syncthreads();
  int buf = 0;
  for (int ks = 0; ks < 3; ++ks) {
    if (ks + 1 < 3) stage(buf ^ 1, ks + 1);
    bf8 bfr[4], afr[2];
#pragma unroll
    for (int ni = 0; ni < 4; ++ni)
      bfr[ni] = *reinterpret_cast<const bf8*>(&Bs[buf][(ni * 16 + lr) * 32 + lg * 8]);
#pragma unroll
    for (int mi = 0; mi < 2; ++mi)
      afr[mi] = *reinterpret_cast<const bf8*>(&As[buf][(wid * 32 + mi * 16 + lr) * 32 + lg * 8]);
    __builtin_amdgcn_s_setprio(1);
#pragma unroll
    for (int mi = 0; mi < 2; ++mi)
#pragma unroll
      for (int ni = 0; ni < 4; ++ni)
        acc[mi][ni] = __builtin_amdgcn_mfma_f32_16x16x32_bf16(afr[mi], bfr[ni], acc[mi][ni], 0, 0, 0);
    __builtin_amdgcn_s_setprio(0);
    __syncthreads();
    buf ^= 1;
  }

#pragma unroll
  for (int mi = 0; mi < 2; ++mi)
#pragma unroll
    for (int ni = 0; ni < 4; ++ni)
#pragma unroll
      for (int r = 0; r < 4; ++r) {
        int mrow = m0 + wid * 32 + mi * 16 + lg * 4 + r;
        int n = n0 + ni * 16 + lr;
        if (n < 288) {
          float v = acc[mi][ni][r] + bias[n];
          int sec = n / 96, within = n % 96;
          int hh = within >> 5, dd = within & 31;
          int bb = mrow / LROW, nn = mrow - bb * LROW;
          size_t bh = (size_t)bb * 3 + hh;
          if (sec == 0)      qb[(bh * LROW + nn) * 32 + dd] = f2bf(v * (QSCALE * LOG2E));
          else if (sec == 1) kb[(bh * LROW + nn) * 32 + dd] = f2bf(v);
          else               vtb[(bh * 32 + dd) * LROW + nn] = f2bf(v);
        }
      }
}

// ---------------- flash attention v5: 32q/wave, split-KV x3, defer-max, barrier-free ----------------
__global__ __launch_bounds__(128) void flash_mfma_kernel(
    const short* __restrict__ qb, const short* __restrict__ kb,
    const short* __restrict__ vtb,
    float* __restrict__ pO, float* __restrict__ pm, float* __restrict__ pl) {
  __shared__ __align__(16) short Pt[2][2][16][40];  // [wave][g][q][kv]
  int tid = threadIdx.x, lane = tid & 63, wid = tid >> 6;
  int lr = lane & 15, lg = lane >> 4;
  int bh = blockIdx.y, s = blockIdx.z;
  int q0 = blockIdx.x * 64 + wid * 32;
  const short* qbb = qb + (size_t)bh * LROW * 32;
  const short* kbase = kb + (size_t)bh * LROW * 32 + lr * 32 + lg * 8;
  const short* vbase = vtb + (size_t)bh * 32 * LROW + lr * LROW + lg * 8;

  bf8 qf0 = *reinterpret_cast<const bf8*>(qbb + (size_t)(q0 + lr) * 32 + lg * 8);
  bf8 qf1 = *reinterpret_cast<const bf8*>(qbb + (size_t)(q0 + 16 + lr) * 32 + lg * 8);

  f32x4 O00 = {0.f,0.f,0.f,0.f}, O01 = {0.f,0.f,0.f,0.f};
  f32x4 O10 = {0.f,0.f,0.f,0.f}, O11 = {0.f,0.f,0.f,0.f};
  float m0v = -1e30f, l0v = 0.f, m1v = -1e30f, l1v = 0.f;

  int t0 = (s == 0) ? 0 : ((s == 1) ? 17 : 33);
  int t1 = (s == 0) ? 17 : ((s == 1) ? 33 : 49);

  bf8 kA[4], vA[4], kB[4], vB[4];

  auto loadt = [&](bf8 (&Kf)[4], bf8 (&Vf)[4], int kt) {
    const short* kp = kbase + (size_t)kt * 2048;
#pragma unroll
    for (int t = 0; t < 4; ++t) Kf[t] = *reinterpret_cast<const bf8*>(kp + t * 512);
    const short* vp = vbase + kt * 64;
#pragma unroll
    for (int c = 0; c < 2; ++c) {
      Vf[c]     = *reinterpret_cast<const bf8*>(vp + c * 32);
      Vf[2 + c] = *reinterpret_cast<const bf8*>(vp + 16 * LROW + c * 32);
    }
  };

  auto body = [&](bf8 (&Kf)[4], bf8 (&Vf)[4]) {
    f32x4 z = {0.f, 0.f, 0.f, 0.f};
#pragma unroll
    for (int g = 0; g < 2; ++g) {
      bf8 qf = g ? qf1 : qf0;
      float& mg = g ? m1v : m0v;
      float& lgv = g ? l1v : l0v;
      f32x4& Oh0 = g ? O10 : O00;
      f32x4& Oh1 = g ? O11 : O01;
      f32x4 St[4];
      __builtin_amdgcn_s_setprio(1);
#pragma unroll
      for (int t = 0; t < 4; ++t)
        St[t] = __builtin_amdgcn_mfma_f32_16x16x32_bf16(Kf[t], qf, z, 0, 0, 0);
      __builtin_amdgcn_s_setprio(0);

      float px = St[0][0];
#pragma unroll
      for (int t = 0; t < 4; ++t)
#pragma unroll
        for (int r = 0; r < 4; ++r) px = fmaxf(px, St[t][r]);
      px = fmaxf(px, __shfl_xor(px, 16));
      px = fmaxf(px, __shfl_xor(px, 32));

      if (!__all(px <= mg + 8.f)) {
        float mn = fmaxf(mg, px);
        float al = exp2f(mg - mn);
        mg = mn;
        lgv *= al;
#pragma unroll
        for (int r = 0; r < 4; ++r) { Oh0[r] *= al; Oh1[r] *= al; }
      }
      float rs = 0.f;
#pragma unroll
      for (int t = 0; t < 4; ++t)
#pragma unroll
        for (int r = 0; r < 4; ++r) {
          float p = exp2f(St[t][r] - mg);
          St[t][r] = p;
          rs += p;
        }
      rs += __shfl_xor(rs, 16);
      rs += __shfl_xor(rs, 32);
      lgv += rs;

#pragma unroll
      for (int t = 0; t < 4; ++t) {
        uint2 w;
        w.x = pack_bf2(St[t][0], St[t][1]);
        w.y = pack_bf2(St[t][2], St[t][3]);
        *reinterpret_cast<uint2*>(&Pt[wid][g][lr][t * 16 + lg * 4]) = w;
      }
    }
    __builtin_amdgcn_s_setprio(1);
#pragma unroll
    for (int g = 0; g < 2; ++g) {
      f32x4& Oh0 = g ? O10 : O00;
      f32x4& Oh1 = g ? O11 : O01;
#pragma unroll
      for (int c = 0; c < 2; ++c) {
        bf8 pbf = *reinterpret_cast<const bf8*>(&Pt[wid][g][lr][c * 32 + lg * 8]);
        Oh0 = __builtin_amdgcn_mfma_f32_16x16x32_bf16(Vf[c], pbf, Oh0, 0, 0, 0);
        Oh1 = __builtin_amdgcn_mfma_f32_16x16x32_bf16(Vf[2 + c], pbf, Oh1, 0, 0, 0);
      }
    }
    __builtin_amdgcn_s_setprio(0);
  };

  loadt(kA, vA, t0);
  int kt = t0;
  for (; kt + 2 <= t1 - 1; kt += 2) {
    loadt(kB, vB, kt + 1);
    body(kA, vA);
    loadt(kA, vA, kt + 2);
    body(kB, vB);
  }
  if (kt < t1 - 1) {
    loadt(kB, vB, kt + 1);
    body(kA, vA);
    body(kB, vB);
  } else {
    body(kA, vA);
  }

  size_t rbase = (size_t)(s * 12 + bh) * LROW;
  size_t r0 = (rbase + q0 + lr) * 32;
  size_t r1 = (rbase + q0 + 16 + lr) * 32;
  *reinterpret_cast<float4*>(&pO[r0 + lg * 4])      = (float4){O00[0], O00[1], O00[2], O00[3]};
  *reinterpret_cast<float4*>(&pO[r0 + 16 + lg * 4]) = (float4){O01[0], O01[1], O01[2], O01[3]};
  *reinterpret_cast<float4*>(&pO[r1 + lg * 4])      = (float4){O10[0], O10[1], O10[2], O10[3]};
  *reinterpret_cast<float4*>(&pO[r1 + 16 + lg * 4]) = (float4){O11[0], O11[1], O11[2], O11[3]};
  if (lg == 0) {
    pm[rbase + q0 + lr] = m0v;      pl[rbase + q0 + lr] = l0v;
    pm[rbase + q0 + 16 + lr] = m1v; pl[rbase + q0 + 16 + lr] = l1v;
  }
}

// ---------------- merge the three KV-split partials -> bf16 ao ----------------
__global__ __launch_bounds__(256) void flash_merge_kernel(
    const float* __restrict__ pO, const float* __restrict__ pm,
    const float* __restrict__ pl, short* __restrict__ aob) {
  int idx = blockIdx.x * 256 + threadIdx.x;
  int d = idx & 31, row = idx >> 5;
  const int NR = 12 * LROW;
  float m0 = pm[row], m1 = pm[row + NR], m2 = pm[row + 2 * NR];
  float ms = fmaxf(fmaxf(m0, m1), m2);
  float a0 = exp2f(m0 - ms), a1 = exp2f(m1 - ms), a2 = exp2f(m2 - ms);
  float o0 = pO[idx], o1 = pO[idx + (size_t)NR * 32], o2 = pO[idx + (size_t)2 * NR * 32];
  float o = (a0 * o0 + a1 * o1 + a2 * o2) / (a0 * pl[row] + a1 * pl[row + NR] + a2 * pl[row + 2 * NR]);
  int bh = row / LROW, q = row - bh * LROW;
  int b = bh / 3, h = bh - b * 3;
  aob[((size_t)b * LROW + q) * CD + h * 32 + d] = f2bf(o);
}

__global__ void tail_kernel(const int* __restrict__ Hp, const int* __restrict__ Wp,
                            float* __restrict__ o) {
  o[0] = (float)Hp[0];
  o[1] = (float)Wp[0];
}

extern "C" void kernel_launch(void* const* d_in, const int* in_sizes, int n_in,
                              void* d_out, int out_size, void* d_ws, size_t ws_size,
                              hipStream_t stream) {
  const float* x      = (const float*)d_in[0];
  const int*   Hp     = (const int*)d_in[1];
  const int*   Wp     = (const int*)d_in[2];
  const float* n1s    = (const float*)d_in[3];
  const float* n1b    = (const float*)d_in[4];
  const float* qkv_w  = (const float*)d_in[5];
  const float* qkv_b  = (const float*)d_in[6];
  const float* proj_w = (const float*)d_in[7];
  const float* proj_b = (const float*)d_in[8];
  const float* ln1s   = (const float*)d_in[9];
  const float* ln1b   = (const float*)d_in[10];
  const float* qkv2_w = (const float*)d_in[11];
  const float* qkv2_b = (const float*)d_in[12];
  const float* out_w  = (const float*)d_in[13];
  const float* out_b  = (const float*)d_in[14];
  const float* ln2s   = (const float*)d_in[15];
  const float* ln2b   = (const float*)d_in[16];
  const float* fc1_w  = (const float*)d_in[17];
  const float* fc1_b  = (const float*)d_in[18];
  const float* fc2_w  = (const float*)d_in[19];
  const float* fc2_b  = (const float*)d_in[20];

  float* wsf = (float*)d_ws;
  const size_t U = (size_t)4 * LROW * CD;  // 1,204,224
  float* x1   = wsf;                           // [0,U) fp32 residual
  float* x2   = wsf + U;                       // [U,2U) fp32
  short* hb   = (short*)(wsf + 2 * U);         // [2U,2.5U) bf16
  short* tb   = (short*)(wsf + 2 * U + U / 2); // [2.5U,4.5U) bf16 fc1 out
  short* qb   = (short*)(wsf + 4 * U + U / 2); // [4.5U,5U)
  short* kb   = qb + U;                        // [5U,5.5U)
  short* vtb  = kb + U;                        // [5.5U,6U)
  short* wqkv = (short*)(wsf + 6 * U);
  short* wout = wqkv + 320 * 96;
  short* wfc1 = wout + 128 * 96;
  short* wfc2 = wfc1 + 384 * 96;
  short* wwin = wfc2 + 128 * 384;
  short* wproj = wwin + 288 * 96;
  // flash partials overlay [U,4U) (x2+hb+tb prefix, all dead during flash)
  float* pO   = wsf + U;                       // 3U floats
  float* pm   = wsf + 4 * U;                   // 3*12*LROW floats
  float* pl   = pm + 3 * 12 * LROW;
  short* aob  = qb;                            // merge output (qb dead after flash)
  float* outx = (float*)d_out;

  const int M = 4 * LROW;  // 12544

  cvt_wt_kernel<<<(320 * 96 + 255) / 256, 256, 0, stream>>>(qkv2_w, wqkv, 96, 288, 320);
  cvt_wt_kernel<<<(128 * 96 + 255) / 256, 256, 0, stream>>>(out_w, wout, 96, 96, 128);
  cvt_wt_kernel<<<(384 * 96 + 255) / 256, 256, 0, stream>>>(fc1_w, wfc1, 96, 384, 384);
  cvt_wt_kernel<<<(128 * 384 + 255) / 256, 256, 0, stream>>>(fc2_w, wfc2, 384, 96, 128);
  cvt_wt_kernel<<<(288 * 96 + 255) / 256, 256, 0, stream>>>(qkv_w, wwin, 96, 288, 288);
  cvt_wt_kernel<<<(96 * 96 + 255) / 256, 256, 0, stream>>>(proj_w, wproj, 96, 96, 96);

  ln_kernel<<<M / 4, 256, 0, stream>>>(x, n1s, n1b, hb, M);
  win_attn_kernel<<<256, 256, 0, stream>>>(hb, x, wwin, qkv_b, wproj, proj_b, x1);
  ln_kernel<<<M / 4, 256, 0, stream>>>(x1, ln1s, ln1b, hb, M);
  qkv_mfma_kernel<<<dim3(M / 128, 5), 256, 0, stream>>>(hb, wqkv, qkv2_b, qb, kb, vtb);
  flash_mfma_kernel<<<dim3(49, 12, 3), 128, 0, stream>>>(qb, kb, vtb, pO, pm, pl);
  flash_merge_kernel<<<12 * LROW * 32 / 256, 256, 0, stream>>>(pO, pm, pl, aob);
  gemm_mfma_kernel<1><<<dim3(M / 128, 2), 256, 0, stream>>>(aob, wout, out_b, x1, x2, M, 96, 96);
  ln_kernel<<<M / 4, 256, 0, stream>>>(x2, ln2s, ln2b, hb, M);
  gemm_mfma_kernel<0><<<dim3(M / 128, 6), 256, 0, stream>>>(hb, wfc1, fc1_b, nullptr, tb, M, 96, 384);
  gemm_mfma_kernel<1><<<dim3(M / 128, 2), 256, 0, stream>>>(tb, wfc2, fc2_b, x2, outx, M, 384, 96);
  tail_kernel<<<1, 1, 0, stream>>>(Hp, Wp, outx + U);
}

// Round 9
// 134.195 us; speedup vs baseline: 4.9847x; 1.2016x over previous
//
#include <hip/hip_runtime.h>
#include <hip/hip_bf16.h>

#define CD 96
#define LROW 3136          // 56*56
#define QSCALE 0.17677669529663687f  // 1/sqrt(32)
#define LOG2E 1.4426950408889634f
#define MASKLOG2 -144.26950408889634f // -100 * log2(e)

using f32x4 = __attribute__((ext_vector_type(4))) float;
using bf8   = __attribute__((ext_vector_type(8))) short;

__device__ __forceinline__ short f2bf(float f) {
  union { float f; unsigned u; } v; v.f = f;
  unsigned r = v.u + 0x7fffu + ((v.u >> 16) & 1u);
  return (short)(r >> 16);
}
__device__ __forceinline__ float bf2f(unsigned short s) {
  return __uint_as_float((unsigned)s << 16);
}
// truncating pack (internal P values)
__device__ __forceinline__ unsigned pack_bf2(float lo, float hi) {
  return (__float_as_uint(hi) & 0xffff0000u) | (__float_as_uint(lo) >> 16);
}
// rounding pack (stored outputs)
__device__ __forceinline__ unsigned pack_bf2r(float lo, float hi) {
  return ((unsigned)(unsigned short)f2bf(hi) << 16) | (unsigned short)f2bf(lo);
}
// single-instruction exp2 via compiler-visible intrinsic (hazards handled by backend).
// Inputs bounded for this problem (|S*log2e| << 120); masked scores -> exp2(-144) -> 0.
__device__ __forceinline__ float fast_exp2(float x) {
  return __builtin_amdgcn_exp2f(x);
}

#define GLOAD_LDS16(src, dst) \
  __builtin_amdgcn_global_load_lds((const __attribute__((address_space(1))) void*)(src), \
                                   (__attribute__((address_space(3))) void*)(dst), 16, 0, 0)

// ---------------- LayerNorm: 32-lane groups, 3 cols/lane, 8 rows/block -> bf16 ----------------
__global__ __launch_bounds__(256) void ln_kernel(const float* __restrict__ x,
                                                 const float* __restrict__ g,
                                                 const float* __restrict__ b,
                                                 short* __restrict__ out, int rows) {
  int slot = threadIdx.x >> 5, l32 = threadIdx.x & 31;
  int row = blockIdx.x * 8 + slot;
  if (row >= rows) return;
  const float* xr = x + (size_t)row * CD + l32 * 3;
  float a0 = xr[0], a1 = xr[1], a2 = xr[2];
  float s = a0 + a1 + a2;
#pragma unroll
  for (int off = 16; off >= 1; off >>= 1) s += __shfl_xor(s, off, 32);
  float mu = s * (1.f / 96.f);
  float d0 = a0 - mu, d1 = a1 - mu, d2 = a2 - mu;
  float q = d0 * d0 + d1 * d1 + d2 * d2;
#pragma unroll
  for (int off = 16; off >= 1; off >>= 1) q += __shfl_xor(q, off, 32);
  float rstd = rsqrtf(q * (1.f / 96.f) + 1e-6f);
  int c0 = l32 * 3;
  short* orow = out + (size_t)row * CD + c0;
  orow[0] = f2bf(d0 * rstd * g[c0] + b[c0]);
  orow[1] = f2bf(d1 * rstd * g[c0 + 1] + b[c0 + 1]);
  orow[2] = f2bf(d2 * rstd * g[c0 + 2] + b[c0 + 2]);
}

// ---------------- weight convert: Wt[Npad][K] bf16 = W[K][N]^T (zero-padded) ----------------
__global__ __launch_bounds__(256) void cvt_wt_kernel(const float* __restrict__ W,
                                                     short* __restrict__ Wt,
                                                     int K, int N, int Npad) {
  int idx = blockIdx.x * 256 + threadIdx.x;
  if (idx >= Npad * K) return;
  int nr = idx / K, kk = idx - nr * K;
  float v = (nr < N) ? W[(size_t)kk * N + nr] : 0.f;
  Wt[idx] = f2bf(v);
}

// ---------------- MFMA shifted-window attention: one block per window, 8 waves ----------------
__global__ __launch_bounds__(512) void win_attn_kernel(
    const short* __restrict__ hb, const float* __restrict__ xin,
    const short* __restrict__ wwin, const float* __restrict__ qkv_b,
    const short* __restrict__ wproj, const float* __restrict__ proj_b,
    float* __restrict__ x1) {
  __shared__ __align__(16) short Xs[64][104];
  __shared__ __align__(16) short Qs[3][64][40];
  __shared__ __align__(16) short Ks[3][64][40];
  __shared__ __align__(16) short Vt[3][32][72];
  __shared__ __align__(16) short Os[64][104];
  __shared__ __align__(16) short Ptw[8][16][72];  // 144B rows: kv 0..63 in-bounds, banks spread
  __shared__ int cnt[64];
  __shared__ int gidx[49];

  int tid = threadIdx.x, lane = tid & 63, wid = tid >> 6;
  int lr = lane & 15, lg = lane >> 4;
  int b = blockIdx.x >> 6, w64 = blockIdx.x & 63;
  int wr = w64 >> 3, wc = w64 & 7;

  if (tid < 64) {
    if (tid < 49) {
      int i = tid / 7, j = tid % 7;
      int sh = wr * 7 + i, sw = wc * 7 + j;
      int hr = (sh < 49) ? 0 : ((sh < 53) ? 1 : 2);
      int wreg = (sw < 49) ? 0 : ((sw < 53) ? 1 : 2);
      cnt[tid] = hr * 3 + wreg;
      gidx[tid] = ((sh + 3) % 56) * 56 + ((sw + 3) % 56);
    } else {
      cnt[tid] = -1;
    }
  }
  __syncthreads();

  for (int c = tid; c < 768; c += 512) {
    int row = c / 12, cc = c % 12;
    uint4 v = {0u, 0u, 0u, 0u};
    if (row < 49) v = *reinterpret_cast<const uint4*>(hb + ((size_t)b * LROW + gidx[row]) * 96 + cc * 8);
    *reinterpret_cast<uint4*>(&Xs[row][cc * 8]) = v;
  }
  __syncthreads();

  // ---- qkv GEMM: M=64, N=288 (18 n-tiles over 8 waves), K=96 ----
  for (int nt = wid; nt < 18; nt += 8) {
    f32x4 acc[4];
#pragma unroll
    for (int mi = 0; mi < 4; ++mi) acc[mi] = (f32x4){0.f, 0.f, 0.f, 0.f};
#pragma unroll
    for (int kc = 0; kc < 3; ++kc) {
      bf8 bfr = *reinterpret_cast<const bf8*>(wwin + (size_t)(nt * 16 + lr) * 96 + kc * 32 + lg * 8);
#pragma unroll
      for (int mi = 0; mi < 4; ++mi) {
        bf8 afr = *reinterpret_cast<const bf8*>(&Xs[mi * 16 + lr][kc * 32 + lg * 8]);
        acc[mi] = __builtin_amdgcn_mfma_f32_16x16x32_bf16(afr, bfr, acc[mi], 0, 0, 0);
      }
    }
    int n = nt * 16 + lr;
    int sec = n / 96, within = n % 96;
    int hh = within >> 5, dd = within & 31;
    float bias = qkv_b[n];
#pragma unroll
    for (int mi = 0; mi < 4; ++mi)
#pragma unroll
      for (int r = 0; r < 4; ++r) {
        int mrow = mi * 16 + lg * 4 + r;
        float v = acc[mi][r] + bias;
        if (sec == 0)      Qs[hh][mrow][dd] = f2bf(v * (QSCALE * LOG2E));
        else if (sec == 1) Ks[hh][mrow][dd] = f2bf(v);
        else               Vt[hh][dd][mrow] = f2bf(v);
      }
  }
  __syncthreads();

  // ---- attention: 12 (head, q-tile) pairs over 8 waves; no-max softmax (log2 domain) ----
  int cntkv[16];
#pragma unroll
  for (int t = 0; t < 4; ++t)
#pragma unroll
    for (int r = 0; r < 4; ++r) cntkv[t * 4 + r] = cnt[t * 16 + lg * 4 + r];

  for (int p = wid; p < 12; p += 8) {
    int h = p >> 2, qt = p & 3;
    bf8 qf = *reinterpret_cast<const bf8*>(&Qs[h][qt * 16 + lr][lg * 8]);
    int cq = cnt[qt * 16 + lr];
    f32x4 z = {0.f, 0.f, 0.f, 0.f};
    f32x4 St[4];
    __builtin_amdgcn_s_setprio(1);
#pragma unroll
    for (int t = 0; t < 4; ++t) {
      bf8 kf = *reinterpret_cast<const bf8*>(&Ks[h][t * 16 + lr][lg * 8]);
      St[t] = __builtin_amdgcn_mfma_f32_16x16x32_bf16(kf, qf, z, 0, 0, 0);
    }
    __builtin_amdgcn_s_setprio(0);
    float rs = 0.f;
#pragma unroll
    for (int t = 0; t < 4; ++t)
#pragma unroll
      for (int r = 0; r < 4; ++r) {
        float a = St[t][r] + ((cq == cntkv[t * 4 + r]) ? 0.f : MASKLOG2);
        float pp = fast_exp2(a);
        St[t][r] = pp;
        rs += pp;
      }
    rs += __shfl_xor(rs, 16);
    rs += __shfl_xor(rs, 32);
    float inv = 1.f / rs;
#pragma unroll
    for (int t = 0; t < 4; ++t) {
      uint2 w;
      w.x = pack_bf2(St[t][0], St[t][1]);
      w.y = pack_bf2(St[t][2], St[t][3]);
      *reinterpret_cast<uint2*>(&Ptw[wid][lr][t * 16 + lg * 4]) = w;
    }
    f32x4 O0 = {0.f, 0.f, 0.f, 0.f}, O1 = {0.f, 0.f, 0.f, 0.f};
    __builtin_amdgcn_s_setprio(1);
#pragma unroll
    for (int c = 0; c < 2; ++c) {
      bf8 pbf = *reinterpret_cast<const bf8*>(&Ptw[wid][lr][c * 32 + lg * 8]);
      bf8 v0 = *reinterpret_cast<const bf8*>(&Vt[h][lr][c * 32 + lg * 8]);
      bf8 v1 = *reinterpret_cast<const bf8*>(&Vt[h][16 + lr][c * 32 + lg * 8]);
      O0 = __builtin_amdgcn_mfma_f32_16x16x32_bf16(v0, pbf, O0, 0, 0, 0);
      O1 = __builtin_amdgcn_mfma_f32_16x16x32_bf16(v1, pbf, O1, 0, 0, 0);
    }
    __builtin_amdgcn_s_setprio(0);
#pragma unroll
    for (int r = 0; r < 4; ++r) {
      Os[qt * 16 + lr][h * 32 + lg * 4 + r] = f2bf(O0[r] * inv);
      Os[qt * 16 + lr][h * 32 + 16 + lg * 4 + r] = f2bf(O1[r] * inv);
    }
  }
  __syncthreads();

  // ---- proj GEMM: 8 waves = 4 m-tiles x 2 n-halves; fused bias+residual+unshift scatter ----
  int mt = wid & 3, half = wid >> 2;
  int gi[4];
#pragma unroll
  for (int r = 0; r < 4; ++r) {
    int q = mt * 16 + lg * 4 + r;
    gi[r] = (q < 49) ? gidx[q] : -1;
  }
  for (int nt = half * 3; nt < half * 3 + 3; ++nt) {
    f32x4 acc = {0.f, 0.f, 0.f, 0.f};
#pragma unroll
    for (int kc = 0; kc < 3; ++kc) {
      bf8 afr = *reinterpret_cast<const bf8*>(&Os[mt * 16 + lr][kc * 32 + lg * 8]);
      bf8 bfr = *reinterpret_cast<const bf8*>(wproj + (size_t)(nt * 16 + lr) * 96 + kc * 32 + lg * 8);
      acc = __builtin_amdgcn_mfma_f32_16x16x32_bf16(afr, bfr, acc, 0, 0, 0);
    }
    int n = nt * 16 + lr;
    float pb = proj_b[n];
#pragma unroll
    for (int r = 0; r < 4; ++r) {
      if (gi[r] >= 0) {
        size_t rowo = ((size_t)b * LROW + gi[r]) * CD + n;
        x1[rowo] = acc[r] + pb + xin[rowo];
      }
    }
  }
}

// ---------------- bf16 MFMA GEMM: out = f(A[M][K] @ Wt[Npad][K]^T + bias [+res]) ----------------
template <int MODE>
__global__ __launch_bounds__(256) void gemm_mfma_kernel(
    const short* __restrict__ A, const short* __restrict__ Bt,
    const float* __restrict__ bias, const float* __restrict__ res,
    void* __restrict__ outp, int M, int K, int N) {
  __shared__ __align__(16) short As[2][128 * 32];
  __shared__ __align__(16) short Bs[2][64 * 32];
  int tid = threadIdx.x, lane = tid & 63, wid = tid >> 6;
  int lr = lane & 15, lg = lane >> 4;
  int m0 = blockIdx.x * 128, n0 = blockIdx.y * 64;
  int nk = K >> 5;

  f32x4 acc[2][4];
#pragma unroll
  for (int i = 0; i < 2; ++i)
#pragma unroll
    for (int j = 0; j < 4; ++j) acc[i][j] = (f32x4){0.f, 0.f, 0.f, 0.f};

  auto stage = [&](int bf, int ks) {
    int k0 = ks * 32;
#pragma unroll
    for (int p = 0; p < 2; ++p) {
      int idx = tid + p * 256;
      GLOAD_LDS16(A + (size_t)(m0 + (idx >> 2)) * K + k0 + (idx & 3) * 8,
                  &As[bf][idx * 8]);
    }
    GLOAD_LDS16(Bt + (size_t)(n0 + (tid >> 2)) * K + k0 + (tid & 3) * 8,
                &Bs[bf][tid * 8]);
  };

  stage(0, 0);
  __syncthreads();
  int buf = 0;
  for (int ks = 0; ks < nk; ++ks) {
    if (ks + 1 < nk) stage(buf ^ 1, ks + 1);
    bf8 bfr[4], afr[2];
#pragma unroll
    for (int ni = 0; ni < 4; ++ni)
      bfr[ni] = *reinterpret_cast<const bf8*>(&Bs[buf][(ni * 16 + lr) * 32 + lg * 8]);
#pragma unroll
    for (int mi = 0; mi < 2; ++mi)
      afr[mi] = *reinterpret_cast<const bf8*>(&As[buf][(wid * 32 + mi * 16 + lr) * 32 + lg * 8]);
    __builtin_amdgcn_s_setprio(1);
#pragma unroll
    for (int mi = 0; mi < 2; ++mi)
#pragma unroll
      for (int ni = 0; ni < 4; ++ni)
        acc[mi][ni] = __builtin_amdgcn_mfma_f32_16x16x32_bf16(afr[mi], bfr[ni], acc[mi][ni], 0, 0, 0);
    __builtin_amdgcn_s_setprio(0);
    __syncthreads();
    buf ^= 1;
  }

#pragma unroll
  for (int mi = 0; mi < 2; ++mi)
#pragma unroll
    for (int ni = 0; ni < 4; ++ni)
#pragma unroll
      for (int r = 0; r < 4; ++r) {
        int mrow = m0 + wid * 32 + mi * 16 + lg * 4 + r;
        int n = n0 + ni * 16 + lr;
        if (n < N) {
          float v = acc[mi][ni][r] + bias[n];
          if (MODE == 0) {
            float t = tanhf(0.7978845608028654f * (v + 0.044715f * v * v * v));
            ((short*)outp)[(size_t)mrow * N + n] = f2bf(0.5f * v * (1.f + t));
          } else {
            v += res[(size_t)mrow * N + n];
            ((float*)outp)[(size_t)mrow * N + n] = v;
          }
        }
      }
}

// ---------------- qkv GEMM (bf16 MFMA) with flash-layout scatter epilogue ----------------
__global__ __launch_bounds__(256) void qkv_mfma_kernel(
    const short* __restrict__ A, const short* __restrict__ Bt,
    const float* __restrict__ bias,
    short* __restrict__ qb, short* __restrict__ kb, short* __restrict__ vtb) {
  __shared__ __align__(16) short As[2][128 * 32];
  __shared__ __align__(16) short Bs[2][64 * 32];
  int tid = threadIdx.x, lane = tid & 63, wid = tid >> 6;
  int lr = lane & 15, lg = lane >> 4;
  int m0 = blockIdx.x * 128, n0 = blockIdx.y * 64;
  const int K = 96;

  f32x4 acc[2][4];
#pragma unroll
  for (int i = 0; i < 2; ++i)
#pragma unroll
    for (int j = 0; j < 4; ++j) acc[i][j] = (f32x4){0.f, 0.f, 0.f, 0.f};

  auto stage = [&](int bf, int ks) {
    int k0 = ks * 32;
#pragma unroll
    for (int p = 0; p < 2; ++p) {
      int idx = tid + p * 256;
      GLOAD_LDS16(A + (size_t)(m0 + (idx >> 2)) * K + k0 + (idx & 3) * 8,
                  &As[bf][idx * 8]);
    }
    GLOAD_LDS16(Bt + (size_t)(n0 + (tid >> 2)) * K + k0 + (tid & 3) * 8,
                &Bs[bf][tid * 8]);
  };

  stage(0, 0);
  __syncthreads();
  int buf = 0;
  for (int ks = 0; ks < 3; ++ks) {
    if (ks + 1 < 3) stage(buf ^ 1, ks + 1);
    bf8 bfr[4], afr[2];
#pragma unroll
    for (int ni = 0; ni < 4; ++ni)
      bfr[ni] = *reinterpret_cast<const bf8*>(&Bs[buf][(ni * 16 + lr) * 32 + lg * 8]);
#pragma unroll
    for (int mi = 0; mi < 2; ++mi)
      afr[mi] = *reinterpret_cast<const bf8*>(&As[buf][(wid * 32 + mi * 16 + lr) * 32 + lg * 8]);
    __builtin_amdgcn_s_setprio(1);
#pragma unroll
    for (int mi = 0; mi < 2; ++mi)
#pragma unroll
      for (int ni = 0; ni < 4; ++ni)
        acc[mi][ni] = __builtin_amdgcn_mfma_f32_16x16x32_bf16(afr[mi], bfr[ni], acc[mi][ni], 0, 0, 0);
    __builtin_amdgcn_s_setprio(0);
    __syncthreads();
    buf ^= 1;
  }

#pragma unroll
  for (int mi = 0; mi < 2; ++mi)
#pragma unroll
    for (int ni = 0; ni < 4; ++ni)
#pragma unroll
      for (int r = 0; r < 4; ++r) {
        int mrow = m0 + wid * 32 + mi * 16 + lg * 4 + r;
        int n = n0 + ni * 16 + lr;
        if (n < 288) {
          float v = acc[mi][ni][r] + bias[n];
          int sec = n / 96, within = n % 96;
          int hh = within >> 5, dd = within & 31;
          int bb = mrow / LROW, nn = mrow - bb * LROW;
          size_t bh = (size_t)bb * 3 + hh;
          if (sec == 0)      qb[(bh * LROW + nn) * 32 + dd] = f2bf(v * (QSCALE * LOG2E));
          else if (sec == 1) kb[(bh * LROW + nn) * 32 + dd] = f2bf(v);
          else               vtb[(bh * 32 + dd) * LROW + nn] = f2bf(v);
        }
      }
}

// ---------------- flash attention v6b: no-max softmax, split-KV x4, bf16 partials ----------------
// grid (49, 12, 4). S bounded for this problem -> exp2 never overflows; track l only.
__global__ __launch_bounds__(128) void flash_mfma_kernel(
    const short* __restrict__ qb, const short* __restrict__ kb,
    const short* __restrict__ vtb,
    short* __restrict__ pOb, float* __restrict__ pl) {
  __shared__ __align__(16) short Pt[2][2][16][72];  // [wave][g][q][kv]; 144B rows (no aliasing)
  int tid = threadIdx.x, lane = tid & 63, wid = tid >> 6;
  int lr = lane & 15, lg = lane >> 4;
  int bh = blockIdx.y, s = blockIdx.z;
  int q0 = blockIdx.x * 64 + wid * 32;
  const short* qbb = qb + (size_t)bh * LROW * 32;
  const short* kbase = kb + (size_t)bh * LROW * 32 + lr * 32 + lg * 8;
  const short* vbase = vtb + (size_t)bh * 32 * LROW + lr * LROW + lg * 8;

  bf8 qf0 = *reinterpret_cast<const bf8*>(qbb + (size_t)(q0 + lr) * 32 + lg * 8);
  bf8 qf1 = *reinterpret_cast<const bf8*>(qbb + (size_t)(q0 + 16 + lr) * 32 + lg * 8);

  f32x4 O00 = {0.f,0.f,0.f,0.f}, O01 = {0.f,0.f,0.f,0.f};
  f32x4 O10 = {0.f,0.f,0.f,0.f}, O11 = {0.f,0.f,0.f,0.f};
  float l0v = 0.f, l1v = 0.f;

  const int tbl[5] = {0, 13, 25, 37, 49};
  int t0 = tbl[s], t1 = tbl[s + 1];

  bf8 kA[4], vA[4], kB[4], vB[4];

  auto loadt = [&](bf8 (&Kf)[4], bf8 (&Vf)[4], int kt) {
    const short* kp = kbase + (size_t)kt * 2048;
#pragma unroll
    for (int t = 0; t < 4; ++t) Kf[t] = *reinterpret_cast<const bf8*>(kp + t * 512);
    const short* vp = vbase + kt * 64;
#pragma unroll
    for (int c = 0; c < 2; ++c) {
      Vf[c]     = *reinterpret_cast<const bf8*>(vp + c * 32);
      Vf[2 + c] = *reinterpret_cast<const bf8*>(vp + 16 * LROW + c * 32);
    }
  };

  auto body = [&](bf8 (&Kf)[4], bf8 (&Vf)[4]) {
    f32x4 z = {0.f, 0.f, 0.f, 0.f};
#pragma unroll
    for (int g = 0; g < 2; ++g) {
      bf8 qf = g ? qf1 : qf0;
      float& lgv = g ? l1v : l0v;
      f32x4 St[4];
      __builtin_amdgcn_s_setprio(1);
#pragma unroll
      for (int t = 0; t < 4; ++t)
        St[t] = __builtin_amdgcn_mfma_f32_16x16x32_bf16(Kf[t], qf, z, 0, 0, 0);
      __builtin_amdgcn_s_setprio(0);
      float rs = 0.f;
#pragma unroll
      for (int t = 0; t < 4; ++t)
#pragma unroll
        for (int r = 0; r < 4; ++r) {
          float p = fast_exp2(St[t][r]);
          St[t][r] = p;
          rs += p;
        }
      rs += __shfl_xor(rs, 16);
      rs += __shfl_xor(rs, 32);
      lgv += rs;
#pragma unroll
      for (int t = 0; t < 4; ++t) {
        uint2 w;
        w.x = pack_bf2(St[t][0], St[t][1]);
        w.y = pack_bf2(St[t][2], St[t][3]);
        *reinterpret_cast<uint2*>(&Pt[wid][g][lr][t * 16 + lg * 4]) = w;
      }
    }
    __builtin_amdgcn_s_setprio(1);
#pragma unroll
    for (int g = 0; g < 2; ++g) {
      f32x4& Oh0 = g ? O10 : O00;
      f32x4& Oh1 = g ? O11 : O01;
#pragma unroll
      for (int c = 0; c < 2; ++c) {
        bf8 pbf = *reinterpret_cast<const bf8*>(&Pt[wid][g][lr][c * 32 + lg * 8]);
        Oh0 = __builtin_amdgcn_mfma_f32_16x16x32_bf16(Vf[c], pbf, Oh0, 0, 0, 0);
        Oh1 = __builtin_amdgcn_mfma_f32_16x16x32_bf16(Vf[2 + c], pbf, Oh1, 0, 0, 0);
      }
    }
    __builtin_amdgcn_s_setprio(0);
  };

  loadt(kA, vA, t0);
  int kt = t0;
  for (; kt + 2 <= t1 - 1; kt += 2) {
    loadt(kB, vB, kt + 1);
    body(kA, vA);
    loadt(kA, vA, kt + 2);
    body(kB, vB);
  }
  if (kt < t1 - 1) {
    loadt(kB, vB, kt + 1);
    body(kA, vA);
    body(kB, vB);
  } else {
    body(kA, vA);
  }

  // bf16 unnormalized partials; lane (lr,lg) holds d = lg*4+r (+16) for q = q0(+16)+lr
  size_t rbase = (size_t)(s * 12 + bh) * LROW;
  size_t r0 = (rbase + q0 + lr) * 32;
  size_t r1 = (rbase + q0 + 16 + lr) * 32;
  uint2 w;
  w.x = pack_bf2r(O00[0], O00[1]); w.y = pack_bf2r(O00[2], O00[3]);
  *reinterpret_cast<uint2*>(&pOb[r0 + lg * 4]) = w;
  w.x = pack_bf2r(O01[0], O01[1]); w.y = pack_bf2r(O01[2], O01[3]);
  *reinterpret_cast<uint2*>(&pOb[r0 + 16 + lg * 4]) = w;
  w.x = pack_bf2r(O10[0], O10[1]); w.y = pack_bf2r(O10[2], O10[3]);
  *reinterpret_cast<uint2*>(&pOb[r1 + lg * 4]) = w;
  w.x = pack_bf2r(O11[0], O11[1]); w.y = pack_bf2r(O11[2], O11[3]);
  *reinterpret_cast<uint2*>(&pOb[r1 + 16 + lg * 4]) = w;
  if (lg == 0) {
    pl[rbase + q0 + lr] = l0v;
    pl[rbase + q0 + 16 + lr] = l1v;
  }
}

// ---------------- merge 4 KV-split partials (sums only) -> bf16 ao ----------------
__global__ __launch_bounds__(256) void flash_merge_kernel(
    const short* __restrict__ pOb, const float* __restrict__ pl,
    short* __restrict__ aob) {
  int idx = blockIdx.x * 256 + threadIdx.x;
  int d = idx & 31, row = idx >> 5;
  const int NR = 12 * LROW;
  float o = 0.f, l = 0.f;
#pragma unroll
  for (int s = 0; s < 4; ++s) {
    o += bf2f((unsigned short)pOb[(size_t)s * NR * 32 + idx]);
    l += pl[(size_t)s * NR + row];
  }
  int bh = row / LROW, q = row - bh * LROW;
  int b = bh / 3, h = bh - b * 3;
  aob[((size_t)b * LROW + q) * CD + h * 32 + d] = f2bf(o / l);
}

__global__ void tail_kernel(const int* __restrict__ Hp, const int* __restrict__ Wp,
                            float* __restrict__ o) {
  o[0] = (float)Hp[0];
  o[1] = (float)Wp[0];
}

extern "C" void kernel_launch(void* const* d_in, const int* in_sizes, int n_in,
                              void* d_out, int out_size, void* d_ws, size_t ws_size,
                              hipStream_t stream) {
  const float* x      = (const float*)d_in[0];
  const int*   Hp     = (const int*)d_in[1];
  const int*   Wp     = (const int*)d_in[2];
  const float* n1s    = (const float*)d_in[3];
  const float* n1b    = (const float*)d_in[4];
  const float* qkv_w  = (const float*)d_in[5];
  const float* qkv_b  = (const float*)d_in[6];
  const float* proj_w = (const float*)d_in[7];
  const float* proj_b = (const float*)d_in[8];
  const float* ln1s   = (const float*)d_in[9];
  const float* ln1b   = (const float*)d_in[10];
  const float* qkv2_w = (const float*)d_in[11];
  const float* qkv2_b = (const float*)d_in[12];
  const float* out_w  = (const float*)d_in[13];
  const float* out_b  = (const float*)d_in[14];
  const float* ln2s   = (const float*)d_in[15];
  const float* ln2b   = (const float*)d_in[16];
  const float* fc1_w  = (const float*)d_in[17];
  const float* fc1_b  = (const float*)d_in[18];
  const float* fc2_w  = (const float*)d_in[19];
  const float* fc2_b  = (const float*)d_in[20];

  float* wsf = (float*)d_ws;
  const size_t U = (size_t)4 * LROW * CD;  // 1,204,224
  float* x1   = wsf;                           // [0,U) fp32 residual
  float* x2   = wsf + U;                       // [U,2U) fp32
  short* hb   = (short*)(wsf + 2 * U);         // [2U,2.5U) bf16
  short* tb   = (short*)(wsf + 2 * U + U / 2); // [2.5U,4.5U) bf16 fc1 out
  short* qb   = (short*)(wsf + 4 * U + U / 2); // [4.5U,5U)
  short* kb   = qb + U;                        // [5U,5.5U)
  short* vtb  = kb + U;                        // [5.5U,6U)
  short* wqkv = (short*)(wsf + 6 * U);
  short* wout = wqkv + 320 * 96;
  short* wfc1 = wout + 128 * 96;
  short* wfc2 = wfc1 + 384 * 96;
  short* wwin = wfc2 + 128 * 384;
  short* wproj = wwin + 288 * 96;
  // flash partials overlay [U,3.2U): pOb bf16 4 splits (2U floats) + pl fp32
  short* pOb  = (short*)(wsf + U);             // 4 * 12*LROW*32 shorts = 2U floats
  float* pl   = wsf + 3 * U;                   // 4 * 12*LROW floats
  short* aob  = qb;                            // merge output (qb dead after flash)
  float* outx = (float*)d_out;

  const int M = 4 * LROW;  // 12544

  cvt_wt_kernel<<<(320 * 96 + 255) / 256, 256, 0, stream>>>(qkv2_w, wqkv, 96, 288, 320);
  cvt_wt_kernel<<<(128 * 96 + 255) / 256, 256, 0, stream>>>(out_w, wout, 96, 96, 128);
  cvt_wt_kernel<<<(384 * 96 + 255) / 256, 256, 0, stream>>>(fc1_w, wfc1, 96, 384, 384);
  cvt_wt_kernel<<<(128 * 384 + 255) / 256, 256, 0, stream>>>(fc2_w, wfc2, 384, 96, 128);
  cvt_wt_kernel<<<(288 * 96 + 255) / 256, 256, 0, stream>>>(qkv_w, wwin, 96, 288, 288);
  cvt_wt_kernel<<<(96 * 96 + 255) / 256, 256, 0, stream>>>(proj_w, wproj, 96, 96, 96);

  ln_kernel<<<M / 8, 256, 0, stream>>>(x, n1s, n1b, hb, M);
  win_attn_kernel<<<256, 512, 0, stream>>>(hb, x, wwin, qkv_b, wproj, proj_b, x1);
  ln_kernel<<<M / 8, 256, 0, stream>>>(x1, ln1s, ln1b, hb, M);
  qkv_mfma_kernel<<<dim3(M / 128, 5), 256, 0, stream>>>(hb, wqkv, qkv2_b, qb, kb, vtb);
  flash_mfma_kernel<<<dim3(49, 12, 4), 128, 0, stream>>>(qb, kb, vtb, pOb, pl);
  flash_merge_kernel<<<12 * LROW * 32 / 256, 256, 0, stream>>>(pOb, pl, aob);
  gemm_mfma_kernel<1><<<dim3(M / 128, 2), 256, 0, stream>>>(aob, wout, out_b, x1, x2, M, 96, 96);
  ln_kernel<<<M / 8, 256, 0, stream>>>(x2, ln2s, ln2b, hb, M);
  gemm_mfma_kernel<0><<<dim3(M / 128, 6), 256, 0, stream>>>(hb, wfc1, fc1_b, nullptr, tb, M, 96, 384);
  gemm_mfma_kernel<1><<<dim3(M / 128, 2), 256, 0, stream>>>(tb, wfc2, fc2_b, x2, outx, M, 384, 96);
  tail_kernel<<<1, 1, 0, stream>>>(Hp, Wp, outx + U);
}

// Round 10
// 123.273 us; speedup vs baseline: 5.4264x; 1.0886x over previous
//
#include <hip/hip_runtime.h>
#include <hip/hip_bf16.h>

#define CD 96
#define LROW 3136          // 56*56
#define QSCALE 0.17677669529663687f  // 1/sqrt(32)
#define LOG2E 1.4426950408889634f
#define MASKLOG2 -144.26950408889634f // -100 * log2(e)

using f32x4 = __attribute__((ext_vector_type(4))) float;
using bf8   = __attribute__((ext_vector_type(8))) short;

__device__ __forceinline__ short f2bf(float f) {
  union { float f; unsigned u; } v; v.f = f;
  unsigned r = v.u + 0x7fffu + ((v.u >> 16) & 1u);
  return (short)(r >> 16);
}
__device__ __forceinline__ float bf2f(unsigned short s) {
  return __uint_as_float((unsigned)s << 16);
}
// truncating pack (internal P values)
__device__ __forceinline__ unsigned pack_bf2(float lo, float hi) {
  return (__float_as_uint(hi) & 0xffff0000u) | (__float_as_uint(lo) >> 16);
}
// rounding pack (stored outputs)
__device__ __forceinline__ unsigned pack_bf2r(float lo, float hi) {
  return ((unsigned)(unsigned short)f2bf(hi) << 16) | (unsigned short)f2bf(lo);
}
// single-instruction exp2 via compiler-visible intrinsic (hazards handled by backend).
__device__ __forceinline__ float fast_exp2(float x) {
  return __builtin_amdgcn_exp2f(x);
}

#define GLOAD_LDS16(src, dst) \
  __builtin_amdgcn_global_load_lds((const __attribute__((address_space(1))) void*)(src), \
                                   (__attribute__((address_space(3))) void*)(dst), 16, 0, 0)

// ---------------- LayerNorm: 32-lane groups, 3 cols/lane, 8 rows/block -> bf16 ----------------
__global__ __launch_bounds__(256) void ln_kernel(const float* __restrict__ x,
                                                 const float* __restrict__ g,
                                                 const float* __restrict__ b,
                                                 short* __restrict__ out, int rows) {
  int slot = threadIdx.x >> 5, l32 = threadIdx.x & 31;
  int row = blockIdx.x * 8 + slot;
  if (row >= rows) return;
  const float* xr = x + (size_t)row * CD + l32 * 3;
  float a0 = xr[0], a1 = xr[1], a2 = xr[2];
  float s = a0 + a1 + a2;
#pragma unroll
  for (int off = 16; off >= 1; off >>= 1) s += __shfl_xor(s, off, 32);
  float mu = s * (1.f / 96.f);
  float d0 = a0 - mu, d1 = a1 - mu, d2 = a2 - mu;
  float q = d0 * d0 + d1 * d1 + d2 * d2;
#pragma unroll
  for (int off = 16; off >= 1; off >>= 1) q += __shfl_xor(q, off, 32);
  float rstd = rsqrtf(q * (1.f / 96.f) + 1e-6f);
  int c0 = l32 * 3;
  short* orow = out + (size_t)row * CD + c0;
  orow[0] = f2bf(d0 * rstd * g[c0] + b[c0]);
  orow[1] = f2bf(d1 * rstd * g[c0 + 1] + b[c0 + 1]);
  orow[2] = f2bf(d2 * rstd * g[c0 + 2] + b[c0 + 2]);
}

// ---------------- fused weight convert: all six W[K][N] -> Wt[Npad][K] bf16, one launch ----------------
// destinations are contiguous: wqkv(320x96) wout(128x96) wfc1(384x96) wfc2(128x384) wwin(288x96) wproj(96x96)
__global__ __launch_bounds__(256) void cvt_all_kernel(
    const float* __restrict__ qkv2_w, const float* __restrict__ out_w,
    const float* __restrict__ fc1_w, const float* __restrict__ fc2_w,
    const float* __restrict__ qkv_w, const float* __restrict__ proj_w,
    short* __restrict__ dst) {
  int idx = blockIdx.x * 256 + threadIdx.x;
  if (idx >= 165888) return;
  const float* W; int K, N, off;
  if (idx < 30720)       { W = qkv2_w; K = 96;  N = 288; off = idx; }
  else if (idx < 43008)  { W = out_w;  K = 96;  N = 96;  off = idx - 30720; }
  else if (idx < 79872)  { W = fc1_w;  K = 96;  N = 384; off = idx - 43008; }
  else if (idx < 129024) { W = fc2_w;  K = 384; N = 96;  off = idx - 79872; }
  else if (idx < 156672) { W = qkv_w;  K = 96;  N = 288; off = idx - 129024; }
  else                   { W = proj_w; K = 96;  N = 96;  off = idx - 156672; }
  int nr = off / K, kk = off - nr * K;
  float v = (nr < N) ? W[(size_t)kk * N + nr] : 0.f;
  dst[idx] = f2bf(v);
}

// ---------------- MFMA shifted-window attention: one block per window, 8 waves ----------------
__global__ __launch_bounds__(512) void win_attn_kernel(
    const short* __restrict__ hb, const float* __restrict__ xin,
    const short* __restrict__ wwin, const float* __restrict__ qkv_b,
    const short* __restrict__ wproj, const float* __restrict__ proj_b,
    float* __restrict__ x1) {
  __shared__ __align__(16) short Xs[64][104];
  __shared__ __align__(16) short Qs[3][64][40];
  __shared__ __align__(16) short Ks[3][64][40];
  __shared__ __align__(16) short Vt[3][32][72];
  __shared__ __align__(16) short Os[64][104];
  __shared__ __align__(16) short Ptw[8][16][72];  // 144B rows: kv 0..63 in-bounds, banks spread
  __shared__ int cnt[64];
  __shared__ int gidx[49];

  int tid = threadIdx.x, lane = tid & 63, wid = tid >> 6;
  int lr = lane & 15, lg = lane >> 4;
  int b = blockIdx.x >> 6, w64 = blockIdx.x & 63;
  int wr = w64 >> 3, wc = w64 & 7;

  if (tid < 64) {
    if (tid < 49) {
      int i = tid / 7, j = tid % 7;
      int sh = wr * 7 + i, sw = wc * 7 + j;
      int hr = (sh < 49) ? 0 : ((sh < 53) ? 1 : 2);
      int wreg = (sw < 49) ? 0 : ((sw < 53) ? 1 : 2);
      cnt[tid] = hr * 3 + wreg;
      gidx[tid] = ((sh + 3) % 56) * 56 + ((sw + 3) % 56);
    } else {
      cnt[tid] = -1;
    }
  }
  __syncthreads();

  for (int c = tid; c < 768; c += 512) {
    int row = c / 12, cc = c % 12;
    uint4 v = {0u, 0u, 0u, 0u};
    if (row < 49) v = *reinterpret_cast<const uint4*>(hb + ((size_t)b * LROW + gidx[row]) * 96 + cc * 8);
    *reinterpret_cast<uint4*>(&Xs[row][cc * 8]) = v;
  }
  __syncthreads();

  // ---- qkv GEMM: M=64, N=288 (18 n-tiles over 8 waves), K=96 ----
  for (int nt = wid; nt < 18; nt += 8) {
    f32x4 acc[4];
#pragma unroll
    for (int mi = 0; mi < 4; ++mi) acc[mi] = (f32x4){0.f, 0.f, 0.f, 0.f};
#pragma unroll
    for (int kc = 0; kc < 3; ++kc) {
      bf8 bfr = *reinterpret_cast<const bf8*>(wwin + (size_t)(nt * 16 + lr) * 96 + kc * 32 + lg * 8);
#pragma unroll
      for (int mi = 0; mi < 4; ++mi) {
        bf8 afr = *reinterpret_cast<const bf8*>(&Xs[mi * 16 + lr][kc * 32 + lg * 8]);
        acc[mi] = __builtin_amdgcn_mfma_f32_16x16x32_bf16(afr, bfr, acc[mi], 0, 0, 0);
      }
    }
    int n = nt * 16 + lr;
    int sec = n / 96, within = n % 96;
    int hh = within >> 5, dd = within & 31;
    float bias = qkv_b[n];
#pragma unroll
    for (int mi = 0; mi < 4; ++mi)
#pragma unroll
      for (int r = 0; r < 4; ++r) {
        int mrow = mi * 16 + lg * 4 + r;
        float v = acc[mi][r] + bias;
        if (sec == 0)      Qs[hh][mrow][dd] = f2bf(v * (QSCALE * LOG2E));
        else if (sec == 1) Ks[hh][mrow][dd] = f2bf(v);
        else               Vt[hh][dd][mrow] = f2bf(v);
      }
  }
  __syncthreads();

  // ---- attention: 12 (head, q-tile) pairs over 8 waves; no-max softmax, tree-reduced sum ----
  int cntkv[16];
#pragma unroll
  for (int t = 0; t < 4; ++t)
#pragma unroll
    for (int r = 0; r < 4; ++r) cntkv[t * 4 + r] = cnt[t * 16 + lg * 4 + r];

  for (int p = wid; p < 12; p += 8) {
    int h = p >> 2, qt = p & 3;
    bf8 qf = *reinterpret_cast<const bf8*>(&Qs[h][qt * 16 + lr][lg * 8]);
    int cq = cnt[qt * 16 + lr];
    f32x4 z = {0.f, 0.f, 0.f, 0.f};
    f32x4 St[4];
    __builtin_amdgcn_s_setprio(1);
#pragma unroll
    for (int t = 0; t < 4; ++t) {
      bf8 kf = *reinterpret_cast<const bf8*>(&Ks[h][t * 16 + lr][lg * 8]);
      St[t] = __builtin_amdgcn_mfma_f32_16x16x32_bf16(kf, qf, z, 0, 0, 0);
    }
    __builtin_amdgcn_s_setprio(0);
    float pr[4];
#pragma unroll
    for (int t = 0; t < 4; ++t) {
      float p0 = fast_exp2(St[t][0] + ((cq == cntkv[t * 4 + 0]) ? 0.f : MASKLOG2));
      float p1 = fast_exp2(St[t][1] + ((cq == cntkv[t * 4 + 1]) ? 0.f : MASKLOG2));
      float p2 = fast_exp2(St[t][2] + ((cq == cntkv[t * 4 + 2]) ? 0.f : MASKLOG2));
      float p3 = fast_exp2(St[t][3] + ((cq == cntkv[t * 4 + 3]) ? 0.f : MASKLOG2));
      St[t][0] = p0; St[t][1] = p1; St[t][2] = p2; St[t][3] = p3;
      pr[t] = (p0 + p1) + (p2 + p3);
    }
    float rs = (pr[0] + pr[1]) + (pr[2] + pr[3]);
    rs += __shfl_xor(rs, 16);
    rs += __shfl_xor(rs, 32);
    float inv = 1.f / rs;
#pragma unroll
    for (int t = 0; t < 4; ++t) {
      uint2 w;
      w.x = pack_bf2(St[t][0], St[t][1]);
      w.y = pack_bf2(St[t][2], St[t][3]);
      *reinterpret_cast<uint2*>(&Ptw[wid][lr][t * 16 + lg * 4]) = w;
    }
    f32x4 O0 = {0.f, 0.f, 0.f, 0.f}, O1 = {0.f, 0.f, 0.f, 0.f};
    __builtin_amdgcn_s_setprio(1);
#pragma unroll
    for (int c = 0; c < 2; ++c) {
      bf8 pbf = *reinterpret_cast<const bf8*>(&Ptw[wid][lr][c * 32 + lg * 8]);
      bf8 v0 = *reinterpret_cast<const bf8*>(&Vt[h][lr][c * 32 + lg * 8]);
      bf8 v1 = *reinterpret_cast<const bf8*>(&Vt[h][16 + lr][c * 32 + lg * 8]);
      O0 = __builtin_amdgcn_mfma_f32_16x16x32_bf16(v0, pbf, O0, 0, 0, 0);
      O1 = __builtin_amdgcn_mfma_f32_16x16x32_bf16(v1, pbf, O1, 0, 0, 0);
    }
    __builtin_amdgcn_s_setprio(0);
#pragma unroll
    for (int r = 0; r < 4; ++r) {
      Os[qt * 16 + lr][h * 32 + lg * 4 + r] = f2bf(O0[r] * inv);
      Os[qt * 16 + lr][h * 32 + 16 + lg * 4 + r] = f2bf(O1[r] * inv);
    }
  }
  __syncthreads();

  // ---- proj GEMM: 8 waves = 4 m-tiles x 2 n-halves; fused bias+residual+unshift scatter ----
  int mt = wid & 3, half = wid >> 2;
  int gi[4];
#pragma unroll
  for (int r = 0; r < 4; ++r) {
    int q = mt * 16 + lg * 4 + r;
    gi[r] = (q < 49) ? gidx[q] : -1;
  }
  for (int nt = half * 3; nt < half * 3 + 3; ++nt) {
    f32x4 acc = {0.f, 0.f, 0.f, 0.f};
#pragma unroll
    for (int kc = 0; kc < 3; ++kc) {
      bf8 afr = *reinterpret_cast<const bf8*>(&Os[mt * 16 + lr][kc * 32 + lg * 8]);
      bf8 bfr = *reinterpret_cast<const bf8*>(wproj + (size_t)(nt * 16 + lr) * 96 + kc * 32 + lg * 8);
      acc = __builtin_amdgcn_mfma_f32_16x16x32_bf16(afr, bfr, acc, 0, 0, 0);
    }
    int n = nt * 16 + lr;
    float pb = proj_b[n];
#pragma unroll
    for (int r = 0; r < 4; ++r) {
      if (gi[r] >= 0) {
        size_t rowo = ((size_t)b * LROW + gi[r]) * CD + n;
        x1[rowo] = acc[r] + pb + xin[rowo];
      }
    }
  }
}

// ---------------- bf16 MFMA GEMM: out = f(A[M][K] @ Wt[Npad][K]^T + bias [+res]) ----------------
template <int MODE>
__global__ __launch_bounds__(256) void gemm_mfma_kernel(
    const short* __restrict__ A, const short* __restrict__ Bt,
    const float* __restrict__ bias, const float* __restrict__ res,
    void* __restrict__ outp, int M, int K, int N) {
  __shared__ __align__(16) short As[2][128 * 32];
  __shared__ __align__(16) short Bs[2][64 * 32];
  int tid = threadIdx.x, lane = tid & 63, wid = tid >> 6;
  int lr = lane & 15, lg = lane >> 4;
  int m0 = blockIdx.x * 128, n0 = blockIdx.y * 64;
  int nk = K >> 5;

  f32x4 acc[2][4];
#pragma unroll
  for (int i = 0; i < 2; ++i)
#pragma unroll
    for (int j = 0; j < 4; ++j) acc[i][j] = (f32x4){0.f, 0.f, 0.f, 0.f};

  auto stage = [&](int bf, int ks) {
    int k0 = ks * 32;
#pragma unroll
    for (int p = 0; p < 2; ++p) {
      int idx = tid + p * 256;
      GLOAD_LDS16(A + (size_t)(m0 + (idx >> 2)) * K + k0 + (idx & 3) * 8,
                  &As[bf][idx * 8]);
    }
    GLOAD_LDS16(Bt + (size_t)(n0 + (tid >> 2)) * K + k0 + (tid & 3) * 8,
                &Bs[bf][tid * 8]);
  };

  stage(0, 0);
  __syncthreads();
  int buf = 0;
  for (int ks = 0; ks < nk; ++ks) {
    if (ks + 1 < nk) stage(buf ^ 1, ks + 1);
    bf8 bfr[4], afr[2];
#pragma unroll
    for (int ni = 0; ni < 4; ++ni)
      bfr[ni] = *reinterpret_cast<const bf8*>(&Bs[buf][(ni * 16 + lr) * 32 + lg * 8]);
#pragma unroll
    for (int mi = 0; mi < 2; ++mi)
      afr[mi] = *reinterpret_cast<const bf8*>(&As[buf][(wid * 32 + mi * 16 + lr) * 32 + lg * 8]);
    __builtin_amdgcn_s_setprio(1);
#pragma unroll
    for (int mi = 0; mi < 2; ++mi)
#pragma unroll
      for (int ni = 0; ni < 4; ++ni)
        acc[mi][ni] = __builtin_amdgcn_mfma_f32_16x16x32_bf16(afr[mi], bfr[ni], acc[mi][ni], 0, 0, 0);
    __builtin_amdgcn_s_setprio(0);
    __syncthreads();
    buf ^= 1;
  }

#pragma unroll
  for (int mi = 0; mi < 2; ++mi)
#pragma unroll
    for (int ni = 0; ni < 4; ++ni)
#pragma unroll
      for (int r = 0; r < 4; ++r) {
        int mrow = m0 + wid * 32 + mi * 16 + lg * 4 + r;
        int n = n0 + ni * 16 + lr;
        if (n < N) {
          float v = acc[mi][ni][r] + bias[n];
          if (MODE == 0) {
            float t = tanhf(0.7978845608028654f * (v + 0.044715f * v * v * v));
            ((short*)outp)[(size_t)mrow * N + n] = f2bf(0.5f * v * (1.f + t));
          } else {
            v += res[(size_t)mrow * N + n];
            ((float*)outp)[(size_t)mrow * N + n] = v;
          }
        }
      }
}

// ---------------- qkv GEMM (bf16 MFMA) with flash-layout scatter epilogue ----------------
__global__ __launch_bounds__(256) void qkv_mfma_kernel(
    const short* __restrict__ A, const short* __restrict__ Bt,
    const float* __restrict__ bias,
    short* __restrict__ qb, short* __restrict__ kb, short* __restrict__ vtb) {
  __shared__ __align__(16) short As[2][128 * 32];
  __shared__ __align__(16) short Bs[2][64 * 32];
  int tid = threadIdx.x, lane = tid & 63, wid = tid >> 6;
  int lr = lane & 15, lg = lane >> 4;
  int m0 = blockIdx.x * 128, n0 = blockIdx.y * 64;
  const int K = 96;

  f32x4 acc[2][4];
#pragma unroll
  for (int i = 0; i < 2; ++i)
#pragma unroll
    for (int j = 0; j < 4; ++j) acc[i][j] = (f32x4){0.f, 0.f, 0.f, 0.f};

  auto stage = [&](int bf, int ks) {
    int k0 = ks * 32;
#pragma unroll
    for (int p = 0; p < 2; ++p) {
      int idx = tid + p * 256;
      GLOAD_LDS16(A + (size_t)(m0 + (idx >> 2)) * K + k0 + (idx & 3) * 8,
                  &As[bf][idx * 8]);
    }
    GLOAD_LDS16(Bt + (size_t)(n0 + (tid >> 2)) * K + k0 + (tid & 3) * 8,
                &Bs[bf][tid * 8]);
  };

  stage(0, 0);
  __syncthreads();
  int buf = 0;
  for (int ks = 0; ks < 3; ++ks) {
    if (ks + 1 < 3) stage(buf ^ 1, ks + 1);
    bf8 bfr[4], afr[2];
#pragma unroll
    for (int ni = 0; ni < 4; ++ni)
      bfr[ni] = *reinterpret_cast<const bf8*>(&Bs[buf][(ni * 16 + lr) * 32 + lg * 8]);
#pragma unroll
    for (int mi = 0; mi < 2; ++mi)
      afr[mi] = *reinterpret_cast<const bf8*>(&As[buf][(wid * 32 + mi * 16 + lr) * 32 + lg * 8]);
    __builtin_amdgcn_s_setprio(1);
#pragma unroll
    for (int mi = 0; mi < 2; ++mi)
#pragma unroll
      for (int ni = 0; ni < 4; ++ni)
        acc[mi][ni] = __builtin_amdgcn_mfma_f32_16x16x32_bf16(afr[mi], bfr[ni], acc[mi][ni], 0, 0, 0);
    __builtin_amdgcn_s_setprio(0);
    __syncthreads();
    buf ^= 1;
  }

#pragma unroll
  for (int mi = 0; mi < 2; ++mi)
#pragma unroll
    for (int ni = 0; ni < 4; ++ni)
#pragma unroll
      for (int r = 0; r < 4; ++r) {
        int mrow = m0 + wid * 32 + mi * 16 + lg * 4 + r;
        int n = n0 + ni * 16 + lr;
        if (n < 288) {
          float v = acc[mi][ni][r] + bias[n];
          int sec = n / 96, within = n % 96;
          int hh = within >> 5, dd = within & 31;
          int bb = mrow / LROW, nn = mrow - bb * LROW;
          size_t bh = (size_t)bb * 3 + hh;
          if (sec == 0)      qb[(bh * LROW + nn) * 32 + dd] = f2bf(v * (QSCALE * LOG2E));
          else if (sec == 1) kb[(bh * LROW + nn) * 32 + dd] = f2bf(v);
          else               vtb[(bh * 32 + dd) * LROW + nn] = f2bf(v);
        }
      }
}

// ---------------- flash attention v7: no-max softmax, split-KV x6, tree-reduced sum ----------------
// grid (49, 12, 6). S bounded for this problem -> exp2 never overflows; track l only.
__global__ __launch_bounds__(128) void flash_mfma_kernel(
    const short* __restrict__ qb, const short* __restrict__ kb,
    const short* __restrict__ vtb,
    short* __restrict__ pOb, float* __restrict__ pl) {
  __shared__ __align__(16) short Pt[2][2][16][72];  // [wave][g][q][kv]; 144B rows (no aliasing)
  int tid = threadIdx.x, lane = tid & 63, wid = tid >> 6;
  int lr = lane & 15, lg = lane >> 4;
  int bh = blockIdx.y, s = blockIdx.z;
  int q0 = blockIdx.x * 64 + wid * 32;
  const short* qbb = qb + (size_t)bh * LROW * 32;
  const short* kbase = kb + (size_t)bh * LROW * 32 + lr * 32 + lg * 8;
  const short* vbase = vtb + (size_t)bh * 32 * LROW + lr * LROW + lg * 8;

  bf8 qf0 = *reinterpret_cast<const bf8*>(qbb + (size_t)(q0 + lr) * 32 + lg * 8);
  bf8 qf1 = *reinterpret_cast<const bf8*>(qbb + (size_t)(q0 + 16 + lr) * 32 + lg * 8);

  f32x4 O00 = {0.f,0.f,0.f,0.f}, O01 = {0.f,0.f,0.f,0.f};
  f32x4 O10 = {0.f,0.f,0.f,0.f}, O11 = {0.f,0.f,0.f,0.f};
  float l0v = 0.f, l1v = 0.f;

  const int tbl[7] = {0, 9, 17, 25, 33, 41, 49};
  int t0 = tbl[s], t1 = tbl[s + 1];

  bf8 kA[4], vA[4], kB[4], vB[4];

  auto loadt = [&](bf8 (&Kf)[4], bf8 (&Vf)[4], int kt) {
    const short* kp = kbase + (size_t)kt * 2048;
#pragma unroll
    for (int t = 0; t < 4; ++t) Kf[t] = *reinterpret_cast<const bf8*>(kp + t * 512);
    const short* vp = vbase + kt * 64;
#pragma unroll
    for (int c = 0; c < 2; ++c) {
      Vf[c]     = *reinterpret_cast<const bf8*>(vp + c * 32);
      Vf[2 + c] = *reinterpret_cast<const bf8*>(vp + 16 * LROW + c * 32);
    }
  };

  auto body = [&](bf8 (&Kf)[4], bf8 (&Vf)[4]) {
    f32x4 z = {0.f, 0.f, 0.f, 0.f};
#pragma unroll
    for (int g = 0; g < 2; ++g) {
      bf8 qf = g ? qf1 : qf0;
      float& lgv = g ? l1v : l0v;
      f32x4 St[4];
      __builtin_amdgcn_s_setprio(1);
#pragma unroll
      for (int t = 0; t < 4; ++t)
        St[t] = __builtin_amdgcn_mfma_f32_16x16x32_bf16(Kf[t], qf, z, 0, 0, 0);
      __builtin_amdgcn_s_setprio(0);
      float pr[4];
#pragma unroll
      for (int t = 0; t < 4; ++t) {
        float p0 = fast_exp2(St[t][0]);
        float p1 = fast_exp2(St[t][1]);
        float p2 = fast_exp2(St[t][2]);
        float p3 = fast_exp2(St[t][3]);
        St[t][0] = p0; St[t][1] = p1; St[t][2] = p2; St[t][3] = p3;
        pr[t] = (p0 + p1) + (p2 + p3);
      }
      float rs = (pr[0] + pr[1]) + (pr[2] + pr[3]);
      rs += __shfl_xor(rs, 16);
      rs += __shfl_xor(rs, 32);
      lgv += rs;
#pragma unroll
      for (int t = 0; t < 4; ++t) {
        uint2 w;
        w.x = pack_bf2(St[t][0], St[t][1]);
        w.y = pack_bf2(St[t][2], St[t][3]);
        *reinterpret_cast<uint2*>(&Pt[wid][g][lr][t * 16 + lg * 4]) = w;
      }
    }
    __builtin_amdgcn_s_setprio(1);
#pragma unroll
    for (int g = 0; g < 2; ++g) {
      f32x4& Oh0 = g ? O10 : O00;
      f32x4& Oh1 = g ? O11 : O01;
#pragma unroll
      for (int c = 0; c < 2; ++c) {
        bf8 pbf = *reinterpret_cast<const bf8*>(&Pt[wid][g][lr][c * 32 + lg * 8]);
        Oh0 = __builtin_amdgcn_mfma_f32_16x16x32_bf16(Vf[c], pbf, Oh0, 0, 0, 0);
        Oh1 = __builtin_amdgcn_mfma_f32_16x16x32_bf16(Vf[2 + c], pbf, Oh1, 0, 0, 0);
      }
    }
    __builtin_amdgcn_s_setprio(0);
  };

  loadt(kA, vA, t0);
  int kt = t0;
  for (; kt + 2 <= t1 - 1; kt += 2) {
    loadt(kB, vB, kt + 1);
    body(kA, vA);
    loadt(kA, vA, kt + 2);
    body(kB, vB);
  }
  if (kt < t1 - 1) {
    loadt(kB, vB, kt + 1);
    body(kA, vA);
    body(kB, vB);
  } else {
    body(kA, vA);
  }

  // bf16 unnormalized partials; lane (lr,lg) holds d = lg*4+r (+16) for q = q0(+16)+lr
  size_t rbase = (size_t)(s * 12 + bh) * LROW;
  size_t r0 = (rbase + q0 + lr) * 32;
  size_t r1 = (rbase + q0 + 16 + lr) * 32;
  uint2 w;
  w.x = pack_bf2r(O00[0], O00[1]); w.y = pack_bf2r(O00[2], O00[3]);
  *reinterpret_cast<uint2*>(&pOb[r0 + lg * 4]) = w;
  w.x = pack_bf2r(O01[0], O01[1]); w.y = pack_bf2r(O01[2], O01[3]);
  *reinterpret_cast<uint2*>(&pOb[r0 + 16 + lg * 4]) = w;
  w.x = pack_bf2r(O10[0], O10[1]); w.y = pack_bf2r(O10[2], O10[3]);
  *reinterpret_cast<uint2*>(&pOb[r1 + lg * 4]) = w;
  w.x = pack_bf2r(O11[0], O11[1]); w.y = pack_bf2r(O11[2], O11[3]);
  *reinterpret_cast<uint2*>(&pOb[r1 + 16 + lg * 4]) = w;
  if (lg == 0) {
    pl[rbase + q0 + lr] = l0v;
    pl[rbase + q0 + 16 + lr] = l1v;
  }
}

// ---------------- merge 6 KV-split partials (sums only) -> bf16 ao ----------------
__global__ __launch_bounds__(256) void flash_merge_kernel(
    const short* __restrict__ pOb, const float* __restrict__ pl,
    short* __restrict__ aob) {
  int idx = blockIdx.x * 256 + threadIdx.x;
  int d = idx & 31, row = idx >> 5;
  const int NR = 12 * LROW;
  float o = 0.f, l = 0.f;
#pragma unroll
  for (int s = 0; s < 6; ++s) {
    o += bf2f((unsigned short)pOb[(size_t)s * NR * 32 + idx]);
    l += pl[(size_t)s * NR + row];
  }
  int bh = row / LROW, q = row - bh * LROW;
  int b = bh / 3, h = bh - b * 3;
  aob[((size_t)b * LROW + q) * CD + h * 32 + d] = f2bf(o / l);
}

__global__ void tail_kernel(const int* __restrict__ Hp, const int* __restrict__ Wp,
                            float* __restrict__ o) {
  o[0] = (float)Hp[0];
  o[1] = (float)Wp[0];
}

extern "C" void kernel_launch(void* const* d_in, const int* in_sizes, int n_in,
                              void* d_out, int out_size, void* d_ws, size_t ws_size,
                              hipStream_t stream) {
  const float* x      = (const float*)d_in[0];
  const int*   Hp     = (const int*)d_in[1];
  const int*   Wp     = (const int*)d_in[2];
  const float* n1s    = (const float*)d_in[3];
  const float* n1b    = (const float*)d_in[4];
  const float* qkv_w  = (const float*)d_in[5];
  const float* qkv_b  = (const float*)d_in[6];
  const float* proj_w = (const float*)d_in[7];
  const float* proj_b = (const float*)d_in[8];
  const float* ln1s   = (const float*)d_in[9];
  const float* ln1b   = (const float*)d_in[10];
  const float* qkv2_w = (const float*)d_in[11];
  const float* qkv2_b = (const float*)d_in[12];
  const float* out_w  = (const float*)d_in[13];
  const float* out_b  = (const float*)d_in[14];
  const float* ln2s   = (const float*)d_in[15];
  const float* ln2b   = (const float*)d_in[16];
  const float* fc1_w  = (const float*)d_in[17];
  const float* fc1_b  = (const float*)d_in[18];
  const float* fc2_w  = (const float*)d_in[19];
  const float* fc2_b  = (const float*)d_in[20];

  float* wsf = (float*)d_ws;
  const size_t U = (size_t)4 * LROW * CD;  // 1,204,224
  float* x1   = wsf;                           // [0,U) fp32 residual
  float* x2   = wsf + U;                       // [U,2U) fp32
  short* hb   = (short*)(wsf + 2 * U);         // [2U,2.5U) bf16
  short* tb   = (short*)(wsf + 2 * U + U / 2); // [2.5U,4.5U) bf16 fc1 out
  short* qb   = (short*)(wsf + 4 * U + U / 2); // [4.5U,5U)
  short* kb   = qb + U;                        // [5U,5.5U)
  short* vtb  = kb + U;                        // [5.5U,6U)
  short* wall = (short*)(wsf + 6 * U);         // contiguous bf16 weights, 165888 shorts
  short* wqkv = wall;                          // 320*96
  short* wout = wqkv + 320 * 96;               // 128*96
  short* wfc1 = wout + 128 * 96;               // 384*96
  short* wfc2 = wfc1 + 384 * 96;               // 128*384
  short* wwin = wfc2 + 128 * 384;              // 288*96
  short* wproj = wwin + 288 * 96;              // 96*96
  // flash partials overlay [U,4.2U): pOb bf16 6 splits (3U floats) + pl fp32
  short* pOb  = (short*)(wsf + U);             // 6 * 12*LROW*32 shorts = 3U floats
  float* pl   = wsf + 4 * U;                   // 6 * 12*LROW floats (within dead tb tail)
  short* aob  = qb;                            // merge output (qb dead after flash)
  float* outx = (float*)d_out;

  const int M = 4 * LROW;  // 12544

  cvt_all_kernel<<<(165888 + 255) / 256, 256, 0, stream>>>(qkv2_w, out_w, fc1_w, fc2_w, qkv_w, proj_w, wall);

  ln_kernel<<<M / 8, 256, 0, stream>>>(x, n1s, n1b, hb, M);
  win_attn_kernel<<<256, 512, 0, stream>>>(hb, x, wwin, qkv_b, wproj, proj_b, x1);
  ln_kernel<<<M / 8, 256, 0, stream>>>(x1, ln1s, ln1b, hb, M);
  qkv_mfma_kernel<<<dim3(M / 128, 5), 256, 0, stream>>>(hb, wqkv, qkv2_b, qb, kb, vtb);
  flash_mfma_kernel<<<dim3(49, 12, 6), 128, 0, stream>>>(qb, kb, vtb, pOb, pl);
  flash_merge_kernel<<<12 * LROW * 32 / 256, 256, 0, stream>>>(pOb, pl, aob);
  gemm_mfma_kernel<1><<<dim3(M / 128, 2), 256, 0, stream>>>(aob, wout, out_b, x1, x2, M, 96, 96);
  ln_kernel<<<M / 8, 256, 0, stream>>>(x2, ln2s, ln2b, hb, M);
  gemm_mfma_kernel<0><<<dim3(M / 128, 6), 256, 0, stream>>>(hb, wfc1, fc1_b, nullptr, tb, M, 96, 384);
  gemm_mfma_kernel<1><<<dim3(M / 128, 2), 256, 0, stream>>>(tb, wfc2, fc2_b, x2, outx, M, 384, 96);
  tail_kernel<<<1, 1, 0, stream>>>(Hp, Wp, outx + U);
}

// Round 11
// 118.096 us; speedup vs baseline: 5.6643x; 1.0438x over previous
//
#include <hip/hip_runtime.h>
#include <hip/hip_bf16.h>

#define CD 96
#define LROW 3136          // 56*56
#define QSCALE 0.17677669529663687f  // 1/sqrt(32)
#define LOG2E 1.4426950408889634f
#define MASKLOG2 -144.26950408889634f // -100 * log2(e)

using f32x4 = __attribute__((ext_vector_type(4))) float;
using bf8   = __attribute__((ext_vector_type(8))) short;

__device__ __forceinline__ short f2bf(float f) {
  union { float f; unsigned u; } v; v.f = f;
  unsigned r = v.u + 0x7fffu + ((v.u >> 16) & 1u);
  return (short)(r >> 16);
}
__device__ __forceinline__ float bf2f(unsigned short s) {
  return __uint_as_float((unsigned)s << 16);
}
__device__ __forceinline__ unsigned pack_bf2(float lo, float hi) {
  return (__float_as_uint(hi) & 0xffff0000u) | (__float_as_uint(lo) >> 16);
}
__device__ __forceinline__ unsigned pack_bf2r(float lo, float hi) {
  return ((unsigned)(unsigned short)f2bf(hi) << 16) | (unsigned short)f2bf(lo);
}
__device__ __forceinline__ float fast_exp2(float x) {
  return __builtin_amdgcn_exp2f(x);
}

#define GLOAD_LDS16(src, dst) \
  __builtin_amdgcn_global_load_lds((const __attribute__((address_space(1))) void*)(src), \
                                   (__attribute__((address_space(3))) void*)(dst), 16, 0, 0)

// ---------------- LayerNorm (LN1 only): 32-lane groups, 3 cols/lane -> bf16 ----------------
__global__ __launch_bounds__(256) void ln_kernel(const float* __restrict__ x,
                                                 const float* __restrict__ g,
                                                 const float* __restrict__ b,
                                                 short* __restrict__ out, int rows) {
  int slot = threadIdx.x >> 5, l32 = threadIdx.x & 31;
  int row = blockIdx.x * 8 + slot;
  if (row >= rows) return;
  const float* xr = x + (size_t)row * CD + l32 * 3;
  float a0 = xr[0], a1 = xr[1], a2 = xr[2];
  float s = a0 + a1 + a2;
#pragma unroll
  for (int off = 16; off >= 1; off >>= 1) s += __shfl_xor(s, off, 32);
  float mu = s * (1.f / 96.f);
  float d0 = a0 - mu, d1 = a1 - mu, d2 = a2 - mu;
  float q = d0 * d0 + d1 * d1 + d2 * d2;
#pragma unroll
  for (int off = 16; off >= 1; off >>= 1) q += __shfl_xor(q, off, 32);
  float rstd = rsqrtf(q * (1.f / 96.f) + 1e-6f);
  int c0 = l32 * 3;
  short* orow = out + (size_t)row * CD + c0;
  orow[0] = f2bf(d0 * rstd * g[c0] + b[c0]);
  orow[1] = f2bf(d1 * rstd * g[c0 + 1] + b[c0 + 1]);
  orow[2] = f2bf(d2 * rstd * g[c0 + 2] + b[c0 + 2]);
}

// ---------------- fused weight convert (+ tail scalars) ----------------
__global__ __launch_bounds__(256) void cvt_all_kernel(
    const float* __restrict__ qkv2_w, const float* __restrict__ out_w,
    const float* __restrict__ fc1_w, const float* __restrict__ fc2_w,
    const float* __restrict__ qkv_w, const float* __restrict__ proj_w,
    short* __restrict__ dst,
    const int* __restrict__ Hp, const int* __restrict__ Wp,
    float* __restrict__ tail_out) {
  int idx = blockIdx.x * 256 + threadIdx.x;
  if (idx == 0) {
    tail_out[0] = (float)Hp[0];
    tail_out[1] = (float)Wp[0];
  }
  if (idx >= 165888) return;
  const float* W; int K, N, off;
  if (idx < 30720)       { W = qkv2_w; K = 96;  N = 288; off = idx; }
  else if (idx < 43008)  { W = out_w;  K = 96;  N = 96;  off = idx - 30720; }
  else if (idx < 79872)  { W = fc1_w;  K = 96;  N = 384; off = idx - 43008; }
  else if (idx < 129024) { W = fc2_w;  K = 384; N = 96;  off = idx - 79872; }
  else if (idx < 156672) { W = qkv_w;  K = 96;  N = 288; off = idx - 129024; }
  else                   { W = proj_w; K = 96;  N = 96;  off = idx - 156672; }
  int nr = off / K, kk = off - nr * K;
  float v = (nr < N) ? W[(size_t)kk * N + nr] : 0.f;
  dst[idx] = f2bf(v);
}

// ---------------- MFMA shifted-window attention + fused LN-tb1 epilogue ----------------
__global__ __launch_bounds__(512) void win_attn_kernel(
    const short* __restrict__ hb_in, const float* __restrict__ xin,
    const short* __restrict__ wwin, const float* __restrict__ qkv_b,
    const short* __restrict__ wproj, const float* __restrict__ proj_b,
    const float* __restrict__ ln1s, const float* __restrict__ ln1b,
    float* __restrict__ x1, short* __restrict__ hb2) {
  __shared__ __align__(16) short Xs[64][104];
  __shared__ __align__(16) short Qs[3][64][40];
  __shared__ __align__(16) short Ks[3][64][40];
  __shared__ __align__(16) short Vt[3][32][72];
  __shared__ __align__(16) short Os[64][104];
  __shared__ __align__(16) short Ptw[8][16][72];
  __shared__ int cnt[64];
  __shared__ int gidx[49];

  int tid = threadIdx.x, lane = tid & 63, wid = tid >> 6;
  int lr = lane & 15, lg = lane >> 4;
  int b = blockIdx.x >> 6, w64 = blockIdx.x & 63;
  int wr = w64 >> 3, wc = w64 & 7;

  if (tid < 64) {
    if (tid < 49) {
      int i = tid / 7, j = tid % 7;
      int sh = wr * 7 + i, sw = wc * 7 + j;
      int hr = (sh < 49) ? 0 : ((sh < 53) ? 1 : 2);
      int wreg = (sw < 49) ? 0 : ((sw < 53) ? 1 : 2);
      cnt[tid] = hr * 3 + wreg;
      gidx[tid] = ((sh + 3) % 56) * 56 + ((sw + 3) % 56);
    } else {
      cnt[tid] = -1;
    }
  }
  __syncthreads();

  for (int c = tid; c < 768; c += 512) {
    int row = c / 12, cc = c % 12;
    uint4 v = {0u, 0u, 0u, 0u};
    if (row < 49) v = *reinterpret_cast<const uint4*>(hb_in + ((size_t)b * LROW + gidx[row]) * 96 + cc * 8);
    *reinterpret_cast<uint4*>(&Xs[row][cc * 8]) = v;
  }
  __syncthreads();

  // ---- qkv GEMM: M=64, N=288 (18 n-tiles over 8 waves), K=96 ----
  for (int nt = wid; nt < 18; nt += 8) {
    f32x4 acc[4];
#pragma unroll
    for (int mi = 0; mi < 4; ++mi) acc[mi] = (f32x4){0.f, 0.f, 0.f, 0.f};
#pragma unroll
    for (int kc = 0; kc < 3; ++kc) {
      bf8 bfr = *reinterpret_cast<const bf8*>(wwin + (size_t)(nt * 16 + lr) * 96 + kc * 32 + lg * 8);
#pragma unroll
      for (int mi = 0; mi < 4; ++mi) {
        bf8 afr = *reinterpret_cast<const bf8*>(&Xs[mi * 16 + lr][kc * 32 + lg * 8]);
        acc[mi] = __builtin_amdgcn_mfma_f32_16x16x32_bf16(afr, bfr, acc[mi], 0, 0, 0);
      }
    }
    int n = nt * 16 + lr;
    int sec = n / 96, within = n % 96;
    int hh = within >> 5, dd = within & 31;
    float bias = qkv_b[n];
#pragma unroll
    for (int mi = 0; mi < 4; ++mi)
#pragma unroll
      for (int r = 0; r < 4; ++r) {
        int mrow = mi * 16 + lg * 4 + r;
        float v = acc[mi][r] + bias;
        if (sec == 0)      Qs[hh][mrow][dd] = f2bf(v * (QSCALE * LOG2E));
        else if (sec == 1) Ks[hh][mrow][dd] = f2bf(v);
        else               Vt[hh][dd][mrow] = f2bf(v);
      }
  }
  __syncthreads();

  // ---- attention: 12 (head, q-tile) pairs over 8 waves; no-max softmax, tree sum ----
  int cntkv[16];
#pragma unroll
  for (int t = 0; t < 4; ++t)
#pragma unroll
    for (int r = 0; r < 4; ++r) cntkv[t * 4 + r] = cnt[t * 16 + lg * 4 + r];

  for (int p = wid; p < 12; p += 8) {
    int h = p >> 2, qt = p & 3;
    bf8 qf = *reinterpret_cast<const bf8*>(&Qs[h][qt * 16 + lr][lg * 8]);
    int cq = cnt[qt * 16 + lr];
    f32x4 z = {0.f, 0.f, 0.f, 0.f};
    f32x4 St[4];
    __builtin_amdgcn_s_setprio(1);
#pragma unroll
    for (int t = 0; t < 4; ++t) {
      bf8 kf = *reinterpret_cast<const bf8*>(&Ks[h][t * 16 + lr][lg * 8]);
      St[t] = __builtin_amdgcn_mfma_f32_16x16x32_bf16(kf, qf, z, 0, 0, 0);
    }
    __builtin_amdgcn_s_setprio(0);
    float pr[4];
#pragma unroll
    for (int t = 0; t < 4; ++t) {
      float p0 = fast_exp2(St[t][0] + ((cq == cntkv[t * 4 + 0]) ? 0.f : MASKLOG2));
      float p1 = fast_exp2(St[t][1] + ((cq == cntkv[t * 4 + 1]) ? 0.f : MASKLOG2));
      float p2 = fast_exp2(St[t][2] + ((cq == cntkv[t * 4 + 2]) ? 0.f : MASKLOG2));
      float p3 = fast_exp2(St[t][3] + ((cq == cntkv[t * 4 + 3]) ? 0.f : MASKLOG2));
      St[t][0] = p0; St[t][1] = p1; St[t][2] = p2; St[t][3] = p3;
      pr[t] = (p0 + p1) + (p2 + p3);
    }
    float rs = (pr[0] + pr[1]) + (pr[2] + pr[3]);
    rs += __shfl_xor(rs, 16);
    rs += __shfl_xor(rs, 32);
    float inv = 1.f / rs;
#pragma unroll
    for (int t = 0; t < 4; ++t) {
      uint2 w;
      w.x = pack_bf2(St[t][0], St[t][1]);
      w.y = pack_bf2(St[t][2], St[t][3]);
      *reinterpret_cast<uint2*>(&Ptw[wid][lr][t * 16 + lg * 4]) = w;
    }
    f32x4 O0 = {0.f, 0.f, 0.f, 0.f}, O1 = {0.f, 0.f, 0.f, 0.f};
    __builtin_amdgcn_s_setprio(1);
#pragma unroll
    for (int c = 0; c < 2; ++c) {
      bf8 pbf = *reinterpret_cast<const bf8*>(&Ptw[wid][lr][c * 32 + lg * 8]);
      bf8 v0 = *reinterpret_cast<const bf8*>(&Vt[h][lr][c * 32 + lg * 8]);
      bf8 v1 = *reinterpret_cast<const bf8*>(&Vt[h][16 + lr][c * 32 + lg * 8]);
      O0 = __builtin_amdgcn_mfma_f32_16x16x32_bf16(v0, pbf, O0, 0, 0, 0);
      O1 = __builtin_amdgcn_mfma_f32_16x16x32_bf16(v1, pbf, O1, 0, 0, 0);
    }
    __builtin_amdgcn_s_setprio(0);
#pragma unroll
    for (int r = 0; r < 4; ++r) {
      Os[qt * 16 + lr][h * 32 + lg * 4 + r] = f2bf(O0[r] * inv);
      Os[qt * 16 + lr][h * 32 + 16 + lg * 4 + r] = f2bf(O1[r] * inv);
    }
  }
  __syncthreads();

  // ---- proj GEMM (waves 0..3, full N per wave) + fused residual + LN-tb1 ----
  if (wid < 4) {
    int mt = wid;
    f32x4 acc[6];
#pragma unroll
    for (int nt = 0; nt < 6; ++nt) acc[nt] = (f32x4){0.f, 0.f, 0.f, 0.f};
#pragma unroll
    for (int kc = 0; kc < 3; ++kc) {
      bf8 afr = *reinterpret_cast<const bf8*>(&Os[mt * 16 + lr][kc * 32 + lg * 8]);
#pragma unroll
      for (int nt = 0; nt < 6; ++nt) {
        bf8 bfr = *reinterpret_cast<const bf8*>(wproj + (size_t)(nt * 16 + lr) * 96 + kc * 32 + lg * 8);
        acc[nt] = __builtin_amdgcn_mfma_f32_16x16x32_bf16(afr, bfr, acc[nt], 0, 0, 0);
      }
    }
    float pbv[6], gv[6], bv[6];
#pragma unroll
    for (int nt = 0; nt < 6; ++nt) {
      int col = nt * 16 + lr;
      pbv[nt] = proj_b[col];
      gv[nt] = ln1s[col];
      bv[nt] = ln1b[col];
    }
#pragma unroll
    for (int r = 0; r < 4; ++r) {
      int q = mt * 16 + lg * 4 + r;
      if (q >= 49) continue;           // uniform across the 16 lr lanes
      size_t rb = ((size_t)b * LROW + gidx[q]) * CD;
      float v[6];
#pragma unroll
      for (int nt = 0; nt < 6; ++nt)
        v[nt] = acc[nt][r] + pbv[nt] + xin[rb + nt * 16 + lr];
      float s = ((v[0] + v[1]) + (v[2] + v[3])) + (v[4] + v[5]);
      s += __shfl_xor(s, 1); s += __shfl_xor(s, 2);
      s += __shfl_xor(s, 4); s += __shfl_xor(s, 8);
      float mu = s * (1.f / 96.f);
      float d[6];
      float qs = 0.f;
#pragma unroll
      for (int nt = 0; nt < 6; ++nt) { d[nt] = v[nt] - mu; qs += d[nt] * d[nt]; }
      qs += __shfl_xor(qs, 1); qs += __shfl_xor(qs, 2);
      qs += __shfl_xor(qs, 4); qs += __shfl_xor(qs, 8);
      float rstd = rsqrtf(qs * (1.f / 96.f) + 1e-6f);
#pragma unroll
      for (int nt = 0; nt < 6; ++nt) {
        x1[rb + nt * 16 + lr] = v[nt];
        hb2[rb + nt * 16 + lr] = f2bf(d[nt] * rstd * gv[nt] + bv[nt]);
      }
    }
  }
}

// ---------------- bf16 MFMA GEMM: out = f(A[M][K] @ Wt[Npad][K]^T + bias [+res]) ----------------
template <int MODE>
__global__ __launch_bounds__(256) void gemm_mfma_kernel(
    const short* __restrict__ A, const short* __restrict__ Bt,
    const float* __restrict__ bias, const float* __restrict__ res,
    void* __restrict__ outp, int M, int K, int N) {
  __shared__ __align__(16) short As[2][128 * 32];
  __shared__ __align__(16) short Bs[2][64 * 32];
  int tid = threadIdx.x, lane = tid & 63, wid = tid >> 6;
  int lr = lane & 15, lg = lane >> 4;
  int m0 = blockIdx.x * 128, n0 = blockIdx.y * 64;
  int nk = K >> 5;

  f32x4 acc[2][4];
#pragma unroll
  for (int i = 0; i < 2; ++i)
#pragma unroll
    for (int j = 0; j < 4; ++j) acc[i][j] = (f32x4){0.f, 0.f, 0.f, 0.f};

  auto stage = [&](int bf, int ks) {
    int k0 = ks * 32;
#pragma unroll
    for (int p = 0; p < 2; ++p) {
      int idx = tid + p * 256;
      GLOAD_LDS16(A + (size_t)(m0 + (idx >> 2)) * K + k0 + (idx & 3) * 8,
                  &As[bf][idx * 8]);
    }
    GLOAD_LDS16(Bt + (size_t)(n0 + (tid >> 2)) * K + k0 + (tid & 3) * 8,
                &Bs[bf][tid * 8]);
  };

  stage(0, 0);
  __syncthreads();
  int buf = 0;
  for (int ks = 0; ks < nk; ++ks) {
    if (ks + 1 < nk) stage(buf ^ 1, ks + 1);
    bf8 bfr[4], afr[2];
#pragma unroll
    for (int ni = 0; ni < 4; ++ni)
      bfr[ni] = *reinterpret_cast<const bf8*>(&Bs[buf][(ni * 16 + lr) * 32 + lg * 8]);
#pragma unroll
    for (int mi = 0; mi < 2; ++mi)
      afr[mi] = *reinterpret_cast<const bf8*>(&As[buf][(wid * 32 + mi * 16 + lr) * 32 + lg * 8]);
    __builtin_amdgcn_s_setprio(1);
#pragma unroll
    for (int mi = 0; mi < 2; ++mi)
#pragma unroll
      for (int ni = 0; ni < 4; ++ni)
        acc[mi][ni] = __builtin_amdgcn_mfma_f32_16x16x32_bf16(afr[mi], bfr[ni], acc[mi][ni], 0, 0, 0);
    __builtin_amdgcn_s_setprio(0);
    __syncthreads();
    buf ^= 1;
  }

#pragma unroll
  for (int mi = 0; mi < 2; ++mi)
#pragma unroll
    for (int ni = 0; ni < 4; ++ni)
#pragma unroll
      for (int r = 0; r < 4; ++r) {
        int mrow = m0 + wid * 32 + mi * 16 + lg * 4 + r;
        int n = n0 + ni * 16 + lr;
        if (n < N) {
          float v = acc[mi][ni][r] + bias[n];
          if (MODE == 0) {
            float t = tanhf(0.7978845608028654f * (v + 0.044715f * v * v * v));
            ((short*)outp)[(size_t)mrow * N + n] = f2bf(0.5f * v * (1.f + t));
          } else {
            v += res[(size_t)mrow * N + n];
            ((float*)outp)[(size_t)mrow * N + n] = v;
          }
        }
      }
}

// ---------------- out-proj GEMM (N=96 full-row) + residual + fused LN2 ----------------
__global__ __launch_bounds__(256) void gemm_out_ln_kernel(
    const short* __restrict__ A, const short* __restrict__ Bt,
    const float* __restrict__ bias, const float* __restrict__ res,
    const float* __restrict__ g2, const float* __restrict__ b2,
    float* __restrict__ x2, short* __restrict__ hb) {
  __shared__ __align__(16) short As[2][128 * 32];
  __shared__ __align__(16) short Bs[2][96 * 32];
  int tid = threadIdx.x, lane = tid & 63, wid = tid >> 6;
  int lr = lane & 15, lg = lane >> 4;
  int m0 = blockIdx.x * 128;
  const int K = 96;

  f32x4 acc[2][6];
#pragma unroll
  for (int i = 0; i < 2; ++i)
#pragma unroll
    for (int j = 0; j < 6; ++j) acc[i][j] = (f32x4){0.f, 0.f, 0.f, 0.f};

  auto stage = [&](int bf, int ks) {
    int k0 = ks * 32;
#pragma unroll
    for (int p = 0; p < 2; ++p) {
      int idx = tid + p * 256;
      GLOAD_LDS16(A + (size_t)(m0 + (idx >> 2)) * K + k0 + (idx & 3) * 8,
                  &As[bf][idx * 8]);
    }
    for (int l = tid; l < 384; l += 256) {
      GLOAD_LDS16(Bt + (size_t)(l >> 2) * K + k0 + (l & 3) * 8,
                  &Bs[bf][l * 8]);
    }
  };

  stage(0, 0);
  __syncthreads();
  int buf = 0;
  for (int ks = 0; ks < 3; ++ks) {
    if (ks + 1 < 3) stage(buf ^ 1, ks + 1);
    bf8 bfr[6], afr[2];
#pragma unroll
    for (int ni = 0; ni < 6; ++ni)
      bfr[ni] = *reinterpret_cast<const bf8*>(&Bs[buf][(ni * 16 + lr) * 32 + lg * 8]);
#pragma unroll
    for (int mi = 0; mi < 2; ++mi)
      afr[mi] = *reinterpret_cast<const bf8*>(&As[buf][(wid * 32 + mi * 16 + lr) * 32 + lg * 8]);
    __builtin_amdgcn_s_setprio(1);
#pragma unroll
    for (int mi = 0; mi < 2; ++mi)
#pragma unroll
      for (int ni = 0; ni < 6; ++ni)
        acc[mi][ni] = __builtin_amdgcn_mfma_f32_16x16x32_bf16(afr[mi], bfr[ni], acc[mi][ni], 0, 0, 0);
    __builtin_amdgcn_s_setprio(0);
    __syncthreads();
    buf ^= 1;
  }

  float bb[6], gv[6], bv[6];
#pragma unroll
  for (int ni = 0; ni < 6; ++ni) {
    int col = ni * 16 + lr;
    bb[ni] = bias[col];
    gv[ni] = g2[col];
    bv[ni] = b2[col];
  }
#pragma unroll
  for (int mi = 0; mi < 2; ++mi)
#pragma unroll
    for (int r = 0; r < 4; ++r) {
      int row = m0 + wid * 32 + mi * 16 + lg * 4 + r;
      size_t rb = (size_t)row * CD;
      float v[6];
#pragma unroll
      for (int ni = 0; ni < 6; ++ni)
        v[ni] = acc[mi][ni][r] + bb[ni] + res[rb + ni * 16 + lr];
      float s = ((v[0] + v[1]) + (v[2] + v[3])) + (v[4] + v[5]);
      s += __shfl_xor(s, 1); s += __shfl_xor(s, 2);
      s += __shfl_xor(s, 4); s += __shfl_xor(s, 8);
      float mu = s * (1.f / 96.f);
      float d[6];
      float qs = 0.f;
#pragma unroll
      for (int ni = 0; ni < 6; ++ni) { d[ni] = v[ni] - mu; qs += d[ni] * d[ni]; }
      qs += __shfl_xor(qs, 1); qs += __shfl_xor(qs, 2);
      qs += __shfl_xor(qs, 4); qs += __shfl_xor(qs, 8);
      float rstd = rsqrtf(qs * (1.f / 96.f) + 1e-6f);
#pragma unroll
      for (int ni = 0; ni < 6; ++ni) {
        x2[rb + ni * 16 + lr] = v[ni];
        hb[rb + ni * 16 + lr] = f2bf(d[ni] * rstd * gv[ni] + bv[ni]);
      }
    }
}

// ---------------- qkv GEMM (bf16 MFMA) with flash-layout scatter epilogue ----------------
__global__ __launch_bounds__(256) void qkv_mfma_kernel(
    const short* __restrict__ A, const short* __restrict__ Bt,
    const float* __restrict__ bias,
    short* __restrict__ qb, short* __restrict__ kb, short* __restrict__ vtb) {
  __shared__ __align__(16) short As[2][128 * 32];
  __shared__ __align__(16) short Bs[2][64 * 32];
  int tid = threadIdx.x, lane = tid & 63, wid = tid >> 6;
  int lr = lane & 15, lg = lane >> 4;
  int m0 = blockIdx.x * 128, n0 = blockIdx.y * 64;
  const int K = 96;

  f32x4 acc[2][4];
#pragma unroll
  for (int i = 0; i < 2; ++i)
#pragma unroll
    for (int j = 0; j < 4; ++j) acc[i][j] = (f32x4){0.f, 0.f, 0.f, 0.f};

  auto stage = [&](int bf, int ks) {
    int k0 = ks * 32;
#pragma unroll
    for (int p = 0; p < 2; ++p) {
      int idx = tid + p * 256;
      GLOAD_LDS16(A + (size_t)(m0 + (idx >> 2)) * K + k0 + (idx & 3) * 8,
                  &As[bf][idx * 8]);
    }
    GLOAD_LDS16(Bt + (size_t)(n0 + (tid >> 2)) * K + k0 + (tid & 3) * 8,
                &Bs[bf][tid * 8]);
  };

  stage(0, 0);
  __syncthreads();
  int buf = 0;
  for (int ks = 0; ks < 3; ++ks) {
    if (ks + 1 < 3) stage(buf ^ 1, ks + 1);
    bf8 bfr[4], afr[2];
#pragma unroll
    for (int ni = 0; ni < 4; ++ni)
      bfr[ni] = *reinterpret_cast<const bf8*>(&Bs[buf][(ni * 16 + lr) * 32 + lg * 8]);
#pragma unroll
    for (int mi = 0; mi < 2; ++mi)
      afr[mi] = *reinterpret_cast<const bf8*>(&As[buf][(wid * 32 + mi * 16 + lr) * 32 + lg * 8]);
    __builtin_amdgcn_s_setprio(1);
#pragma unroll
    for (int mi = 0; mi < 2; ++mi)
#pragma unroll
      for (int ni = 0; ni < 4; ++ni)
        acc[mi][ni] = __builtin_amdgcn_mfma_f32_16x16x32_bf16(afr[mi], bfr[ni], acc[mi][ni], 0, 0, 0);
    __builtin_amdgcn_s_setprio(0);
    __syncthreads();
    buf ^= 1;
  }

#pragma unroll
  for (int mi = 0; mi < 2; ++mi)
#pragma unroll
    for (int ni = 0; ni < 4; ++ni)
#pragma unroll
      for (int r = 0; r < 4; ++r) {
        int mrow = m0 + wid * 32 + mi * 16 + lg * 4 + r;
        int n = n0 + ni * 16 + lr;
        if (n < 288) {
          float v = acc[mi][ni][r] + bias[n];
          int sec = n / 96, within = n % 96;
          int hh = within >> 5, dd = within & 31;
          int bb = mrow / LROW, nn = mrow - bb * LROW;
          size_t bh = (size_t)bb * 3 + hh;
          if (sec == 0)      qb[(bh * LROW + nn) * 32 + dd] = f2bf(v * (QSCALE * LOG2E));
          else if (sec == 1) kb[(bh * LROW + nn) * 32 + dd] = f2bf(v);
          else               vtb[(bh * 32 + dd) * LROW + nn] = f2bf(v);
        }
      }
}

// ---------------- flash attention v7: no-max softmax, split-KV x6, tree-reduced sum ----------------
__global__ __launch_bounds__(128) void flash_mfma_kernel(
    const short* __restrict__ qb, const short* __restrict__ kb,
    const short* __restrict__ vtb,
    short* __restrict__ pOb, float* __restrict__ pl) {
  __shared__ __align__(16) short Pt[2][2][16][72];  // [wave][g][q][kv]; 144B rows (no aliasing)
  int tid = threadIdx.x, lane = tid & 63, wid = tid >> 6;
  int lr = lane & 15, lg = lane >> 4;
  int bh = blockIdx.y, s = blockIdx.z;
  int q0 = blockIdx.x * 64 + wid * 32;
  const short* qbb = qb + (size_t)bh * LROW * 32;
  const short* kbase = kb + (size_t)bh * LROW * 32 + lr * 32 + lg * 8;
  const short* vbase = vtb + (size_t)bh * 32 * LROW + lr * LROW + lg * 8;

  bf8 qf0 = *reinterpret_cast<const bf8*>(qbb + (size_t)(q0 + lr) * 32 + lg * 8);
  bf8 qf1 = *reinterpret_cast<const bf8*>(qbb + (size_t)(q0 + 16 + lr) * 32 + lg * 8);

  f32x4 O00 = {0.f,0.f,0.f,0.f}, O01 = {0.f,0.f,0.f,0.f};
  f32x4 O10 = {0.f,0.f,0.f,0.f}, O11 = {0.f,0.f,0.f,0.f};
  float l0v = 0.f, l1v = 0.f;

  const int tbl[7] = {0, 9, 17, 25, 33, 41, 49};
  int t0 = tbl[s], t1 = tbl[s + 1];

  bf8 kA[4], vA[4], kB[4], vB[4];

  auto loadt = [&](bf8 (&Kf)[4], bf8 (&Vf)[4], int kt) {
    const short* kp = kbase + (size_t)kt * 2048;
#pragma unroll
    for (int t = 0; t < 4; ++t) Kf[t] = *reinterpret_cast<const bf8*>(kp + t * 512);
    const short* vp = vbase + kt * 64;
#pragma unroll
    for (int c = 0; c < 2; ++c) {
      Vf[c]     = *reinterpret_cast<const bf8*>(vp + c * 32);
      Vf[2 + c] = *reinterpret_cast<const bf8*>(vp + 16 * LROW + c * 32);
    }
  };

  auto body = [&](bf8 (&Kf)[4], bf8 (&Vf)[4]) {
    f32x4 z = {0.f, 0.f, 0.f, 0.f};
#pragma unroll
    for (int g = 0; g < 2; ++g) {
      bf8 qf = g ? qf1 : qf0;
      float& lgv = g ? l1v : l0v;
      f32x4 St[4];
      __builtin_amdgcn_s_setprio(1);
#pragma unroll
      for (int t = 0; t < 4; ++t)
        St[t] = __builtin_amdgcn_mfma_f32_16x16x32_bf16(Kf[t], qf, z, 0, 0, 0);
      __builtin_amdgcn_s_setprio(0);
      float pr[4];
#pragma unroll
      for (int t = 0; t < 4; ++t) {
        float p0 = fast_exp2(St[t][0]);
        float p1 = fast_exp2(St[t][1]);
        float p2 = fast_exp2(St[t][2]);
        float p3 = fast_exp2(St[t][3]);
        St[t][0] = p0; St[t][1] = p1; St[t][2] = p2; St[t][3] = p3;
        pr[t] = (p0 + p1) + (p2 + p3);
      }
      float rs = (pr[0] + pr[1]) + (pr[2] + pr[3]);
      rs += __shfl_xor(rs, 16);
      rs += __shfl_xor(rs, 32);
      lgv += rs;
#pragma unroll
      for (int t = 0; t < 4; ++t) {
        uint2 w;
        w.x = pack_bf2(St[t][0], St[t][1]);
        w.y = pack_bf2(St[t][2], St[t][3]);
        *reinterpret_cast<uint2*>(&Pt[wid][g][lr][t * 16 + lg * 4]) = w;
      }
    }
    __builtin_amdgcn_s_setprio(1);
#pragma unroll
    for (int g = 0; g < 2; ++g) {
      f32x4& Oh0 = g ? O10 : O00;
      f32x4& Oh1 = g ? O11 : O01;
#pragma unroll
      for (int c = 0; c < 2; ++c) {
        bf8 pbf = *reinterpret_cast<const bf8*>(&Pt[wid][g][lr][c * 32 + lg * 8]);
        Oh0 = __builtin_amdgcn_mfma_f32_16x16x32_bf16(Vf[c], pbf, Oh0, 0, 0, 0);
        Oh1 = __builtin_amdgcn_mfma_f32_16x16x32_bf16(Vf[2 + c], pbf, Oh1, 0, 0, 0);
      }
    }
    __builtin_amdgcn_s_setprio(0);
  };

  loadt(kA, vA, t0);
  int kt = t0;
  for (; kt + 2 <= t1 - 1; kt += 2) {
    loadt(kB, vB, kt + 1);
    body(kA, vA);
    loadt(kA, vA, kt + 2);
    body(kB, vB);
  }
  if (kt < t1 - 1) {
    loadt(kB, vB, kt + 1);
    body(kA, vA);
    body(kB, vB);
  } else {
    body(kA, vA);
  }

  size_t rbase = (size_t)(s * 12 + bh) * LROW;
  size_t r0 = (rbase + q0 + lr) * 32;
  size_t r1 = (rbase + q0 + 16 + lr) * 32;
  uint2 w;
  w.x = pack_bf2r(O00[0], O00[1]); w.y = pack_bf2r(O00[2], O00[3]);
  *reinterpret_cast<uint2*>(&pOb[r0 + lg * 4]) = w;
  w.x = pack_bf2r(O01[0], O01[1]); w.y = pack_bf2r(O01[2], O01[3]);
  *reinterpret_cast<uint2*>(&pOb[r0 + 16 + lg * 4]) = w;
  w.x = pack_bf2r(O10[0], O10[1]); w.y = pack_bf2r(O10[2], O10[3]);
  *reinterpret_cast<uint2*>(&pOb[r1 + lg * 4]) = w;
  w.x = pack_bf2r(O11[0], O11[1]); w.y = pack_bf2r(O11[2], O11[3]);
  *reinterpret_cast<uint2*>(&pOb[r1 + 16 + lg * 4]) = w;
  if (lg == 0) {
    pl[rbase + q0 + lr] = l0v;
    pl[rbase + q0 + 16 + lr] = l1v;
  }
}

// ---------------- merge 6 KV-split partials (sums only) -> bf16 ao ----------------
__global__ __launch_bounds__(256) void flash_merge_kernel(
    const short* __restrict__ pOb, const float* __restrict__ pl,
    short* __restrict__ aob) {
  int idx = blockIdx.x * 256 + threadIdx.x;
  int d = idx & 31, row = idx >> 5;
  const int NR = 12 * LROW;
  float o = 0.f, l = 0.f;
#pragma unroll
  for (int s = 0; s < 6; ++s) {
    o += bf2f((unsigned short)pOb[(size_t)s * NR * 32 + idx]);
    l += pl[(size_t)s * NR + row];
  }
  int bh = row / LROW, q = row - bh * LROW;
  int b = bh / 3, h = bh - b * 3;
  aob[((size_t)b * LROW + q) * CD + h * 32 + d] = f2bf(o / l);
}

extern "C" void kernel_launch(void* const* d_in, const int* in_sizes, int n_in,
                              void* d_out, int out_size, void* d_ws, size_t ws_size,
                              hipStream_t stream) {
  const float* x      = (const float*)d_in[0];
  const int*   Hp     = (const int*)d_in[1];
  const int*   Wp     = (const int*)d_in[2];
  const float* n1s    = (const float*)d_in[3];
  const float* n1b    = (const float*)d_in[4];
  const float* qkv_w  = (const float*)d_in[5];
  const float* qkv_b  = (const float*)d_in[6];
  const float* proj_w = (const float*)d_in[7];
  const float* proj_b = (const float*)d_in[8];
  const float* ln1s   = (const float*)d_in[9];
  const float* ln1b   = (const float*)d_in[10];
  const float* qkv2_w = (const float*)d_in[11];
  const float* qkv2_b = (const float*)d_in[12];
  const float* out_w  = (const float*)d_in[13];
  const float* out_b  = (const float*)d_in[14];
  const float* ln2s   = (const float*)d_in[15];
  const float* ln2b   = (const float*)d_in[16];
  const float* fc1_w  = (const float*)d_in[17];
  const float* fc1_b  = (const float*)d_in[18];
  const float* fc2_w  = (const float*)d_in[19];
  const float* fc2_b  = (const float*)d_in[20];

  float* wsf = (float*)d_ws;
  const size_t U = (size_t)4 * LROW * CD;  // 1,204,224
  float* x1   = wsf;                           // [0,U) fp32 residual (win out)
  float* x2   = wsf + U;                       // [U,2U) fp32 (out-proj out)
  short* hb   = (short*)(wsf + 2 * U);         // [2U,2.5U) bf16 (LN1 out; later LN2 out)
  short* tb   = (short*)(wsf + 2 * U + U / 2); // [2.5U,4.5U) bf16 fc1 out
  short* qb   = (short*)(wsf + 4 * U + U / 2); // [4.5U,5U)
  short* kb   = qb + U;                        // [5U,5.5U)
  short* vtb  = kb + U;                        // [5.5U,6U)
  short* wall = (short*)(wsf + 6 * U);         // contiguous bf16 weights, 165888 shorts
  short* wqkv = wall;                          // 320*96
  short* wout = wqkv + 320 * 96;               // 128*96
  short* wfc1 = wout + 128 * 96;               // 384*96
  short* wfc2 = wfc1 + 384 * 96;               // 128*384
  short* wwin = wfc2 + 128 * 384;              // 288*96
  short* wproj = wwin + 288 * 96;              // 96*96
  short* hb2  = (short*)(wsf + 6 * U + 82944); // bf16 LN-tb1 out (U shorts)
  // flash partials overlay [U,4.2U): pOb bf16 6 splits (3U floats) + pl fp32
  short* pOb  = (short*)(wsf + U);             // 6 * 12*LROW*32 shorts = 3U floats
  float* pl   = wsf + 4 * U;                   // 6 * 12*LROW floats (dead tb tail)
  short* aob  = qb;                            // merge output (qb dead after flash)
  float* outx = (float*)d_out;

  const int M = 4 * LROW;  // 12544

  cvt_all_kernel<<<(165888 + 255) / 256, 256, 0, stream>>>(
      qkv2_w, out_w, fc1_w, fc2_w, qkv_w, proj_w, wall, Hp, Wp, outx + U);

  ln_kernel<<<M / 8, 256, 0, stream>>>(x, n1s, n1b, hb, M);
  win_attn_kernel<<<256, 512, 0, stream>>>(hb, x, wwin, qkv_b, wproj, proj_b,
                                           ln1s, ln1b, x1, hb2);
  qkv_mfma_kernel<<<dim3(M / 128, 5), 256, 0, stream>>>(hb2, wqkv, qkv2_b, qb, kb, vtb);
  flash_mfma_kernel<<<dim3(49, 12, 6), 128, 0, stream>>>(qb, kb, vtb, pOb, pl);
  flash_merge_kernel<<<12 * LROW * 32 / 256, 256, 0, stream>>>(pOb, pl, aob);
  gemm_out_ln_kernel<<<M / 128, 256, 0, stream>>>(aob, wout, out_b, x1, ln2s, ln2b, x2, hb);
  gemm_mfma_kernel<0><<<dim3(M / 128, 6), 256, 0, stream>>>(hb, wfc1, fc1_b, nullptr, tb, M, 96, 384);
  gemm_mfma_kernel<1><<<dim3(M / 128, 2), 256, 0, stream>>>(tb, wfc2, fc2_b, x2, outx, M, 384, 96);
}

// Round 12
// 114.895 us; speedup vs baseline: 5.8221x; 1.0279x over previous
//
#include <hip/hip_runtime.h>
#include <hip/hip_bf16.h>

#define CD 96
#define LROW 3136          // 56*56
#define QSCALE 0.17677669529663687f  // 1/sqrt(32)
#define LOG2E 1.4426950408889634f
#define MASKLOG2 -144.26950408889634f // -100 * log2(e)

using f32x4 = __attribute__((ext_vector_type(4))) float;
using bf8   = __attribute__((ext_vector_type(8))) short;

__device__ __forceinline__ short f2bf(float f) {
  union { float f; unsigned u; } v; v.f = f;
  unsigned r = v.u + 0x7fffu + ((v.u >> 16) & 1u);
  return (short)(r >> 16);
}
__device__ __forceinline__ float bf2f(unsigned short s) {
  return __uint_as_float((unsigned)s << 16);
}
__device__ __forceinline__ unsigned pack_bf2(float lo, float hi) {
  return (__float_as_uint(hi) & 0xffff0000u) | (__float_as_uint(lo) >> 16);
}
__device__ __forceinline__ unsigned pack_bf2r(float lo, float hi) {
  return ((unsigned)(unsigned short)f2bf(hi) << 16) | (unsigned short)f2bf(lo);
}
__device__ __forceinline__ float fast_exp2(float x) {
  return __builtin_amdgcn_exp2f(x);
}
// gelu tanh-approx via exp2: 0.5v(1+tanh(u)) = v*e/(e+1), e = exp(2u)
__device__ __forceinline__ float gelu_f(float v) {
  float u = 0.7978845608028654f * (v + 0.044715f * v * v * v);
  float e = fast_exp2(u * 2.8853900817779268f);  // 2*log2(e)
  return v * e * __builtin_amdgcn_rcpf(e + 1.f);
}

#define GLOAD_LDS16(src, dst) \
  __builtin_amdgcn_global_load_lds((const __attribute__((address_space(1))) void*)(src), \
                                   (__attribute__((address_space(3))) void*)(dst), 16, 0, 0)

// ---------------- LayerNorm (LN1 only): 32-lane groups, 3 cols/lane -> bf16 ----------------
__global__ __launch_bounds__(256) void ln_kernel(const float* __restrict__ x,
                                                 const float* __restrict__ g,
                                                 const float* __restrict__ b,
                                                 short* __restrict__ out, int rows) {
  int slot = threadIdx.x >> 5, l32 = threadIdx.x & 31;
  int row = blockIdx.x * 8 + slot;
  if (row >= rows) return;
  const float* xr = x + (size_t)row * CD + l32 * 3;
  float a0 = xr[0], a1 = xr[1], a2 = xr[2];
  float s = a0 + a1 + a2;
#pragma unroll
  for (int off = 16; off >= 1; off >>= 1) s += __shfl_xor(s, off, 32);
  float mu = s * (1.f / 96.f);
  float d0 = a0 - mu, d1 = a1 - mu, d2 = a2 - mu;
  float q = d0 * d0 + d1 * d1 + d2 * d2;
#pragma unroll
  for (int off = 16; off >= 1; off >>= 1) q += __shfl_xor(q, off, 32);
  float rstd = rsqrtf(q * (1.f / 96.f) + 1e-6f);
  int c0 = l32 * 3;
  short* orow = out + (size_t)row * CD + c0;
  orow[0] = f2bf(d0 * rstd * g[c0] + b[c0]);
  orow[1] = f2bf(d1 * rstd * g[c0 + 1] + b[c0 + 1]);
  orow[2] = f2bf(d2 * rstd * g[c0 + 2] + b[c0 + 2]);
}

// ---------------- fused weight convert (+ tail scalars) ----------------
__global__ __launch_bounds__(256) void cvt_all_kernel(
    const float* __restrict__ qkv2_w, const float* __restrict__ out_w,
    const float* __restrict__ fc1_w, const float* __restrict__ fc2_w,
    const float* __restrict__ qkv_w, const float* __restrict__ proj_w,
    short* __restrict__ dst,
    const int* __restrict__ Hp, const int* __restrict__ Wp,
    float* __restrict__ tail_out) {
  int idx = blockIdx.x * 256 + threadIdx.x;
  if (idx == 0) {
    tail_out[0] = (float)Hp[0];
    tail_out[1] = (float)Wp[0];
  }
  if (idx >= 165888) return;
  const float* W; int K, N, off;
  if (idx < 30720)       { W = qkv2_w; K = 96;  N = 288; off = idx; }
  else if (idx < 43008)  { W = out_w;  K = 96;  N = 96;  off = idx - 30720; }
  else if (idx < 79872)  { W = fc1_w;  K = 96;  N = 384; off = idx - 43008; }
  else if (idx < 129024) { W = fc2_w;  K = 384; N = 96;  off = idx - 79872; }
  else if (idx < 156672) { W = qkv_w;  K = 96;  N = 288; off = idx - 129024; }
  else                   { W = proj_w; K = 96;  N = 96;  off = idx - 156672; }
  int nr = off / K, kk = off - nr * K;
  float v = (nr < N) ? W[(size_t)kk * N + nr] : 0.f;
  dst[idx] = f2bf(v);
}

// ---------------- MFMA shifted-window attention + fused LN-tb1 epilogue ----------------
__global__ __launch_bounds__(512) void win_attn_kernel(
    const short* __restrict__ hb_in, const float* __restrict__ xin,
    const short* __restrict__ wwin, const float* __restrict__ qkv_b,
    const short* __restrict__ wproj, const float* __restrict__ proj_b,
    const float* __restrict__ ln1s, const float* __restrict__ ln1b,
    float* __restrict__ x1, short* __restrict__ hb2) {
  __shared__ __align__(16) short Xs[64][104];
  __shared__ __align__(16) short Qs[3][64][40];
  __shared__ __align__(16) short Ks[3][64][40];
  __shared__ __align__(16) short Vt[3][32][72];
  __shared__ __align__(16) short Os[64][104];
  __shared__ __align__(16) short Ptw[8][16][72];
  __shared__ int cnt[64];
  __shared__ int gidx[49];

  int tid = threadIdx.x, lane = tid & 63, wid = tid >> 6;
  int lr = lane & 15, lg = lane >> 4;
  int b = blockIdx.x >> 6, w64 = blockIdx.x & 63;
  int wr = w64 >> 3, wc = w64 & 7;

  if (tid < 64) {
    if (tid < 49) {
      int i = tid / 7, j = tid % 7;
      int sh = wr * 7 + i, sw = wc * 7 + j;
      int hr = (sh < 49) ? 0 : ((sh < 53) ? 1 : 2);
      int wreg = (sw < 49) ? 0 : ((sw < 53) ? 1 : 2);
      cnt[tid] = hr * 3 + wreg;
      gidx[tid] = ((sh + 3) % 56) * 56 + ((sw + 3) % 56);
    } else {
      cnt[tid] = -1;
    }
  }
  __syncthreads();

  for (int c = tid; c < 768; c += 512) {
    int row = c / 12, cc = c % 12;
    uint4 v = {0u, 0u, 0u, 0u};
    if (row < 49) v = *reinterpret_cast<const uint4*>(hb_in + ((size_t)b * LROW + gidx[row]) * 96 + cc * 8);
    *reinterpret_cast<uint4*>(&Xs[row][cc * 8]) = v;
  }
  __syncthreads();

  // ---- qkv GEMM: M=64, N=288 (18 n-tiles over 8 waves), K=96 ----
  for (int nt = wid; nt < 18; nt += 8) {
    f32x4 acc[4];
#pragma unroll
    for (int mi = 0; mi < 4; ++mi) acc[mi] = (f32x4){0.f, 0.f, 0.f, 0.f};
#pragma unroll
    for (int kc = 0; kc < 3; ++kc) {
      bf8 bfr = *reinterpret_cast<const bf8*>(wwin + (size_t)(nt * 16 + lr) * 96 + kc * 32 + lg * 8);
#pragma unroll
      for (int mi = 0; mi < 4; ++mi) {
        bf8 afr = *reinterpret_cast<const bf8*>(&Xs[mi * 16 + lr][kc * 32 + lg * 8]);
        acc[mi] = __builtin_amdgcn_mfma_f32_16x16x32_bf16(afr, bfr, acc[mi], 0, 0, 0);
      }
    }
    int n = nt * 16 + lr;
    int sec = n / 96, within = n % 96;
    int hh = within >> 5, dd = within & 31;
    float bias = qkv_b[n];
#pragma unroll
    for (int mi = 0; mi < 4; ++mi)
#pragma unroll
      for (int r = 0; r < 4; ++r) {
        int mrow = mi * 16 + lg * 4 + r;
        float v = acc[mi][r] + bias;
        if (sec == 0)      Qs[hh][mrow][dd] = f2bf(v * (QSCALE * LOG2E));
        else if (sec == 1) Ks[hh][mrow][dd] = f2bf(v);
        else               Vt[hh][dd][mrow] = f2bf(v);
      }
  }
  __syncthreads();

  // ---- attention: 12 (head, q-tile) pairs over 8 waves; no-max softmax, tree sum ----
  int cntkv[16];
#pragma unroll
  for (int t = 0; t < 4; ++t)
#pragma unroll
    for (int r = 0; r < 4; ++r) cntkv[t * 4 + r] = cnt[t * 16 + lg * 4 + r];

  for (int p = wid; p < 12; p += 8) {
    int h = p >> 2, qt = p & 3;
    bf8 qf = *reinterpret_cast<const bf8*>(&Qs[h][qt * 16 + lr][lg * 8]);
    int cq = cnt[qt * 16 + lr];
    f32x4 z = {0.f, 0.f, 0.f, 0.f};
    f32x4 St[4];
    __builtin_amdgcn_s_setprio(1);
#pragma unroll
    for (int t = 0; t < 4; ++t) {
      bf8 kf = *reinterpret_cast<const bf8*>(&Ks[h][t * 16 + lr][lg * 8]);
      St[t] = __builtin_amdgcn_mfma_f32_16x16x32_bf16(kf, qf, z, 0, 0, 0);
    }
    __builtin_amdgcn_s_setprio(0);
    float pr[4];
#pragma unroll
    for (int t = 0; t < 4; ++t) {
      float p0 = fast_exp2(St[t][0] + ((cq == cntkv[t * 4 + 0]) ? 0.f : MASKLOG2));
      float p1 = fast_exp2(St[t][1] + ((cq == cntkv[t * 4 + 1]) ? 0.f : MASKLOG2));
      float p2 = fast_exp2(St[t][2] + ((cq == cntkv[t * 4 + 2]) ? 0.f : MASKLOG2));
      float p3 = fast_exp2(St[t][3] + ((cq == cntkv[t * 4 + 3]) ? 0.f : MASKLOG2));
      St[t][0] = p0; St[t][1] = p1; St[t][2] = p2; St[t][3] = p3;
      pr[t] = (p0 + p1) + (p2 + p3);
    }
    float rs = (pr[0] + pr[1]) + (pr[2] + pr[3]);
    rs += __shfl_xor(rs, 16);
    rs += __shfl_xor(rs, 32);
    float inv = 1.f / rs;
#pragma unroll
    for (int t = 0; t < 4; ++t) {
      uint2 w;
      w.x = pack_bf2(St[t][0], St[t][1]);
      w.y = pack_bf2(St[t][2], St[t][3]);
      *reinterpret_cast<uint2*>(&Ptw[wid][lr][t * 16 + lg * 4]) = w;
    }
    f32x4 O0 = {0.f, 0.f, 0.f, 0.f}, O1 = {0.f, 0.f, 0.f, 0.f};
    __builtin_amdgcn_s_setprio(1);
#pragma unroll
    for (int c = 0; c < 2; ++c) {
      bf8 pbf = *reinterpret_cast<const bf8*>(&Ptw[wid][lr][c * 32 + lg * 8]);
      bf8 v0 = *reinterpret_cast<const bf8*>(&Vt[h][lr][c * 32 + lg * 8]);
      bf8 v1 = *reinterpret_cast<const bf8*>(&Vt[h][16 + lr][c * 32 + lg * 8]);
      O0 = __builtin_amdgcn_mfma_f32_16x16x32_bf16(v0, pbf, O0, 0, 0, 0);
      O1 = __builtin_amdgcn_mfma_f32_16x16x32_bf16(v1, pbf, O1, 0, 0, 0);
    }
    __builtin_amdgcn_s_setprio(0);
#pragma unroll
    for (int r = 0; r < 4; ++r) {
      Os[qt * 16 + lr][h * 32 + lg * 4 + r] = f2bf(O0[r] * inv);
      Os[qt * 16 + lr][h * 32 + 16 + lg * 4 + r] = f2bf(O1[r] * inv);
    }
  }
  __syncthreads();

  // ---- proj GEMM (waves 0..3, full N per wave) + fused residual + LN-tb1 ----
  if (wid < 4) {
    int mt = wid;
    f32x4 acc[6];
#pragma unroll
    for (int nt = 0; nt < 6; ++nt) acc[nt] = (f32x4){0.f, 0.f, 0.f, 0.f};
#pragma unroll
    for (int kc = 0; kc < 3; ++kc) {
      bf8 afr = *reinterpret_cast<const bf8*>(&Os[mt * 16 + lr][kc * 32 + lg * 8]);
#pragma unroll
      for (int nt = 0; nt < 6; ++nt) {
        bf8 bfr = *reinterpret_cast<const bf8*>(wproj + (size_t)(nt * 16 + lr) * 96 + kc * 32 + lg * 8);
        acc[nt] = __builtin_amdgcn_mfma_f32_16x16x32_bf16(afr, bfr, acc[nt], 0, 0, 0);
      }
    }
    float pbv[6], gv[6], bv[6];
#pragma unroll
    for (int nt = 0; nt < 6; ++nt) {
      int col = nt * 16 + lr;
      pbv[nt] = proj_b[col];
      gv[nt] = ln1s[col];
      bv[nt] = ln1b[col];
    }
#pragma unroll
    for (int r = 0; r < 4; ++r) {
      int q = mt * 16 + lg * 4 + r;
      if (q >= 49) continue;           // uniform across the 16 lr lanes
      size_t rb = ((size_t)b * LROW + gidx[q]) * CD;
      float v[6];
#pragma unroll
      for (int nt = 0; nt < 6; ++nt)
        v[nt] = acc[nt][r] + pbv[nt] + xin[rb + nt * 16 + lr];
      float s = ((v[0] + v[1]) + (v[2] + v[3])) + (v[4] + v[5]);
      s += __shfl_xor(s, 1); s += __shfl_xor(s, 2);
      s += __shfl_xor(s, 4); s += __shfl_xor(s, 8);
      float mu = s * (1.f / 96.f);
      float d[6];
      float qs = 0.f;
#pragma unroll
      for (int nt = 0; nt < 6; ++nt) { d[nt] = v[nt] - mu; qs += d[nt] * d[nt]; }
      qs += __shfl_xor(qs, 1); qs += __shfl_xor(qs, 2);
      qs += __shfl_xor(qs, 4); qs += __shfl_xor(qs, 8);
      float rstd = rsqrtf(qs * (1.f / 96.f) + 1e-6f);
#pragma unroll
      for (int nt = 0; nt < 6; ++nt) {
        x1[rb + nt * 16 + lr] = v[nt];
        hb2[rb + nt * 16 + lr] = f2bf(d[nt] * rstd * gv[nt] + bv[nt]);
      }
    }
  }
}

// ---------------- qkv GEMM (bf16 MFMA) with flash-layout scatter epilogue ----------------
__global__ __launch_bounds__(256) void qkv_mfma_kernel(
    const short* __restrict__ A, const short* __restrict__ Bt,
    const float* __restrict__ bias,
    short* __restrict__ qb, short* __restrict__ kb, short* __restrict__ vtb) {
  __shared__ __align__(16) short As[2][128 * 32];
  __shared__ __align__(16) short Bs[2][64 * 32];
  int tid = threadIdx.x, lane = tid & 63, wid = tid >> 6;
  int lr = lane & 15, lg = lane >> 4;
  int m0 = blockIdx.x * 128, n0 = blockIdx.y * 64;
  const int K = 96;

  f32x4 acc[2][4];
#pragma unroll
  for (int i = 0; i < 2; ++i)
#pragma unroll
    for (int j = 0; j < 4; ++j) acc[i][j] = (f32x4){0.f, 0.f, 0.f, 0.f};

  auto stage = [&](int bf, int ks) {
    int k0 = ks * 32;
#pragma unroll
    for (int p = 0; p < 2; ++p) {
      int idx = tid + p * 256;
      GLOAD_LDS16(A + (size_t)(m0 + (idx >> 2)) * K + k0 + (idx & 3) * 8,
                  &As[bf][idx * 8]);
    }
    GLOAD_LDS16(Bt + (size_t)(n0 + (tid >> 2)) * K + k0 + (tid & 3) * 8,
                &Bs[bf][tid * 8]);
  };

  stage(0, 0);
  __syncthreads();
  int buf = 0;
  for (int ks = 0; ks < 3; ++ks) {
    if (ks + 1 < 3) stage(buf ^ 1, ks + 1);
    bf8 bfr[4], afr[2];
#pragma unroll
    for (int ni = 0; ni < 4; ++ni)
      bfr[ni] = *reinterpret_cast<const bf8*>(&Bs[buf][(ni * 16 + lr) * 32 + lg * 8]);
#pragma unroll
    for (int mi = 0; mi < 2; ++mi)
      afr[mi] = *reinterpret_cast<const bf8*>(&As[buf][(wid * 32 + mi * 16 + lr) * 32 + lg * 8]);
    __builtin_amdgcn_s_setprio(1);
#pragma unroll
    for (int mi = 0; mi < 2; ++mi)
#pragma unroll
      for (int ni = 0; ni < 4; ++ni)
        acc[mi][ni] = __builtin_amdgcn_mfma_f32_16x16x32_bf16(afr[mi], bfr[ni], acc[mi][ni], 0, 0, 0);
    __builtin_amdgcn_s_setprio(0);
    __syncthreads();
    buf ^= 1;
  }

#pragma unroll
  for (int mi = 0; mi < 2; ++mi)
#pragma unroll
    for (int ni = 0; ni < 4; ++ni)
#pragma unroll
      for (int r = 0; r < 4; ++r) {
        int mrow = m0 + wid * 32 + mi * 16 + lg * 4 + r;
        int n = n0 + ni * 16 + lr;
        if (n < 288) {
          float v = acc[mi][ni][r] + bias[n];
          int sec = n / 96, within = n % 96;
          int hh = within >> 5, dd = within & 31;
          int bb = mrow / LROW, nn = mrow - bb * LROW;
          size_t bh = (size_t)bb * 3 + hh;
          if (sec == 0)      qb[(bh * LROW + nn) * 32 + dd] = f2bf(v * (QSCALE * LOG2E));
          else if (sec == 1) kb[(bh * LROW + nn) * 32 + dd] = f2bf(v);
          else               vtb[(bh * 32 + dd) * LROW + nn] = f2bf(v);
        }
      }
}

// ---------------- flash attention v7: no-max softmax, split-KV x6, tree-reduced sum ----------------
__global__ __launch_bounds__(128) void flash_mfma_kernel(
    const short* __restrict__ qb, const short* __restrict__ kb,
    const short* __restrict__ vtb,
    short* __restrict__ pOb, float* __restrict__ pl) {
  __shared__ __align__(16) short Pt[2][2][16][72];  // [wave][g][q][kv]; 144B rows (no aliasing)
  int tid = threadIdx.x, lane = tid & 63, wid = tid >> 6;
  int lr = lane & 15, lg = lane >> 4;
  int bh = blockIdx.y, s = blockIdx.z;
  int q0 = blockIdx.x * 64 + wid * 32;
  const short* qbb = qb + (size_t)bh * LROW * 32;
  const short* kbase = kb + (size_t)bh * LROW * 32 + lr * 32 + lg * 8;
  const short* vbase = vtb + (size_t)bh * 32 * LROW + lr * LROW + lg * 8;

  bf8 qf0 = *reinterpret_cast<const bf8*>(qbb + (size_t)(q0 + lr) * 32 + lg * 8);
  bf8 qf1 = *reinterpret_cast<const bf8*>(qbb + (size_t)(q0 + 16 + lr) * 32 + lg * 8);

  f32x4 O00 = {0.f,0.f,0.f,0.f}, O01 = {0.f,0.f,0.f,0.f};
  f32x4 O10 = {0.f,0.f,0.f,0.f}, O11 = {0.f,0.f,0.f,0.f};
  float l0v = 0.f, l1v = 0.f;

  const int tbl[7] = {0, 9, 17, 25, 33, 41, 49};
  int t0 = tbl[s], t1 = tbl[s + 1];

  bf8 kA[4], vA[4], kB[4], vB[4];

  auto loadt = [&](bf8 (&Kf)[4], bf8 (&Vf)[4], int kt) {
    const short* kp = kbase + (size_t)kt * 2048;
#pragma unroll
    for (int t = 0; t < 4; ++t) Kf[t] = *reinterpret_cast<const bf8*>(kp + t * 512);
    const short* vp = vbase + kt * 64;
#pragma unroll
    for (int c = 0; c < 2; ++c) {
      Vf[c]     = *reinterpret_cast<const bf8*>(vp + c * 32);
      Vf[2 + c] = *reinterpret_cast<const bf8*>(vp + 16 * LROW + c * 32);
    }
  };

  auto body = [&](bf8 (&Kf)[4], bf8 (&Vf)[4]) {
    f32x4 z = {0.f, 0.f, 0.f, 0.f};
#pragma unroll
    for (int g = 0; g < 2; ++g) {
      bf8 qf = g ? qf1 : qf0;
      float& lgv = g ? l1v : l0v;
      f32x4 St[4];
      __builtin_amdgcn_s_setprio(1);
#pragma unroll
      for (int t = 0; t < 4; ++t)
        St[t] = __builtin_amdgcn_mfma_f32_16x16x32_bf16(Kf[t], qf, z, 0, 0, 0);
      __builtin_amdgcn_s_setprio(0);
      float pr[4];
#pragma unroll
      for (int t = 0; t < 4; ++t) {
        float p0 = fast_exp2(St[t][0]);
        float p1 = fast_exp2(St[t][1]);
        float p2 = fast_exp2(St[t][2]);
        float p3 = fast_exp2(St[t][3]);
        St[t][0] = p0; St[t][1] = p1; St[t][2] = p2; St[t][3] = p3;
        pr[t] = (p0 + p1) + (p2 + p3);
      }
      float rs = (pr[0] + pr[1]) + (pr[2] + pr[3]);
      rs += __shfl_xor(rs, 16);
      rs += __shfl_xor(rs, 32);
      lgv += rs;
#pragma unroll
      for (int t = 0; t < 4; ++t) {
        uint2 w;
        w.x = pack_bf2(St[t][0], St[t][1]);
        w.y = pack_bf2(St[t][2], St[t][3]);
        *reinterpret_cast<uint2*>(&Pt[wid][g][lr][t * 16 + lg * 4]) = w;
      }
    }
    __builtin_amdgcn_s_setprio(1);
#pragma unroll
    for (int g = 0; g < 2; ++g) {
      f32x4& Oh0 = g ? O10 : O00;
      f32x4& Oh1 = g ? O11 : O01;
#pragma unroll
      for (int c = 0; c < 2; ++c) {
        bf8 pbf = *reinterpret_cast<const bf8*>(&Pt[wid][g][lr][c * 32 + lg * 8]);
        Oh0 = __builtin_amdgcn_mfma_f32_16x16x32_bf16(Vf[c], pbf, Oh0, 0, 0, 0);
        Oh1 = __builtin_amdgcn_mfma_f32_16x16x32_bf16(Vf[2 + c], pbf, Oh1, 0, 0, 0);
      }
    }
    __builtin_amdgcn_s_setprio(0);
  };

  loadt(kA, vA, t0);
  int kt = t0;
  for (; kt + 2 <= t1 - 1; kt += 2) {
    loadt(kB, vB, kt + 1);
    body(kA, vA);
    loadt(kA, vA, kt + 2);
    body(kB, vB);
  }
  if (kt < t1 - 1) {
    loadt(kB, vB, kt + 1);
    body(kA, vA);
    body(kB, vB);
  } else {
    body(kA, vA);
  }

  size_t rbase = (size_t)(s * 12 + bh) * LROW;
  size_t r0 = (rbase + q0 + lr) * 32;
  size_t r1 = (rbase + q0 + 16 + lr) * 32;
  uint2 w;
  w.x = pack_bf2r(O00[0], O00[1]); w.y = pack_bf2r(O00[2], O00[3]);
  *reinterpret_cast<uint2*>(&pOb[r0 + lg * 4]) = w;
  w.x = pack_bf2r(O01[0], O01[1]); w.y = pack_bf2r(O01[2], O01[3]);
  *reinterpret_cast<uint2*>(&pOb[r0 + 16 + lg * 4]) = w;
  w.x = pack_bf2r(O10[0], O10[1]); w.y = pack_bf2r(O10[2], O10[3]);
  *reinterpret_cast<uint2*>(&pOb[r1 + lg * 4]) = w;
  w.x = pack_bf2r(O11[0], O11[1]); w.y = pack_bf2r(O11[2], O11[3]);
  *reinterpret_cast<uint2*>(&pOb[r1 + 16 + lg * 4]) = w;
  if (lg == 0) {
    pl[rbase + q0 + lr] = l0v;
    pl[rbase + q0 + 16 + lr] = l1v;
  }
}

// ---------------- out-proj GEMM with fused 6-split merge (A-stage) + residual + LN2 ----------------
// A[128][96] built in LDS from pOb/pl partials; B = wout (padded 128x96) double-buffered.
__global__ __launch_bounds__(256) void gemm_out_merge_ln_kernel(
    const short* __restrict__ pOb, const float* __restrict__ pl,
    const short* __restrict__ Bt,
    const float* __restrict__ bias, const float* __restrict__ res,
    const float* __restrict__ g2, const float* __restrict__ b2,
    float* __restrict__ x2, short* __restrict__ hb3) {
  __shared__ __align__(16) short As[128][104];   // merged bf16 A, padded rows
  __shared__ __align__(16) short Bs[2][96 * 32];
  int tid = threadIdx.x, lane = tid & 63, wid = tid >> 6;
  int lr = lane & 15, lg = lane >> 4;
  int m0 = blockIdx.x * 128;
  const int K = 96;
  const int NR = 12 * LROW;

  // ---- merge-stage A: thread handles (row, head) pairs ----
  for (int pi = tid; pi < 384; pi += 256) {
    int rloc = pi / 3, h = pi % 3;
    int grow = m0 + rloc;
    int bb = grow / LROW, q = grow - bb * LROW;
    size_t pbase = ((size_t)(bb * 3 + h)) * LROW + q;
    float l = 0.f;
#pragma unroll
    for (int s = 0; s < 6; ++s) l += pl[(size_t)s * NR + pbase];
    float invl = 1.f / l;
    float o[32];
#pragma unroll
    for (int d = 0; d < 32; ++d) o[d] = 0.f;
#pragma unroll
    for (int s = 0; s < 6; ++s) {
      const uint4* p4 = reinterpret_cast<const uint4*>(pOb + ((size_t)s * NR + pbase) * 32);
#pragma unroll
      for (int u = 0; u < 4; ++u) {
        uint4 v = p4[u];
        unsigned wd0 = v.x, wd1 = v.y, wd2 = v.z, wd3 = v.w;
        o[u*8+0] += __uint_as_float(wd0 << 16);
        o[u*8+1] += __uint_as_float(wd0 & 0xffff0000u);
        o[u*8+2] += __uint_as_float(wd1 << 16);
        o[u*8+3] += __uint_as_float(wd1 & 0xffff0000u);
        o[u*8+4] += __uint_as_float(wd2 << 16);
        o[u*8+5] += __uint_as_float(wd2 & 0xffff0000u);
        o[u*8+6] += __uint_as_float(wd3 << 16);
        o[u*8+7] += __uint_as_float(wd3 & 0xffff0000u);
      }
    }
    short* dst = &As[rloc][h * 32];
#pragma unroll
    for (int u2 = 0; u2 < 4; ++u2) {
      uint4 w;
      w.x = pack_bf2r(o[u2*8+0]*invl, o[u2*8+1]*invl);
      w.y = pack_bf2r(o[u2*8+2]*invl, o[u2*8+3]*invl);
      w.z = pack_bf2r(o[u2*8+4]*invl, o[u2*8+5]*invl);
      w.w = pack_bf2r(o[u2*8+6]*invl, o[u2*8+7]*invl);
      *reinterpret_cast<uint4*>(dst + u2 * 8) = w;
    }
  }

  f32x4 acc[2][6];
#pragma unroll
  for (int i = 0; i < 2; ++i)
#pragma unroll
    for (int j = 0; j < 6; ++j) acc[i][j] = (f32x4){0.f, 0.f, 0.f, 0.f};

  auto stageB = [&](int bf, int ks) {
    int k0 = ks * 32;
    for (int l = tid; l < 384; l += 256) {
      GLOAD_LDS16(Bt + (size_t)(l >> 2) * K + k0 + (l & 3) * 8,
                  &Bs[bf][l * 8]);
    }
  };

  stageB(0, 0);
  __syncthreads();   // drains merge ds_writes + GLOAD vmcnt
  int buf = 0;
  for (int ks = 0; ks < 3; ++ks) {
    if (ks + 1 < 3) stageB(buf ^ 1, ks + 1);
    bf8 bfr[6], afr[2];
#pragma unroll
    for (int ni = 0; ni < 6; ++ni)
      bfr[ni] = *reinterpret_cast<const bf8*>(&Bs[buf][(ni * 16 + lr) * 32 + lg * 8]);
#pragma unroll
    for (int mi = 0; mi < 2; ++mi)
      afr[mi] = *reinterpret_cast<const bf8*>(&As[wid * 32 + mi * 16 + lr][ks * 32 + lg * 8]);
    __builtin_amdgcn_s_setprio(1);
#pragma unroll
    for (int mi = 0; mi < 2; ++mi)
#pragma unroll
      for (int ni = 0; ni < 6; ++ni)
        acc[mi][ni] = __builtin_amdgcn_mfma_f32_16x16x32_bf16(afr[mi], bfr[ni], acc[mi][ni], 0, 0, 0);
    __builtin_amdgcn_s_setprio(0);
    __syncthreads();
    buf ^= 1;
  }

  float bb[6], gv[6], bv[6];
#pragma unroll
  for (int ni = 0; ni < 6; ++ni) {
    int col = ni * 16 + lr;
    bb[ni] = bias[col];
    gv[ni] = g2[col];
    bv[ni] = b2[col];
  }
#pragma unroll
  for (int mi = 0; mi < 2; ++mi)
#pragma unroll
    for (int r = 0; r < 4; ++r) {
      int row = m0 + wid * 32 + mi * 16 + lg * 4 + r;
      size_t rb = (size_t)row * CD;
      float v[6];
#pragma unroll
      for (int ni = 0; ni < 6; ++ni)
        v[ni] = acc[mi][ni][r] + bb[ni] + res[rb + ni * 16 + lr];
      float s = ((v[0] + v[1]) + (v[2] + v[3])) + (v[4] + v[5]);
      s += __shfl_xor(s, 1); s += __shfl_xor(s, 2);
      s += __shfl_xor(s, 4); s += __shfl_xor(s, 8);
      float mu = s * (1.f / 96.f);
      float d[6];
      float qs = 0.f;
#pragma unroll
      for (int ni = 0; ni < 6; ++ni) { d[ni] = v[ni] - mu; qs += d[ni] * d[ni]; }
      qs += __shfl_xor(qs, 1); qs += __shfl_xor(qs, 2);
      qs += __shfl_xor(qs, 4); qs += __shfl_xor(qs, 8);
      float rstd = rsqrtf(qs * (1.f / 96.f) + 1e-6f);
#pragma unroll
      for (int ni = 0; ni < 6; ++ni) {
        x2[rb + ni * 16 + lr] = v[ni];
        hb3[rb + ni * 16 + lr] = f2bf(d[ni] * rstd * gv[ni] + bv[ni]);
      }
    }
}

// ---------------- fused MLP: fc1 (gelu) -> LDS -> fc2 (+bias+residual) -> out ----------------
// BM=64, 4 waves. fc1: wave w owns cols [w*96,(w+1)*96); fc2: wave w owns rows [w*16,(w+1)*16).
// B fragments read directly from global (weights L2-resident).
__global__ __launch_bounds__(256) void mlp_kernel(
    const short* __restrict__ hb3, const short* __restrict__ wfc1,
    const float* __restrict__ fc1_b, const short* __restrict__ wfc2,
    const float* __restrict__ fc2_b, const float* __restrict__ resid,
    float* __restrict__ outx) {
  __shared__ __align__(16) short Ah[64][104];
  __shared__ __align__(16) short T[64][392];
  int tid = threadIdx.x, lane = tid & 63, wid = tid >> 6;
  int lr = lane & 15, lg = lane >> 4;
  int m0 = blockIdx.x * 64;

  // stage A (64 x 96 bf16), padded rows
  for (int i = tid; i < 768; i += 256) {
    int row = i / 12, c8 = i % 12;
    uint4 v = *reinterpret_cast<const uint4*>(hb3 + (size_t)(m0 + row) * 96 + c8 * 8);
    *reinterpret_cast<uint4*>(&Ah[row][c8 * 8]) = v;
  }
  __syncthreads();

  // ---- fc1: M=64, N-strip=96 per wave, K=96 ----
  {
    f32x4 acc[4][6];
#pragma unroll
    for (int i = 0; i < 4; ++i)
#pragma unroll
      for (int j = 0; j < 6; ++j) acc[i][j] = (f32x4){0.f, 0.f, 0.f, 0.f};
#pragma unroll
    for (int kc = 0; kc < 3; ++kc) {
      bf8 bfr[6], afr[4];
#pragma unroll
      for (int nt = 0; nt < 6; ++nt)
        bfr[nt] = *reinterpret_cast<const bf8*>(wfc1 + (size_t)(wid * 96 + nt * 16 + lr) * 96 + kc * 32 + lg * 8);
#pragma unroll
      for (int mi = 0; mi < 4; ++mi)
        afr[mi] = *reinterpret_cast<const bf8*>(&Ah[mi * 16 + lr][kc * 32 + lg * 8]);
      __builtin_amdgcn_s_setprio(1);
#pragma unroll
      for (int mi = 0; mi < 4; ++mi)
#pragma unroll
        for (int nt = 0; nt < 6; ++nt)
          acc[mi][nt] = __builtin_amdgcn_mfma_f32_16x16x32_bf16(afr[mi], bfr[nt], acc[mi][nt], 0, 0, 0);
      __builtin_amdgcn_s_setprio(0);
    }
    // gelu -> T (scalar bf16 stores; C-frag layout scatters rows)
#pragma unroll
    for (int nt = 0; nt < 6; ++nt) {
      float b1 = fc1_b[wid * 96 + nt * 16 + lr];
      int col = wid * 96 + nt * 16 + lr;
#pragma unroll
      for (int mi = 0; mi < 4; ++mi)
#pragma unroll
        for (int r = 0; r < 4; ++r)
          T[mi * 16 + lg * 4 + r][col] = f2bf(gelu_f(acc[mi][nt][r] + b1));
    }
  }
  __syncthreads();

  // ---- fc2: rows [w*16,(w+1)*16), N=96, K=384 ----
  {
    f32x4 a2[6];
#pragma unroll
    for (int j = 0; j < 6; ++j) a2[j] = (f32x4){0.f, 0.f, 0.f, 0.f};
#pragma unroll
    for (int kc = 0; kc < 12; ++kc) {
      bf8 afr2 = *reinterpret_cast<const bf8*>(&T[wid * 16 + lr][kc * 32 + lg * 8]);
      bf8 bfr2[6];
#pragma unroll
      for (int nt = 0; nt < 6; ++nt)
        bfr2[nt] = *reinterpret_cast<const bf8*>(wfc2 + (size_t)(nt * 16 + lr) * 384 + kc * 32 + lg * 8);
      __builtin_amdgcn_s_setprio(1);
#pragma unroll
      for (int nt = 0; nt < 6; ++nt)
        a2[nt] = __builtin_amdgcn_mfma_f32_16x16x32_bf16(afr2, bfr2[nt], a2[nt], 0, 0, 0);
      __builtin_amdgcn_s_setprio(0);
    }
#pragma unroll
    for (int nt = 0; nt < 6; ++nt) {
      float b2v = fc2_b[nt * 16 + lr];
#pragma unroll
      for (int r = 0; r < 4; ++r) {
        int row = m0 + wid * 16 + lg * 4 + r;
        size_t idx = (size_t)row * CD + nt * 16 + lr;
        outx[idx] = a2[nt][r] + b2v + resid[idx];
      }
    }
  }
}

extern "C" void kernel_launch(void* const* d_in, const int* in_sizes, int n_in,
                              void* d_out, int out_size, void* d_ws, size_t ws_size,
                              hipStream_t stream) {
  const float* x      = (const float*)d_in[0];
  const int*   Hp     = (const int*)d_in[1];
  const int*   Wp     = (const int*)d_in[2];
  const float* n1s    = (const float*)d_in[3];
  const float* n1b    = (const float*)d_in[4];
  const float* qkv_w  = (const float*)d_in[5];
  const float* qkv_b  = (const float*)d_in[6];
  const float* proj_w = (const float*)d_in[7];
  const float* proj_b = (const float*)d_in[8];
  const float* ln1s   = (const float*)d_in[9];
  const float* ln1b   = (const float*)d_in[10];
  const float* qkv2_w = (const float*)d_in[11];
  const float* qkv2_b = (const float*)d_in[12];
  const float* out_w  = (const float*)d_in[13];
  const float* out_b  = (const float*)d_in[14];
  const float* ln2s   = (const float*)d_in[15];
  const float* ln2b   = (const float*)d_in[16];
  const float* fc1_w  = (const float*)d_in[17];
  const float* fc1_b  = (const float*)d_in[18];
  const float* fc2_w  = (const float*)d_in[19];
  const float* fc2_b  = (const float*)d_in[20];

  float* wsf = (float*)d_ws;
  const size_t U = (size_t)4 * LROW * CD;  // 1,204,224
  float* x1   = wsf;                           // [0,U) fp32 residual (win out)
  short* hb   = (short*)(wsf + 2 * U);         // [2U,2.5U) bf16 LN1 out (dead before flash)
  short* qb   = (short*)(wsf + 4 * U + U / 2); // [4.5U,5U)
  short* kb   = qb + U;                        // [5U,5.5U)
  short* vtb  = kb + U;                        // [5.5U,6U)
  short* wall = (short*)(wsf + 6 * U);         // contiguous bf16 weights, 165888 shorts
  short* wqkv = wall;                          // 320*96
  short* wout = wqkv + 320 * 96;               // 128*96
  short* wfc1 = wout + 128 * 96;               // 384*96
  short* wfc2 = wfc1 + 384 * 96;               // 128*384
  short* wwin = wfc2 + 128 * 384;              // 288*96
  short* wproj = wwin + 288 * 96;              // 96*96
  short* hb2  = (short*)(wsf + 6 * U + 82944); // bf16 LN-tb1 out (U shorts)
  // flash partials overlay [U,4U): pOb bf16 6 splits (3U floats); pl at [4U,4.2U)
  short* pOb  = (short*)(wsf + U);             // 6 * 12*LROW*32 shorts = 3U floats
  float* pl   = wsf + 4 * U;                   // 6 * 12*LROW floats
  // post-flash outputs live OUTSIDE the pOb overlay (qb/kb/vtb dead after flash):
  float* x2f  = (float*)qb;                    // U floats over [4.5U,5.5U)
  short* hb3  = vtb;                           // U shorts, LN2 out bf16
  float* outx = (float*)d_out;

  const int M = 4 * LROW;  // 12544

  cvt_all_kernel<<<(165888 + 255) / 256, 256, 0, stream>>>(
      qkv2_w, out_w, fc1_w, fc2_w, qkv_w, proj_w, wall, Hp, Wp, outx + U);

  ln_kernel<<<M / 8, 256, 0, stream>>>(x, n1s, n1b, hb, M);
  win_attn_kernel<<<256, 512, 0, stream>>>(hb, x, wwin, qkv_b, wproj, proj_b,
                                           ln1s, ln1b, x1, hb2);
  qkv_mfma_kernel<<<dim3(M / 128, 5), 256, 0, stream>>>(hb2, wqkv, qkv2_b, qb, kb, vtb);
  flash_mfma_kernel<<<dim3(49, 12, 6), 128, 0, stream>>>(qb, kb, vtb, pOb, pl);
  gemm_out_merge_ln_kernel<<<M / 128, 256, 0, stream>>>(pOb, pl, wout, out_b, x1,
                                                        ln2s, ln2b, x2f, hb3);
  mlp_kernel<<<M / 64, 256, 0, stream>>>(hb3, wfc1, fc1_b, wfc2, fc2_b, x2f, outx);
}

// Round 13
// 114.830 us; speedup vs baseline: 5.8254x; 1.0006x over previous
//
#include <hip/hip_runtime.h>
#include <hip/hip_bf16.h>

#define CD 96
#define LROW 3136          // 56*56
#define QSCALE 0.17677669529663687f  // 1/sqrt(32)
#define LOG2E 1.4426950408889634f
#define MASKLOG2 -144.26950408889634f // -100 * log2(e)

using f32x4 = __attribute__((ext_vector_type(4))) float;
using bf8   = __attribute__((ext_vector_type(8))) short;

__device__ __forceinline__ short f2bf(float f) {
  union { float f; unsigned u; } v; v.f = f;
  unsigned r = v.u + 0x7fffu + ((v.u >> 16) & 1u);
  return (short)(r >> 16);
}
__device__ __forceinline__ float bf2f(unsigned short s) {
  return __uint_as_float((unsigned)s << 16);
}
__device__ __forceinline__ unsigned pack_bf2(float lo, float hi) {
  return (__float_as_uint(hi) & 0xffff0000u) | (__float_as_uint(lo) >> 16);
}
__device__ __forceinline__ unsigned pack_bf2r(float lo, float hi) {
  return ((unsigned)(unsigned short)f2bf(hi) << 16) | (unsigned short)f2bf(lo);
}
__device__ __forceinline__ float fast_exp2(float x) {
  return __builtin_amdgcn_exp2f(x);
}
// gelu tanh-approx via exp2: 0.5v(1+tanh(u)) = v*e/(e+1), e = exp(2u)
__device__ __forceinline__ float gelu_f(float v) {
  float u = 0.7978845608028654f * (v + 0.044715f * v * v * v);
  float e = fast_exp2(u * 2.8853900817779268f);  // 2*log2(e)
  return v * e * __builtin_amdgcn_rcpf(e + 1.f);
}

#define GLOAD_LDS16(src, dst) \
  __builtin_amdgcn_global_load_lds((const __attribute__((address_space(1))) void*)(src), \
                                   (__attribute__((address_space(3))) void*)(dst), 16, 0, 0)

// ---------------- LayerNorm (LN1 only): 32-lane groups, 3 cols/lane -> bf16 ----------------
__global__ __launch_bounds__(256) void ln_kernel(const float* __restrict__ x,
                                                 const float* __restrict__ g,
                                                 const float* __restrict__ b,
                                                 short* __restrict__ out, int rows) {
  int slot = threadIdx.x >> 5, l32 = threadIdx.x & 31;
  int row = blockIdx.x * 8 + slot;
  if (row >= rows) return;
  const float* xr = x + (size_t)row * CD + l32 * 3;
  float a0 = xr[0], a1 = xr[1], a2 = xr[2];
  float s = a0 + a1 + a2;
#pragma unroll
  for (int off = 16; off >= 1; off >>= 1) s += __shfl_xor(s, off, 32);
  float mu = s * (1.f / 96.f);
  float d0 = a0 - mu, d1 = a1 - mu, d2 = a2 - mu;
  float q = d0 * d0 + d1 * d1 + d2 * d2;
#pragma unroll
  for (int off = 16; off >= 1; off >>= 1) q += __shfl_xor(q, off, 32);
  float rstd = rsqrtf(q * (1.f / 96.f) + 1e-6f);
  int c0 = l32 * 3;
  short* orow = out + (size_t)row * CD + c0;
  orow[0] = f2bf(d0 * rstd * g[c0] + b[c0]);
  orow[1] = f2bf(d1 * rstd * g[c0 + 1] + b[c0 + 1]);
  orow[2] = f2bf(d2 * rstd * g[c0 + 2] + b[c0 + 2]);
}

// ---------------- fused weight convert (+ tail scalars) ----------------
__global__ __launch_bounds__(256) void cvt_all_kernel(
    const float* __restrict__ qkv2_w, const float* __restrict__ out_w,
    const float* __restrict__ fc1_w, const float* __restrict__ fc2_w,
    const float* __restrict__ qkv_w, const float* __restrict__ proj_w,
    short* __restrict__ dst,
    const int* __restrict__ Hp, const int* __restrict__ Wp,
    float* __restrict__ tail_out) {
  int idx = blockIdx.x * 256 + threadIdx.x;
  if (idx == 0) {
    tail_out[0] = (float)Hp[0];
    tail_out[1] = (float)Wp[0];
  }
  if (idx >= 165888) return;
  const float* W; int K, N, off;
  if (idx < 30720)       { W = qkv2_w; K = 96;  N = 288; off = idx; }
  else if (idx < 43008)  { W = out_w;  K = 96;  N = 96;  off = idx - 30720; }
  else if (idx < 79872)  { W = fc1_w;  K = 96;  N = 384; off = idx - 43008; }
  else if (idx < 129024) { W = fc2_w;  K = 384; N = 96;  off = idx - 79872; }
  else if (idx < 156672) { W = qkv_w;  K = 96;  N = 288; off = idx - 129024; }
  else                   { W = proj_w; K = 96;  N = 96;  off = idx - 156672; }
  int nr = off / K, kk = off - nr * K;
  float v = (nr < N) ? W[(size_t)kk * N + nr] : 0.f;
  dst[idx] = f2bf(v);
}

// ---------------- MFMA shifted-window attention + fused LN-tb1 epilogue ----------------
__global__ __launch_bounds__(512) void win_attn_kernel(
    const short* __restrict__ hb_in, const float* __restrict__ xin,
    const short* __restrict__ wwin, const float* __restrict__ qkv_b,
    const short* __restrict__ wproj, const float* __restrict__ proj_b,
    const float* __restrict__ ln1s, const float* __restrict__ ln1b,
    float* __restrict__ x1, short* __restrict__ hb2) {
  __shared__ __align__(16) short Xs[64][104];
  __shared__ __align__(16) short Qs[3][64][40];
  __shared__ __align__(16) short Ks[3][64][40];
  __shared__ __align__(16) short Vt[3][32][72];
  __shared__ __align__(16) short Os[64][104];
  __shared__ __align__(16) short Ptw[8][16][72];
  __shared__ int cnt[64];
  __shared__ int gidx[49];

  int tid = threadIdx.x, lane = tid & 63, wid = tid >> 6;
  int lr = lane & 15, lg = lane >> 4;
  int b = blockIdx.x >> 6, w64 = blockIdx.x & 63;
  int wr = w64 >> 3, wc = w64 & 7;

  if (tid < 64) {
    if (tid < 49) {
      int i = tid / 7, j = tid % 7;
      int sh = wr * 7 + i, sw = wc * 7 + j;
      int hr = (sh < 49) ? 0 : ((sh < 53) ? 1 : 2);
      int wreg = (sw < 49) ? 0 : ((sw < 53) ? 1 : 2);
      cnt[tid] = hr * 3 + wreg;
      gidx[tid] = ((sh + 3) % 56) * 56 + ((sw + 3) % 56);
    } else {
      cnt[tid] = -1;
    }
  }
  __syncthreads();

  for (int c = tid; c < 768; c += 512) {
    int row = c / 12, cc = c % 12;
    uint4 v = {0u, 0u, 0u, 0u};
    if (row < 49) v = *reinterpret_cast<const uint4*>(hb_in + ((size_t)b * LROW + gidx[row]) * 96 + cc * 8);
    *reinterpret_cast<uint4*>(&Xs[row][cc * 8]) = v;
  }
  __syncthreads();

  // ---- qkv GEMM: M=64, N=288 (18 n-tiles over 8 waves), K=96 ----
  for (int nt = wid; nt < 18; nt += 8) {
    f32x4 acc[4];
#pragma unroll
    for (int mi = 0; mi < 4; ++mi) acc[mi] = (f32x4){0.f, 0.f, 0.f, 0.f};
#pragma unroll
    for (int kc = 0; kc < 3; ++kc) {
      bf8 bfr = *reinterpret_cast<const bf8*>(wwin + (size_t)(nt * 16 + lr) * 96 + kc * 32 + lg * 8);
#pragma unroll
      for (int mi = 0; mi < 4; ++mi) {
        bf8 afr = *reinterpret_cast<const bf8*>(&Xs[mi * 16 + lr][kc * 32 + lg * 8]);
        acc[mi] = __builtin_amdgcn_mfma_f32_16x16x32_bf16(afr, bfr, acc[mi], 0, 0, 0);
      }
    }
    int n = nt * 16 + lr;
    int sec = n / 96, within = n % 96;
    int hh = within >> 5, dd = within & 31;
    float bias = qkv_b[n];
#pragma unroll
    for (int mi = 0; mi < 4; ++mi)
#pragma unroll
      for (int r = 0; r < 4; ++r) {
        int mrow = mi * 16 + lg * 4 + r;
        float v = acc[mi][r] + bias;
        if (sec == 0)      Qs[hh][mrow][dd] = f2bf(v * (QSCALE * LOG2E));
        else if (sec == 1) Ks[hh][mrow][dd] = f2bf(v);
        else               Vt[hh][dd][mrow] = f2bf(v);
      }
  }
  __syncthreads();

  // ---- attention: 12 (head, q-tile) pairs over 8 waves; no-max softmax, tree sum ----
  int cntkv[16];
#pragma unroll
  for (int t = 0; t < 4; ++t)
#pragma unroll
    for (int r = 0; r < 4; ++r) cntkv[t * 4 + r] = cnt[t * 16 + lg * 4 + r];

  for (int p = wid; p < 12; p += 8) {
    int h = p >> 2, qt = p & 3;
    bf8 qf = *reinterpret_cast<const bf8*>(&Qs[h][qt * 16 + lr][lg * 8]);
    int cq = cnt[qt * 16 + lr];
    f32x4 z = {0.f, 0.f, 0.f, 0.f};
    f32x4 St[4];
    __builtin_amdgcn_s_setprio(1);
#pragma unroll
    for (int t = 0; t < 4; ++t) {
      bf8 kf = *reinterpret_cast<const bf8*>(&Ks[h][t * 16 + lr][lg * 8]);
      St[t] = __builtin_amdgcn_mfma_f32_16x16x32_bf16(kf, qf, z, 0, 0, 0);
    }
    __builtin_amdgcn_s_setprio(0);
    float pr[4];
#pragma unroll
    for (int t = 0; t < 4; ++t) {
      float p0 = fast_exp2(St[t][0] + ((cq == cntkv[t * 4 + 0]) ? 0.f : MASKLOG2));
      float p1 = fast_exp2(St[t][1] + ((cq == cntkv[t * 4 + 1]) ? 0.f : MASKLOG2));
      float p2 = fast_exp2(St[t][2] + ((cq == cntkv[t * 4 + 2]) ? 0.f : MASKLOG2));
      float p3 = fast_exp2(St[t][3] + ((cq == cntkv[t * 4 + 3]) ? 0.f : MASKLOG2));
      St[t][0] = p0; St[t][1] = p1; St[t][2] = p2; St[t][3] = p3;
      pr[t] = (p0 + p1) + (p2 + p3);
    }
    float rs = (pr[0] + pr[1]) + (pr[2] + pr[3]);
    rs += __shfl_xor(rs, 16);
    rs += __shfl_xor(rs, 32);
    float inv = 1.f / rs;
#pragma unroll
    for (int t = 0; t < 4; ++t) {
      uint2 w;
      w.x = pack_bf2(St[t][0], St[t][1]);
      w.y = pack_bf2(St[t][2], St[t][3]);
      *reinterpret_cast<uint2*>(&Ptw[wid][lr][t * 16 + lg * 4]) = w;
    }
    f32x4 O0 = {0.f, 0.f, 0.f, 0.f}, O1 = {0.f, 0.f, 0.f, 0.f};
    __builtin_amdgcn_s_setprio(1);
#pragma unroll
    for (int c = 0; c < 2; ++c) {
      bf8 pbf = *reinterpret_cast<const bf8*>(&Ptw[wid][lr][c * 32 + lg * 8]);
      bf8 v0 = *reinterpret_cast<const bf8*>(&Vt[h][lr][c * 32 + lg * 8]);
      bf8 v1 = *reinterpret_cast<const bf8*>(&Vt[h][16 + lr][c * 32 + lg * 8]);
      O0 = __builtin_amdgcn_mfma_f32_16x16x32_bf16(v0, pbf, O0, 0, 0, 0);
      O1 = __builtin_amdgcn_mfma_f32_16x16x32_bf16(v1, pbf, O1, 0, 0, 0);
    }
    __builtin_amdgcn_s_setprio(0);
#pragma unroll
    for (int r = 0; r < 4; ++r) {
      Os[qt * 16 + lr][h * 32 + lg * 4 + r] = f2bf(O0[r] * inv);
      Os[qt * 16 + lr][h * 32 + 16 + lg * 4 + r] = f2bf(O1[r] * inv);
    }
  }
  __syncthreads();

  // ---- proj GEMM (waves 0..3, full N per wave) + fused residual + LN-tb1 ----
  if (wid < 4) {
    int mt = wid;
    f32x4 acc[6];
#pragma unroll
    for (int nt = 0; nt < 6; ++nt) acc[nt] = (f32x4){0.f, 0.f, 0.f, 0.f};
#pragma unroll
    for (int kc = 0; kc < 3; ++kc) {
      bf8 afr = *reinterpret_cast<const bf8*>(&Os[mt * 16 + lr][kc * 32 + lg * 8]);
#pragma unroll
      for (int nt = 0; nt < 6; ++nt) {
        bf8 bfr = *reinterpret_cast<const bf8*>(wproj + (size_t)(nt * 16 + lr) * 96 + kc * 32 + lg * 8);
        acc[nt] = __builtin_amdgcn_mfma_f32_16x16x32_bf16(afr, bfr, acc[nt], 0, 0, 0);
      }
    }
    float pbv[6], gv[6], bv[6];
#pragma unroll
    for (int nt = 0; nt < 6; ++nt) {
      int col = nt * 16 + lr;
      pbv[nt] = proj_b[col];
      gv[nt] = ln1s[col];
      bv[nt] = ln1b[col];
    }
#pragma unroll
    for (int r = 0; r < 4; ++r) {
      int q = mt * 16 + lg * 4 + r;
      if (q >= 49) continue;           // uniform across the 16 lr lanes
      size_t rb = ((size_t)b * LROW + gidx[q]) * CD;
      float v[6];
#pragma unroll
      for (int nt = 0; nt < 6; ++nt)
        v[nt] = acc[nt][r] + pbv[nt] + xin[rb + nt * 16 + lr];
      float s = ((v[0] + v[1]) + (v[2] + v[3])) + (v[4] + v[5]);
      s += __shfl_xor(s, 1); s += __shfl_xor(s, 2);
      s += __shfl_xor(s, 4); s += __shfl_xor(s, 8);
      float mu = s * (1.f / 96.f);
      float d[6];
      float qs = 0.f;
#pragma unroll
      for (int nt = 0; nt < 6; ++nt) { d[nt] = v[nt] - mu; qs += d[nt] * d[nt]; }
      qs += __shfl_xor(qs, 1); qs += __shfl_xor(qs, 2);
      qs += __shfl_xor(qs, 4); qs += __shfl_xor(qs, 8);
      float rstd = rsqrtf(qs * (1.f / 96.f) + 1e-6f);
#pragma unroll
      for (int nt = 0; nt < 6; ++nt) {
        x1[rb + nt * 16 + lr] = v[nt];
        hb2[rb + nt * 16 + lr] = f2bf(d[nt] * rstd * gv[nt] + bv[nt]);
      }
    }
  }
}

// ---------------- qkv GEMM (bf16 MFMA) with flash-layout scatter epilogue ----------------
__global__ __launch_bounds__(256) void qkv_mfma_kernel(
    const short* __restrict__ A, const short* __restrict__ Bt,
    const float* __restrict__ bias,
    short* __restrict__ qb, short* __restrict__ kb, short* __restrict__ vtb) {
  __shared__ __align__(16) short As[2][128 * 32];
  __shared__ __align__(16) short Bs[2][64 * 32];
  int tid = threadIdx.x, lane = tid & 63, wid = tid >> 6;
  int lr = lane & 15, lg = lane >> 4;
  int m0 = blockIdx.x * 128, n0 = blockIdx.y * 64;
  const int K = 96;

  f32x4 acc[2][4];
#pragma unroll
  for (int i = 0; i < 2; ++i)
#pragma unroll
    for (int j = 0; j < 4; ++j) acc[i][j] = (f32x4){0.f, 0.f, 0.f, 0.f};

  auto stage = [&](int bf, int ks) {
    int k0 = ks * 32;
#pragma unroll
    for (int p = 0; p < 2; ++p) {
      int idx = tid + p * 256;
      GLOAD_LDS16(A + (size_t)(m0 + (idx >> 2)) * K + k0 + (idx & 3) * 8,
                  &As[bf][idx * 8]);
    }
    GLOAD_LDS16(Bt + (size_t)(n0 + (tid >> 2)) * K + k0 + (tid & 3) * 8,
                &Bs[bf][tid * 8]);
  };

  stage(0, 0);
  __syncthreads();
  int buf = 0;
  for (int ks = 0; ks < 3; ++ks) {
    if (ks + 1 < 3) stage(buf ^ 1, ks + 1);
    bf8 bfr[4], afr[2];
#pragma unroll
    for (int ni = 0; ni < 4; ++ni)
      bfr[ni] = *reinterpret_cast<const bf8*>(&Bs[buf][(ni * 16 + lr) * 32 + lg * 8]);
#pragma unroll
    for (int mi = 0; mi < 2; ++mi)
      afr[mi] = *reinterpret_cast<const bf8*>(&As[buf][(wid * 32 + mi * 16 + lr) * 32 + lg * 8]);
    __builtin_amdgcn_s_setprio(1);
#pragma unroll
    for (int mi = 0; mi < 2; ++mi)
#pragma unroll
      for (int ni = 0; ni < 4; ++ni)
        acc[mi][ni] = __builtin_amdgcn_mfma_f32_16x16x32_bf16(afr[mi], bfr[ni], acc[mi][ni], 0, 0, 0);
    __builtin_amdgcn_s_setprio(0);
    __syncthreads();
    buf ^= 1;
  }

#pragma unroll
  for (int mi = 0; mi < 2; ++mi)
#pragma unroll
    for (int ni = 0; ni < 4; ++ni)
#pragma unroll
      for (int r = 0; r < 4; ++r) {
        int mrow = m0 + wid * 32 + mi * 16 + lg * 4 + r;
        int n = n0 + ni * 16 + lr;
        if (n < 288) {
          float v = acc[mi][ni][r] + bias[n];
          int sec = n / 96, within = n % 96;
          int hh = within >> 5, dd = within & 31;
          int bb = mrow / LROW, nn = mrow - bb * LROW;
          size_t bh = (size_t)bb * 3 + hh;
          if (sec == 0)      qb[(bh * LROW + nn) * 32 + dd] = f2bf(v * (QSCALE * LOG2E));
          else if (sec == 1) kb[(bh * LROW + nn) * 32 + dd] = f2bf(v);
          else               vtb[(bh * 32 + dd) * LROW + nn] = f2bf(v);
        }
      }
}

// ---------------- flash attention v8: l-sum via ones-MFMA (no cross-lane ops in body) ----------------
// grid (49, 12, 6). S bounded -> exp2 never overflows. l accumulates in an MFMA C-operand:
// lacc = mfma(ones, P^T, lacc) gives every row = colsum(P) for q=lr; l = lacc[0].
__global__ __launch_bounds__(128) void flash_mfma_kernel(
    const short* __restrict__ qb, const short* __restrict__ kb,
    const short* __restrict__ vtb,
    short* __restrict__ pOb, float* __restrict__ pl) {
  __shared__ __align__(16) short Pt[2][2][16][72];  // [wave][g][q][kv]; 144B rows (no aliasing)
  int tid = threadIdx.x, lane = tid & 63, wid = tid >> 6;
  int lr = lane & 15, lg = lane >> 4;
  int bh = blockIdx.y, s = blockIdx.z;
  int q0 = blockIdx.x * 64 + wid * 32;
  const short* qbb = qb + (size_t)bh * LROW * 32;
  const short* kbase = kb + (size_t)bh * LROW * 32 + lr * 32 + lg * 8;
  const short* vbase = vtb + (size_t)bh * 32 * LROW + lr * LROW + lg * 8;

  bf8 qf0 = *reinterpret_cast<const bf8*>(qbb + (size_t)(q0 + lr) * 32 + lg * 8);
  bf8 qf1 = *reinterpret_cast<const bf8*>(qbb + (size_t)(q0 + 16 + lr) * 32 + lg * 8);

  const bf8 onesf = {16256, 16256, 16256, 16256, 16256, 16256, 16256, 16256};  // bf16 1.0

  f32x4 O00 = {0.f,0.f,0.f,0.f}, O01 = {0.f,0.f,0.f,0.f};
  f32x4 O10 = {0.f,0.f,0.f,0.f}, O11 = {0.f,0.f,0.f,0.f};
  f32x4 La0 = {0.f,0.f,0.f,0.f}, La1 = {0.f,0.f,0.f,0.f};  // l accumulators (all rows equal)

  const int tbl[7] = {0, 9, 17, 25, 33, 41, 49};
  int t0 = tbl[s], t1 = tbl[s + 1];

  bf8 kA[4], vA[4], kB[4], vB[4];

  auto loadt = [&](bf8 (&Kf)[4], bf8 (&Vf)[4], int kt) {
    const short* kp = kbase + (size_t)kt * 2048;
#pragma unroll
    for (int t = 0; t < 4; ++t) Kf[t] = *reinterpret_cast<const bf8*>(kp + t * 512);
    const short* vp = vbase + kt * 64;
#pragma unroll
    for (int c = 0; c < 2; ++c) {
      Vf[c]     = *reinterpret_cast<const bf8*>(vp + c * 32);
      Vf[2 + c] = *reinterpret_cast<const bf8*>(vp + 16 * LROW + c * 32);
    }
  };

  auto body = [&](bf8 (&Kf)[4], bf8 (&Vf)[4]) {
    f32x4 z = {0.f, 0.f, 0.f, 0.f};
#pragma unroll
    for (int g = 0; g < 2; ++g) {
      bf8 qf = g ? qf1 : qf0;
      f32x4 St[4];
      __builtin_amdgcn_s_setprio(1);
#pragma unroll
      for (int t = 0; t < 4; ++t)
        St[t] = __builtin_amdgcn_mfma_f32_16x16x32_bf16(Kf[t], qf, z, 0, 0, 0);
      __builtin_amdgcn_s_setprio(0);
#pragma unroll
      for (int t = 0; t < 4; ++t) {
        float p0 = fast_exp2(St[t][0]);
        float p1 = fast_exp2(St[t][1]);
        float p2 = fast_exp2(St[t][2]);
        float p3 = fast_exp2(St[t][3]);
        uint2 w;
        w.x = pack_bf2(p0, p1);
        w.y = pack_bf2(p2, p3);
        *reinterpret_cast<uint2*>(&Pt[wid][g][lr][t * 16 + lg * 4]) = w;
      }
    }
    __builtin_amdgcn_s_setprio(1);
#pragma unroll
    for (int g = 0; g < 2; ++g) {
      f32x4& Oh0 = g ? O10 : O00;
      f32x4& Oh1 = g ? O11 : O01;
      f32x4& La  = g ? La1 : La0;
#pragma unroll
      for (int c = 0; c < 2; ++c) {
        bf8 pbf = *reinterpret_cast<const bf8*>(&Pt[wid][g][lr][c * 32 + lg * 8]);
        Oh0 = __builtin_amdgcn_mfma_f32_16x16x32_bf16(Vf[c], pbf, Oh0, 0, 0, 0);
        Oh1 = __builtin_amdgcn_mfma_f32_16x16x32_bf16(Vf[2 + c], pbf, Oh1, 0, 0, 0);
        La  = __builtin_amdgcn_mfma_f32_16x16x32_bf16(onesf, pbf, La, 0, 0, 0);
      }
    }
    __builtin_amdgcn_s_setprio(0);
  };

  loadt(kA, vA, t0);
  int kt = t0;
  for (; kt + 2 <= t1 - 1; kt += 2) {
    loadt(kB, vB, kt + 1);
    body(kA, vA);
    loadt(kA, vA, kt + 2);
    body(kB, vB);
  }
  if (kt < t1 - 1) {
    loadt(kB, vB, kt + 1);
    body(kA, vA);
    body(kB, vB);
  } else {
    body(kA, vA);
  }

  // bf16 unnormalized partials; lane (lr,lg) holds d = lg*4+r (+16) for q = q0(+16)+lr
  size_t rbase = (size_t)(s * 12 + bh) * LROW;
  size_t r0 = (rbase + q0 + lr) * 32;
  size_t r1 = (rbase + q0 + 16 + lr) * 32;
  uint2 w;
  w.x = pack_bf2r(O00[0], O00[1]); w.y = pack_bf2r(O00[2], O00[3]);
  *reinterpret_cast<uint2*>(&pOb[r0 + lg * 4]) = w;
  w.x = pack_bf2r(O01[0], O01[1]); w.y = pack_bf2r(O01[2], O01[3]);
  *reinterpret_cast<uint2*>(&pOb[r0 + 16 + lg * 4]) = w;
  w.x = pack_bf2r(O10[0], O10[1]); w.y = pack_bf2r(O10[2], O10[3]);
  *reinterpret_cast<uint2*>(&pOb[r1 + lg * 4]) = w;
  w.x = pack_bf2r(O11[0], O11[1]); w.y = pack_bf2r(O11[2], O11[3]);
  *reinterpret_cast<uint2*>(&pOb[r1 + 16 + lg * 4]) = w;
  if (lg == 0) {
    pl[rbase + q0 + lr] = La0[0];
    pl[rbase + q0 + 16 + lr] = La1[0];
  }
}

// ---------------- out-proj GEMM with fused 6-split merge (A-stage) + residual + LN2 ----------------
__global__ __launch_bounds__(256) void gemm_out_merge_ln_kernel(
    const short* __restrict__ pOb, const float* __restrict__ pl,
    const short* __restrict__ Bt,
    const float* __restrict__ bias, const float* __restrict__ res,
    const float* __restrict__ g2, const float* __restrict__ b2,
    float* __restrict__ x2, short* __restrict__ hb3) {
  __shared__ __align__(16) short As[128][104];   // merged bf16 A, padded rows
  __shared__ __align__(16) short Bs[2][96 * 32];
  int tid = threadIdx.x, lane = tid & 63, wid = tid >> 6;
  int lr = lane & 15, lg = lane >> 4;
  int m0 = blockIdx.x * 128;
  const int K = 96;
  const int NR = 12 * LROW;

  // ---- merge-stage A: thread handles (row, head) pairs ----
  for (int pi = tid; pi < 384; pi += 256) {
    int rloc = pi / 3, h = pi % 3;
    int grow = m0 + rloc;
    int bb = grow / LROW, q = grow - bb * LROW;
    size_t pbase = ((size_t)(bb * 3 + h)) * LROW + q;
    float l = 0.f;
#pragma unroll
    for (int s = 0; s < 6; ++s) l += pl[(size_t)s * NR + pbase];
    float invl = 1.f / l;
    float o[32];
#pragma unroll
    for (int d = 0; d < 32; ++d) o[d] = 0.f;
#pragma unroll
    for (int s = 0; s < 6; ++s) {
      const uint4* p4 = reinterpret_cast<const uint4*>(pOb + ((size_t)s * NR + pbase) * 32);
#pragma unroll
      for (int u = 0; u < 4; ++u) {
        uint4 v = p4[u];
        unsigned wd0 = v.x, wd1 = v.y, wd2 = v.z, wd3 = v.w;
        o[u*8+0] += __uint_as_float(wd0 << 16);
        o[u*8+1] += __uint_as_float(wd0 & 0xffff0000u);
        o[u*8+2] += __uint_as_float(wd1 << 16);
        o[u*8+3] += __uint_as_float(wd1 & 0xffff0000u);
        o[u*8+4] += __uint_as_float(wd2 << 16);
        o[u*8+5] += __uint_as_float(wd2 & 0xffff0000u);
        o[u*8+6] += __uint_as_float(wd3 << 16);
        o[u*8+7] += __uint_as_float(wd3 & 0xffff0000u);
      }
    }
    short* dst = &As[rloc][h * 32];
#pragma unroll
    for (int u2 = 0; u2 < 4; ++u2) {
      uint4 w;
      w.x = pack_bf2r(o[u2*8+0]*invl, o[u2*8+1]*invl);
      w.y = pack_bf2r(o[u2*8+2]*invl, o[u2*8+3]*invl);
      w.z = pack_bf2r(o[u2*8+4]*invl, o[u2*8+5]*invl);
      w.w = pack_bf2r(o[u2*8+6]*invl, o[u2*8+7]*invl);
      *reinterpret_cast<uint4*>(dst + u2 * 8) = w;
    }
  }

  f32x4 acc[2][6];
#pragma unroll
  for (int i = 0; i < 2; ++i)
#pragma unroll
    for (int j = 0; j < 6; ++j) acc[i][j] = (f32x4){0.f, 0.f, 0.f, 0.f};

  auto stageB = [&](int bf, int ks) {
    int k0 = ks * 32;
    for (int l = tid; l < 384; l += 256) {
      GLOAD_LDS16(Bt + (size_t)(l >> 2) * K + k0 + (l & 3) * 8,
                  &Bs[bf][l * 8]);
    }
  };

  stageB(0, 0);
  __syncthreads();   // drains merge ds_writes + GLOAD vmcnt
  int buf = 0;
  for (int ks = 0; ks < 3; ++ks) {
    if (ks + 1 < 3) stageB(buf ^ 1, ks + 1);
    bf8 bfr[6], afr[2];
#pragma unroll
    for (int ni = 0; ni < 6; ++ni)
      bfr[ni] = *reinterpret_cast<const bf8*>(&Bs[buf][(ni * 16 + lr) * 32 + lg * 8]);
#pragma unroll
    for (int mi = 0; mi < 2; ++mi)
      afr[mi] = *reinterpret_cast<const bf8*>(&As[wid * 32 + mi * 16 + lr][ks * 32 + lg * 8]);
    __builtin_amdgcn_s_setprio(1);
#pragma unroll
    for (int mi = 0; mi < 2; ++mi)
#pragma unroll
      for (int ni = 0; ni < 6; ++ni)
        acc[mi][ni] = __builtin_amdgcn_mfma_f32_16x16x32_bf16(afr[mi], bfr[ni], acc[mi][ni], 0, 0, 0);
    __builtin_amdgcn_s_setprio(0);
    __syncthreads();
    buf ^= 1;
  }

  float bb[6], gv[6], bv[6];
#pragma unroll
  for (int ni = 0; ni < 6; ++ni) {
    int col = ni * 16 + lr;
    bb[ni] = bias[col];
    gv[ni] = g2[col];
    bv[ni] = b2[col];
  }
#pragma unroll
  for (int mi = 0; mi < 2; ++mi)
#pragma unroll
    for (int r = 0; r < 4; ++r) {
      int row = m0 + wid * 32 + mi * 16 + lg * 4 + r;
      size_t rb = (size_t)row * CD;
      float v[6];
#pragma unroll
      for (int ni = 0; ni < 6; ++ni)
        v[ni] = acc[mi][ni][r] + bb[ni] + res[rb + ni * 16 + lr];
      float s = ((v[0] + v[1]) + (v[2] + v[3])) + (v[4] + v[5]);
      s += __shfl_xor(s, 1); s += __shfl_xor(s, 2);
      s += __shfl_xor(s, 4); s += __shfl_xor(s, 8);
      float mu = s * (1.f / 96.f);
      float d[6];
      float qs = 0.f;
#pragma unroll
      for (int ni = 0; ni < 6; ++ni) { d[ni] = v[ni] - mu; qs += d[ni] * d[ni]; }
      qs += __shfl_xor(qs, 1); qs += __shfl_xor(qs, 2);
      qs += __shfl_xor(qs, 4); qs += __shfl_xor(qs, 8);
      float rstd = rsqrtf(qs * (1.f / 96.f) + 1e-6f);
#pragma unroll
      for (int ni = 0; ni < 6; ++ni) {
        x2[rb + ni * 16 + lr] = v[ni];
        hb3[rb + ni * 16 + lr] = f2bf(d[ni] * rstd * gv[ni] + bv[ni]);
      }
    }
}

// ---------------- fused MLP: fc1 (gelu) -> LDS -> fc2 (+bias+residual) -> out ----------------
__global__ __launch_bounds__(256) void mlp_kernel(
    const short* __restrict__ hb3, const short* __restrict__ wfc1,
    const float* __restrict__ fc1_b, const short* __restrict__ wfc2,
    const float* __restrict__ fc2_b, const float* __restrict__ resid,
    float* __restrict__ outx) {
  __shared__ __align__(16) short Ah[64][104];
  __shared__ __align__(16) short T[64][392];
  int tid = threadIdx.x, lane = tid & 63, wid = tid >> 6;
  int lr = lane & 15, lg = lane >> 4;
  int m0 = blockIdx.x * 64;

  for (int i = tid; i < 768; i += 256) {
    int row = i / 12, c8 = i % 12;
    uint4 v = *reinterpret_cast<const uint4*>(hb3 + (size_t)(m0 + row) * 96 + c8 * 8);
    *reinterpret_cast<uint4*>(&Ah[row][c8 * 8]) = v;
  }
  __syncthreads();

  // ---- fc1: M=64, N-strip=96 per wave, K=96 ----
  {
    f32x4 acc[4][6];
#pragma unroll
    for (int i = 0; i < 4; ++i)
#pragma unroll
      for (int j = 0; j < 6; ++j) acc[i][j] = (f32x4){0.f, 0.f, 0.f, 0.f};
#pragma unroll
    for (int kc = 0; kc < 3; ++kc) {
      bf8 bfr[6], afr[4];
#pragma unroll
      for (int nt = 0; nt < 6; ++nt)
        bfr[nt] = *reinterpret_cast<const bf8*>(wfc1 + (size_t)(wid * 96 + nt * 16 + lr) * 96 + kc * 32 + lg * 8);
#pragma unroll
      for (int mi = 0; mi < 4; ++mi)
        afr[mi] = *reinterpret_cast<const bf8*>(&Ah[mi * 16 + lr][kc * 32 + lg * 8]);
      __builtin_amdgcn_s_setprio(1);
#pragma unroll
      for (int mi = 0; mi < 4; ++mi)
#pragma unroll
        for (int nt = 0; nt < 6; ++nt)
          acc[mi][nt] = __builtin_amdgcn_mfma_f32_16x16x32_bf16(afr[mi], bfr[nt], acc[mi][nt], 0, 0, 0);
      __builtin_amdgcn_s_setprio(0);
    }
#pragma unroll
    for (int nt = 0; nt < 6; ++nt) {
      float b1 = fc1_b[wid * 96 + nt * 16 + lr];
      int col = wid * 96 + nt * 16 + lr;
#pragma unroll
      for (int mi = 0; mi < 4; ++mi)
#pragma unroll
        for (int r = 0; r < 4; ++r)
          T[mi * 16 + lg * 4 + r][col] = f2bf(gelu_f(acc[mi][nt][r] + b1));
    }
  }
  __syncthreads();

  // ---- fc2: rows [w*16,(w+1)*16), N=96, K=384 ----
  {
    f32x4 a2[6];
#pragma unroll
    for (int j = 0; j < 6; ++j) a2[j] = (f32x4){0.f, 0.f, 0.f, 0.f};
#pragma unroll
    for (int kc = 0; kc < 12; ++kc) {
      bf8 afr2 = *reinterpret_cast<const bf8*>(&T[wid * 16 + lr][kc * 32 + lg * 8]);
      bf8 bfr2[6];
#pragma unroll
      for (int nt = 0; nt < 6; ++nt)
        bfr2[nt] = *reinterpret_cast<const bf8*>(wfc2 + (size_t)(nt * 16 + lr) * 384 + kc * 32 + lg * 8);
      __builtin_amdgcn_s_setprio(1);
#pragma unroll
      for (int nt = 0; nt < 6; ++nt)
        a2[nt] = __builtin_amdgcn_mfma_f32_16x16x32_bf16(afr2, bfr2[nt], a2[nt], 0, 0, 0);
      __builtin_amdgcn_s_setprio(0);
    }
#pragma unroll
    for (int nt = 0; nt < 6; ++nt) {
      float b2v = fc2_b[nt * 16 + lr];
#pragma unroll
      for (int r = 0; r < 4; ++r) {
        int row = m0 + wid * 16 + lg * 4 + r;
        size_t idx = (size_t)row * CD + nt * 16 + lr;
        outx[idx] = a2[nt][r] + b2v + resid[idx];
      }
    }
  }
}

extern "C" void kernel_launch(void* const* d_in, const int* in_sizes, int n_in,
                              void* d_out, int out_size, void* d_ws, size_t ws_size,
                              hipStream_t stream) {
  const float* x      = (const float*)d_in[0];
  const int*   Hp     = (const int*)d_in[1];
  const int*   Wp     = (const int*)d_in[2];
  const float* n1s    = (const float*)d_in[3];
  const float* n1b    = (const float*)d_in[4];
  const float* qkv_w  = (const float*)d_in[5];
  const float* qkv_b  = (const float*)d_in[6];
  const float* proj_w = (const float*)d_in[7];
  const float* proj_b = (const float*)d_in[8];
  const float* ln1s   = (const float*)d_in[9];
  const float* ln1b   = (const float*)d_in[10];
  const float* qkv2_w = (const float*)d_in[11];
  const float* qkv2_b = (const float*)d_in[12];
  const float* out_w  = (const float*)d_in[13];
  const float* out_b  = (const float*)d_in[14];
  const float* ln2s   = (const float*)d_in[15];
  const float* ln2b   = (const float*)d_in[16];
  const float* fc1_w  = (const float*)d_in[17];
  const float* fc1_b  = (const float*)d_in[18];
  const float* fc2_w  = (const float*)d_in[19];
  const float* fc2_b  = (const float*)d_in[20];

  float* wsf = (float*)d_ws;
  const size_t U = (size_t)4 * LROW * CD;  // 1,204,224
  float* x1   = wsf;                           // [0,U) fp32 residual (win out)
  short* hb   = (short*)(wsf + 2 * U);         // [2U,2.5U) bf16 LN1 out (dead before flash)
  short* qb   = (short*)(wsf + 4 * U + U / 2); // [4.5U,5U)
  short* kb   = qb + U;                        // [5U,5.5U)
  short* vtb  = kb + U;                        // [5.5U,6U)
  short* wall = (short*)(wsf + 6 * U);         // contiguous bf16 weights, 165888 shorts
  short* wqkv = wall;                          // 320*96
  short* wout = wqkv + 320 * 96;               // 128*96
  short* wfc1 = wout + 128 * 96;               // 384*96
  short* wfc2 = wfc1 + 384 * 96;               // 128*384
  short* wwin = wfc2 + 128 * 384;              // 288*96
  short* wproj = wwin + 288 * 96;              // 96*96
  short* hb2  = (short*)(wsf + 6 * U + 82944); // bf16 LN-tb1 out (U shorts)
  // flash partials overlay [U,4U): pOb bf16 6 splits (3U floats); pl at [4U,4.2U)
  short* pOb  = (short*)(wsf + U);             // 6 * 12*LROW*32 shorts = 3U floats
  float* pl   = wsf + 4 * U;                   // 6 * 12*LROW floats
  // post-flash outputs live OUTSIDE the pOb overlay (qb/kb/vtb dead after flash):
  float* x2f  = (float*)qb;                    // U floats over [4.5U,5.5U)
  short* hb3  = vtb;                           // U shorts, LN2 out bf16
  float* outx = (float*)d_out;

  const int M = 4 * LROW;  // 12544

  cvt_all_kernel<<<(165888 + 255) / 256, 256, 0, stream>>>(
      qkv2_w, out_w, fc1_w, fc2_w, qkv_w, proj_w, wall, Hp, Wp, outx + U);

  ln_kernel<<<M / 8, 256, 0, stream>>>(x, n1s, n1b, hb, M);
  win_attn_kernel<<<256, 512, 0, stream>>>(hb, x, wwin, qkv_b, wproj, proj_b,
                                           ln1s, ln1b, x1, hb2);
  qkv_mfma_kernel<<<dim3(M / 128, 5), 256, 0, stream>>>(hb2, wqkv, qkv2_b, qb, kb, vtb);
  flash_mfma_kernel<<<dim3(49, 12, 6), 128, 0, stream>>>(qb, kb, vtb, pOb, pl);
  gemm_out_merge_ln_kernel<<<M / 128, 256, 0, stream>>>(pOb, pl, wout, out_b, x1,
                                                        ln2s, ln2b, x2f, hb3);
  mlp_kernel<<<M / 64, 256, 0, stream>>>(hb3, wfc1, fc1_b, wfc2, fc2_b, x2f, outx);
}

// Round 14
// 114.253 us; speedup vs baseline: 5.8548x; 1.0050x over previous
//
#include <hip/hip_runtime.h>
#include <hip/hip_bf16.h>

#define CD 96
#define LROW 3136          // 56*56
#define QSCALE 0.17677669529663687f  // 1/sqrt(32)
#define LOG2E 1.4426950408889634f
#define MASKLOG2 -144.26950408889634f // -100 * log2(e)

using f32x4 = __attribute__((ext_vector_type(4))) float;
using bf8   = __attribute__((ext_vector_type(8))) short;

__device__ __forceinline__ short f2bf(float f) {
  union { float f; unsigned u; } v; v.f = f;
  unsigned r = v.u + 0x7fffu + ((v.u >> 16) & 1u);
  return (short)(r >> 16);
}
__device__ __forceinline__ float bf2f(unsigned short s) {
  return __uint_as_float((unsigned)s << 16);
}
__device__ __forceinline__ unsigned pack_bf2(float lo, float hi) {
  return (__float_as_uint(hi) & 0xffff0000u) | (__float_as_uint(lo) >> 16);
}
__device__ __forceinline__ unsigned pack_bf2r(float lo, float hi) {
  return ((unsigned)(unsigned short)f2bf(hi) << 16) | (unsigned short)f2bf(lo);
}
__device__ __forceinline__ float fast_exp2(float x) {
  return __builtin_amdgcn_exp2f(x);
}
// gelu tanh-approx via exp2: 0.5v(1+tanh(u)) = v*e/(e+1), e = exp(2u)
__device__ __forceinline__ float gelu_f(float v) {
  float u = 0.7978845608028654f * (v + 0.044715f * v * v * v);
  float e = fast_exp2(u * 2.8853900817779268f);  // 2*log2(e)
  return v * e * __builtin_amdgcn_rcpf(e + 1.f);
}

#define GLOAD_LDS16(src, dst) \
  __builtin_amdgcn_global_load_lds((const __attribute__((address_space(1))) void*)(src), \
                                   (__attribute__((address_space(3))) void*)(dst), 16, 0, 0)

// ---------------- LayerNorm (LN1 only): 32-lane groups, 3 cols/lane -> bf16 ----------------
__global__ __launch_bounds__(256) void ln_kernel(const float* __restrict__ x,
                                                 const float* __restrict__ g,
                                                 const float* __restrict__ b,
                                                 short* __restrict__ out, int rows) {
  int slot = threadIdx.x >> 5, l32 = threadIdx.x & 31;
  int row = blockIdx.x * 8 + slot;
  if (row >= rows) return;
  const float* xr = x + (size_t)row * CD + l32 * 3;
  float a0 = xr[0], a1 = xr[1], a2 = xr[2];
  float s = a0 + a1 + a2;
#pragma unroll
  for (int off = 16; off >= 1; off >>= 1) s += __shfl_xor(s, off, 32);
  float mu = s * (1.f / 96.f);
  float d0 = a0 - mu, d1 = a1 - mu, d2 = a2 - mu;
  float q = d0 * d0 + d1 * d1 + d2 * d2;
#pragma unroll
  for (int off = 16; off >= 1; off >>= 1) q += __shfl_xor(q, off, 32);
  float rstd = rsqrtf(q * (1.f / 96.f) + 1e-6f);
  int c0 = l32 * 3;
  short* orow = out + (size_t)row * CD + c0;
  orow[0] = f2bf(d0 * rstd * g[c0] + b[c0]);
  orow[1] = f2bf(d1 * rstd * g[c0 + 1] + b[c0 + 1]);
  orow[2] = f2bf(d2 * rstd * g[c0 + 2] + b[c0 + 2]);
}

// ---------------- fused weight convert (+ tail scalars) ----------------
__global__ __launch_bounds__(256) void cvt_all_kernel(
    const float* __restrict__ qkv2_w, const float* __restrict__ out_w,
    const float* __restrict__ fc1_w, const float* __restrict__ fc2_w,
    const float* __restrict__ qkv_w, const float* __restrict__ proj_w,
    short* __restrict__ dst,
    const int* __restrict__ Hp, const int* __restrict__ Wp,
    float* __restrict__ tail_out) {
  int idx = blockIdx.x * 256 + threadIdx.x;
  if (idx == 0) {
    tail_out[0] = (float)Hp[0];
    tail_out[1] = (float)Wp[0];
  }
  if (idx >= 165888) return;
  const float* W; int K, N, off;
  if (idx < 30720)       { W = qkv2_w; K = 96;  N = 288; off = idx; }
  else if (idx < 43008)  { W = out_w;  K = 96;  N = 96;  off = idx - 30720; }
  else if (idx < 79872)  { W = fc1_w;  K = 96;  N = 384; off = idx - 43008; }
  else if (idx < 129024) { W = fc2_w;  K = 384; N = 96;  off = idx - 79872; }
  else if (idx < 156672) { W = qkv_w;  K = 96;  N = 288; off = idx - 129024; }
  else                   { W = proj_w; K = 96;  N = 96;  off = idx - 156672; }
  int nr = off / K, kk = off - nr * K;
  float v = (nr < N) ? W[(size_t)kk * N + nr] : 0.f;
  dst[idx] = f2bf(v);
}

// ---------------- MFMA shifted-window attention + fused LN-tb1 epilogue ----------------
__global__ __launch_bounds__(512) void win_attn_kernel(
    const short* __restrict__ hb_in, const float* __restrict__ xin,
    const short* __restrict__ wwin, const float* __restrict__ qkv_b,
    const short* __restrict__ wproj, const float* __restrict__ proj_b,
    const float* __restrict__ ln1s, const float* __restrict__ ln1b,
    float* __restrict__ x1, short* __restrict__ hb2) {
  __shared__ __align__(16) short Xs[64][104];
  __shared__ __align__(16) short Qs[3][64][40];
  __shared__ __align__(16) short Ks[3][64][40];
  __shared__ __align__(16) short Vt[3][32][72];
  __shared__ __align__(16) short Os[64][104];
  __shared__ __align__(16) short Ptw[8][16][72];
  __shared__ int cnt[64];
  __shared__ int gidx[49];

  int tid = threadIdx.x, lane = tid & 63, wid = tid >> 6;
  int lr = lane & 15, lg = lane >> 4;
  int b = blockIdx.x >> 6, w64 = blockIdx.x & 63;
  int wr = w64 >> 3, wc = w64 & 7;

  if (tid < 64) {
    if (tid < 49) {
      int i = tid / 7, j = tid % 7;
      int sh = wr * 7 + i, sw = wc * 7 + j;
      int hr = (sh < 49) ? 0 : ((sh < 53) ? 1 : 2);
      int wreg = (sw < 49) ? 0 : ((sw < 53) ? 1 : 2);
      cnt[tid] = hr * 3 + wreg;
      gidx[tid] = ((sh + 3) % 56) * 56 + ((sw + 3) % 56);
    } else {
      cnt[tid] = -1;
    }
  }
  __syncthreads();

  for (int c = tid; c < 768; c += 512) {
    int row = c / 12, cc = c % 12;
    uint4 v = {0u, 0u, 0u, 0u};
    if (row < 49) v = *reinterpret_cast<const uint4*>(hb_in + ((size_t)b * LROW + gidx[row]) * 96 + cc * 8);
    *reinterpret_cast<uint4*>(&Xs[row][cc * 8]) = v;
  }
  __syncthreads();

  // ---- qkv GEMM: M=64, N=288 (18 n-tiles over 8 waves), K=96 ----
  for (int nt = wid; nt < 18; nt += 8) {
    f32x4 acc[4];
#pragma unroll
    for (int mi = 0; mi < 4; ++mi) acc[mi] = (f32x4){0.f, 0.f, 0.f, 0.f};
#pragma unroll
    for (int kc = 0; kc < 3; ++kc) {
      bf8 bfr = *reinterpret_cast<const bf8*>(wwin + (size_t)(nt * 16 + lr) * 96 + kc * 32 + lg * 8);
#pragma unroll
      for (int mi = 0; mi < 4; ++mi) {
        bf8 afr = *reinterpret_cast<const bf8*>(&Xs[mi * 16 + lr][kc * 32 + lg * 8]);
        acc[mi] = __builtin_amdgcn_mfma_f32_16x16x32_bf16(afr, bfr, acc[mi], 0, 0, 0);
      }
    }
    int n = nt * 16 + lr;
    int sec = n / 96, within = n % 96;
    int hh = within >> 5, dd = within & 31;
    float bias = qkv_b[n];
#pragma unroll
    for (int mi = 0; mi < 4; ++mi)
#pragma unroll
      for (int r = 0; r < 4; ++r) {
        int mrow = mi * 16 + lg * 4 + r;
        float v = acc[mi][r] + bias;
        if (sec == 0)      Qs[hh][mrow][dd] = f2bf(v * (QSCALE * LOG2E));
        else if (sec == 1) Ks[hh][mrow][dd] = f2bf(v);
        else               Vt[hh][dd][mrow] = f2bf(v);
      }
  }
  __syncthreads();

  // ---- attention: 12 (head, q-tile) pairs over 8 waves; no-max softmax, tree sum ----
  int cntkv[16];
#pragma unroll
  for (int t = 0; t < 4; ++t)
#pragma unroll
    for (int r = 0; r < 4; ++r) cntkv[t * 4 + r] = cnt[t * 16 + lg * 4 + r];

  for (int p = wid; p < 12; p += 8) {
    int h = p >> 2, qt = p & 3;
    bf8 qf = *reinterpret_cast<const bf8*>(&Qs[h][qt * 16 + lr][lg * 8]);
    int cq = cnt[qt * 16 + lr];
    f32x4 z = {0.f, 0.f, 0.f, 0.f};
    f32x4 St[4];
    __builtin_amdgcn_s_setprio(1);
#pragma unroll
    for (int t = 0; t < 4; ++t) {
      bf8 kf = *reinterpret_cast<const bf8*>(&Ks[h][t * 16 + lr][lg * 8]);
      St[t] = __builtin_amdgcn_mfma_f32_16x16x32_bf16(kf, qf, z, 0, 0, 0);
    }
    __builtin_amdgcn_s_setprio(0);
    float pr[4];
#pragma unroll
    for (int t = 0; t < 4; ++t) {
      float p0 = fast_exp2(St[t][0] + ((cq == cntkv[t * 4 + 0]) ? 0.f : MASKLOG2));
      float p1 = fast_exp2(St[t][1] + ((cq == cntkv[t * 4 + 1]) ? 0.f : MASKLOG2));
      float p2 = fast_exp2(St[t][2] + ((cq == cntkv[t * 4 + 2]) ? 0.f : MASKLOG2));
      float p3 = fast_exp2(St[t][3] + ((cq == cntkv[t * 4 + 3]) ? 0.f : MASKLOG2));
      St[t][0] = p0; St[t][1] = p1; St[t][2] = p2; St[t][3] = p3;
      pr[t] = (p0 + p1) + (p2 + p3);
    }
    float rs = (pr[0] + pr[1]) + (pr[2] + pr[3]);
    rs += __shfl_xor(rs, 16);
    rs += __shfl_xor(rs, 32);
    float inv = 1.f / rs;
#pragma unroll
    for (int t = 0; t < 4; ++t) {
      uint2 w;
      w.x = pack_bf2(St[t][0], St[t][1]);
      w.y = pack_bf2(St[t][2], St[t][3]);
      *reinterpret_cast<uint2*>(&Ptw[wid][lr][t * 16 + lg * 4]) = w;
    }
    f32x4 O0 = {0.f, 0.f, 0.f, 0.f}, O1 = {0.f, 0.f, 0.f, 0.f};
    __builtin_amdgcn_s_setprio(1);
#pragma unroll
    for (int c = 0; c < 2; ++c) {
      bf8 pbf = *reinterpret_cast<const bf8*>(&Ptw[wid][lr][c * 32 + lg * 8]);
      bf8 v0 = *reinterpret_cast<const bf8*>(&Vt[h][lr][c * 32 + lg * 8]);
      bf8 v1 = *reinterpret_cast<const bf8*>(&Vt[h][16 + lr][c * 32 + lg * 8]);
      O0 = __builtin_amdgcn_mfma_f32_16x16x32_bf16(v0, pbf, O0, 0, 0, 0);
      O1 = __builtin_amdgcn_mfma_f32_16x16x32_bf16(v1, pbf, O1, 0, 0, 0);
    }
    __builtin_amdgcn_s_setprio(0);
#pragma unroll
    for (int r = 0; r < 4; ++r) {
      Os[qt * 16 + lr][h * 32 + lg * 4 + r] = f2bf(O0[r] * inv);
      Os[qt * 16 + lr][h * 32 + 16 + lg * 4 + r] = f2bf(O1[r] * inv);
    }
  }
  __syncthreads();

  // ---- proj GEMM (waves 0..3, full N per wave) + fused residual + LN-tb1 ----
  if (wid < 4) {
    int mt = wid;
    f32x4 acc[6];
#pragma unroll
    for (int nt = 0; nt < 6; ++nt) acc[nt] = (f32x4){0.f, 0.f, 0.f, 0.f};
#pragma unroll
    for (int kc = 0; kc < 3; ++kc) {
      bf8 afr = *reinterpret_cast<const bf8*>(&Os[mt * 16 + lr][kc * 32 + lg * 8]);
#pragma unroll
      for (int nt = 0; nt < 6; ++nt) {
        bf8 bfr = *reinterpret_cast<const bf8*>(wproj + (size_t)(nt * 16 + lr) * 96 + kc * 32 + lg * 8);
        acc[nt] = __builtin_amdgcn_mfma_f32_16x16x32_bf16(afr, bfr, acc[nt], 0, 0, 0);
      }
    }
    float pbv[6], gv[6], bv[6];
#pragma unroll
    for (int nt = 0; nt < 6; ++nt) {
      int col = nt * 16 + lr;
      pbv[nt] = proj_b[col];
      gv[nt] = ln1s[col];
      bv[nt] = ln1b[col];
    }
#pragma unroll
    for (int r = 0; r < 4; ++r) {
      int q = mt * 16 + lg * 4 + r;
      if (q >= 49) continue;           // uniform across the 16 lr lanes
      size_t rb = ((size_t)b * LROW + gidx[q]) * CD;
      float v[6];
#pragma unroll
      for (int nt = 0; nt < 6; ++nt)
        v[nt] = acc[nt][r] + pbv[nt] + xin[rb + nt * 16 + lr];
      float s = ((v[0] + v[1]) + (v[2] + v[3])) + (v[4] + v[5]);
      s += __shfl_xor(s, 1); s += __shfl_xor(s, 2);
      s += __shfl_xor(s, 4); s += __shfl_xor(s, 8);
      float mu = s * (1.f / 96.f);
      float d[6];
      float qs = 0.f;
#pragma unroll
      for (int nt = 0; nt < 6; ++nt) { d[nt] = v[nt] - mu; qs += d[nt] * d[nt]; }
      qs += __shfl_xor(qs, 1); qs += __shfl_xor(qs, 2);
      qs += __shfl_xor(qs, 4); qs += __shfl_xor(qs, 8);
      float rstd = rsqrtf(qs * (1.f / 96.f) + 1e-6f);
#pragma unroll
      for (int nt = 0; nt < 6; ++nt) {
        x1[rb + nt * 16 + lr] = v[nt];
        hb2[rb + nt * 16 + lr] = f2bf(d[nt] * rstd * gv[nt] + bv[nt]);
      }
    }
  }
}

// ---------------- qkv GEMM (bf16 MFMA); V stored tile-blocked [bh][49][32][64] ----------------
__global__ __launch_bounds__(256) void qkv_mfma_kernel(
    const short* __restrict__ A, const short* __restrict__ Bt,
    const float* __restrict__ bias,
    short* __restrict__ qb, short* __restrict__ kb, short* __restrict__ vtb) {
  __shared__ __align__(16) short As[2][128 * 32];
  __shared__ __align__(16) short Bs[2][64 * 32];
  int tid = threadIdx.x, lane = tid & 63, wid = tid >> 6;
  int lr = lane & 15, lg = lane >> 4;
  int m0 = blockIdx.x * 128, n0 = blockIdx.y * 64;
  const int K = 96;

  f32x4 acc[2][4];
#pragma unroll
  for (int i = 0; i < 2; ++i)
#pragma unroll
    for (int j = 0; j < 4; ++j) acc[i][j] = (f32x4){0.f, 0.f, 0.f, 0.f};

  auto stage = [&](int bf, int ks) {
    int k0 = ks * 32;
#pragma unroll
    for (int p = 0; p < 2; ++p) {
      int idx = tid + p * 256;
      GLOAD_LDS16(A + (size_t)(m0 + (idx >> 2)) * K + k0 + (idx & 3) * 8,
                  &As[bf][idx * 8]);
    }
    GLOAD_LDS16(Bt + (size_t)(n0 + (tid >> 2)) * K + k0 + (tid & 3) * 8,
                &Bs[bf][tid * 8]);
  };

  stage(0, 0);
  __syncthreads();
  int buf = 0;
  for (int ks = 0; ks < 3; ++ks) {
    if (ks + 1 < 3) stage(buf ^ 1, ks + 1);
    bf8 bfr[4], afr[2];
#pragma unroll
    for (int ni = 0; ni < 4; ++ni)
      bfr[ni] = *reinterpret_cast<const bf8*>(&Bs[buf][(ni * 16 + lr) * 32 + lg * 8]);
#pragma unroll
    for (int mi = 0; mi < 2; ++mi)
      afr[mi] = *reinterpret_cast<const bf8*>(&As[buf][(wid * 32 + mi * 16 + lr) * 32 + lg * 8]);
    __builtin_amdgcn_s_setprio(1);
#pragma unroll
    for (int mi = 0; mi < 2; ++mi)
#pragma unroll
      for (int ni = 0; ni < 4; ++ni)
        acc[mi][ni] = __builtin_amdgcn_mfma_f32_16x16x32_bf16(afr[mi], bfr[ni], acc[mi][ni], 0, 0, 0);
    __builtin_amdgcn_s_setprio(0);
    __syncthreads();
    buf ^= 1;
  }

#pragma unroll
  for (int mi = 0; mi < 2; ++mi)
#pragma unroll
    for (int ni = 0; ni < 4; ++ni)
#pragma unroll
      for (int r = 0; r < 4; ++r) {
        int mrow = m0 + wid * 32 + mi * 16 + lg * 4 + r;
        int n = n0 + ni * 16 + lr;
        if (n < 288) {
          float v = acc[mi][ni][r] + bias[n];
          int sec = n / 96, within = n % 96;
          int hh = within >> 5, dd = within & 31;
          int bb = mrow / LROW, nn = mrow - bb * LROW;
          size_t bh = (size_t)bb * 3 + hh;
          if (sec == 0)      qb[(bh * LROW + nn) * 32 + dd] = f2bf(v * (QSCALE * LOG2E));
          else if (sec == 1) kb[(bh * LROW + nn) * 32 + dd] = f2bf(v);
          else               vtb[((bh * 49 + (nn >> 6)) * 32 + dd) * 64 + (nn & 63)] = f2bf(v);
        }
      }
}

// ---------------- flash attention v9: tile-blocked V (contiguous 4KB/tile), l via ones-MFMA ----------------
// grid (49, 12, 6). vtb layout [bh][kt][32][64]: V fragment loads hit adjacent, fully-consumed lines.
__global__ __launch_bounds__(128) void flash_mfma_kernel(
    const short* __restrict__ qb, const short* __restrict__ kb,
    const short* __restrict__ vtb,
    short* __restrict__ pOb, float* __restrict__ pl) {
  __shared__ __align__(16) short Pt[2][2][16][72];  // [wave][g][q][kv]; 144B rows (no aliasing)
  int tid = threadIdx.x, lane = tid & 63, wid = tid >> 6;
  int lr = lane & 15, lg = lane >> 4;
  int bh = blockIdx.y, s = blockIdx.z;
  int q0 = blockIdx.x * 64 + wid * 32;
  const short* qbb = qb + (size_t)bh * LROW * 32;
  const short* kbase = kb + (size_t)bh * LROW * 32 + lr * 32 + lg * 8;
  const short* vbase = vtb + (size_t)bh * 49 * 2048 + lr * 64 + lg * 8;  // tile t at +t*2048

  bf8 qf0 = *reinterpret_cast<const bf8*>(qbb + (size_t)(q0 + lr) * 32 + lg * 8);
  bf8 qf1 = *reinterpret_cast<const bf8*>(qbb + (size_t)(q0 + 16 + lr) * 32 + lg * 8);

  const bf8 onesf = {16256, 16256, 16256, 16256, 16256, 16256, 16256, 16256};  // bf16 1.0

  f32x4 O00 = {0.f,0.f,0.f,0.f}, O01 = {0.f,0.f,0.f,0.f};
  f32x4 O10 = {0.f,0.f,0.f,0.f}, O11 = {0.f,0.f,0.f,0.f};
  f32x4 La0 = {0.f,0.f,0.f,0.f}, La1 = {0.f,0.f,0.f,0.f};  // l accumulators (all rows equal)

  const int tbl[7] = {0, 9, 17, 25, 33, 41, 49};
  int t0 = tbl[s], t1 = tbl[s + 1];

  bf8 kA[4], vA[4], kB[4], vB[4];

  auto loadt = [&](bf8 (&Kf)[4], bf8 (&Vf)[4], int kt) {
    const short* kp = kbase + (size_t)kt * 2048;
#pragma unroll
    for (int t = 0; t < 4; ++t) Kf[t] = *reinterpret_cast<const bf8*>(kp + t * 512);
    const short* vp = vbase + (size_t)kt * 2048;   // rows d=lr; +1024 => d=16+lr
#pragma unroll
    for (int c = 0; c < 2; ++c) {
      Vf[c]     = *reinterpret_cast<const bf8*>(vp + c * 32);
      Vf[2 + c] = *reinterpret_cast<const bf8*>(vp + 1024 + c * 32);
    }
  };

  auto body = [&](bf8 (&Kf)[4], bf8 (&Vf)[4]) {
    f32x4 z = {0.f, 0.f, 0.f, 0.f};
#pragma unroll
    for (int g = 0; g < 2; ++g) {
      bf8 qf = g ? qf1 : qf0;
      f32x4 St[4];
      __builtin_amdgcn_s_setprio(1);
#pragma unroll
      for (int t = 0; t < 4; ++t)
        St[t] = __builtin_amdgcn_mfma_f32_16x16x32_bf16(Kf[t], qf, z, 0, 0, 0);
      __builtin_amdgcn_s_setprio(0);
#pragma unroll
      for (int t = 0; t < 4; ++t) {
        float p0 = fast_exp2(St[t][0]);
        float p1 = fast_exp2(St[t][1]);
        float p2 = fast_exp2(St[t][2]);
        float p3 = fast_exp2(St[t][3]);
        uint2 w;
        w.x = pack_bf2(p0, p1);
        w.y = pack_bf2(p2, p3);
        *reinterpret_cast<uint2*>(&Pt[wid][g][lr][t * 16 + lg * 4]) = w;
      }
    }
    __builtin_amdgcn_s_setprio(1);
#pragma unroll
    for (int g = 0; g < 2; ++g) {
      f32x4& Oh0 = g ? O10 : O00;
      f32x4& Oh1 = g ? O11 : O01;
      f32x4& La  = g ? La1 : La0;
#pragma unroll
      for (int c = 0; c < 2; ++c) {
        bf8 pbf = *reinterpret_cast<const bf8*>(&Pt[wid][g][lr][c * 32 + lg * 8]);
        Oh0 = __builtin_amdgcn_mfma_f32_16x16x32_bf16(Vf[c], pbf, Oh0, 0, 0, 0);
        Oh1 = __builtin_amdgcn_mfma_f32_16x16x32_bf16(Vf[2 + c], pbf, Oh1, 0, 0, 0);
        La  = __builtin_amdgcn_mfma_f32_16x16x32_bf16(onesf, pbf, La, 0, 0, 0);
      }
    }
    __builtin_amdgcn_s_setprio(0);
  };

  loadt(kA, vA, t0);
  int kt = t0;
  for (; kt + 2 <= t1 - 1; kt += 2) {
    loadt(kB, vB, kt + 1);
    body(kA, vA);
    loadt(kA, vA, kt + 2);
    body(kB, vB);
  }
  if (kt < t1 - 1) {
    loadt(kB, vB, kt + 1);
    body(kA, vA);
    body(kB, vB);
  } else {
    body(kA, vA);
  }

  // bf16 unnormalized partials; lane (lr,lg) holds d = lg*4+r (+16) for q = q0(+16)+lr
  size_t rbase = (size_t)(s * 12 + bh) * LROW;
  size_t r0 = (rbase + q0 + lr) * 32;
  size_t r1 = (rbase + q0 + 16 + lr) * 32;
  uint2 w;
  w.x = pack_bf2r(O00[0], O00[1]); w.y = pack_bf2r(O00[2], O00[3]);
  *reinterpret_cast<uint2*>(&pOb[r0 + lg * 4]) = w;
  w.x = pack_bf2r(O01[0], O01[1]); w.y = pack_bf2r(O01[2], O01[3]);
  *reinterpret_cast<uint2*>(&pOb[r0 + 16 + lg * 4]) = w;
  w.x = pack_bf2r(O10[0], O10[1]); w.y = pack_bf2r(O10[2], O10[3]);
  *reinterpret_cast<uint2*>(&pOb[r1 + lg * 4]) = w;
  w.x = pack_bf2r(O11[0], O11[1]); w.y = pack_bf2r(O11[2], O11[3]);
  *reinterpret_cast<uint2*>(&pOb[r1 + 16 + lg * 4]) = w;
  if (lg == 0) {
    pl[rbase + q0 + lr] = La0[0];
    pl[rbase + q0 + 16 + lr] = La1[0];
  }
}

// ---------------- out-proj GEMM with fused 6-split merge (A-stage) + residual + LN2 ----------------
__global__ __launch_bounds__(256) void gemm_out_merge_ln_kernel(
    const short* __restrict__ pOb, const float* __restrict__ pl,
    const short* __restrict__ Bt,
    const float* __restrict__ bias, const float* __restrict__ res,
    const float* __restrict__ g2, const float* __restrict__ b2,
    float* __restrict__ x2, short* __restrict__ hb3) {
  __shared__ __align__(16) short As[128][104];   // merged bf16 A, padded rows
  __shared__ __align__(16) short Bs[2][96 * 32];
  int tid = threadIdx.x, lane = tid & 63, wid = tid >> 6;
  int lr = lane & 15, lg = lane >> 4;
  int m0 = blockIdx.x * 128;
  const int K = 96;
  const int NR = 12 * LROW;

  // ---- merge-stage A: thread handles (row, head) pairs ----
  for (int pi = tid; pi < 384; pi += 256) {
    int rloc = pi / 3, h = pi % 3;
    int grow = m0 + rloc;
    int bb = grow / LROW, q = grow - bb * LROW;
    size_t pbase = ((size_t)(bb * 3 + h)) * LROW + q;
    float l = 0.f;
#pragma unroll
    for (int s = 0; s < 6; ++s) l += pl[(size_t)s * NR + pbase];
    float invl = 1.f / l;
    float o[32];
#pragma unroll
    for (int d = 0; d < 32; ++d) o[d] = 0.f;
#pragma unroll
    for (int s = 0; s < 6; ++s) {
      const uint4* p4 = reinterpret_cast<const uint4*>(pOb + ((size_t)s * NR + pbase) * 32);
#pragma unroll
      for (int u = 0; u < 4; ++u) {
        uint4 v = p4[u];
        unsigned wd0 = v.x, wd1 = v.y, wd2 = v.z, wd3 = v.w;
        o[u*8+0] += __uint_as_float(wd0 << 16);
        o[u*8+1] += __uint_as_float(wd0 & 0xffff0000u);
        o[u*8+2] += __uint_as_float(wd1 << 16);
        o[u*8+3] += __uint_as_float(wd1 & 0xffff0000u);
        o[u*8+4] += __uint_as_float(wd2 << 16);
        o[u*8+5] += __uint_as_float(wd2 & 0xffff0000u);
        o[u*8+6] += __uint_as_float(wd3 << 16);
        o[u*8+7] += __uint_as_float(wd3 & 0xffff0000u);
      }
    }
    short* dst = &As[rloc][h * 32];
#pragma unroll
    for (int u2 = 0; u2 < 4; ++u2) {
      uint4 w;
      w.x = pack_bf2r(o[u2*8+0]*invl, o[u2*8+1]*invl);
      w.y = pack_bf2r(o[u2*8+2]*invl, o[u2*8+3]*invl);
      w.z = pack_bf2r(o[u2*8+4]*invl, o[u2*8+5]*invl);
      w.w = pack_bf2r(o[u2*8+6]*invl, o[u2*8+7]*invl);
      *reinterpret_cast<uint4*>(dst + u2 * 8) = w;
    }
  }

  f32x4 acc[2][6];
#pragma unroll
  for (int i = 0; i < 2; ++i)
#pragma unroll
    for (int j = 0; j < 6; ++j) acc[i][j] = (f32x4){0.f, 0.f, 0.f, 0.f};

  auto stageB = [&](int bf, int ks) {
    int k0 = ks * 32;
    for (int l = tid; l < 384; l += 256) {
      GLOAD_LDS16(Bt + (size_t)(l >> 2) * K + k0 + (l & 3) * 8,
                  &Bs[bf][l * 8]);
    }
  };

  stageB(0, 0);
  __syncthreads();   // drains merge ds_writes + GLOAD vmcnt
  int buf = 0;
  for (int ks = 0; ks < 3; ++ks) {
    if (ks + 1 < 3) stageB(buf ^ 1, ks + 1);
    bf8 bfr[6], afr[2];
#pragma unroll
    for (int ni = 0; ni < 6; ++ni)
      bfr[ni] = *reinterpret_cast<const bf8*>(&Bs[buf][(ni * 16 + lr) * 32 + lg * 8]);
#pragma unroll
    for (int mi = 0; mi < 2; ++mi)
      afr[mi] = *reinterpret_cast<const bf8*>(&As[wid * 32 + mi * 16 + lr][ks * 32 + lg * 8]);
    __builtin_amdgcn_s_setprio(1);
#pragma unroll
    for (int mi = 0; mi < 2; ++mi)
#pragma unroll
      for (int ni = 0; ni < 6; ++ni)
        acc[mi][ni] = __builtin_amdgcn_mfma_f32_16x16x32_bf16(afr[mi], bfr[ni], acc[mi][ni], 0, 0, 0);
    __builtin_amdgcn_s_setprio(0);
    __syncthreads();
    buf ^= 1;
  }

  float bb[6], gv[6], bv[6];
#pragma unroll
  for (int ni = 0; ni < 6; ++ni) {
    int col = ni * 16 + lr;
    bb[ni] = bias[col];
    gv[ni] = g2[col];
    bv[ni] = b2[col];
  }
#pragma unroll
  for (int mi = 0; mi < 2; ++mi)
#pragma unroll
    for (int r = 0; r < 4; ++r) {
      int row = m0 + wid * 32 + mi * 16 + lg * 4 + r;
      size_t rb = (size_t)row * CD;
      float v[6];
#pragma unroll
      for (int ni = 0; ni < 6; ++ni)
        v[ni] = acc[mi][ni][r] + bb[ni] + res[rb + ni * 16 + lr];
      float s = ((v[0] + v[1]) + (v[2] + v[3])) + (v[4] + v[5]);
      s += __shfl_xor(s, 1); s += __shfl_xor(s, 2);
      s += __shfl_xor(s, 4); s += __shfl_xor(s, 8);
      float mu = s * (1.f / 96.f);
      float d[6];
      float qs = 0.f;
#pragma unroll
      for (int ni = 0; ni < 6; ++ni) { d[ni] = v[ni] - mu; qs += d[ni] * d[ni]; }
      qs += __shfl_xor(qs, 1); qs += __shfl_xor(qs, 2);
      qs += __shfl_xor(qs, 4); qs += __shfl_xor(qs, 8);
      float rstd = rsqrtf(qs * (1.f / 96.f) + 1e-6f);
#pragma unroll
      for (int ni = 0; ni < 6; ++ni) {
        x2[rb + ni * 16 + lr] = v[ni];
        hb3[rb + ni * 16 + lr] = f2bf(d[ni] * rstd * gv[ni] + bv[ni]);
      }
    }
}

// ---------------- fused MLP: fc1 (gelu) -> LDS -> fc2 (+bias+residual) -> out ----------------
__global__ __launch_bounds__(256) void mlp_kernel(
    const short* __restrict__ hb3, const short* __restrict__ wfc1,
    const float* __restrict__ fc1_b, const short* __restrict__ wfc2,
    const float* __restrict__ fc2_b, const float* __restrict__ resid,
    float* __restrict__ outx) {
  __shared__ __align__(16) short Ah[64][104];
  __shared__ __align__(16) short T[64][392];
  int tid = threadIdx.x, lane = tid & 63, wid = tid >> 6;
  int lr = lane & 15, lg = lane >> 4;
  int m0 = blockIdx.x * 64;

  for (int i = tid; i < 768; i += 256) {
    int row = i / 12, c8 = i % 12;
    uint4 v = *reinterpret_cast<const uint4*>(hb3 + (size_t)(m0 + row) * 96 + c8 * 8);
    *reinterpret_cast<uint4*>(&Ah[row][c8 * 8]) = v;
  }
  __syncthreads();

  // ---- fc1: M=64, N-strip=96 per wave, K=96 ----
  {
    f32x4 acc[4][6];
#pragma unroll
    for (int i = 0; i < 4; ++i)
#pragma unroll
      for (int j = 0; j < 6; ++j) acc[i][j] = (f32x4){0.f, 0.f, 0.f, 0.f};
#pragma unroll
    for (int kc = 0; kc < 3; ++kc) {
      bf8 bfr[6], afr[4];
#pragma unroll
      for (int nt = 0; nt < 6; ++nt)
        bfr[nt] = *reinterpret_cast<const bf8*>(wfc1 + (size_t)(wid * 96 + nt * 16 + lr) * 96 + kc * 32 + lg * 8);
#pragma unroll
      for (int mi = 0; mi < 4; ++mi)
        afr[mi] = *reinterpret_cast<const bf8*>(&Ah[mi * 16 + lr][kc * 32 + lg * 8]);
      __builtin_amdgcn_s_setprio(1);
#pragma unroll
      for (int mi = 0; mi < 4; ++mi)
#pragma unroll
        for (int nt = 0; nt < 6; ++nt)
          acc[mi][nt] = __builtin_amdgcn_mfma_f32_16x16x32_bf16(afr[mi], bfr[nt], acc[mi][nt], 0, 0, 0);
      __builtin_amdgcn_s_setprio(0);
    }
#pragma unroll
    for (int nt = 0; nt < 6; ++nt) {
      float b1 = fc1_b[wid * 96 + nt * 16 + lr];
      int col = wid * 96 + nt * 16 + lr;
#pragma unroll
      for (int mi = 0; mi < 4; ++mi)
#pragma unroll
        for (int r = 0; r < 4; ++r)
          T[mi * 16 + lg * 4 + r][col] = f2bf(gelu_f(acc[mi][nt][r] + b1));
    }
  }
  __syncthreads();

  // ---- fc2: rows [w*16,(w+1)*16), N=96, K=384 ----
  {
    f32x4 a2[6];
#pragma unroll
    for (int j = 0; j < 6; ++j) a2[j] = (f32x4){0.f, 0.f, 0.f, 0.f};
#pragma unroll
    for (int kc = 0; kc < 12; ++kc) {
      bf8 afr2 = *reinterpret_cast<const bf8*>(&T[wid * 16 + lr][kc * 32 + lg * 8]);
      bf8 bfr2[6];
#pragma unroll
      for (int nt = 0; nt < 6; ++nt)
        bfr2[nt] = *reinterpret_cast<const bf8*>(wfc2 + (size_t)(nt * 16 + lr) * 384 + kc * 32 + lg * 8);
      __builtin_amdgcn_s_setprio(1);
#pragma unroll
      for (int nt = 0; nt < 6; ++nt)
        a2[nt] = __builtin_amdgcn_mfma_f32_16x16x32_bf16(afr2, bfr2[nt], a2[nt], 0, 0, 0);
      __builtin_amdgcn_s_setprio(0);
    }
#pragma unroll
    for (int nt = 0; nt < 6; ++nt) {
      float b2v = fc2_b[nt * 16 + lr];
#pragma unroll
      for (int r = 0; r < 4; ++r) {
        int row = m0 + wid * 16 + lg * 4 + r;
        size_t idx = (size_t)row * CD + nt * 16 + lr;
        outx[idx] = a2[nt][r] + b2v + resid[idx];
      }
    }
  }
}

extern "C" void kernel_launch(void* const* d_in, const int* in_sizes, int n_in,
                              void* d_out, int out_size, void* d_ws, size_t ws_size,
                              hipStream_t stream) {
  const float* x      = (const float*)d_in[0];
  const int*   Hp     = (const int*)d_in[1];
  const int*   Wp     = (const int*)d_in[2];
  const float* n1s    = (const float*)d_in[3];
  const float* n1b    = (const float*)d_in[4];
  const float* qkv_w  = (const float*)d_in[5];
  const float* qkv_b  = (const float*)d_in[6];
  const float* proj_w = (const float*)d_in[7];
  const float* proj_b = (const float*)d_in[8];
  const float* ln1s   = (const float*)d_in[9];
  const float* ln1b   = (const float*)d_in[10];
  const float* qkv2_w = (const float*)d_in[11];
  const float* qkv2_b = (const float*)d_in[12];
  const float* out_w  = (const float*)d_in[13];
  const float* out_b  = (const float*)d_in[14];
  const float* ln2s   = (const float*)d_in[15];
  const float* ln2b   = (const float*)d_in[16];
  const float* fc1_w  = (const float*)d_in[17];
  const float* fc1_b  = (const float*)d_in[18];
  const float* fc2_w  = (const float*)d_in[19];
  const float* fc2_b  = (const float*)d_in[20];

  float* wsf = (float*)d_ws;
  const size_t U = (size_t)4 * LROW * CD;  // 1,204,224
  float* x1   = wsf;                           // [0,U) fp32 residual (win out)
  short* hb   = (short*)(wsf + 2 * U);         // [2U,2.5U) bf16 LN1 out (dead before flash)
  short* qb   = (short*)(wsf + 4 * U + U / 2); // [4.5U,5U)
  short* kb   = qb + U;                        // [5U,5.5U)
  short* vtb  = kb + U;                        // [5.5U,6U); holds 12*49*2048 = 1,204,224 shorts (tile-blocked)
  short* wall = (short*)(wsf + 6 * U);         // contiguous bf16 weights, 165888 shorts
  short* wqkv = wall;                          // 320*96
  short* wout = wqkv + 320 * 96;               // 128*96
  short* wfc1 = wout + 128 * 96;               // 384*96
  short* wfc2 = wfc1 + 384 * 96;               // 128*384
  short* wwin = wfc2 + 128 * 384;              // 288*96
  short* wproj = wwin + 288 * 96;              // 96*96
  short* hb2  = (short*)(wsf + 6 * U + 82944); // bf16 LN-tb1 out (U shorts)
  // flash partials overlay [U,4U): pOb bf16 6 splits (3U floats); pl at [4U,4.2U)
  short* pOb  = (short*)(wsf + U);             // 6 * 12*LROW*32 shorts = 3U floats
  float* pl   = wsf + 4 * U;                   // 6 * 12*LROW floats
  // post-flash outputs live OUTSIDE the pOb overlay (qb/kb/vtb dead after flash):
  float* x2f  = (float*)qb;                    // U floats over [4.5U,5.5U)
  short* hb3  = vtb;                           // U shorts, LN2 out bf16
  float* outx = (float*)d_out;

  const int M = 4 * LROW;  // 12544

  cvt_all_kernel<<<(165888 + 255) / 256, 256, 0, stream>>>(
      qkv2_w, out_w, fc1_w, fc2_w, qkv_w, proj_w, wall, Hp, Wp, outx + U);

  ln_kernel<<<M / 8, 256, 0, stream>>>(x, n1s, n1b, hb, M);
  win_attn_kernel<<<256, 512, 0, stream>>>(hb, x, wwin, qkv_b, wproj, proj_b,
                                           ln1s, ln1b, x1, hb2);
  qkv_mfma_kernel<<<dim3(M / 128, 5), 256, 0, stream>>>(hb2, wqkv, qkv2_b, qb, kb, vtb);
  flash_mfma_kernel<<<dim3(49, 12, 6), 128, 0, stream>>>(qb, kb, vtb, pOb, pl);
  gemm_out_merge_ln_kernel<<<M / 128, 256, 0, stream>>>(pOb, pl, wout, out_b, x1,
                                                        ln2s, ln2b, x2f, hb3);
  mlp_kernel<<<M / 64, 256, 0, stream>>>(hb3, wfc1, fc1_b, wfc2, fc2_b, x2f, outx);
}